// Round 2
// baseline (1085.808 us; speedup 1.0000x reference)
//
#include <hip/hip_runtime.h>
#include <math.h>

// Problem constants (fixed by setup_inputs)
#define Bz 8
#define Tz 1024
#define Dz 512
#define FFz 2048
#define Hz 8
#define DHz 64
#define Mz (Bz * Tz)  // 8192 rows

typedef __attribute__((ext_vector_type(8))) short short8;   // 8 bf16 (4 VGPRs)
typedef __attribute__((ext_vector_type(4))) float f32x4;    // MFMA accumulator

__device__ inline unsigned short f2bf(float f) {  // RNE fp32 -> bf16
  unsigned u = __builtin_bit_cast(unsigned, f);
  return (unsigned short)((u + 0x7FFFu + ((u >> 16) & 1u)) >> 16);
}
__device__ inline float bf2f(unsigned short h) {
  unsigned u = (unsigned)h << 16;
  return __builtin_bit_cast(float, u);
}

// ---------------------------------------------------------------------------
// Fused prep: 10 weight convert+transposes (fp32 [K,N] -> bf16 [N,K]) +
// colsum zero-fill + x -> bf16.
// ---------------------------------------------------------------------------
struct WDesc { const float* src; unsigned short* dst; int K; int N; int blk0; };
struct PrepArgs { WDesc d[10]; int nwc; };

__global__ __launch_bounds__(256) void prep_kernel(PrepArgs P,
    const float* __restrict__ x, unsigned short* __restrict__ xbf,
    float* __restrict__ csz)
{
  const int bid = blockIdx.x;
  const int tid = threadIdx.x;
  if (bid < P.nwc) {  // wconv slice
    int i = 0;
    while (i < 9 && bid >= P.d[i + 1].blk0) ++i;
    const WDesc w = P.d[i];
    const int lb = bid - w.blk0;
    const int nbn = w.N / 32;
    const int bn = (lb % nbn) * 32, bk = (lb / nbn) * 32;
    __shared__ float t[32][33];
    const int tx = tid & 31, ty = tid >> 5;
#pragma unroll
    for (int r = 0; r < 32; r += 8)
      t[ty + r][tx] = w.src[(size_t)(bk + ty + r) * w.N + bn + tx];
    __syncthreads();
#pragma unroll
    for (int r = 0; r < 32; r += 8)
      w.dst[(size_t)(bn + ty + r) * w.K + bk + tx] = f2bf(t[tx][ty + r]);
  } else if (bid < P.nwc + 64) {  // zero slice (CS1+CS2 = 16384 floats)
    int idx = (bid - P.nwc) * 256 + tid;
    csz[idx] = 0.f;
  } else {  // fconv slice: 4096 blocks, 4 floats/thread
    int i = (bid - P.nwc - 64) * 256 + tid;
    float4 v = *reinterpret_cast<const float4*>(&x[(size_t)i * 4]);
    ushort4 o;
    o.x = f2bf(v.x); o.y = f2bf(v.y); o.z = f2bf(v.z); o.w = f2bf(v.w);
    *reinterpret_cast<ushort4*>(&xbf[(size_t)i * 4]) = o;
  }
}

// ---------------------------------------------------------------------------
// bf16 MFMA GEMM, 64x64 tile per wave, direct-from-global fragments.
// Epilogue modes: 0 fp32 C | 1 bf16 C | 2 bf16 C + ReLU
//   | 4 V^T layout: p1[((b*H+h)*64+d)*T + t] bf16 (N must be 512)
//   | 5 merged QKV (N=1536): cols 0-511 -> p1 bf16, 512-1023 -> p2,
//     1024-1535 -> p3 in V^T layout.
// ---------------------------------------------------------------------------
__global__ __launch_bounds__(64) void mfma_gemm_kernel(
    const unsigned short* __restrict__ A, const unsigned short* __restrict__ BT,
    void* __restrict__ p1, void* __restrict__ p2, void* __restrict__ p3,
    int K, int N, int mode)
{
  const int l = threadIdx.x;
  const int m0 = blockIdx.y * 64;
  const int n0 = blockIdx.x * 64;
  const int mr = l & 15, quad = l >> 4;

  f32x4 acc[4][4];
  const f32x4 zero = {0.f, 0.f, 0.f, 0.f};
#pragma unroll
  for (int i = 0; i < 4; ++i)
#pragma unroll
    for (int j = 0; j < 4; ++j) acc[i][j] = zero;

  const unsigned short* Ap = A + (size_t)(m0 + mr) * K + quad * 8;
  const unsigned short* Bp = BT + (size_t)(n0 + mr) * K + quad * 8;

  short8 a[4], b[4], an[4], bn[4];
#pragma unroll
  for (int i = 0; i < 4; ++i) {
    a[i] = *reinterpret_cast<const short8*>(Ap + (size_t)i * 16 * K);
    b[i] = *reinterpret_cast<const short8*>(Bp + (size_t)i * 16 * K);
  }
  for (int k0 = 0; k0 < K; k0 += 32) {
    if (k0 + 32 < K) {
#pragma unroll
      for (int i = 0; i < 4; ++i) {
        an[i] = *reinterpret_cast<const short8*>(Ap + (size_t)i * 16 * K + k0 + 32);
        bn[i] = *reinterpret_cast<const short8*>(Bp + (size_t)i * 16 * K + k0 + 32);
      }
    }
#pragma unroll
    for (int i = 0; i < 4; ++i)
#pragma unroll
      for (int j = 0; j < 4; ++j)
        acc[i][j] = __builtin_amdgcn_mfma_f32_16x16x32_bf16(a[i], b[j], acc[i][j], 0, 0, 0);
#pragma unroll
    for (int i = 0; i < 4; ++i) { a[i] = an[i]; b[i] = bn[i]; }
  }

  // C/D layout: col = lane&15, row = quad*4 + reg   [measured: m89/m91]
  int emode = mode;
  unsigned short* Cbf = (unsigned short*)p1;
  unsigned short* Vt  = (unsigned short*)p1;
  int ncol = N, coff = 0;
  if (mode == 5) {  // uniform per block: n0 is a multiple of 64
    if (n0 < 512)       { emode = 1; Cbf = (unsigned short*)p1; ncol = 512; coff = 0; }
    else if (n0 < 1024) { emode = 1; Cbf = (unsigned short*)p2; ncol = 512; coff = 512; }
    else                { emode = 4; Vt = (unsigned short*)p3; coff = 1024; }
  }
  if (emode == 4) {  // V^T: 4 consecutive tokens same feature -> ushort4
#pragma unroll
    for (int i = 0; i < 4; ++i)
#pragma unroll
      for (int j = 0; j < 4; ++j) {
        const int col = n0 - coff + j * 16 + mr;  // feature: h = col>>6, d = col&63
        const int row0 = m0 + i * 16 + quad * 4;  // token base (4 consecutive)
        const int bb = row0 >> 10, t0 = row0 & 1023;
        ushort4 pk;
        pk.x = f2bf(acc[i][j][0]); pk.y = f2bf(acc[i][j][1]);
        pk.z = f2bf(acc[i][j][2]); pk.w = f2bf(acc[i][j][3]);
        *reinterpret_cast<ushort4*>(
            &Vt[((size_t)((bb * Hz + (col >> 6)) * DHz + (col & 63))) * Tz + t0]) = pk;
      }
  } else if (emode == 0) {
    float* Cf = (float*)p1;
#pragma unroll
    for (int i = 0; i < 4; ++i)
#pragma unroll
      for (int j = 0; j < 4; ++j) {
        const int col = n0 + j * 16 + mr;
#pragma unroll
        for (int rr = 0; rr < 4; ++rr)
          Cf[(size_t)(m0 + i * 16 + quad * 4 + rr) * N + col] = acc[i][j][rr];
      }
  } else {
    const bool relu = (emode == 2);
#pragma unroll
    for (int i = 0; i < 4; ++i)
#pragma unroll
      for (int j = 0; j < 4; ++j) {
        const int col = n0 - coff + j * 16 + mr;
#pragma unroll
        for (int rr = 0; rr < 4; ++rr) {
          float v = acc[i][j][rr];
          if (relu) v = fmaxf(v, 0.f);
          Cbf[(size_t)(m0 + i * 16 + quad * 4 + rr) * ncol + col] = f2bf(v);
        }
      }
  }
}

// ---------------------------------------------------------------------------
// fp32 VALU GEMM for layer-1 Q AND K in one dispatch. Epilogue emits
// compensated bf16 hi/lo pairs: hi = bf16(v), lo = bf16(v - hi).
// ---------------------------------------------------------------------------
__global__ __launch_bounds__(256) void gemm_qk_kernel(
    const float* __restrict__ A, const float* __restrict__ vqkv,
    unsigned short* __restrict__ Qhi, unsigned short* __restrict__ Qlo,
    unsigned short* __restrict__ Khi, unsigned short* __restrict__ Klo,
    int N, int K)
{
  __shared__ float As[16][132];
  __shared__ float Bs[16][132];
  const int tid = threadIdx.x;
  const int sel = blockIdx.y >> 6;
  const int bm = (blockIdx.y & 63) * 128;
  const int bn = blockIdx.x * 128;
  const float* Bm = vqkv + (size_t)sel * Dz * Dz;
  unsigned short* Chi = sel ? Khi : Qhi;
  unsigned short* Clo = sel ? Klo : Qlo;
  const int tx = tid & 15, ty = tid >> 4;
  float acc[8][8];
#pragma unroll
  for (int i = 0; i < 8; ++i)
#pragma unroll
    for (int j = 0; j < 8; ++j) acc[i][j] = 0.f;

  for (int k0 = 0; k0 < K; k0 += 16) {
#pragma unroll
    for (int i = 0; i < 2; ++i) {
      int idx = tid + i * 256;
      int r = idx >> 2, kv = (idx & 3) << 2;
      float4 a = *reinterpret_cast<const float4*>(&A[(size_t)(bm + r) * K + k0 + kv]);
      As[kv + 0][r] = a.x; As[kv + 1][r] = a.y; As[kv + 2][r] = a.z; As[kv + 3][r] = a.w;
      int kk = idx >> 5, nv = (idx & 31) << 2;
      *reinterpret_cast<float4*>(&Bs[kk][nv]) =
          *reinterpret_cast<const float4*>(&Bm[(size_t)(k0 + kk) * N + bn + nv]);
    }
    __syncthreads();
#pragma unroll
    for (int kk = 0; kk < 16; ++kk) {
      float ar[8], br[8];
#pragma unroll
      for (int i = 0; i < 8; ++i) ar[i] = As[kk][ty * 8 + i];
#pragma unroll
      for (int j = 0; j < 4; ++j) {
        br[j]     = Bs[kk][tx * 4 + j];
        br[4 + j] = Bs[kk][64 + tx * 4 + j];
      }
#pragma unroll
      for (int i = 0; i < 8; ++i)
#pragma unroll
        for (int j = 0; j < 8; ++j) acc[i][j] += ar[i] * br[j];
    }
    __syncthreads();
  }
#pragma unroll
  for (int i = 0; i < 8; ++i) {
    size_t row = (size_t)(bm + ty * 8 + i);
    ushort4 h0, h1, l0, l1;
#pragma unroll
    for (int j = 0; j < 4; ++j) {
      float v0 = acc[i][j], v1 = acc[i][4 + j];
      unsigned short a0 = f2bf(v0); float r0 = v0 - bf2f(a0);  // exact residual
      unsigned short a1 = f2bf(v1); float r1 = v1 - bf2f(a1);
      reinterpret_cast<unsigned short*>(&h0)[j] = a0;
      reinterpret_cast<unsigned short*>(&l0)[j] = f2bf(r0);
      reinterpret_cast<unsigned short*>(&h1)[j] = a1;
      reinterpret_cast<unsigned short*>(&l1)[j] = f2bf(r1);
    }
    *reinterpret_cast<ushort4*>(&Chi[row * N + bn + tx * 4]) = h0;
    *reinterpret_cast<ushort4*>(&Chi[row * N + bn + 64 + tx * 4]) = h1;
    *reinterpret_cast<ushort4*>(&Clo[row * N + bn + tx * 4]) = l0;
    *reinterpret_cast<ushort4*>(&Clo[row * N + bn + 64 + tx * 4]) = l1;
  }
}

// ---------------------------------------------------------------------------
// Layer-1 fused attention: pass 1 computes z (bf16x3 QK^T, register-resident,
// K pipelined 2 steps ahead); pass 2 computes P, deterministic colsum and PV
// (K pipelined 1 subtile ahead, V loads hoisted ahead of P LDS reads).
// invz is broadcast from the c==0 lane so its bits match the previous
// attn_z->invzG->attn_ctx round trip exactly. All P/z/colsum arithmetic is
// bit-identical to the split-kernel version.
// ---------------------------------------------------------------------------
__global__ __launch_bounds__(256) void attn_ctx_kernel(
    const unsigned short* __restrict__ Qh, const unsigned short* __restrict__ Ql,
    const unsigned short* __restrict__ Kh, const unsigned short* __restrict__ Kl,
    const unsigned short* __restrict__ Vt,
    unsigned short* __restrict__ ctx, float* __restrict__ part)
{
  __shared__ unsigned short Pld[64][76];
  __shared__ float CSP[4][1024];  // per-wave colsum partials (single writer)
  const int tid = threadIdx.x;
  const int lane = tid & 63, wave = tid >> 6;
  const int c = lane & 15, quad = lane >> 4;
  const int qt = blockIdx.x & 15;
  const int h  = (blockIdx.x >> 4) & 7;
  const int b  = blockIdx.x >> 7;
  const size_t bT = (size_t)b * Tz;
  const int qrow = qt * 64 + wave * 16;
  const int hoff = h * DHz;

  const size_t qbase = (bT + qrow + c) * Dz + hoff + quad * 8;
  short8 q0h = *reinterpret_cast<const short8*>(Qh + qbase);
  short8 q1h = *reinterpret_cast<const short8*>(Qh + qbase + 32);
  short8 q0l = *reinterpret_cast<const short8*>(Ql + qbase);
  short8 q1l = *reinterpret_cast<const short8*>(Ql + qbase + 32);

  const unsigned short* Khb = Kh + (bT + c) * Dz + hoff + quad * 8;
  const unsigned short* Klb = Kl + (bT + c) * Dz + hoff + quad * 8;
  const size_t KST = (size_t)16 * Dz;  // elements per 16-key step

  const f32x4 zf = {0.f, 0.f, 0.f, 0.f};

  // ---------------- pass 1: z (flat 64 steps, depth-2 K prefetch) ----------
  short8 ka0, ka1, ka2, ka3, kb0, kb1, kb2, kb3, kn0, kn1, kn2, kn3;
  ka0 = *reinterpret_cast<const short8*>(Khb);
  ka1 = *reinterpret_cast<const short8*>(Khb + 32);
  ka2 = *reinterpret_cast<const short8*>(Klb);
  ka3 = *reinterpret_cast<const short8*>(Klb + 32);
  kb0 = *reinterpret_cast<const short8*>(Khb + KST);
  kb1 = *reinterpret_cast<const short8*>(Khb + KST + 32);
  kb2 = *reinterpret_cast<const short8*>(Klb + KST);
  kb3 = *reinterpret_cast<const short8*>(Klb + KST + 32);

  float z[4] = {0.f, 0.f, 0.f, 0.f};
  for (int step = 0; step < 64; ++step) {
    if (step < 62) {
      const size_t nb = (size_t)(step + 2) * KST;
      kn0 = *reinterpret_cast<const short8*>(Khb + nb);
      kn1 = *reinterpret_cast<const short8*>(Khb + nb + 32);
      kn2 = *reinterpret_cast<const short8*>(Klb + nb);
      kn3 = *reinterpret_cast<const short8*>(Klb + nb + 32);
    }
    f32x4 acc = zf;
    acc = __builtin_amdgcn_mfma_f32_16x16x32_bf16(q0h, ka0, acc, 0, 0, 0);
    acc = __builtin_amdgcn_mfma_f32_16x16x32_bf16(q1h, ka1, acc, 0, 0, 0);
    acc = __builtin_amdgcn_mfma_f32_16x16x32_bf16(q0h, ka2, acc, 0, 0, 0);
    acc = __builtin_amdgcn_mfma_f32_16x16x32_bf16(q1h, ka3, acc, 0, 0, 0);
    acc = __builtin_amdgcn_mfma_f32_16x16x32_bf16(q0l, ka0, acc, 0, 0, 0);
    acc = __builtin_amdgcn_mfma_f32_16x16x32_bf16(q1l, ka1, acc, 0, 0, 0);
#pragma unroll
    for (int rr = 0; rr < 4; ++rr) z[rr] += __expf(acc[rr] * 0.125f);
    ka0 = kb0; ka1 = kb1; ka2 = kb2; ka3 = kb3;
    kb0 = kn0; kb1 = kn1; kb2 = kn2; kb3 = kn3;
  }
#pragma unroll
  for (int w = 1; w < 16; w <<= 1) {
#pragma unroll
    for (int rr = 0; rr < 4; ++rr) z[rr] += __shfl_xor(z[rr], w);
  }
  float invz[4];
#pragma unroll
  for (int rr = 0; rr < 4; ++rr) {
    z[rr] = __shfl(z[rr], lane & 48);  // take c==0 lane's bits (match round 1)
    invz[rr] = 1.f / z[rr];
  }

  // ---------------- pass 2: P, colsum, PV ----------------
  f32x4 ot[4] = {zf, zf, zf, zf};
  ka0 = *reinterpret_cast<const short8*>(Khb);
  ka1 = *reinterpret_cast<const short8*>(Khb + 32);
  ka2 = *reinterpret_cast<const short8*>(Klb);
  ka3 = *reinterpret_cast<const short8*>(Klb + 32);

  for (int t = 0; t < 16; ++t) {
    const int k0 = t * 64;
#pragma unroll
    for (int sub = 0; sub < 4; ++sub) {
      if (sub < 3 || t < 15) {  // prefetch next subtile (crosses into tile t+1)
        const size_t nb = (size_t)(t * 4 + sub + 1) * KST;
        kn0 = *reinterpret_cast<const short8*>(Khb + nb);
        kn1 = *reinterpret_cast<const short8*>(Khb + nb + 32);
        kn2 = *reinterpret_cast<const short8*>(Klb + nb);
        kn3 = *reinterpret_cast<const short8*>(Klb + nb + 32);
      }
      f32x4 acc = zf;
      acc = __builtin_amdgcn_mfma_f32_16x16x32_bf16(q0h, ka0, acc, 0, 0, 0);
      acc = __builtin_amdgcn_mfma_f32_16x16x32_bf16(q1h, ka1, acc, 0, 0, 0);
      acc = __builtin_amdgcn_mfma_f32_16x16x32_bf16(q0h, ka2, acc, 0, 0, 0);
      acc = __builtin_amdgcn_mfma_f32_16x16x32_bf16(q1h, ka3, acc, 0, 0, 0);
      acc = __builtin_amdgcn_mfma_f32_16x16x32_bf16(q0l, ka0, acc, 0, 0, 0);
      acc = __builtin_amdgcn_mfma_f32_16x16x32_bf16(q1l, ka1, acc, 0, 0, 0);
      float p[4];
#pragma unroll
      for (int rr = 0; rr < 4; ++rr)
        p[rr] = __expf(acc[rr] * 0.125f) * invz[rr];
      float cs = p[0] + p[1] + p[2] + p[3];
      cs += __shfl_xor(cs, 16);
      cs += __shfl_xor(cs, 32);
      if (quad == 0) CSP[wave][k0 + sub * 16 + c] = cs;  // key visited once
#pragma unroll
      for (int rr = 0; rr < 4; ++rr)
        Pld[(wave << 4) + quad * 4 + rr][sub * 16 + c] = f2bf(p[rr]);
      ka0 = kn0; ka1 = kn1; ka2 = kn2; ka3 = kn3;
    }
    // V loads hoisted ahead of the P LDS reads (latency overlap)
    const size_t vbase = ((size_t)((b * Hz + h) * DHz + c)) * Tz + k0 + quad * 8;
    short8 v0a = *reinterpret_cast<const short8*>(Vt + vbase);
    short8 v0b = *reinterpret_cast<const short8*>(Vt + vbase + 32);
    short8 v1a = *reinterpret_cast<const short8*>(Vt + vbase + 16 * Tz);
    short8 v1b = *reinterpret_cast<const short8*>(Vt + vbase + 16 * Tz + 32);
    short8 v2a = *reinterpret_cast<const short8*>(Vt + vbase + 32 * Tz);
    short8 v2b = *reinterpret_cast<const short8*>(Vt + vbase + 32 * Tz + 32);
    short8 v3a = *reinterpret_cast<const short8*>(Vt + vbase + 48 * Tz);
    short8 v3b = *reinterpret_cast<const short8*>(Vt + vbase + 48 * Tz + 32);

    union { short8 v; ushort4 hh[2]; } pb0, pb1;
    pb0.hh[0] = *reinterpret_cast<const ushort4*>(&Pld[(wave << 4) + c][quad * 8]);
    pb0.hh[1] = *reinterpret_cast<const ushort4*>(&Pld[(wave << 4) + c][quad * 8 + 4]);
    pb1.hh[0] = *reinterpret_cast<const ushort4*>(&Pld[(wave << 4) + c][32 + quad * 8]);
    pb1.hh[1] = *reinterpret_cast<const ushort4*>(&Pld[(wave << 4) + c][32 + quad * 8 + 4]);

    ot[0] = __builtin_amdgcn_mfma_f32_16x16x32_bf16(v0a, pb0.v, ot[0], 0, 0, 0);
    ot[0] = __builtin_amdgcn_mfma_f32_16x16x32_bf16(v0b, pb1.v, ot[0], 0, 0, 0);
    ot[1] = __builtin_amdgcn_mfma_f32_16x16x32_bf16(v1a, pb0.v, ot[1], 0, 0, 0);
    ot[1] = __builtin_amdgcn_mfma_f32_16x16x32_bf16(v1b, pb1.v, ot[1], 0, 0, 0);
    ot[2] = __builtin_amdgcn_mfma_f32_16x16x32_bf16(v2a, pb0.v, ot[2], 0, 0, 0);
    ot[2] = __builtin_amdgcn_mfma_f32_16x16x32_bf16(v2b, pb1.v, ot[2], 0, 0, 0);
    ot[3] = __builtin_amdgcn_mfma_f32_16x16x32_bf16(v3a, pb0.v, ot[3], 0, 0, 0);
    ot[3] = __builtin_amdgcn_mfma_f32_16x16x32_bf16(v3b, pb1.v, ot[3], 0, 0, 0);
  }

  const size_t cb = (bT + qrow + c) * Dz + hoff;
#pragma unroll
  for (int ds = 0; ds < 4; ++ds) {
    ushort4 pk;
    pk.x = f2bf(ot[ds][0]); pk.y = f2bf(ot[ds][1]);
    pk.z = f2bf(ot[ds][2]); pk.w = f2bf(ot[ds][3]);
    *reinterpret_cast<ushort4*>(&ctx[cb + ds * 16 + quad * 4]) = pk;
  }
  __syncthreads();
  // fixed-order combine + non-atomic block-partial write (deterministic)
  for (int i = tid; i < 1024; i += 256) {
    float v = ((CSP[0][i] + CSP[1][i]) + CSP[2][i]) + CSP[3][i];
    part[(size_t)blockIdx.x * 1024 + i] = v * (1.f / Hz);
  }
}

// ---------------------------------------------------------------------------
// Deterministic colsum reduce: CS1[b,key] = sum over the 128 (h,qt) block
// partials in fixed ascending order. One thread per output.
// ---------------------------------------------------------------------------
__global__ __launch_bounds__(256) void colsum_reduce_kernel(
    const float* __restrict__ part, float* __restrict__ colsum)
{
  const int i = blockIdx.x * 256 + threadIdx.x;  // 0..8191
  const int b = i >> 10, k = i & 1023;
  const float* p = part + (size_t)(b * 128) * 1024 + k;
  float s = 0.f;
  for (int j = 0; j < 128; ++j) s += p[(size_t)j * 1024];
  colsum[i] = s;
}

// ---------------------------------------------------------------------------
// Layer-2 MFMA attention (masked), with k-tile range skipping. CS2 feeds only
// the continuous wl softmax -> atomics are fine here.
// ---------------------------------------------------------------------------
__global__ __launch_bounds__(256) void attn_mfma2_kernel(
    const unsigned short* __restrict__ Qh, const unsigned short* __restrict__ Kh,
    const unsigned short* __restrict__ Vt, const int* __restrict__ ids,
    const int* __restrict__ wst,
    unsigned short* __restrict__ ctx, float* __restrict__ colsum)
{
  __shared__ unsigned short Pld[64][76];
  __shared__ float csb[1024];

  const int tid = threadIdx.x;
  const int lane = tid & 63, wave = tid >> 6;
  const int c = lane & 15, quad = lane >> 4;
  const int qt = blockIdx.x & 15;
  const int h  = (blockIdx.x >> 4) & 7;
  const int b  = blockIdx.x >> 7;
  const size_t bT = (size_t)b * Tz;
  const int qrow = qt * 64 + wave * 16;
  const int hoff = h * DHz;

  for (int i = tid; i < 1024; i += 256) csb[i] = 0.f;

  const int id_lo = ids[bT + qt * 64];
  const int id_hi = ids[bT + qt * 64 + 63];
  const int klo = wst[b * (Tz + 1) + id_lo];
  const int khi = wst[b * (Tz + 1) + id_hi + 1];
  const int t0 = klo >> 6, t1 = (khi - 1) >> 6;

  const size_t qbase = (bT + qrow + c) * Dz + hoff + quad * 8;
  short8 q0 = *reinterpret_cast<const short8*>(Qh + qbase);
  short8 q1 = *reinterpret_cast<const short8*>(Qh + qbase + 32);

  int qid[4];
#pragma unroll
  for (int rr = 0; rr < 4; ++rr) qid[rr] = ids[bT + qrow + quad * 4 + rr];
  __syncthreads();  // csb zeros visible before pass-2 atomics

  const f32x4 zf = {0.f, 0.f, 0.f, 0.f};

  // pass 1: z
  float z[4] = {0.f, 0.f, 0.f, 0.f};
  for (int t = t0; t <= t1; ++t) {
    const int k0 = t * 64;
#pragma unroll
    for (int sub = 0; sub < 4; ++sub) {
      const size_t kb = (bT + k0 + sub * 16 + c) * Dz + hoff + quad * 8;
      short8 kh0 = *reinterpret_cast<const short8*>(Kh + kb);
      short8 kh1 = *reinterpret_cast<const short8*>(Kh + kb + 32);
      f32x4 acc = zf;
      acc = __builtin_amdgcn_mfma_f32_16x16x32_bf16(q0, kh0, acc, 0, 0, 0);
      acc = __builtin_amdgcn_mfma_f32_16x16x32_bf16(q1, kh1, acc, 0, 0, 0);
      int kidv = ids[bT + k0 + sub * 16 + c];
#pragma unroll
      for (int rr = 0; rr < 4; ++rr) {
        float e = __expf(acc[rr] * 0.125f);
        if (qid[rr] != kidv) e = 0.f;
        z[rr] += e;
      }
    }
  }
#pragma unroll
  for (int w = 1; w < 16; w <<= 1) {
#pragma unroll
    for (int rr = 0; rr < 4; ++rr) z[rr] += __shfl_xor(z[rr], w);
  }
  float invz[4];
#pragma unroll
  for (int rr = 0; rr < 4; ++rr) invz[rr] = 1.f / z[rr];

  // pass 2: P, colsum, PV
  f32x4 ot[4] = {zf, zf, zf, zf};
  for (int t = t0; t <= t1; ++t) {
    const int k0 = t * 64;
#pragma unroll
    for (int sub = 0; sub < 4; ++sub) {
      const size_t kb = (bT + k0 + sub * 16 + c) * Dz + hoff + quad * 8;
      short8 kh0 = *reinterpret_cast<const short8*>(Kh + kb);
      short8 kh1 = *reinterpret_cast<const short8*>(Kh + kb + 32);
      f32x4 acc = zf;
      acc = __builtin_amdgcn_mfma_f32_16x16x32_bf16(q0, kh0, acc, 0, 0, 0);
      acc = __builtin_amdgcn_mfma_f32_16x16x32_bf16(q1, kh1, acc, 0, 0, 0);
      int kidv = ids[bT + k0 + sub * 16 + c];
      float p[4];
#pragma unroll
      for (int rr = 0; rr < 4; ++rr) {
        float e = __expf(acc[rr] * 0.125f);
        if (qid[rr] != kidv) e = 0.f;
        p[rr] = e * invz[rr];
      }
      float cs = p[0] + p[1] + p[2] + p[3];
      cs += __shfl_xor(cs, 16);
      cs += __shfl_xor(cs, 32);
      if (quad == 0) atomicAdd(&csb[k0 + sub * 16 + c], cs);
#pragma unroll
      for (int rr = 0; rr < 4; ++rr)
        Pld[(wave << 4) + quad * 4 + rr][sub * 16 + c] = f2bf(p[rr]);
    }
    union { short8 v; ushort4 hh[2]; } pb0, pb1;
    pb0.hh[0] = *reinterpret_cast<const ushort4*>(&Pld[(wave << 4) + c][quad * 8]);
    pb0.hh[1] = *reinterpret_cast<const ushort4*>(&Pld[(wave << 4) + c][quad * 8 + 4]);
    pb1.hh[0] = *reinterpret_cast<const ushort4*>(&Pld[(wave << 4) + c][32 + quad * 8]);
    pb1.hh[1] = *reinterpret_cast<const ushort4*>(&Pld[(wave << 4) + c][32 + quad * 8 + 4]);
#pragma unroll
    for (int ds = 0; ds < 4; ++ds) {
      const size_t va = ((size_t)((b * Hz + h) * DHz + ds * 16 + c)) * Tz + k0 + quad * 8;
      short8 v0 = *reinterpret_cast<const short8*>(Vt + va);
      short8 v1 = *reinterpret_cast<const short8*>(Vt + va + 32);
      ot[ds] = __builtin_amdgcn_mfma_f32_16x16x32_bf16(v0, pb0.v, ot[ds], 0, 0, 0);
      ot[ds] = __builtin_amdgcn_mfma_f32_16x16x32_bf16(v1, pb1.v, ot[ds], 0, 0, 0);
    }
  }

  const size_t cb = (bT + qrow + c) * Dz + hoff;
#pragma unroll
  for (int ds = 0; ds < 4; ++ds) {
    ushort4 pk;
    pk.x = f2bf(ot[ds][0]); pk.y = f2bf(ot[ds][1]);
    pk.z = f2bf(ot[ds][2]); pk.w = f2bf(ot[ds][3]);
    *reinterpret_cast<ushort4*>(&ctx[cb + ds * 16 + quad * 4]) = pk;
  }
  __syncthreads();
  for (int i = tid; i < 1024; i += 256)
    atomicAdd(&colsum[bT + i], csb[i] * (1.f / Hz));
}

// ---------------------------------------------------------------------------
// out = LayerNorm(resid + delta). resid fp32 (residf) if non-null else bf16.
// ---------------------------------------------------------------------------
__global__ __launch_bounds__(256) void ln_kernel(const float* __restrict__ residf,
    const unsigned short* __restrict__ residbf, const float* __restrict__ delta,
    float* __restrict__ outf, unsigned short* __restrict__ outbf)
{
  const size_t base = (size_t)blockIdx.x * Dz;
  const int tid = threadIdx.x;
  float r0, r1;
  if (residf) {
    r0 = residf[base + tid]; r1 = residf[base + tid + 256];
  } else {
    r0 = bf2f(residbf[base + tid]); r1 = bf2f(residbf[base + tid + 256]);
  }
  float x0 = r0 + delta[base + tid];
  float x1 = r1 + delta[base + tid + 256];
  __shared__ float red[4];
  float s = x0 + x1;
#pragma unroll
  for (int off = 32; off; off >>= 1) s += __shfl_down(s, off);
  if ((tid & 63) == 0) red[tid >> 6] = s;
  __syncthreads();
  const float mean = (red[0] + red[1] + red[2] + red[3]) * (1.f / Dz);
  __syncthreads();
  float d0 = x0 - mean, d1 = x1 - mean;
  float v = d0 * d0 + d1 * d1;
#pragma unroll
  for (int off = 32; off; off >>= 1) v += __shfl_down(v, off);
  if ((tid & 63) == 0) red[tid >> 6] = v;
  __syncthreads();
  const float var = (red[0] + red[1] + red[2] + red[3]) * (1.f / Dz);
  const float rstd = rsqrtf(var + 1e-5f);
  float y0 = d0 * rstd, y1 = d1 * rstd;
  if (outf) {
    outf[base + tid] = y0;
    outf[base + tid + 256] = y1;
  }
  outbf[base + tid] = f2bf(y0);
  outbf[base + tid + 256] = f2bf(y1);
}

// ---------------------------------------------------------------------------
// Per batch: min-max normalize colsum, threshold 0.5, run-length window scan.
// All reductions shfl/fixed-order -> deterministic.
// ---------------------------------------------------------------------------
__global__ __launch_bounds__(256) void window_ids_kernel(const float* __restrict__ cs,
    int* __restrict__ ids, int* __restrict__ wst, int* __restrict__ nwin)
{
  const int b = blockIdx.x, tid = threadIdx.x;
  __shared__ float vals[Tz];
  __shared__ unsigned char wb[Tz];
  __shared__ int sids[Tz];
  __shared__ float rmin[4], rmax[4];
  float mn = INFINITY, mx = -INFINITY;
  for (int t = tid; t < Tz; t += 256) {
    float v = cs[b * Tz + t];
    vals[t] = v;
    mn = fminf(mn, v); mx = fmaxf(mx, v);
  }
#pragma unroll
  for (int off = 32; off; off >>= 1) {
    mn = fminf(mn, __shfl_down(mn, off));
    mx = fmaxf(mx, __shfl_down(mx, off));
  }
  if ((tid & 63) == 0) { rmin[tid >> 6] = mn; rmax[tid >> 6] = mx; }
  __syncthreads();
  mn = fminf(fminf(rmin[0], rmin[1]), fminf(rmin[2], rmin[3]));
  mx = fmaxf(fmaxf(rmax[0], rmax[1]), fmaxf(rmax[2], rmax[3]));
  const float inv = 1.f / (mx - mn + 1e-8f);
  for (int t = tid; t < Tz; t += 256) wb[t] = (((vals[t] - mn) * inv) >= 0.5f) ? 1 : 0;
  __syncthreads();
  if (tid == 0) {
    int cur = wb[0], start = 0, wid = 0;
    sids[0] = 0;
    wst[b * (Tz + 1)] = 0;
    for (int t = 1; t < Tz; ++t) {
      int wt = wb[t];
      if (wt != cur) {
        cur = wt;
        if (start + 1 != t) {
          start = t;
          ++wid;
          wst[b * (Tz + 1) + wid] = t;
        }
      }
      sids[t] = wid;
    }
    nwin[b] = wid + 1;
    wst[b * (Tz + 1) + wid + 1] = Tz;
  }
  __syncthreads();
  for (int t = tid; t < Tz; t += 256) ids[b * Tz + t] = sids[t];
}

// ---------------------------------------------------------------------------
// wl[b,:] = softmax over keys of layer-2 colsum.
// ---------------------------------------------------------------------------
__global__ __launch_bounds__(256) void wl_softmax_kernel(const float* __restrict__ cs,
                                                         float* __restrict__ wl)
{
  const int b = blockIdx.x, tid = threadIdx.x;
  __shared__ float vals[Tz];
  __shared__ float red[4];
  float mx = -INFINITY;
  for (int t = tid; t < Tz; t += 256) {
    float v = cs[b * Tz + t];
    vals[t] = v;
    mx = fmaxf(mx, v);
  }
#pragma unroll
  for (int off = 32; off; off >>= 1) mx = fmaxf(mx, __shfl_down(mx, off));
  if ((tid & 63) == 0) red[tid >> 6] = mx;
  __syncthreads();
  mx = fmaxf(fmaxf(red[0], red[1]), fmaxf(red[2], red[3]));
  __syncthreads();
  float se = 0.f;
  for (int t = tid; t < Tz; t += 256) {
    float e = expf(vals[t] - mx);
    vals[t] = e;
    se += e;
  }
#pragma unroll
  for (int off = 32; off; off >>= 1) se += __shfl_down(se, off);
  if ((tid & 63) == 0) red[tid >> 6] = se;
  __syncthreads();
  const float inv = 1.f / (red[0] + red[1] + red[2] + red[3]);
  for (int t = tid; t < Tz; t += 256) wl[b * Tz + t] = vals[t] * inv;
}

// ---------------------------------------------------------------------------
// Fused outputs: word_tokens (blocks 0..8191), winmap (8192..16383),
// copy_x (16384..20479).
// ---------------------------------------------------------------------------
__global__ __launch_bounds__(256) void outputs_kernel(
    const unsigned short* __restrict__ outl, const float* __restrict__ wl,
    const int* __restrict__ wst, const int* __restrict__ nwin,
    const int* __restrict__ ids, const float* __restrict__ x,
    float* __restrict__ out, float* __restrict__ out2)
{
  const int bid = blockIdx.x;
  const int tid = threadIdx.x;
  if (bid < 8192) {  // word_tokens
    const int w = bid & (Tz - 1);
    const int b = bid >> 10;
    float a0 = 0.f, a1 = 0.f;
    if (w < nwin[b]) {
      const int s = wst[b * (Tz + 1) + w], e = wst[b * (Tz + 1) + w + 1];
      for (int t = s; t < e; ++t) {
        const float sc = wl[b * Tz + t];
        const unsigned short* p = &outl[((size_t)(b * Tz + t)) * Dz];
        a0 += bf2f(p[tid]) * sc;
        a1 += bf2f(p[tid + 256]) * sc;
      }
    }
    float* o = &out[((size_t)(b * 2 * Tz + w)) * Dz];
    o[tid] = a0;
    o[tid + 256] = a1;
  } else if (bid < 16384) {  // winmap
    const int lb = bid - 8192;
    const int w = lb & (Tz - 1);
    const int b = lb >> 10;
    const int j = tid * 4;
    int4 id4 = *reinterpret_cast<const int4*>(&ids[b * Tz + j]);
    float4 v;
    v.x = (id4.x == w) ? 1.f : 0.f;
    v.y = (id4.y == w) ? 1.f : 0.f;
    v.z = (id4.z == w) ? 1.f : 0.f;
    v.w = (id4.w == w) ? 1.f : 0.f;
    *reinterpret_cast<float4*>(&out2[((size_t)(b * Tz + w)) * Tz + j]) = v;
  } else {  // copy_x
    size_t i = (size_t)(bid - 16384) * 256 + tid;
    size_t idx = i * 4;
    size_t rowi = idx >> 9;
    size_t d = idx & 511;
    size_t b = rowi >> 10, t = rowi & 1023;
    float4 v = *reinterpret_cast<const float4*>(&x[idx]);
    *reinterpret_cast<float4*>(&out[(((b * 2 * Tz) + Tz + t) << 9) + d]) = v;
  }
}

// ---------------------------------------------------------------------------
// Orchestration: 21 dispatches. attn_z fused into attn_ctx (z pass 1 in
// registers, software-pipelined K loads).
// ---------------------------------------------------------------------------
extern "C" void kernel_launch(void* const* d_in, const int* in_sizes, int n_in,
                              void* d_out, int out_size, void* d_ws, size_t ws_size,
                              hipStream_t stream)
{
  (void)in_sizes; (void)n_in; (void)out_size; (void)ws_size;
  const float* x     = (const float*)d_in[0];
  const float* vqkv  = (const float*)d_in[1];
  const float* voutw = (const float*)d_in[2];
  const float* vw1   = (const float*)d_in[3];
  const float* vw2   = (const float*)d_in[4];
  const float* lqkv  = (const float*)d_in[5];
  const float* loutw = (const float*)d_in[6];
  const float* lw1   = (const float*)d_in[7];
  const float* lw2   = (const float*)d_in[8];
  float* out = (float*)d_out;
  float* ws  = (float*)d_ws;

  unsigned short* QLbf = (unsigned short*)(ws + 0);        // bf16 Q lo (L1)
  unsigned short* KLbf = (unsigned short*)(ws + 2097152);  // bf16 K lo (L1)
  float* PROJ = ws + 0;         // written after attn_ctx (QL/KL dead)
  float* Y1   = ws + 4194304;
  unsigned short* QHbf = (unsigned short*)(ws + 8388608);   // bf16 Q hi (L1+L2)
  unsigned short* KHbf = (unsigned short*)(ws + 10485760);  // bf16 K hi (L1+L2)
  unsigned short* VT   = (unsigned short*)(ws + 12582912);
  unsigned short* SLOT1 = (unsigned short*)(ws + 14680064); // attn ctx bf16
  unsigned short* SLOT2 = (unsigned short*)(ws + 16777216); // LN bf16 out
  unsigned short* HIDbf = (unsigned short*)(ws + 18874368); // FFN hidden
  unsigned short* XBF   = (unsigned short*)(ws + 18874368); // alias (pre-FFN)
  float* PART = ws + 18874368;  // colsum block partials (1024x1024), alias:
                                // written after XBF is dead, dead before FFN1
  // bf16 transposed weights (WLQ0..2 contiguous -> merged [1536,512] matrix)
  unsigned short* WVQV = (unsigned short*)(ws + 27262976);
  unsigned short* WVO  = (unsigned short*)(ws + 27394048);
  unsigned short* WV1  = (unsigned short*)(ws + 27525120);
  unsigned short* WV2  = (unsigned short*)(ws + 28049408);
  unsigned short* WLQ0 = (unsigned short*)(ws + 28573696);
  unsigned short* WLQ1 = (unsigned short*)(ws + 28704768);
  unsigned short* WLQ2 = (unsigned short*)(ws + 28835840);
  unsigned short* WLO  = (unsigned short*)(ws + 28966912);
  unsigned short* WL1  = (unsigned short*)(ws + 29097984);
  unsigned short* WL2  = (unsigned short*)(ws + 29622272);
  // small buffers
  float* CS1   = ws + 30146560;
  float* CS2   = ws + 30154752;
  float* WLs   = ws + 30162944;
  int*   IDS   = (int*)(ws + 30171136);
  int*   WST   = (int*)(ws + 30179328);
  int*   NWIN  = (int*)(ws + 30187776);

  dim3 blk(256);

  // ---- fused prep: 10 wconv + zero + fconv ----
  PrepArgs P;
  auto setw = [&](int i, const float* s, unsigned short* d, int K, int N, int b0) {
    P.d[i].src = s; P.d[i].dst = d; P.d[i].K = K; P.d[i].N = N; P.d[i].blk0 = b0;
  };
  int b0 = 0;
  setw(0, vqkv + 2 * Dz * Dz, WVQV, Dz, Dz, b0); b0 += 256;
  setw(1, voutw, WVO, Dz, Dz, b0); b0 += 256;
  setw(2, vw1, WV1, Dz, FFz, b0); b0 += 1024;
  setw(3, vw2, WV2, FFz, Dz, b0); b0 += 1024;
  setw(4, lqkv + 0 * Dz * Dz, WLQ0, Dz, Dz, b0); b0 += 256;
  setw(5, lqkv + 1 * Dz * Dz, WLQ1, Dz, Dz, b0); b0 += 256;
  setw(6, lqkv + 2 * Dz * Dz, WLQ2, Dz, Dz, b0); b0 += 256;
  setw(7, loutw, WLO, Dz, Dz, b0); b0 += 256;
  setw(8, lw1, WL1, Dz, FFz, b0); b0 += 1024;
  setw(9, lw2, WL2, FFz, Dz, b0); b0 += 1024;
  P.nwc = b0;  // 5632
  prep_kernel<<<dim3(P.nwc + 64 + 4096), blk, 0, stream>>>(P, x, XBF, CS1);

  auto mgemm = [&](const unsigned short* A, const unsigned short* BT, void* p1,
                   void* p2, void* p3, int K, int N, int mode) {
    mfma_gemm_kernel<<<dim3(N / 64, Mz / 64), dim3(64), 0, stream>>>(
        A, BT, p1, p2, p3, K, N, mode);
  };

  // ---------------- layer 1 (vanilla) ----------------
  gemm_qk_kernel<<<dim3(4, 128), blk, 0, stream>>>(x, vqkv, QHbf, QLbf, KHbf, KLbf, Dz, Dz);
  mgemm(XBF, WVQV, VT, nullptr, nullptr, Dz, Dz, 4);        // V -> V^T (XBF dead after)
  attn_ctx_kernel<<<dim3(Bz * Hz * 16), blk, 0, stream>>>(
      QHbf, QLbf, KHbf, KLbf, VT, SLOT1, PART);
  colsum_reduce_kernel<<<dim3(32), blk, 0, stream>>>(PART, CS1);
  window_ids_kernel<<<dim3(Bz), blk, 0, stream>>>(CS1, IDS, WST, NWIN);
  mgemm(SLOT1, WVO, PROJ, nullptr, nullptr, Dz, Dz, 0);     // proj (QL/KL dead)
  ln_kernel<<<dim3(Mz), blk, 0, stream>>>(x, nullptr, PROJ, Y1, SLOT2);
  mgemm(SLOT2, WV1, HIDbf, nullptr, nullptr, Dz, FFz, 2);   // FFN1 + ReLU (PART dead)
  mgemm(HIDbf, WV2, PROJ, nullptr, nullptr, FFz, Dz, 0);    // FFN2
  ln_kernel<<<dim3(Mz), blk, 0, stream>>>(Y1, nullptr, PROJ, nullptr, SLOT2);

  // ---------------- layer 2 (block-diagonal window mask) ----------------
  mgemm(SLOT2, WLQ0, QHbf, KHbf, VT, Dz, 3 * Dz, 5);        // merged QKV
  attn_mfma2_kernel<<<dim3(Bz * Hz * 16), blk, 0, stream>>>(
      QHbf, KHbf, VT, IDS, WST, SLOT1, CS2);
  mgemm(SLOT1, WLO, PROJ, nullptr, nullptr, Dz, Dz, 0);
  ln_kernel<<<dim3(Mz), blk, 0, stream>>>(nullptr, SLOT2, PROJ, Y1, SLOT2);
  mgemm(SLOT2, WL1, HIDbf, nullptr, nullptr, Dz, FFz, 2);
  mgemm(HIDbf, WL2, PROJ, nullptr, nullptr, FFz, Dz, 0);
  ln_kernel<<<dim3(Mz), blk, 0, stream>>>(Y1, nullptr, PROJ, nullptr, SLOT2);

  // ---------------- pooling + outputs ----------------
  wl_softmax_kernel<<<dim3(Bz), blk, 0, stream>>>(CS2, WLs);
  outputs_kernel<<<dim3(20480), blk, 0, stream>>>(SLOT2, WLs, WST, NWIN, IDS, x,
                                                  out, out + (size_t)Bz * 2 * Tz * Dz);
}

// Round 3
// 966.877 us; speedup vs baseline: 1.1230x; 1.1230x over previous
//
#include <hip/hip_runtime.h>
#include <math.h>

// Problem constants (fixed by setup_inputs)
#define Bz 8
#define Tz 1024
#define Dz 512
#define FFz 2048
#define Hz 8
#define DHz 64
#define Mz (Bz * Tz)  // 8192 rows

typedef __attribute__((ext_vector_type(8))) short short8;   // 8 bf16 (4 VGPRs)
typedef __attribute__((ext_vector_type(4))) float f32x4;    // MFMA accumulator

__device__ inline unsigned short f2bf(float f) {  // RNE fp32 -> bf16
  unsigned u = __builtin_bit_cast(unsigned, f);
  return (unsigned short)((u + 0x7FFFu + ((u >> 16) & 1u)) >> 16);
}
__device__ inline float bf2f(unsigned short h) {
  unsigned u = (unsigned)h << 16;
  return __builtin_bit_cast(float, u);
}

// ---------------------------------------------------------------------------
// Fused prep: 10 weight convert+transposes (fp32 [K,N] -> bf16 [N,K]) +
// colsum zero-fill + x -> bf16.
// ---------------------------------------------------------------------------
struct WDesc { const float* src; unsigned short* dst; int K; int N; int blk0; };
struct PrepArgs { WDesc d[10]; int nwc; };

__global__ __launch_bounds__(256) void prep_kernel(PrepArgs P,
    const float* __restrict__ x, unsigned short* __restrict__ xbf,
    float* __restrict__ csz)
{
  const int bid = blockIdx.x;
  const int tid = threadIdx.x;
  if (bid < P.nwc) {  // wconv slice
    int i = 0;
    while (i < 9 && bid >= P.d[i + 1].blk0) ++i;
    const WDesc w = P.d[i];
    const int lb = bid - w.blk0;
    const int nbn = w.N / 32;
    const int bn = (lb % nbn) * 32, bk = (lb / nbn) * 32;
    __shared__ float t[32][33];
    const int tx = tid & 31, ty = tid >> 5;
#pragma unroll
    for (int r = 0; r < 32; r += 8)
      t[ty + r][tx] = w.src[(size_t)(bk + ty + r) * w.N + bn + tx];
    __syncthreads();
#pragma unroll
    for (int r = 0; r < 32; r += 8)
      w.dst[(size_t)(bn + ty + r) * w.K + bk + tx] = f2bf(t[tx][ty + r]);
  } else if (bid < P.nwc + 64) {  // zero slice (CS1+CS2 = 16384 floats)
    int idx = (bid - P.nwc) * 256 + tid;
    csz[idx] = 0.f;
  } else {  // fconv slice: 4096 blocks, 4 floats/thread
    int i = (bid - P.nwc - 64) * 256 + tid;
    float4 v = *reinterpret_cast<const float4*>(&x[(size_t)i * 4]);
    ushort4 o;
    o.x = f2bf(v.x); o.y = f2bf(v.y); o.z = f2bf(v.z); o.w = f2bf(v.w);
    *reinterpret_cast<ushort4*>(&xbf[(size_t)i * 4]) = o;
  }
}

// ---------------------------------------------------------------------------
// bf16 MFMA GEMM, 64x64 tile per wave, direct-from-global fragments.
// Epilogue modes: 0 fp32 C | 1 bf16 C | 2 bf16 C + ReLU
//   | 4 V^T layout: p1[((b*H+h)*64+d)*T + t] bf16 (N must be 512)
//   | 5 merged QKV (N=1536): cols 0-511 -> p1 bf16, 512-1023 -> p2,
//     1024-1535 -> p3 in V^T layout.
// ---------------------------------------------------------------------------
__global__ __launch_bounds__(64) void mfma_gemm_kernel(
    const unsigned short* __restrict__ A, const unsigned short* __restrict__ BT,
    void* __restrict__ p1, void* __restrict__ p2, void* __restrict__ p3,
    int K, int N, int mode)
{
  const int l = threadIdx.x;
  const int m0 = blockIdx.y * 64;
  const int n0 = blockIdx.x * 64;
  const int mr = l & 15, quad = l >> 4;

  f32x4 acc[4][4];
  const f32x4 zero = {0.f, 0.f, 0.f, 0.f};
#pragma unroll
  for (int i = 0; i < 4; ++i)
#pragma unroll
    for (int j = 0; j < 4; ++j) acc[i][j] = zero;

  const unsigned short* Ap = A + (size_t)(m0 + mr) * K + quad * 8;
  const unsigned short* Bp = BT + (size_t)(n0 + mr) * K + quad * 8;

  short8 a[4], b[4], an[4], bn[4];
#pragma unroll
  for (int i = 0; i < 4; ++i) {
    a[i] = *reinterpret_cast<const short8*>(Ap + (size_t)i * 16 * K);
    b[i] = *reinterpret_cast<const short8*>(Bp + (size_t)i * 16 * K);
  }
  for (int k0 = 0; k0 < K; k0 += 32) {
    if (k0 + 32 < K) {
#pragma unroll
      for (int i = 0; i < 4; ++i) {
        an[i] = *reinterpret_cast<const short8*>(Ap + (size_t)i * 16 * K + k0 + 32);
        bn[i] = *reinterpret_cast<const short8*>(Bp + (size_t)i * 16 * K + k0 + 32);
      }
    }
#pragma unroll
    for (int i = 0; i < 4; ++i)
#pragma unroll
      for (int j = 0; j < 4; ++j)
        acc[i][j] = __builtin_amdgcn_mfma_f32_16x16x32_bf16(a[i], b[j], acc[i][j], 0, 0, 0);
#pragma unroll
    for (int i = 0; i < 4; ++i) { a[i] = an[i]; b[i] = bn[i]; }
  }

  // C/D layout: col = lane&15, row = quad*4 + reg   [measured: m89/m91]
  int emode = mode;
  unsigned short* Cbf = (unsigned short*)p1;
  unsigned short* Vt  = (unsigned short*)p1;
  int ncol = N, coff = 0;
  if (mode == 5) {  // uniform per block: n0 is a multiple of 64
    if (n0 < 512)       { emode = 1; Cbf = (unsigned short*)p1; ncol = 512; coff = 0; }
    else if (n0 < 1024) { emode = 1; Cbf = (unsigned short*)p2; ncol = 512; coff = 512; }
    else                { emode = 4; Vt = (unsigned short*)p3; coff = 1024; }
  }
  if (emode == 4) {  // V^T: 4 consecutive tokens same feature -> ushort4
#pragma unroll
    for (int i = 0; i < 4; ++i)
#pragma unroll
      for (int j = 0; j < 4; ++j) {
        const int col = n0 - coff + j * 16 + mr;  // feature: h = col>>6, d = col&63
        const int row0 = m0 + i * 16 + quad * 4;  // token base (4 consecutive)
        const int bb = row0 >> 10, t0 = row0 & 1023;
        ushort4 pk;
        pk.x = f2bf(acc[i][j][0]); pk.y = f2bf(acc[i][j][1]);
        pk.z = f2bf(acc[i][j][2]); pk.w = f2bf(acc[i][j][3]);
        *reinterpret_cast<ushort4*>(
            &Vt[((size_t)((bb * Hz + (col >> 6)) * DHz + (col & 63))) * Tz + t0]) = pk;
      }
  } else if (emode == 0) {
    float* Cf = (float*)p1;
#pragma unroll
    for (int i = 0; i < 4; ++i)
#pragma unroll
      for (int j = 0; j < 4; ++j) {
        const int col = n0 + j * 16 + mr;
#pragma unroll
        for (int rr = 0; rr < 4; ++rr)
          Cf[(size_t)(m0 + i * 16 + quad * 4 + rr) * N + col] = acc[i][j][rr];
      }
  } else {
    const bool relu = (emode == 2);
#pragma unroll
    for (int i = 0; i < 4; ++i)
#pragma unroll
      for (int j = 0; j < 4; ++j) {
        const int col = n0 - coff + j * 16 + mr;
#pragma unroll
        for (int rr = 0; rr < 4; ++rr) {
          float v = acc[i][j][rr];
          if (relu) v = fmaxf(v, 0.f);
          Cbf[(size_t)(m0 + i * 16 + quad * 4 + rr) * ncol + col] = f2bf(v);
        }
      }
  }
}

// ---------------------------------------------------------------------------
// fp32 VALU GEMM for layer-1 Q AND K in one dispatch. Epilogue emits
// compensated bf16 hi/lo pairs: hi = bf16(v), lo = bf16(v - hi).
// ---------------------------------------------------------------------------
__global__ __launch_bounds__(256) void gemm_qk_kernel(
    const float* __restrict__ A, const float* __restrict__ vqkv,
    unsigned short* __restrict__ Qhi, unsigned short* __restrict__ Qlo,
    unsigned short* __restrict__ Khi, unsigned short* __restrict__ Klo,
    int N, int K)
{
  __shared__ float As[16][132];
  __shared__ float Bs[16][132];
  const int tid = threadIdx.x;
  const int sel = blockIdx.y >> 6;
  const int bm = (blockIdx.y & 63) * 128;
  const int bn = blockIdx.x * 128;
  const float* Bm = vqkv + (size_t)sel * Dz * Dz;
  unsigned short* Chi = sel ? Khi : Qhi;
  unsigned short* Clo = sel ? Klo : Qlo;
  const int tx = tid & 15, ty = tid >> 4;
  float acc[8][8];
#pragma unroll
  for (int i = 0; i < 8; ++i)
#pragma unroll
    for (int j = 0; j < 8; ++j) acc[i][j] = 0.f;

  for (int k0 = 0; k0 < K; k0 += 16) {
#pragma unroll
    for (int i = 0; i < 2; ++i) {
      int idx = tid + i * 256;
      int r = idx >> 2, kv = (idx & 3) << 2;
      float4 a = *reinterpret_cast<const float4*>(&A[(size_t)(bm + r) * K + k0 + kv]);
      As[kv + 0][r] = a.x; As[kv + 1][r] = a.y; As[kv + 2][r] = a.z; As[kv + 3][r] = a.w;
      int kk = idx >> 5, nv = (idx & 31) << 2;
      *reinterpret_cast<float4*>(&Bs[kk][nv]) =
          *reinterpret_cast<const float4*>(&Bm[(size_t)(k0 + kk) * N + bn + nv]);
    }
    __syncthreads();
#pragma unroll
    for (int kk = 0; kk < 16; ++kk) {
      float ar[8], br[8];
#pragma unroll
      for (int i = 0; i < 8; ++i) ar[i] = As[kk][ty * 8 + i];
#pragma unroll
      for (int j = 0; j < 4; ++j) {
        br[j]     = Bs[kk][tx * 4 + j];
        br[4 + j] = Bs[kk][64 + tx * 4 + j];
      }
#pragma unroll
      for (int i = 0; i < 8; ++i)
#pragma unroll
        for (int j = 0; j < 8; ++j) acc[i][j] += ar[i] * br[j];
    }
    __syncthreads();
  }
#pragma unroll
  for (int i = 0; i < 8; ++i) {
    size_t row = (size_t)(bm + ty * 8 + i);
    ushort4 h0, h1, l0, l1;
#pragma unroll
    for (int j = 0; j < 4; ++j) {
      float v0 = acc[i][j], v1 = acc[i][4 + j];
      unsigned short a0 = f2bf(v0); float r0 = v0 - bf2f(a0);  // exact residual
      unsigned short a1 = f2bf(v1); float r1 = v1 - bf2f(a1);
      reinterpret_cast<unsigned short*>(&h0)[j] = a0;
      reinterpret_cast<unsigned short*>(&l0)[j] = f2bf(r0);
      reinterpret_cast<unsigned short*>(&h1)[j] = a1;
      reinterpret_cast<unsigned short*>(&l1)[j] = f2bf(r1);
    }
    *reinterpret_cast<ushort4*>(&Chi[row * N + bn + tx * 4]) = h0;
    *reinterpret_cast<ushort4*>(&Chi[row * N + bn + 64 + tx * 4]) = h1;
    *reinterpret_cast<ushort4*>(&Clo[row * N + bn + tx * 4]) = l0;
    *reinterpret_cast<ushort4*>(&Clo[row * N + bn + 64 + tx * 4]) = l1;
  }
}

// ---------------------------------------------------------------------------
// Layer-1 z pass, CHEAP: plain-bf16 QK^T (2 independent MFMAs). z feeds only
// invz; error analysis: S abs err ~4.5e-3 -> per-e rel err ~5.6e-4 -> z rel
// err ~1.8e-5 after 1024-term averaging -> colsum shift ~1e-6 (below the
// ~1e-5 already tolerated by the mask threshold). 1/3 the MFMA work and
// half the K traffic of the bf16x3 version.
// ---------------------------------------------------------------------------
__global__ __launch_bounds__(256) void attn_z_kernel(
    const unsigned short* __restrict__ Qh, const unsigned short* __restrict__ Kh,
    float* __restrict__ invzG)
{
  const int tid = threadIdx.x;
  const int lane = tid & 63, wave = tid >> 6;
  const int c = lane & 15, quad = lane >> 4;
  const int qt = blockIdx.x & 15;
  const int h  = (blockIdx.x >> 4) & 7;
  const int b  = blockIdx.x >> 7;
  const size_t bT = (size_t)b * Tz;
  const int qrow = qt * 64 + wave * 16;
  const int hoff = h * DHz;

  const size_t qbase = (bT + qrow + c) * Dz + hoff + quad * 8;
  short8 q0 = *reinterpret_cast<const short8*>(Qh + qbase);
  short8 q1 = *reinterpret_cast<const short8*>(Qh + qbase + 32);

  const f32x4 zf = {0.f, 0.f, 0.f, 0.f};
  float z[4] = {0.f, 0.f, 0.f, 0.f};

  for (int t = 0; t < 16; ++t) {
    const int k0 = t * 64;
#pragma unroll
    for (int sub = 0; sub < 4; ++sub) {
      const size_t kb = (bT + k0 + sub * 16 + c) * Dz + hoff + quad * 8;
      short8 kh0 = *reinterpret_cast<const short8*>(Kh + kb);
      short8 kh1 = *reinterpret_cast<const short8*>(Kh + kb + 32);
      f32x4 aA = zf, aB = zf;
      aA = __builtin_amdgcn_mfma_f32_16x16x32_bf16(q0, kh0, aA, 0, 0, 0);
      aB = __builtin_amdgcn_mfma_f32_16x16x32_bf16(q1, kh1, aB, 0, 0, 0);
#pragma unroll
      for (int rr = 0; rr < 4; ++rr) z[rr] += __expf((aA[rr] + aB[rr]) * 0.125f);
    }
  }
#pragma unroll
  for (int w = 1; w < 16; w <<= 1) {
#pragma unroll
    for (int rr = 0; rr < 4; ++rr) z[rr] += __shfl_xor(z[rr], w);
  }
  if (c == 0) {
#pragma unroll
    for (int rr = 0; rr < 4; ++rr)
      invzG[(size_t)(b * Hz + h) * Tz + qrow + quad * 4 + rr] = 1.f / z[rr];
  }
}

// ---------------------------------------------------------------------------
// Layer-1 ctx via MFMA with FUSED deterministic colsum (round-1 structure).
// QK^T is bf16x3 (mask-grade precision) with a 2-accumulator ILP split
// (two independent 3-MFMA chains instead of one 6-chain). P stored bf16
// for PV. Colsum: per-wave single-writer CSP rows, fixed-order combine.
// ---------------------------------------------------------------------------
__global__ __launch_bounds__(256) void attn_ctx_kernel(
    const unsigned short* __restrict__ Qh, const unsigned short* __restrict__ Ql,
    const unsigned short* __restrict__ Kh, const unsigned short* __restrict__ Kl,
    const unsigned short* __restrict__ Vt, const float* __restrict__ invzG,
    unsigned short* __restrict__ ctx, float* __restrict__ part)
{
  __shared__ unsigned short Pld[64][76];
  __shared__ float CSP[4][1024];  // per-wave colsum partials (single writer)
  const int tid = threadIdx.x;
  const int lane = tid & 63, wave = tid >> 6;
  const int c = lane & 15, quad = lane >> 4;
  const int qt = blockIdx.x & 15;
  const int h  = (blockIdx.x >> 4) & 7;
  const int b  = blockIdx.x >> 7;
  const size_t bT = (size_t)b * Tz;
  const int qrow = qt * 64 + wave * 16;
  const int hoff = h * DHz;

  const size_t qbase = (bT + qrow + c) * Dz + hoff + quad * 8;
  short8 q0h = *reinterpret_cast<const short8*>(Qh + qbase);
  short8 q1h = *reinterpret_cast<const short8*>(Qh + qbase + 32);
  short8 q0l = *reinterpret_cast<const short8*>(Ql + qbase);
  short8 q1l = *reinterpret_cast<const short8*>(Ql + qbase + 32);

  float invz[4];
#pragma unroll
  for (int rr = 0; rr < 4; ++rr)
    invz[rr] = invzG[(size_t)(b * Hz + h) * Tz + qrow + quad * 4 + rr];

  const f32x4 zf = {0.f, 0.f, 0.f, 0.f};
  f32x4 ot[4] = {zf, zf, zf, zf};

  for (int t = 0; t < 16; ++t) {
    const int k0 = t * 64;
#pragma unroll
    for (int sub = 0; sub < 4; ++sub) {
      const size_t kb = (bT + k0 + sub * 16 + c) * Dz + hoff + quad * 8;
      short8 kh0 = *reinterpret_cast<const short8*>(Kh + kb);
      short8 kh1 = *reinterpret_cast<const short8*>(Kh + kb + 32);
      short8 kl0 = *reinterpret_cast<const short8*>(Kl + kb);
      short8 kl1 = *reinterpret_cast<const short8*>(Kl + kb + 32);
      f32x4 aA = zf, aB = zf;  // two independent chains (depth 3 each)
      aA = __builtin_amdgcn_mfma_f32_16x16x32_bf16(q0h, kh0, aA, 0, 0, 0);
      aB = __builtin_amdgcn_mfma_f32_16x16x32_bf16(q1h, kh1, aB, 0, 0, 0);
      aA = __builtin_amdgcn_mfma_f32_16x16x32_bf16(q0h, kl0, aA, 0, 0, 0);
      aB = __builtin_amdgcn_mfma_f32_16x16x32_bf16(q1h, kl1, aB, 0, 0, 0);
      aA = __builtin_amdgcn_mfma_f32_16x16x32_bf16(q0l, kh0, aA, 0, 0, 0);
      aB = __builtin_amdgcn_mfma_f32_16x16x32_bf16(q1l, kh1, aB, 0, 0, 0);
      float p[4];
#pragma unroll
      for (int rr = 0; rr < 4; ++rr)
        p[rr] = __expf((aA[rr] + aB[rr]) * 0.125f) * invz[rr];
      float cs = p[0] + p[1] + p[2] + p[3];
      cs += __shfl_xor(cs, 16);
      cs += __shfl_xor(cs, 32);
      if (quad == 0) CSP[wave][k0 + sub * 16 + c] = cs;  // key visited once
#pragma unroll
      for (int rr = 0; rr < 4; ++rr)
        Pld[(wave << 4) + quad * 4 + rr][sub * 16 + c] = f2bf(p[rr]);
    }
    union { short8 v; ushort4 hh[2]; } pb0, pb1;
    pb0.hh[0] = *reinterpret_cast<const ushort4*>(&Pld[(wave << 4) + c][quad * 8]);
    pb0.hh[1] = *reinterpret_cast<const ushort4*>(&Pld[(wave << 4) + c][quad * 8 + 4]);
    pb1.hh[0] = *reinterpret_cast<const ushort4*>(&Pld[(wave << 4) + c][32 + quad * 8]);
    pb1.hh[1] = *reinterpret_cast<const ushort4*>(&Pld[(wave << 4) + c][32 + quad * 8 + 4]);
#pragma unroll
    for (int ds = 0; ds < 4; ++ds) {
      const size_t va = ((size_t)((b * Hz + h) * DHz + ds * 16 + c)) * Tz + k0 + quad * 8;
      short8 v0 = *reinterpret_cast<const short8*>(Vt + va);
      short8 v1 = *reinterpret_cast<const short8*>(Vt + va + 32);
      ot[ds] = __builtin_amdgcn_mfma_f32_16x16x32_bf16(v0, pb0.v, ot[ds], 0, 0, 0);
      ot[ds] = __builtin_amdgcn_mfma_f32_16x16x32_bf16(v1, pb1.v, ot[ds], 0, 0, 0);
    }
  }

  const size_t cb = (bT + qrow + c) * Dz + hoff;
#pragma unroll
  for (int ds = 0; ds < 4; ++ds) {
    ushort4 pk;
    pk.x = f2bf(ot[ds][0]); pk.y = f2bf(ot[ds][1]);
    pk.z = f2bf(ot[ds][2]); pk.w = f2bf(ot[ds][3]);
    *reinterpret_cast<ushort4*>(&ctx[cb + ds * 16 + quad * 4]) = pk;
  }
  __syncthreads();
  // fixed-order combine + non-atomic block-partial write (deterministic)
  for (int i = tid; i < 1024; i += 256) {
    float v = ((CSP[0][i] + CSP[1][i]) + CSP[2][i]) + CSP[3][i];
    part[(size_t)blockIdx.x * 1024 + i] = v * (1.f / Hz);
  }
}

// ---------------------------------------------------------------------------
// Deterministic colsum reduce: CS1[b,key] = sum over the 128 (h,qt) block
// partials in fixed ascending order. One thread per output.
// ---------------------------------------------------------------------------
__global__ __launch_bounds__(256) void colsum_reduce_kernel(
    const float* __restrict__ part, float* __restrict__ colsum)
{
  const int i = blockIdx.x * 256 + threadIdx.x;  // 0..8191
  const int b = i >> 10, k = i & 1023;
  const float* p = part + (size_t)(b * 128) * 1024 + k;
  float s = 0.f;
  for (int j = 0; j < 128; ++j) s += p[(size_t)j * 1024];
  colsum[i] = s;
}

// ---------------------------------------------------------------------------
// Layer-2 MFMA attention (masked), with k-tile range skipping. CS2 feeds only
// the continuous wl softmax -> atomics are fine here.
// ---------------------------------------------------------------------------
__global__ __launch_bounds__(256) void attn_mfma2_kernel(
    const unsigned short* __restrict__ Qh, const unsigned short* __restrict__ Kh,
    const unsigned short* __restrict__ Vt, const int* __restrict__ ids,
    const int* __restrict__ wst,
    unsigned short* __restrict__ ctx, float* __restrict__ colsum)
{
  __shared__ unsigned short Pld[64][76];
  __shared__ float csb[1024];

  const int tid = threadIdx.x;
  const int lane = tid & 63, wave = tid >> 6;
  const int c = lane & 15, quad = lane >> 4;
  const int qt = blockIdx.x & 15;
  const int h  = (blockIdx.x >> 4) & 7;
  const int b  = blockIdx.x >> 7;
  const size_t bT = (size_t)b * Tz;
  const int qrow = qt * 64 + wave * 16;
  const int hoff = h * DHz;

  for (int i = tid; i < 1024; i += 256) csb[i] = 0.f;

  const int id_lo = ids[bT + qt * 64];
  const int id_hi = ids[bT + qt * 64 + 63];
  const int klo = wst[b * (Tz + 1) + id_lo];
  const int khi = wst[b * (Tz + 1) + id_hi + 1];
  const int t0 = klo >> 6, t1 = (khi - 1) >> 6;

  const size_t qbase = (bT + qrow + c) * Dz + hoff + quad * 8;
  short8 q0 = *reinterpret_cast<const short8*>(Qh + qbase);
  short8 q1 = *reinterpret_cast<const short8*>(Qh + qbase + 32);

  int qid[4];
#pragma unroll
  for (int rr = 0; rr < 4; ++rr) qid[rr] = ids[bT + qrow + quad * 4 + rr];
  __syncthreads();  // csb zeros visible before pass-2 atomics

  const f32x4 zf = {0.f, 0.f, 0.f, 0.f};

  // pass 1: z
  float z[4] = {0.f, 0.f, 0.f, 0.f};
  for (int t = t0; t <= t1; ++t) {
    const int k0 = t * 64;
#pragma unroll
    for (int sub = 0; sub < 4; ++sub) {
      const size_t kb = (bT + k0 + sub * 16 + c) * Dz + hoff + quad * 8;
      short8 kh0 = *reinterpret_cast<const short8*>(Kh + kb);
      short8 kh1 = *reinterpret_cast<const short8*>(Kh + kb + 32);
      f32x4 acc = zf;
      acc = __builtin_amdgcn_mfma_f32_16x16x32_bf16(q0, kh0, acc, 0, 0, 0);
      acc = __builtin_amdgcn_mfma_f32_16x16x32_bf16(q1, kh1, acc, 0, 0, 0);
      int kidv = ids[bT + k0 + sub * 16 + c];
#pragma unroll
      for (int rr = 0; rr < 4; ++rr) {
        float e = __expf(acc[rr] * 0.125f);
        if (qid[rr] != kidv) e = 0.f;
        z[rr] += e;
      }
    }
  }
#pragma unroll
  for (int w = 1; w < 16; w <<= 1) {
#pragma unroll
    for (int rr = 0; rr < 4; ++rr) z[rr] += __shfl_xor(z[rr], w);
  }
  float invz[4];
#pragma unroll
  for (int rr = 0; rr < 4; ++rr) invz[rr] = 1.f / z[rr];

  // pass 2: P, colsum, PV
  f32x4 ot[4] = {zf, zf, zf, zf};
  for (int t = t0; t <= t1; ++t) {
    const int k0 = t * 64;
#pragma unroll
    for (int sub = 0; sub < 4; ++sub) {
      const size_t kb = (bT + k0 + sub * 16 + c) * Dz + hoff + quad * 8;
      short8 kh0 = *reinterpret_cast<const short8*>(Kh + kb);
      short8 kh1 = *reinterpret_cast<const short8*>(Kh + kb + 32);
      f32x4 acc = zf;
      acc = __builtin_amdgcn_mfma_f32_16x16x32_bf16(q0, kh0, acc, 0, 0, 0);
      acc = __builtin_amdgcn_mfma_f32_16x16x32_bf16(q1, kh1, acc, 0, 0, 0);
      int kidv = ids[bT + k0 + sub * 16 + c];
      float p[4];
#pragma unroll
      for (int rr = 0; rr < 4; ++rr) {
        float e = __expf(acc[rr] * 0.125f);
        if (qid[rr] != kidv) e = 0.f;
        p[rr] = e * invz[rr];
      }
      float cs = p[0] + p[1] + p[2] + p[3];
      cs += __shfl_xor(cs, 16);
      cs += __shfl_xor(cs, 32);
      if (quad == 0) atomicAdd(&csb[k0 + sub * 16 + c], cs);
#pragma unroll
      for (int rr = 0; rr < 4; ++rr)
        Pld[(wave << 4) + quad * 4 + rr][sub * 16 + c] = f2bf(p[rr]);
    }
    union { short8 v; ushort4 hh[2]; } pb0, pb1;
    pb0.hh[0] = *reinterpret_cast<const ushort4*>(&Pld[(wave << 4) + c][quad * 8]);
    pb0.hh[1] = *reinterpret_cast<const ushort4*>(&Pld[(wave << 4) + c][quad * 8 + 4]);
    pb1.hh[0] = *reinterpret_cast<const ushort4*>(&Pld[(wave << 4) + c][32 + quad * 8]);
    pb1.hh[1] = *reinterpret_cast<const ushort4*>(&Pld[(wave << 4) + c][32 + quad * 8 + 4]);
#pragma unroll
    for (int ds = 0; ds < 4; ++ds) {
      const size_t va = ((size_t)((b * Hz + h) * DHz + ds * 16 + c)) * Tz + k0 + quad * 8;
      short8 v0 = *reinterpret_cast<const short8*>(Vt + va);
      short8 v1 = *reinterpret_cast<const short8*>(Vt + va + 32);
      ot[ds] = __builtin_amdgcn_mfma_f32_16x16x32_bf16(v0, pb0.v, ot[ds], 0, 0, 0);
      ot[ds] = __builtin_amdgcn_mfma_f32_16x16x32_bf16(v1, pb1.v, ot[ds], 0, 0, 0);
    }
  }

  const size_t cb = (bT + qrow + c) * Dz + hoff;
#pragma unroll
  for (int ds = 0; ds < 4; ++ds) {
    ushort4 pk;
    pk.x = f2bf(ot[ds][0]); pk.y = f2bf(ot[ds][1]);
    pk.z = f2bf(ot[ds][2]); pk.w = f2bf(ot[ds][3]);
    *reinterpret_cast<ushort4*>(&ctx[cb + ds * 16 + quad * 4]) = pk;
  }
  __syncthreads();
  for (int i = tid; i < 1024; i += 256)
    atomicAdd(&colsum[bT + i], csb[i] * (1.f / Hz));
}

// ---------------------------------------------------------------------------
// out = LayerNorm(resid + delta). resid fp32 (residf) if non-null else bf16.
// ---------------------------------------------------------------------------
__global__ __launch_bounds__(256) void ln_kernel(const float* __restrict__ residf,
    const unsigned short* __restrict__ residbf, const float* __restrict__ delta,
    float* __restrict__ outf, unsigned short* __restrict__ outbf)
{
  const size_t base = (size_t)blockIdx.x * Dz;
  const int tid = threadIdx.x;
  float r0, r1;
  if (residf) {
    r0 = residf[base + tid]; r1 = residf[base + tid + 256];
  } else {
    r0 = bf2f(residbf[base + tid]); r1 = bf2f(residbf[base + tid + 256]);
  }
  float x0 = r0 + delta[base + tid];
  float x1 = r1 + delta[base + tid + 256];
  __shared__ float red[4];
  float s = x0 + x1;
#pragma unroll
  for (int off = 32; off; off >>= 1) s += __shfl_down(s, off);
  if ((tid & 63) == 0) red[tid >> 6] = s;
  __syncthreads();
  const float mean = (red[0] + red[1] + red[2] + red[3]) * (1.f / Dz);
  __syncthreads();
  float d0 = x0 - mean, d1 = x1 - mean;
  float v = d0 * d0 + d1 * d1;
#pragma unroll
  for (int off = 32; off; off >>= 1) v += __shfl_down(v, off);
  if ((tid & 63) == 0) red[tid >> 6] = v;
  __syncthreads();
  const float var = (red[0] + red[1] + red[2] + red[3]) * (1.f / Dz);
  const float rstd = rsqrtf(var + 1e-5f);
  float y0 = d0 * rstd, y1 = d1 * rstd;
  if (outf) {
    outf[base + tid] = y0;
    outf[base + tid + 256] = y1;
  }
  outbf[base + tid] = f2bf(y0);
  outbf[base + tid + 256] = f2bf(y1);
}

// ---------------------------------------------------------------------------
// Per batch: min-max normalize colsum, threshold 0.5, run-length window scan.
// All reductions shfl/fixed-order -> deterministic.
// ---------------------------------------------------------------------------
__global__ __launch_bounds__(256) void window_ids_kernel(const float* __restrict__ cs,
    int* __restrict__ ids, int* __restrict__ wst, int* __restrict__ nwin)
{
  const int b = blockIdx.x, tid = threadIdx.x;
  __shared__ float vals[Tz];
  __shared__ unsigned char wb[Tz];
  __shared__ int sids[Tz];
  __shared__ float rmin[4], rmax[4];
  float mn = INFINITY, mx = -INFINITY;
  for (int t = tid; t < Tz; t += 256) {
    float v = cs[b * Tz + t];
    vals[t] = v;
    mn = fminf(mn, v); mx = fmaxf(mx, v);
  }
#pragma unroll
  for (int off = 32; off; off >>= 1) {
    mn = fminf(mn, __shfl_down(mn, off));
    mx = fmaxf(mx, __shfl_down(mx, off));
  }
  if ((tid & 63) == 0) { rmin[tid >> 6] = mn; rmax[tid >> 6] = mx; }
  __syncthreads();
  mn = fminf(fminf(rmin[0], rmin[1]), fminf(rmin[2], rmin[3]));
  mx = fmaxf(fmaxf(rmax[0], rmax[1]), fmaxf(rmax[2], rmax[3]));
  const float inv = 1.f / (mx - mn + 1e-8f);
  for (int t = tid; t < Tz; t += 256) wb[t] = (((vals[t] - mn) * inv) >= 0.5f) ? 1 : 0;
  __syncthreads();
  if (tid == 0) {
    int cur = wb[0], start = 0, wid = 0;
    sids[0] = 0;
    wst[b * (Tz + 1)] = 0;
    for (int t = 1; t < Tz; ++t) {
      int wt = wb[t];
      if (wt != cur) {
        cur = wt;
        if (start + 1 != t) {
          start = t;
          ++wid;
          wst[b * (Tz + 1) + wid] = t;
        }
      }
      sids[t] = wid;
    }
    nwin[b] = wid + 1;
    wst[b * (Tz + 1) + wid + 1] = Tz;
  }
  __syncthreads();
  for (int t = tid; t < Tz; t += 256) ids[b * Tz + t] = sids[t];
}

// ---------------------------------------------------------------------------
// wl[b,:] = softmax over keys of layer-2 colsum.
// ---------------------------------------------------------------------------
__global__ __launch_bounds__(256) void wl_softmax_kernel(const float* __restrict__ cs,
                                                         float* __restrict__ wl)
{
  const int b = blockIdx.x, tid = threadIdx.x;
  __shared__ float vals[Tz];
  __shared__ float red[4];
  float mx = -INFINITY;
  for (int t = tid; t < Tz; t += 256) {
    float v = cs[b * Tz + t];
    vals[t] = v;
    mx = fmaxf(mx, v);
  }
#pragma unroll
  for (int off = 32; off; off >>= 1) mx = fmaxf(mx, __shfl_down(mx, off));
  if ((tid & 63) == 0) red[tid >> 6] = mx;
  __syncthreads();
  mx = fmaxf(fmaxf(red[0], red[1]), fmaxf(red[2], red[3]));
  __syncthreads();
  float se = 0.f;
  for (int t = tid; t < Tz; t += 256) {
    float e = expf(vals[t] - mx);
    vals[t] = e;
    se += e;
  }
#pragma unroll
  for (int off = 32; off; off >>= 1) se += __shfl_down(se, off);
  if ((tid & 63) == 0) red[tid >> 6] = se;
  __syncthreads();
  const float inv = 1.f / (red[0] + red[1] + red[2] + red[3]);
  for (int t = tid; t < Tz; t += 256) wl[b * Tz + t] = vals[t] * inv;
}

// ---------------------------------------------------------------------------
// Fused outputs: word_tokens (blocks 0..8191), winmap (8192..16383),
// copy_x (16384..20479).
// ---------------------------------------------------------------------------
__global__ __launch_bounds__(256) void outputs_kernel(
    const unsigned short* __restrict__ outl, const float* __restrict__ wl,
    const int* __restrict__ wst, const int* __restrict__ nwin,
    const int* __restrict__ ids, const float* __restrict__ x,
    float* __restrict__ out, float* __restrict__ out2)
{
  const int bid = blockIdx.x;
  const int tid = threadIdx.x;
  if (bid < 8192) {  // word_tokens
    const int w = bid & (Tz - 1);
    const int b = bid >> 10;
    float a0 = 0.f, a1 = 0.f;
    if (w < nwin[b]) {
      const int s = wst[b * (Tz + 1) + w], e = wst[b * (Tz + 1) + w + 1];
      for (int t = s; t < e; ++t) {
        const float sc = wl[b * Tz + t];
        const unsigned short* p = &outl[((size_t)(b * Tz + t)) * Dz];
        a0 += bf2f(p[tid]) * sc;
        a1 += bf2f(p[tid + 256]) * sc;
      }
    }
    float* o = &out[((size_t)(b * 2 * Tz + w)) * Dz];
    o[tid] = a0;
    o[tid + 256] = a1;
  } else if (bid < 16384) {  // winmap
    const int lb = bid - 8192;
    const int w = lb & (Tz - 1);
    const int b = lb >> 10;
    const int j = tid * 4;
    int4 id4 = *reinterpret_cast<const int4*>(&ids[b * Tz + j]);
    float4 v;
    v.x = (id4.x == w) ? 1.f : 0.f;
    v.y = (id4.y == w) ? 1.f : 0.f;
    v.z = (id4.z == w) ? 1.f : 0.f;
    v.w = (id4.w == w) ? 1.f : 0.f;
    *reinterpret_cast<float4*>(&out2[((size_t)(b * Tz + w)) * Tz + j]) = v;
  } else {  // copy_x
    size_t i = (size_t)(bid - 16384) * 256 + tid;
    size_t idx = i * 4;
    size_t rowi = idx >> 9;
    size_t d = idx & 511;
    size_t b = rowi >> 10, t = rowi & 1023;
    float4 v = *reinterpret_cast<const float4*>(&x[idx]);
    *reinterpret_cast<float4*>(&out[(((b * 2 * Tz) + Tz + t) << 9) + d]) = v;
  }
}

// ---------------------------------------------------------------------------
// Orchestration: 22 dispatches. Round-1 split structure restored; attn_z is
// cheap plain-bf16; attn_ctx has the 2-acc ILP split.
// ---------------------------------------------------------------------------
extern "C" void kernel_launch(void* const* d_in, const int* in_sizes, int n_in,
                              void* d_out, int out_size, void* d_ws, size_t ws_size,
                              hipStream_t stream)
{
  (void)in_sizes; (void)n_in; (void)out_size; (void)ws_size;
  const float* x     = (const float*)d_in[0];
  const float* vqkv  = (const float*)d_in[1];
  const float* voutw = (const float*)d_in[2];
  const float* vw1   = (const float*)d_in[3];
  const float* vw2   = (const float*)d_in[4];
  const float* lqkv  = (const float*)d_in[5];
  const float* loutw = (const float*)d_in[6];
  const float* lw1   = (const float*)d_in[7];
  const float* lw2   = (const float*)d_in[8];
  float* out = (float*)d_out;
  float* ws  = (float*)d_ws;

  unsigned short* QLbf = (unsigned short*)(ws + 0);        // bf16 Q lo (L1)
  unsigned short* KLbf = (unsigned short*)(ws + 2097152);  // bf16 K lo (L1)
  float* PROJ = ws + 0;         // written after attn_ctx (QL/KL dead)
  float* Y1   = ws + 4194304;
  unsigned short* QHbf = (unsigned short*)(ws + 8388608);   // bf16 Q hi (L1+L2)
  unsigned short* KHbf = (unsigned short*)(ws + 10485760);  // bf16 K hi (L1+L2)
  unsigned short* VT   = (unsigned short*)(ws + 12582912);
  unsigned short* SLOT1 = (unsigned short*)(ws + 14680064); // attn ctx bf16
  unsigned short* SLOT2 = (unsigned short*)(ws + 16777216); // LN bf16 out
  unsigned short* HIDbf = (unsigned short*)(ws + 18874368); // FFN hidden
  unsigned short* XBF   = (unsigned short*)(ws + 18874368); // alias (pre-FFN)
  float* PART = ws + 18874368;  // colsum block partials (1024x1024), alias:
                                // written after XBF is dead, dead before FFN1
  // bf16 transposed weights (WLQ0..2 contiguous -> merged [1536,512] matrix)
  unsigned short* WVQV = (unsigned short*)(ws + 27262976);
  unsigned short* WVO  = (unsigned short*)(ws + 27394048);
  unsigned short* WV1  = (unsigned short*)(ws + 27525120);
  unsigned short* WV2  = (unsigned short*)(ws + 28049408);
  unsigned short* WLQ0 = (unsigned short*)(ws + 28573696);
  unsigned short* WLQ1 = (unsigned short*)(ws + 28704768);
  unsigned short* WLQ2 = (unsigned short*)(ws + 28835840);
  unsigned short* WLO  = (unsigned short*)(ws + 28966912);
  unsigned short* WL1  = (unsigned short*)(ws + 29097984);
  unsigned short* WL2  = (unsigned short*)(ws + 29622272);
  // small buffers
  float* CS1   = ws + 30146560;
  float* CS2   = ws + 30154752;
  float* WLs   = ws + 30162944;
  int*   IDS   = (int*)(ws + 30171136);
  int*   WST   = (int*)(ws + 30179328);
  int*   NWIN  = (int*)(ws + 30187776);
  float* INVZ  = ws + 30195968;  // (B*H*T) = 65536 floats

  dim3 blk(256);

  // ---- fused prep: 10 wconv + zero + fconv ----
  PrepArgs P;
  auto setw = [&](int i, const float* s, unsigned short* d, int K, int N, int b0) {
    P.d[i].src = s; P.d[i].dst = d; P.d[i].K = K; P.d[i].N = N; P.d[i].blk0 = b0;
  };
  int b0 = 0;
  setw(0, vqkv + 2 * Dz * Dz, WVQV, Dz, Dz, b0); b0 += 256;
  setw(1, voutw, WVO, Dz, Dz, b0); b0 += 256;
  setw(2, vw1, WV1, Dz, FFz, b0); b0 += 1024;
  setw(3, vw2, WV2, FFz, Dz, b0); b0 += 1024;
  setw(4, lqkv + 0 * Dz * Dz, WLQ0, Dz, Dz, b0); b0 += 256;
  setw(5, lqkv + 1 * Dz * Dz, WLQ1, Dz, Dz, b0); b0 += 256;
  setw(6, lqkv + 2 * Dz * Dz, WLQ2, Dz, Dz, b0); b0 += 256;
  setw(7, loutw, WLO, Dz, Dz, b0); b0 += 256;
  setw(8, lw1, WL1, Dz, FFz, b0); b0 += 1024;
  setw(9, lw2, WL2, FFz, Dz, b0); b0 += 1024;
  P.nwc = b0;  // 5632
  prep_kernel<<<dim3(P.nwc + 64 + 4096), blk, 0, stream>>>(P, x, XBF, CS1);

  auto mgemm = [&](const unsigned short* A, const unsigned short* BT, void* p1,
                   void* p2, void* p3, int K, int N, int mode) {
    mfma_gemm_kernel<<<dim3(N / 64, Mz / 64), dim3(64), 0, stream>>>(
        A, BT, p1, p2, p3, K, N, mode);
  };

  // ---------------- layer 1 (vanilla) ----------------
  gemm_qk_kernel<<<dim3(4, 128), blk, 0, stream>>>(x, vqkv, QHbf, QLbf, KHbf, KLbf, Dz, Dz);
  attn_z_kernel<<<dim3(Bz * Hz * 16), blk, 0, stream>>>(QHbf, KHbf, INVZ);  // K L2-warm
  mgemm(XBF, WVQV, VT, nullptr, nullptr, Dz, Dz, 4);        // V -> V^T (XBF dead after)
  attn_ctx_kernel<<<dim3(Bz * Hz * 16), blk, 0, stream>>>(
      QHbf, QLbf, KHbf, KLbf, VT, INVZ, SLOT1, PART);
  colsum_reduce_kernel<<<dim3(32), blk, 0, stream>>>(PART, CS1);
  window_ids_kernel<<<dim3(Bz), blk, 0, stream>>>(CS1, IDS, WST, NWIN);
  mgemm(SLOT1, WVO, PROJ, nullptr, nullptr, Dz, Dz, 0);     // proj (QL/KL dead)
  ln_kernel<<<dim3(Mz), blk, 0, stream>>>(x, nullptr, PROJ, Y1, SLOT2);
  mgemm(SLOT2, WV1, HIDbf, nullptr, nullptr, Dz, FFz, 2);   // FFN1 + ReLU (PART dead)
  mgemm(HIDbf, WV2, PROJ, nullptr, nullptr, FFz, Dz, 0);    // FFN2
  ln_kernel<<<dim3(Mz), blk, 0, stream>>>(Y1, nullptr, PROJ, nullptr, SLOT2);

  // ---------------- layer 2 (block-diagonal window mask) ----------------
  mgemm(SLOT2, WLQ0, QHbf, KHbf, VT, Dz, 3 * Dz, 5);        // merged QKV
  attn_mfma2_kernel<<<dim3(Bz * Hz * 16), blk, 0, stream>>>(
      QHbf, KHbf, VT, IDS, WST, SLOT1, CS2);
  mgemm(SLOT1, WLO, PROJ, nullptr, nullptr, Dz, Dz, 0);
  ln_kernel<<<dim3(Mz), blk, 0, stream>>>(nullptr, SLOT2, PROJ, Y1, SLOT2);
  mgemm(SLOT2, WL1, HIDbf, nullptr, nullptr, Dz, FFz, 2);
  mgemm(HIDbf, WL2, PROJ, nullptr, nullptr, FFz, Dz, 0);
  ln_kernel<<<dim3(Mz), blk, 0, stream>>>(Y1, nullptr, PROJ, nullptr, SLOT2);

  // ---------------- pooling + outputs ----------------
  wl_softmax_kernel<<<dim3(Bz), blk, 0, stream>>>(CS2, WLs);
  outputs_kernel<<<dim3(20480), blk, 0, stream>>>(SLOT2, WLs, WST, NWIN, IDS, x,
                                                  out, out + (size_t)Bz * 2 * Tz * Dz);
}

// Round 4
// 963.438 us; speedup vs baseline: 1.1270x; 1.0036x over previous
//
#include <hip/hip_runtime.h>
#include <math.h>

// Problem constants (fixed by setup_inputs)
#define Bz 8
#define Tz 1024
#define Dz 512
#define FFz 2048
#define Hz 8
#define DHz 64
#define Mz (Bz * Tz)  // 8192 rows

typedef __attribute__((ext_vector_type(8))) short short8;   // 8 bf16 (4 VGPRs)
typedef __attribute__((ext_vector_type(4))) float f32x4;    // MFMA accumulator

__device__ inline unsigned short f2bf(float f) {  // RNE fp32 -> bf16
  unsigned u = __builtin_bit_cast(unsigned, f);
  return (unsigned short)((u + 0x7FFFu + ((u >> 16) & 1u)) >> 16);
}
__device__ inline float bf2f(unsigned short h) {
  unsigned u = (unsigned)h << 16;
  return __builtin_bit_cast(float, u);
}

// XCD-aware decode for the 1024-block attention grids (8 XCDs round-robin by
// blockIdx). g = xcd + 8*(qt + 16*bhi), bh = bhi*8 + xcd: all 16 qt-blocks of
// one (b,h) land on one XCD -> its K/V slice stays L2-resident. Bijective.
__device__ inline void attn_decode(int g, int& b, int& h, int& qt) {
  const int xcd = g & 7;
  const int j = g >> 3;
  qt = j & 15;
  const int bh = ((j >> 4) << 3) | xcd;
  b = bh >> 3;
  h = bh & 7;
}

// ---------------------------------------------------------------------------
// Fused prep: 10 weight convert+transposes (fp32 [K,N] -> bf16 [N,K]) +
// colsum zero-fill + x -> bf16.
// ---------------------------------------------------------------------------
struct WDesc { const float* src; unsigned short* dst; int K; int N; int blk0; };
struct PrepArgs { WDesc d[10]; int nwc; };

__global__ __launch_bounds__(256) void prep_kernel(PrepArgs P,
    const float* __restrict__ x, unsigned short* __restrict__ xbf,
    float* __restrict__ csz)
{
  const int bid = blockIdx.x;
  const int tid = threadIdx.x;
  if (bid < P.nwc) {  // wconv slice
    int i = 0;
    while (i < 9 && bid >= P.d[i + 1].blk0) ++i;
    const WDesc w = P.d[i];
    const int lb = bid - w.blk0;
    const int nbn = w.N / 32;
    const int bn = (lb % nbn) * 32, bk = (lb / nbn) * 32;
    __shared__ float t[32][33];
    const int tx = tid & 31, ty = tid >> 5;
#pragma unroll
    for (int r = 0; r < 32; r += 8)
      t[ty + r][tx] = w.src[(size_t)(bk + ty + r) * w.N + bn + tx];
    __syncthreads();
#pragma unroll
    for (int r = 0; r < 32; r += 8)
      w.dst[(size_t)(bn + ty + r) * w.K + bk + tx] = f2bf(t[tx][ty + r]);
  } else if (bid < P.nwc + 64) {  // zero slice (CS1+CS2 = 16384 floats)
    int idx = (bid - P.nwc) * 256 + tid;
    csz[idx] = 0.f;
  } else {  // fconv slice: 4096 blocks, 4 floats/thread
    int i = (bid - P.nwc - 64) * 256 + tid;
    float4 v = *reinterpret_cast<const float4*>(&x[(size_t)i * 4]);
    ushort4 o;
    o.x = f2bf(v.x); o.y = f2bf(v.y); o.z = f2bf(v.z); o.w = f2bf(v.w);
    *reinterpret_cast<ushort4*>(&xbf[(size_t)i * 4]) = o;
  }
}

// ---------------------------------------------------------------------------
// bf16 MFMA GEMM, 64x64 tile per wave, direct-from-global fragments.
// Epilogue modes: 0 fp32 C | 1 bf16 C | 2 bf16 C + ReLU
//   | 4 V^T layout: p1[((b*H+h)*64+d)*T + t] bf16 (N must be 512)
//   | 5 merged QKV (N=1536): cols 0-511 -> p1 bf16, 512-1023 -> p2,
//     1024-1535 -> p3 in V^T layout.
// ---------------------------------------------------------------------------
__global__ __launch_bounds__(64) void mfma_gemm_kernel(
    const unsigned short* __restrict__ A, const unsigned short* __restrict__ BT,
    void* __restrict__ p1, void* __restrict__ p2, void* __restrict__ p3,
    int K, int N, int mode)
{
  const int l = threadIdx.x;
  const int m0 = blockIdx.y * 64;
  const int n0 = blockIdx.x * 64;
  const int mr = l & 15, quad = l >> 4;

  f32x4 acc[4][4];
  const f32x4 zero = {0.f, 0.f, 0.f, 0.f};
#pragma unroll
  for (int i = 0; i < 4; ++i)
#pragma unroll
    for (int j = 0; j < 4; ++j) acc[i][j] = zero;

  const unsigned short* Ap = A + (size_t)(m0 + mr) * K + quad * 8;
  const unsigned short* Bp = BT + (size_t)(n0 + mr) * K + quad * 8;

  short8 a[4], b[4], an[4], bn[4];
#pragma unroll
  for (int i = 0; i < 4; ++i) {
    a[i] = *reinterpret_cast<const short8*>(Ap + (size_t)i * 16 * K);
    b[i] = *reinterpret_cast<const short8*>(Bp + (size_t)i * 16 * K);
  }
  for (int k0 = 0; k0 < K; k0 += 32) {
    if (k0 + 32 < K) {
#pragma unroll
      for (int i = 0; i < 4; ++i) {
        an[i] = *reinterpret_cast<const short8*>(Ap + (size_t)i * 16 * K + k0 + 32);
        bn[i] = *reinterpret_cast<const short8*>(Bp + (size_t)i * 16 * K + k0 + 32);
      }
    }
#pragma unroll
    for (int i = 0; i < 4; ++i)
#pragma unroll
      for (int j = 0; j < 4; ++j)
        acc[i][j] = __builtin_amdgcn_mfma_f32_16x16x32_bf16(a[i], b[j], acc[i][j], 0, 0, 0);
#pragma unroll
    for (int i = 0; i < 4; ++i) { a[i] = an[i]; b[i] = bn[i]; }
  }

  // C/D layout: col = lane&15, row = quad*4 + reg   [measured: m89/m91]
  int emode = mode;
  unsigned short* Cbf = (unsigned short*)p1;
  unsigned short* Vt  = (unsigned short*)p1;
  int ncol = N, coff = 0;
  if (mode == 5) {  // uniform per block: n0 is a multiple of 64
    if (n0 < 512)       { emode = 1; Cbf = (unsigned short*)p1; ncol = 512; coff = 0; }
    else if (n0 < 1024) { emode = 1; Cbf = (unsigned short*)p2; ncol = 512; coff = 512; }
    else                { emode = 4; Vt = (unsigned short*)p3; coff = 1024; }
  }
  if (emode == 4) {  // V^T: 4 consecutive tokens same feature -> ushort4
#pragma unroll
    for (int i = 0; i < 4; ++i)
#pragma unroll
      for (int j = 0; j < 4; ++j) {
        const int col = n0 - coff + j * 16 + mr;  // feature: h = col>>6, d = col&63
        const int row0 = m0 + i * 16 + quad * 4;  // token base (4 consecutive)
        const int bb = row0 >> 10, t0 = row0 & 1023;
        ushort4 pk;
        pk.x = f2bf(acc[i][j][0]); pk.y = f2bf(acc[i][j][1]);
        pk.z = f2bf(acc[i][j][2]); pk.w = f2bf(acc[i][j][3]);
        *reinterpret_cast<ushort4*>(
            &Vt[((size_t)((bb * Hz + (col >> 6)) * DHz + (col & 63))) * Tz + t0]) = pk;
      }
  } else if (emode == 0) {
    float* Cf = (float*)p1;
#pragma unroll
    for (int i = 0; i < 4; ++i)
#pragma unroll
      for (int j = 0; j < 4; ++j) {
        const int col = n0 + j * 16 + mr;
#pragma unroll
        for (int rr = 0; rr < 4; ++rr)
          Cf[(size_t)(m0 + i * 16 + quad * 4 + rr) * N + col] = acc[i][j][rr];
      }
  } else {
    const bool relu = (emode == 2);
#pragma unroll
    for (int i = 0; i < 4; ++i)
#pragma unroll
      for (int j = 0; j < 4; ++j) {
        const int col = n0 - coff + j * 16 + mr;
#pragma unroll
        for (int rr = 0; rr < 4; ++rr) {
          float v = acc[i][j][rr];
          if (relu) v = fmaxf(v, 0.f);
          Cbf[(size_t)(m0 + i * 16 + quad * 4 + rr) * ncol + col] = f2bf(v);
        }
      }
  }
}

// ---------------------------------------------------------------------------
// fp32 VALU GEMM for layer-1 Q AND K in one dispatch. Epilogue emits
// compensated bf16 hi/lo pairs: hi = bf16(v), lo = bf16(v - hi).
// ---------------------------------------------------------------------------
__global__ __launch_bounds__(256) void gemm_qk_kernel(
    const float* __restrict__ A, const float* __restrict__ vqkv,
    unsigned short* __restrict__ Qhi, unsigned short* __restrict__ Qlo,
    unsigned short* __restrict__ Khi, unsigned short* __restrict__ Klo,
    int N, int K)
{
  __shared__ float As[16][132];
  __shared__ float Bs[16][132];
  const int tid = threadIdx.x;
  const int sel = blockIdx.y >> 6;
  const int bm = (blockIdx.y & 63) * 128;
  const int bn = blockIdx.x * 128;
  const float* Bm = vqkv + (size_t)sel * Dz * Dz;
  unsigned short* Chi = sel ? Khi : Qhi;
  unsigned short* Clo = sel ? Klo : Qlo;
  const int tx = tid & 15, ty = tid >> 4;
  float acc[8][8];
#pragma unroll
  for (int i = 0; i < 8; ++i)
#pragma unroll
    for (int j = 0; j < 8; ++j) acc[i][j] = 0.f;

  for (int k0 = 0; k0 < K; k0 += 16) {
#pragma unroll
    for (int i = 0; i < 2; ++i) {
      int idx = tid + i * 256;
      int r = idx >> 2, kv = (idx & 3) << 2;
      float4 a = *reinterpret_cast<const float4*>(&A[(size_t)(bm + r) * K + k0 + kv]);
      As[kv + 0][r] = a.x; As[kv + 1][r] = a.y; As[kv + 2][r] = a.z; As[kv + 3][r] = a.w;
      int kk = idx >> 5, nv = (idx & 31) << 2;
      *reinterpret_cast<float4*>(&Bs[kk][nv]) =
          *reinterpret_cast<const float4*>(&Bm[(size_t)(k0 + kk) * N + bn + nv]);
    }
    __syncthreads();
#pragma unroll
    for (int kk = 0; kk < 16; ++kk) {
      float ar[8], br[8];
#pragma unroll
      for (int i = 0; i < 8; ++i) ar[i] = As[kk][ty * 8 + i];
#pragma unroll
      for (int j = 0; j < 4; ++j) {
        br[j]     = Bs[kk][tx * 4 + j];
        br[4 + j] = Bs[kk][64 + tx * 4 + j];
      }
#pragma unroll
      for (int i = 0; i < 8; ++i)
#pragma unroll
        for (int j = 0; j < 8; ++j) acc[i][j] += ar[i] * br[j];
    }
    __syncthreads();
  }
#pragma unroll
  for (int i = 0; i < 8; ++i) {
    size_t row = (size_t)(bm + ty * 8 + i);
    ushort4 h0, h1, l0, l1;
#pragma unroll
    for (int j = 0; j < 4; ++j) {
      float v0 = acc[i][j], v1 = acc[i][4 + j];
      unsigned short a0 = f2bf(v0); float r0 = v0 - bf2f(a0);  // exact residual
      unsigned short a1 = f2bf(v1); float r1 = v1 - bf2f(a1);
      reinterpret_cast<unsigned short*>(&h0)[j] = a0;
      reinterpret_cast<unsigned short*>(&l0)[j] = f2bf(r0);
      reinterpret_cast<unsigned short*>(&h1)[j] = a1;
      reinterpret_cast<unsigned short*>(&l1)[j] = f2bf(r1);
    }
    *reinterpret_cast<ushort4*>(&Chi[row * N + bn + tx * 4]) = h0;
    *reinterpret_cast<ushort4*>(&Chi[row * N + bn + 64 + tx * 4]) = h1;
    *reinterpret_cast<ushort4*>(&Clo[row * N + bn + tx * 4]) = l0;
    *reinterpret_cast<ushort4*>(&Clo[row * N + bn + 64 + tx * 4]) = l1;
  }
}

// ---------------------------------------------------------------------------
// Layer-1 z pass, CHEAP: plain-bf16 QK^T (2 independent MFMAs). z feeds only
// invz. XCD-swizzled block decode for K L2 residency.
// ---------------------------------------------------------------------------
__global__ __launch_bounds__(256) void attn_z_kernel(
    const unsigned short* __restrict__ Qh, const unsigned short* __restrict__ Kh,
    float* __restrict__ invzG)
{
  const int tid = threadIdx.x;
  const int lane = tid & 63, wave = tid >> 6;
  const int c = lane & 15, quad = lane >> 4;
  int b, h, qt;
  attn_decode(blockIdx.x, b, h, qt);
  const size_t bT = (size_t)b * Tz;
  const int qrow = qt * 64 + wave * 16;
  const int hoff = h * DHz;

  const size_t qbase = (bT + qrow + c) * Dz + hoff + quad * 8;
  short8 q0 = *reinterpret_cast<const short8*>(Qh + qbase);
  short8 q1 = *reinterpret_cast<const short8*>(Qh + qbase + 32);

  const f32x4 zf = {0.f, 0.f, 0.f, 0.f};
  float z[4] = {0.f, 0.f, 0.f, 0.f};

  for (int t = 0; t < 16; ++t) {
    const int k0 = t * 64;
#pragma unroll
    for (int sub = 0; sub < 4; ++sub) {
      const size_t kb = (bT + k0 + sub * 16 + c) * Dz + hoff + quad * 8;
      short8 kh0 = *reinterpret_cast<const short8*>(Kh + kb);
      short8 kh1 = *reinterpret_cast<const short8*>(Kh + kb + 32);
      f32x4 aA = zf, aB = zf;
      aA = __builtin_amdgcn_mfma_f32_16x16x32_bf16(q0, kh0, aA, 0, 0, 0);
      aB = __builtin_amdgcn_mfma_f32_16x16x32_bf16(q1, kh1, aB, 0, 0, 0);
#pragma unroll
      for (int rr = 0; rr < 4; ++rr) z[rr] += __expf((aA[rr] + aB[rr]) * 0.125f);
    }
  }
#pragma unroll
  for (int w = 1; w < 16; w <<= 1) {
#pragma unroll
    for (int rr = 0; rr < 4; ++rr) z[rr] += __shfl_xor(z[rr], w);
  }
  if (c == 0) {
#pragma unroll
    for (int rr = 0; rr < 4; ++rr)
      invzG[(size_t)(b * Hz + h) * Tz + qrow + quad * 4 + rr] = 1.f / z[rr];
  }
}

// ---------------------------------------------------------------------------
// Layer-1 ctx via MFMA with FUSED deterministic colsum. QK^T is bf16x3 with
// a 2-accumulator ILP split. XCD-swizzled block decode; PART is written at
// the LOGICAL (b,h,qt) slot so the reduce order (and CS1 bits) is unchanged.
// ---------------------------------------------------------------------------
__global__ __launch_bounds__(256) void attn_ctx_kernel(
    const unsigned short* __restrict__ Qh, const unsigned short* __restrict__ Ql,
    const unsigned short* __restrict__ Kh, const unsigned short* __restrict__ Kl,
    const unsigned short* __restrict__ Vt, const float* __restrict__ invzG,
    unsigned short* __restrict__ ctx, float* __restrict__ part)
{
  __shared__ unsigned short Pld[64][76];
  __shared__ float CSP[4][1024];  // per-wave colsum partials (single writer)
  const int tid = threadIdx.x;
  const int lane = tid & 63, wave = tid >> 6;
  const int c = lane & 15, quad = lane >> 4;
  int b, h, qt;
  attn_decode(blockIdx.x, b, h, qt);
  const size_t bT = (size_t)b * Tz;
  const int qrow = qt * 64 + wave * 16;
  const int hoff = h * DHz;
  const int lidx = b * 128 + h * 16 + qt;  // logical PART slot

  const size_t qbase = (bT + qrow + c) * Dz + hoff + quad * 8;
  short8 q0h = *reinterpret_cast<const short8*>(Qh + qbase);
  short8 q1h = *reinterpret_cast<const short8*>(Qh + qbase + 32);
  short8 q0l = *reinterpret_cast<const short8*>(Ql + qbase);
  short8 q1l = *reinterpret_cast<const short8*>(Ql + qbase + 32);

  float invz[4];
#pragma unroll
  for (int rr = 0; rr < 4; ++rr)
    invz[rr] = invzG[(size_t)(b * Hz + h) * Tz + qrow + quad * 4 + rr];

  const f32x4 zf = {0.f, 0.f, 0.f, 0.f};
  f32x4 ot[4] = {zf, zf, zf, zf};

  for (int t = 0; t < 16; ++t) {
    const int k0 = t * 64;
#pragma unroll
    for (int sub = 0; sub < 4; ++sub) {
      const size_t kb = (bT + k0 + sub * 16 + c) * Dz + hoff + quad * 8;
      short8 kh0 = *reinterpret_cast<const short8*>(Kh + kb);
      short8 kh1 = *reinterpret_cast<const short8*>(Kh + kb + 32);
      short8 kl0 = *reinterpret_cast<const short8*>(Kl + kb);
      short8 kl1 = *reinterpret_cast<const short8*>(Kl + kb + 32);
      f32x4 aA = zf, aB = zf;  // two independent chains (depth 3 each)
      aA = __builtin_amdgcn_mfma_f32_16x16x32_bf16(q0h, kh0, aA, 0, 0, 0);
      aB = __builtin_amdgcn_mfma_f32_16x16x32_bf16(q1h, kh1, aB, 0, 0, 0);
      aA = __builtin_amdgcn_mfma_f32_16x16x32_bf16(q0h, kl0, aA, 0, 0, 0);
      aB = __builtin_amdgcn_mfma_f32_16x16x32_bf16(q1h, kl1, aB, 0, 0, 0);
      aA = __builtin_amdgcn_mfma_f32_16x16x32_bf16(q0l, kh0, aA, 0, 0, 0);
      aB = __builtin_amdgcn_mfma_f32_16x16x32_bf16(q1l, kh1, aB, 0, 0, 0);
      float p[4];
#pragma unroll
      for (int rr = 0; rr < 4; ++rr)
        p[rr] = __expf((aA[rr] + aB[rr]) * 0.125f) * invz[rr];
      float cs = p[0] + p[1] + p[2] + p[3];
      cs += __shfl_xor(cs, 16);
      cs += __shfl_xor(cs, 32);
      if (quad == 0) CSP[wave][k0 + sub * 16 + c] = cs;  // key visited once
#pragma unroll
      for (int rr = 0; rr < 4; ++rr)
        Pld[(wave << 4) + quad * 4 + rr][sub * 16 + c] = f2bf(p[rr]);
    }
    union { short8 v; ushort4 hh[2]; } pb0, pb1;
    pb0.hh[0] = *reinterpret_cast<const ushort4*>(&Pld[(wave << 4) + c][quad * 8]);
    pb0.hh[1] = *reinterpret_cast<const ushort4*>(&Pld[(wave << 4) + c][quad * 8 + 4]);
    pb1.hh[0] = *reinterpret_cast<const ushort4*>(&Pld[(wave << 4) + c][32 + quad * 8]);
    pb1.hh[1] = *reinterpret_cast<const ushort4*>(&Pld[(wave << 4) + c][32 + quad * 8 + 4]);
#pragma unroll
    for (int ds = 0; ds < 4; ++ds) {
      const size_t va = ((size_t)((b * Hz + h) * DHz + ds * 16 + c)) * Tz + k0 + quad * 8;
      short8 v0 = *reinterpret_cast<const short8*>(Vt + va);
      short8 v1 = *reinterpret_cast<const short8*>(Vt + va + 32);
      ot[ds] = __builtin_amdgcn_mfma_f32_16x16x32_bf16(v0, pb0.v, ot[ds], 0, 0, 0);
      ot[ds] = __builtin_amdgcn_mfma_f32_16x16x32_bf16(v1, pb1.v, ot[ds], 0, 0, 0);
    }
  }

  const size_t cb = (bT + qrow + c) * Dz + hoff;
#pragma unroll
  for (int ds = 0; ds < 4; ++ds) {
    ushort4 pk;
    pk.x = f2bf(ot[ds][0]); pk.y = f2bf(ot[ds][1]);
    pk.z = f2bf(ot[ds][2]); pk.w = f2bf(ot[ds][3]);
    *reinterpret_cast<ushort4*>(&ctx[cb + ds * 16 + quad * 4]) = pk;
  }
  __syncthreads();
  // fixed-order combine + non-atomic block-partial write (deterministic)
  for (int i = tid; i < 1024; i += 256) {
    float v = ((CSP[0][i] + CSP[1][i]) + CSP[2][i]) + CSP[3][i];
    part[(size_t)lidx * 1024 + i] = v * (1.f / Hz);
  }
}

// ---------------------------------------------------------------------------
// Deterministic colsum reduce: CS1[b,key] = sum over the 128 (h,qt) block
// partials in fixed ascending order. One thread per output.
// ---------------------------------------------------------------------------
__global__ __launch_bounds__(256) void colsum_reduce_kernel(
    const float* __restrict__ part, float* __restrict__ colsum)
{
  const int i = blockIdx.x * 256 + threadIdx.x;  // 0..8191
  const int b = i >> 10, k = i & 1023;
  const float* p = part + (size_t)(b * 128) * 1024 + k;
  float s = 0.f;
  for (int j = 0; j < 128; ++j) s += p[(size_t)j * 1024];
  colsum[i] = s;
}

// ---------------------------------------------------------------------------
// Layer-2 MFMA attention (masked), with k-tile range skipping. CS2 feeds only
// the continuous wl softmax -> atomics are fine here. XCD-swizzled decode.
// ---------------------------------------------------------------------------
__global__ __launch_bounds__(256) void attn_mfma2_kernel(
    const unsigned short* __restrict__ Qh, const unsigned short* __restrict__ Kh,
    const unsigned short* __restrict__ Vt, const int* __restrict__ ids,
    const int* __restrict__ wst,
    unsigned short* __restrict__ ctx, float* __restrict__ colsum)
{
  __shared__ unsigned short Pld[64][76];
  __shared__ float csb[1024];

  const int tid = threadIdx.x;
  const int lane = tid & 63, wave = tid >> 6;
  const int c = lane & 15, quad = lane >> 4;
  int b, h, qt;
  attn_decode(blockIdx.x, b, h, qt);
  const size_t bT = (size_t)b * Tz;
  const int qrow = qt * 64 + wave * 16;
  const int hoff = h * DHz;

  for (int i = tid; i < 1024; i += 256) csb[i] = 0.f;

  const int id_lo = ids[bT + qt * 64];
  const int id_hi = ids[bT + qt * 64 + 63];
  const int klo = wst[b * (Tz + 1) + id_lo];
  const int khi = wst[b * (Tz + 1) + id_hi + 1];
  const int t0 = klo >> 6, t1 = (khi - 1) >> 6;

  const size_t qbase = (bT + qrow + c) * Dz + hoff + quad * 8;
  short8 q0 = *reinterpret_cast<const short8*>(Qh + qbase);
  short8 q1 = *reinterpret_cast<const short8*>(Qh + qbase + 32);

  int qid[4];
#pragma unroll
  for (int rr = 0; rr < 4; ++rr) qid[rr] = ids[bT + qrow + quad * 4 + rr];
  __syncthreads();  // csb zeros visible before pass-2 atomics

  const f32x4 zf = {0.f, 0.f, 0.f, 0.f};

  // pass 1: z
  float z[4] = {0.f, 0.f, 0.f, 0.f};
  for (int t = t0; t <= t1; ++t) {
    const int k0 = t * 64;
#pragma unroll
    for (int sub = 0; sub < 4; ++sub) {
      const size_t kb = (bT + k0 + sub * 16 + c) * Dz + hoff + quad * 8;
      short8 kh0 = *reinterpret_cast<const short8*>(Kh + kb);
      short8 kh1 = *reinterpret_cast<const short8*>(Kh + kb + 32);
      f32x4 acc = zf;
      acc = __builtin_amdgcn_mfma_f32_16x16x32_bf16(q0, kh0, acc, 0, 0, 0);
      acc = __builtin_amdgcn_mfma_f32_16x16x32_bf16(q1, kh1, acc, 0, 0, 0);
      int kidv = ids[bT + k0 + sub * 16 + c];
#pragma unroll
      for (int rr = 0; rr < 4; ++rr) {
        float e = __expf(acc[rr] * 0.125f);
        if (qid[rr] != kidv) e = 0.f;
        z[rr] += e;
      }
    }
  }
#pragma unroll
  for (int w = 1; w < 16; w <<= 1) {
#pragma unroll
    for (int rr = 0; rr < 4; ++rr) z[rr] += __shfl_xor(z[rr], w);
  }
  float invz[4];
#pragma unroll
  for (int rr = 0; rr < 4; ++rr) invz[rr] = 1.f / z[rr];

  // pass 2: P, colsum, PV
  f32x4 ot[4] = {zf, zf, zf, zf};
  for (int t = t0; t <= t1; ++t) {
    const int k0 = t * 64;
#pragma unroll
    for (int sub = 0; sub < 4; ++sub) {
      const size_t kb = (bT + k0 + sub * 16 + c) * Dz + hoff + quad * 8;
      short8 kh0 = *reinterpret_cast<const short8*>(Kh + kb);
      short8 kh1 = *reinterpret_cast<const short8*>(Kh + kb + 32);
      f32x4 acc = zf;
      acc = __builtin_amdgcn_mfma_f32_16x16x32_bf16(q0, kh0, acc, 0, 0, 0);
      acc = __builtin_amdgcn_mfma_f32_16x16x32_bf16(q1, kh1, acc, 0, 0, 0);
      int kidv = ids[bT + k0 + sub * 16 + c];
      float p[4];
#pragma unroll
      for (int rr = 0; rr < 4; ++rr) {
        float e = __expf(acc[rr] * 0.125f);
        if (qid[rr] != kidv) e = 0.f;
        p[rr] = e * invz[rr];
      }
      float cs = p[0] + p[1] + p[2] + p[3];
      cs += __shfl_xor(cs, 16);
      cs += __shfl_xor(cs, 32);
      if (quad == 0) atomicAdd(&csb[k0 + sub * 16 + c], cs);
#pragma unroll
      for (int rr = 0; rr < 4; ++rr)
        Pld[(wave << 4) + quad * 4 + rr][sub * 16 + c] = f2bf(p[rr]);
    }
    union { short8 v; ushort4 hh[2]; } pb0, pb1;
    pb0.hh[0] = *reinterpret_cast<const ushort4*>(&Pld[(wave << 4) + c][quad * 8]);
    pb0.hh[1] = *reinterpret_cast<const ushort4*>(&Pld[(wave << 4) + c][quad * 8 + 4]);
    pb1.hh[0] = *reinterpret_cast<const ushort4*>(&Pld[(wave << 4) + c][32 + quad * 8]);
    pb1.hh[1] = *reinterpret_cast<const ushort4*>(&Pld[(wave << 4) + c][32 + quad * 8 + 4]);
#pragma unroll
    for (int ds = 0; ds < 4; ++ds) {
      const size_t va = ((size_t)((b * Hz + h) * DHz + ds * 16 + c)) * Tz + k0 + quad * 8;
      short8 v0 = *reinterpret_cast<const short8*>(Vt + va);
      short8 v1 = *reinterpret_cast<const short8*>(Vt + va + 32);
      ot[ds] = __builtin_amdgcn_mfma_f32_16x16x32_bf16(v0, pb0.v, ot[ds], 0, 0, 0);
      ot[ds] = __builtin_amdgcn_mfma_f32_16x16x32_bf16(v1, pb1.v, ot[ds], 0, 0, 0);
    }
  }

  const size_t cb = (bT + qrow + c) * Dz + hoff;
#pragma unroll
  for (int ds = 0; ds < 4; ++ds) {
    ushort4 pk;
    pk.x = f2bf(ot[ds][0]); pk.y = f2bf(ot[ds][1]);
    pk.z = f2bf(ot[ds][2]); pk.w = f2bf(ot[ds][3]);
    *reinterpret_cast<ushort4*>(&ctx[cb + ds * 16 + quad * 4]) = pk;
  }
  __syncthreads();
  for (int i = tid; i < 1024; i += 256)
    atomicAdd(&colsum[bT + i], csb[i] * (1.f / Hz));
}

// ---------------------------------------------------------------------------
// out = LayerNorm(resid + delta). resid fp32 (residf) if non-null else bf16.
// ---------------------------------------------------------------------------
__global__ __launch_bounds__(256) void ln_kernel(const float* __restrict__ residf,
    const unsigned short* __restrict__ residbf, const float* __restrict__ delta,
    float* __restrict__ outf, unsigned short* __restrict__ outbf)
{
  const size_t base = (size_t)blockIdx.x * Dz;
  const int tid = threadIdx.x;
  float r0, r1;
  if (residf) {
    r0 = residf[base + tid]; r1 = residf[base + tid + 256];
  } else {
    r0 = bf2f(residbf[base + tid]); r1 = bf2f(residbf[base + tid + 256]);
  }
  float x0 = r0 + delta[base + tid];
  float x1 = r1 + delta[base + tid + 256];
  __shared__ float red[4];
  float s = x0 + x1;
#pragma unroll
  for (int off = 32; off; off >>= 1) s += __shfl_down(s, off);
  if ((tid & 63) == 0) red[tid >> 6] = s;
  __syncthreads();
  const float mean = (red[0] + red[1] + red[2] + red[3]) * (1.f / Dz);
  __syncthreads();
  float d0 = x0 - mean, d1 = x1 - mean;
  float v = d0 * d0 + d1 * d1;
#pragma unroll
  for (int off = 32; off; off >>= 1) v += __shfl_down(v, off);
  if ((tid & 63) == 0) red[tid >> 6] = v;
  __syncthreads();
  const float var = (red[0] + red[1] + red[2] + red[3]) * (1.f / Dz);
  const float rstd = rsqrtf(var + 1e-5f);
  float y0 = d0 * rstd, y1 = d1 * rstd;
  if (outf) {
    outf[base + tid] = y0;
    outf[base + tid + 256] = y1;
  }
  outbf[base + tid] = f2bf(y0);
  outbf[base + tid + 256] = f2bf(y1);
}

// ---------------------------------------------------------------------------
// Per batch: min-max normalize colsum, threshold 0.5, run-length window scan.
// All reductions shfl/fixed-order -> deterministic.
// ---------------------------------------------------------------------------
__global__ __launch_bounds__(256) void window_ids_kernel(const float* __restrict__ cs,
    int* __restrict__ ids, int* __restrict__ wst, int* __restrict__ nwin)
{
  const int b = blockIdx.x, tid = threadIdx.x;
  __shared__ float vals[Tz];
  __shared__ unsigned char wb[Tz];
  __shared__ int sids[Tz];
  __shared__ float rmin[4], rmax[4];
  float mn = INFINITY, mx = -INFINITY;
  for (int t = tid; t < Tz; t += 256) {
    float v = cs[b * Tz + t];
    vals[t] = v;
    mn = fminf(mn, v); mx = fmaxf(mx, v);
  }
#pragma unroll
  for (int off = 32; off; off >>= 1) {
    mn = fminf(mn, __shfl_down(mn, off));
    mx = fmaxf(mx, __shfl_down(mx, off));
  }
  if ((tid & 63) == 0) { rmin[tid >> 6] = mn; rmax[tid >> 6] = mx; }
  __syncthreads();
  mn = fminf(fminf(rmin[0], rmin[1]), fminf(rmin[2], rmin[3]));
  mx = fmaxf(fmaxf(rmax[0], rmax[1]), fmaxf(rmax[2], rmax[3]));
  const float inv = 1.f / (mx - mn + 1e-8f);
  for (int t = tid; t < Tz; t += 256) wb[t] = (((vals[t] - mn) * inv) >= 0.5f) ? 1 : 0;
  __syncthreads();
  if (tid == 0) {
    int cur = wb[0], start = 0, wid = 0;
    sids[0] = 0;
    wst[b * (Tz + 1)] = 0;
    for (int t = 1; t < Tz; ++t) {
      int wt = wb[t];
      if (wt != cur) {
        cur = wt;
        if (start + 1 != t) {
          start = t;
          ++wid;
          wst[b * (Tz + 1) + wid] = t;
        }
      }
      sids[t] = wid;
    }
    nwin[b] = wid + 1;
    wst[b * (Tz + 1) + wid + 1] = Tz;
  }
  __syncthreads();
  for (int t = tid; t < Tz; t += 256) ids[b * Tz + t] = sids[t];
}

// ---------------------------------------------------------------------------
// wl[b,:] = softmax over keys of layer-2 colsum.
// ---------------------------------------------------------------------------
__global__ __launch_bounds__(256) void wl_softmax_kernel(const float* __restrict__ cs,
                                                         float* __restrict__ wl)
{
  const int b = blockIdx.x, tid = threadIdx.x;
  __shared__ float vals[Tz];
  __shared__ float red[4];
  float mx = -INFINITY;
  for (int t = tid; t < Tz; t += 256) {
    float v = cs[b * Tz + t];
    vals[t] = v;
    mx = fmaxf(mx, v);
  }
#pragma unroll
  for (int off = 32; off; off >>= 1) mx = fmaxf(mx, __shfl_down(mx, off));
  if ((tid & 63) == 0) red[tid >> 6] = mx;
  __syncthreads();
  mx = fmaxf(fmaxf(red[0], red[1]), fmaxf(red[2], red[3]));
  __syncthreads();
  float se = 0.f;
  for (int t = tid; t < Tz; t += 256) {
    float e = expf(vals[t] - mx);
    vals[t] = e;
    se += e;
  }
#pragma unroll
  for (int off = 32; off; off >>= 1) se += __shfl_down(se, off);
  if ((tid & 63) == 0) red[tid >> 6] = se;
  __syncthreads();
  const float inv = 1.f / (red[0] + red[1] + red[2] + red[3]);
  for (int t = tid; t < Tz; t += 256) wl[b * Tz + t] = vals[t] * inv;
}

// ---------------------------------------------------------------------------
// Fused outputs: word_tokens (blocks 0..8191), winmap (8192..16383),
// copy_x (16384..20479).
// ---------------------------------------------------------------------------
__global__ __launch_bounds__(256) void outputs_kernel(
    const unsigned short* __restrict__ outl, const float* __restrict__ wl,
    const int* __restrict__ wst, const int* __restrict__ nwin,
    const int* __restrict__ ids, const float* __restrict__ x,
    float* __restrict__ out, float* __restrict__ out2)
{
  const int bid = blockIdx.x;
  const int tid = threadIdx.x;
  if (bid < 8192) {  // word_tokens
    const int w = bid & (Tz - 1);
    const int b = bid >> 10;
    float a0 = 0.f, a1 = 0.f;
    if (w < nwin[b]) {
      const int s = wst[b * (Tz + 1) + w], e = wst[b * (Tz + 1) + w + 1];
      for (int t = s; t < e; ++t) {
        const float sc = wl[b * Tz + t];
        const unsigned short* p = &outl[((size_t)(b * Tz + t)) * Dz];
        a0 += bf2f(p[tid]) * sc;
        a1 += bf2f(p[tid + 256]) * sc;
      }
    }
    float* o = &out[((size_t)(b * 2 * Tz + w)) * Dz];
    o[tid] = a0;
    o[tid + 256] = a1;
  } else if (bid < 16384) {  // winmap
    const int lb = bid - 8192;
    const int w = lb & (Tz - 1);
    const int b = lb >> 10;
    const int j = tid * 4;
    int4 id4 = *reinterpret_cast<const int4*>(&ids[b * Tz + j]);
    float4 v;
    v.x = (id4.x == w) ? 1.f : 0.f;
    v.y = (id4.y == w) ? 1.f : 0.f;
    v.z = (id4.z == w) ? 1.f : 0.f;
    v.w = (id4.w == w) ? 1.f : 0.f;
    *reinterpret_cast<float4*>(&out2[((size_t)(b * Tz + w)) * Tz + j]) = v;
  } else {  // copy_x
    size_t i = (size_t)(bid - 16384) * 256 + tid;
    size_t idx = i * 4;
    size_t rowi = idx >> 9;
    size_t d = idx & 511;
    size_t b = rowi >> 10, t = rowi & 1023;
    float4 v = *reinterpret_cast<const float4*>(&x[idx]);
    *reinterpret_cast<float4*>(&out[(((b * 2 * Tz) + Tz + t) << 9) + d]) = v;
  }
}

// ---------------------------------------------------------------------------
// Orchestration: 22 dispatches. XCD-aware block swizzle on the three
// attention kernels (K/V L2 residency); PART slots stay logical.
// ---------------------------------------------------------------------------
extern "C" void kernel_launch(void* const* d_in, const int* in_sizes, int n_in,
                              void* d_out, int out_size, void* d_ws, size_t ws_size,
                              hipStream_t stream)
{
  (void)in_sizes; (void)n_in; (void)out_size; (void)ws_size;
  const float* x     = (const float*)d_in[0];
  const float* vqkv  = (const float*)d_in[1];
  const float* voutw = (const float*)d_in[2];
  const float* vw1   = (const float*)d_in[3];
  const float* vw2   = (const float*)d_in[4];
  const float* lqkv  = (const float*)d_in[5];
  const float* loutw = (const float*)d_in[6];
  const float* lw1   = (const float*)d_in[7];
  const float* lw2   = (const float*)d_in[8];
  float* out = (float*)d_out;
  float* ws  = (float*)d_ws;

  unsigned short* QLbf = (unsigned short*)(ws + 0);        // bf16 Q lo (L1)
  unsigned short* KLbf = (unsigned short*)(ws + 2097152);  // bf16 K lo (L1)
  float* PROJ = ws + 0;         // written after attn_ctx (QL/KL dead)
  float* Y1   = ws + 4194304;
  unsigned short* QHbf = (unsigned short*)(ws + 8388608);   // bf16 Q hi (L1+L2)
  unsigned short* KHbf = (unsigned short*)(ws + 10485760);  // bf16 K hi (L1+L2)
  unsigned short* VT   = (unsigned short*)(ws + 12582912);
  unsigned short* SLOT1 = (unsigned short*)(ws + 14680064); // attn ctx bf16
  unsigned short* SLOT2 = (unsigned short*)(ws + 16777216); // LN bf16 out
  unsigned short* HIDbf = (unsigned short*)(ws + 18874368); // FFN hidden
  unsigned short* XBF   = (unsigned short*)(ws + 18874368); // alias (pre-FFN)
  float* PART = ws + 18874368;  // colsum block partials (1024x1024), alias:
                                // written after XBF is dead, dead before FFN1
  // bf16 transposed weights (WLQ0..2 contiguous -> merged [1536,512] matrix)
  unsigned short* WVQV = (unsigned short*)(ws + 27262976);
  unsigned short* WVO  = (unsigned short*)(ws + 27394048);
  unsigned short* WV1  = (unsigned short*)(ws + 27525120);
  unsigned short* WV2  = (unsigned short*)(ws + 28049408);
  unsigned short* WLQ0 = (unsigned short*)(ws + 28573696);
  unsigned short* WLQ1 = (unsigned short*)(ws + 28704768);
  unsigned short* WLQ2 = (unsigned short*)(ws + 28835840);
  unsigned short* WLO  = (unsigned short*)(ws + 28966912);
  unsigned short* WL1  = (unsigned short*)(ws + 29097984);
  unsigned short* WL2  = (unsigned short*)(ws + 29622272);
  // small buffers
  float* CS1   = ws + 30146560;
  float* CS2   = ws + 30154752;
  float* WLs   = ws + 30162944;
  int*   IDS   = (int*)(ws + 30171136);
  int*   WST   = (int*)(ws + 30179328);
  int*   NWIN  = (int*)(ws + 30187776);
  float* INVZ  = ws + 30195968;  // (B*H*T) = 65536 floats

  dim3 blk(256);

  // ---- fused prep: 10 wconv + zero + fconv ----
  PrepArgs P;
  auto setw = [&](int i, const float* s, unsigned short* d, int K, int N, int b0) {
    P.d[i].src = s; P.d[i].dst = d; P.d[i].K = K; P.d[i].N = N; P.d[i].blk0 = b0;
  };
  int b0 = 0;
  setw(0, vqkv + 2 * Dz * Dz, WVQV, Dz, Dz, b0); b0 += 256;
  setw(1, voutw, WVO, Dz, Dz, b0); b0 += 256;
  setw(2, vw1, WV1, Dz, FFz, b0); b0 += 1024;
  setw(3, vw2, WV2, FFz, Dz, b0); b0 += 1024;
  setw(4, lqkv + 0 * Dz * Dz, WLQ0, Dz, Dz, b0); b0 += 256;
  setw(5, lqkv + 1 * Dz * Dz, WLQ1, Dz, Dz, b0); b0 += 256;
  setw(6, lqkv + 2 * Dz * Dz, WLQ2, Dz, Dz, b0); b0 += 256;
  setw(7, loutw, WLO, Dz, Dz, b0); b0 += 256;
  setw(8, lw1, WL1, Dz, FFz, b0); b0 += 1024;
  setw(9, lw2, WL2, FFz, Dz, b0); b0 += 1024;
  P.nwc = b0;  // 5632
  prep_kernel<<<dim3(P.nwc + 64 + 4096), blk, 0, stream>>>(P, x, XBF, CS1);

  auto mgemm = [&](const unsigned short* A, const unsigned short* BT, void* p1,
                   void* p2, void* p3, int K, int N, int mode) {
    mfma_gemm_kernel<<<dim3(N / 64, Mz / 64), dim3(64), 0, stream>>>(
        A, BT, p1, p2, p3, K, N, mode);
  };

  // ---------------- layer 1 (vanilla) ----------------
  gemm_qk_kernel<<<dim3(4, 128), blk, 0, stream>>>(x, vqkv, QHbf, QLbf, KHbf, KLbf, Dz, Dz);
  attn_z_kernel<<<dim3(Bz * Hz * 16), blk, 0, stream>>>(QHbf, KHbf, INVZ);  // K L2-warm
  mgemm(XBF, WVQV, VT, nullptr, nullptr, Dz, Dz, 4);        // V -> V^T (XBF dead after)
  attn_ctx_kernel<<<dim3(Bz * Hz * 16), blk, 0, stream>>>(
      QHbf, QLbf, KHbf, KLbf, VT, INVZ, SLOT1, PART);
  colsum_reduce_kernel<<<dim3(32), blk, 0, stream>>>(PART, CS1);
  window_ids_kernel<<<dim3(Bz), blk, 0, stream>>>(CS1, IDS, WST, NWIN);
  mgemm(SLOT1, WVO, PROJ, nullptr, nullptr, Dz, Dz, 0);     // proj (QL/KL dead)
  ln_kernel<<<dim3(Mz), blk, 0, stream>>>(x, nullptr, PROJ, Y1, SLOT2);
  mgemm(SLOT2, WV1, HIDbf, nullptr, nullptr, Dz, FFz, 2);   // FFN1 + ReLU (PART dead)
  mgemm(HIDbf, WV2, PROJ, nullptr, nullptr, FFz, Dz, 0);    // FFN2
  ln_kernel<<<dim3(Mz), blk, 0, stream>>>(Y1, nullptr, PROJ, nullptr, SLOT2);

  // ---------------- layer 2 (block-diagonal window mask) ----------------
  mgemm(SLOT2, WLQ0, QHbf, KHbf, VT, Dz, 3 * Dz, 5);        // merged QKV
  attn_mfma2_kernel<<<dim3(Bz * Hz * 16), blk, 0, stream>>>(
      QHbf, KHbf, VT, IDS, WST, SLOT1, CS2);
  mgemm(SLOT1, WLO, PROJ, nullptr, nullptr, Dz, Dz, 0);
  ln_kernel<<<dim3(Mz), blk, 0, stream>>>(nullptr, SLOT2, PROJ, Y1, SLOT2);
  mgemm(SLOT2, WL1, HIDbf, nullptr, nullptr, Dz, FFz, 2);
  mgemm(HIDbf, WL2, PROJ, nullptr, nullptr, FFz, Dz, 0);
  ln_kernel<<<dim3(Mz), blk, 0, stream>>>(Y1, nullptr, PROJ, nullptr, SLOT2);

  // ---------------- pooling + outputs ----------------
  wl_softmax_kernel<<<dim3(Bz), blk, 0, stream>>>(CS2, WLs);
  outputs_kernel<<<dim3(20480), blk, 0, stream>>>(SLOT2, WLs, WST, NWIN, IDS, x,
                                                  out, out + (size_t)Bz * 2 * Tz * Dz);
}

// Round 5
// 948.225 us; speedup vs baseline: 1.1451x; 1.0160x over previous
//
#include <hip/hip_runtime.h>
#include <math.h>

// Problem constants (fixed by setup_inputs)
#define Bz 8
#define Tz 1024
#define Dz 512
#define FFz 2048
#define Hz 8
#define DHz 64
#define Mz (Bz * Tz)  // 8192 rows

typedef __attribute__((ext_vector_type(8))) short short8;   // 8 bf16 (4 VGPRs)
typedef __attribute__((ext_vector_type(4))) float f32x4;    // MFMA accumulator

__device__ inline unsigned short f2bf(float f) {  // RNE fp32 -> bf16
  unsigned u = __builtin_bit_cast(unsigned, f);
  return (unsigned short)((u + 0x7FFFu + ((u >> 16) & 1u)) >> 16);
}
__device__ inline float bf2f(unsigned short h) {
  unsigned u = (unsigned)h << 16;
  return __builtin_bit_cast(float, u);
}

// XCD-aware decode for the 1024-block attention grids (8 XCDs round-robin by
// blockIdx). g = xcd + 8*(qt + 16*bhi), bh = bhi*8 + xcd.
__device__ inline void attn_decode(int g, int& b, int& h, int& qt) {
  const int xcd = g & 7;
  const int j = g >> 3;
  qt = j & 15;
  const int bh = ((j >> 4) << 3) | xcd;
  b = bh >> 3;
  h = bh & 7;
}

// ---------------------------------------------------------------------------
// Fused prep: 12 weight convert+transposes (fp32 [K,N] -> bf16 [N,K], with
// optional lo-residual output) + colsum zero-fill + x -> bf16 hi/lo.
// ---------------------------------------------------------------------------
struct WDesc { const float* src; unsigned short* dst; unsigned short* dstlo;
               int K; int N; int blk0; };
struct PrepArgs { WDesc d[12]; int nwc; };

__global__ __launch_bounds__(256) void prep_kernel(PrepArgs P,
    const float* __restrict__ x, unsigned short* __restrict__ xbf,
    unsigned short* __restrict__ xlo, float* __restrict__ csz)
{
  const int bid = blockIdx.x;
  const int tid = threadIdx.x;
  if (bid < P.nwc) {  // wconv slice
    int i = 0;
    while (i < 11 && bid >= P.d[i + 1].blk0) ++i;
    const WDesc w = P.d[i];
    const int lb = bid - w.blk0;
    const int nbn = w.N / 32;
    const int bn = (lb % nbn) * 32, bk = (lb / nbn) * 32;
    __shared__ float t[32][33];
    const int tx = tid & 31, ty = tid >> 5;
#pragma unroll
    for (int r = 0; r < 32; r += 8)
      t[ty + r][tx] = w.src[(size_t)(bk + ty + r) * w.N + bn + tx];
    __syncthreads();
#pragma unroll
    for (int r = 0; r < 32; r += 8) {
      float v = t[tx][ty + r];
      unsigned short hv = f2bf(v);
      w.dst[(size_t)(bn + ty + r) * w.K + bk + tx] = hv;
      if (w.dstlo)
        w.dstlo[(size_t)(bn + ty + r) * w.K + bk + tx] = f2bf(v - bf2f(hv));
    }
  } else if (bid < P.nwc + 64) {  // zero slice (CS1+CS2 = 16384 floats)
    int idx = (bid - P.nwc) * 256 + tid;
    csz[idx] = 0.f;
  } else {  // fconv slice: 4096 blocks, 4 floats/thread -> hi + lo
    int i = (bid - P.nwc - 64) * 256 + tid;
    float4 v = *reinterpret_cast<const float4*>(&x[(size_t)i * 4]);
    ushort4 o, ol;
    o.x = f2bf(v.x); o.y = f2bf(v.y); o.z = f2bf(v.z); o.w = f2bf(v.w);
    ol.x = f2bf(v.x - bf2f(o.x)); ol.y = f2bf(v.y - bf2f(o.y));
    ol.z = f2bf(v.z - bf2f(o.z)); ol.w = f2bf(v.w - bf2f(o.w));
    *reinterpret_cast<ushort4*>(&xbf[(size_t)i * 4]) = o;
    *reinterpret_cast<ushort4*>(&xlo[(size_t)i * 4]) = ol;
  }
}

// ---------------------------------------------------------------------------
// bf16 MFMA GEMM, 64x64 tile per wave, direct-from-global fragments.
// Epilogue modes: 0 fp32 C | 1 bf16 C | 2 bf16 C + ReLU
//   | 4 V^T layout | 5 merged QKV (N=1536).
// ---------------------------------------------------------------------------
__global__ __launch_bounds__(64) void mfma_gemm_kernel(
    const unsigned short* __restrict__ A, const unsigned short* __restrict__ BT,
    void* __restrict__ p1, void* __restrict__ p2, void* __restrict__ p3,
    int K, int N, int mode)
{
  const int l = threadIdx.x;
  const int m0 = blockIdx.y * 64;
  const int n0 = blockIdx.x * 64;
  const int mr = l & 15, quad = l >> 4;

  f32x4 acc[4][4];
  const f32x4 zero = {0.f, 0.f, 0.f, 0.f};
#pragma unroll
  for (int i = 0; i < 4; ++i)
#pragma unroll
    for (int j = 0; j < 4; ++j) acc[i][j] = zero;

  const unsigned short* Ap = A + (size_t)(m0 + mr) * K + quad * 8;
  const unsigned short* Bp = BT + (size_t)(n0 + mr) * K + quad * 8;

  short8 a[4], b[4], an[4], bn[4];
#pragma unroll
  for (int i = 0; i < 4; ++i) {
    a[i] = *reinterpret_cast<const short8*>(Ap + (size_t)i * 16 * K);
    b[i] = *reinterpret_cast<const short8*>(Bp + (size_t)i * 16 * K);
  }
  for (int k0 = 0; k0 < K; k0 += 32) {
    if (k0 + 32 < K) {
#pragma unroll
      for (int i = 0; i < 4; ++i) {
        an[i] = *reinterpret_cast<const short8*>(Ap + (size_t)i * 16 * K + k0 + 32);
        bn[i] = *reinterpret_cast<const short8*>(Bp + (size_t)i * 16 * K + k0 + 32);
      }
    }
#pragma unroll
    for (int i = 0; i < 4; ++i)
#pragma unroll
      for (int j = 0; j < 4; ++j)
        acc[i][j] = __builtin_amdgcn_mfma_f32_16x16x32_bf16(a[i], b[j], acc[i][j], 0, 0, 0);
#pragma unroll
    for (int i = 0; i < 4; ++i) { a[i] = an[i]; b[i] = bn[i]; }
  }

  // C/D layout: col = lane&15, row = quad*4 + reg   [measured: m89/m91]
  int emode = mode;
  unsigned short* Cbf = (unsigned short*)p1;
  unsigned short* Vt  = (unsigned short*)p1;
  int ncol = N, coff = 0;
  if (mode == 5) {  // uniform per block: n0 is a multiple of 64
    if (n0 < 512)       { emode = 1; Cbf = (unsigned short*)p1; ncol = 512; coff = 0; }
    else if (n0 < 1024) { emode = 1; Cbf = (unsigned short*)p2; ncol = 512; coff = 512; }
    else                { emode = 4; Vt = (unsigned short*)p3; coff = 1024; }
  }
  if (emode == 4) {  // V^T: 4 consecutive tokens same feature -> ushort4
#pragma unroll
    for (int i = 0; i < 4; ++i)
#pragma unroll
      for (int j = 0; j < 4; ++j) {
        const int col = n0 - coff + j * 16 + mr;  // feature: h = col>>6, d = col&63
        const int row0 = m0 + i * 16 + quad * 4;  // token base (4 consecutive)
        const int bb = row0 >> 10, t0 = row0 & 1023;
        ushort4 pk;
        pk.x = f2bf(acc[i][j][0]); pk.y = f2bf(acc[i][j][1]);
        pk.z = f2bf(acc[i][j][2]); pk.w = f2bf(acc[i][j][3]);
        *reinterpret_cast<ushort4*>(
            &Vt[((size_t)((bb * Hz + (col >> 6)) * DHz + (col & 63))) * Tz + t0]) = pk;
      }
  } else if (emode == 0) {
    float* Cf = (float*)p1;
#pragma unroll
    for (int i = 0; i < 4; ++i)
#pragma unroll
      for (int j = 0; j < 4; ++j) {
        const int col = n0 + j * 16 + mr;
#pragma unroll
        for (int rr = 0; rr < 4; ++rr)
          Cf[(size_t)(m0 + i * 16 + quad * 4 + rr) * N + col] = acc[i][j][rr];
      }
  } else {
    const bool relu = (emode == 2);
#pragma unroll
    for (int i = 0; i < 4; ++i)
#pragma unroll
      for (int j = 0; j < 4; ++j) {
        const int col = n0 - coff + j * 16 + mr;
#pragma unroll
        for (int rr = 0; rr < 4; ++rr) {
          float v = acc[i][j][rr];
          if (relu) v = fmaxf(v, 0.f);
          Cbf[(size_t)(m0 + i * 16 + quad * 4 + rr) * ncol + col] = f2bf(v);
        }
      }
  }
}

// ---------------------------------------------------------------------------
// Layer-1 Q,K via bf16x3 MFMA: Q = Xh.Wh + Xh.Wl + Xl.Wh (fp32 accum,
// ~1.5e-5 rel err vs fp32 GEMM — mask-grade). Epilogue re-splits into
// bf16 hi/lo pairs exactly as the old fp32 kernel did.
// ---------------------------------------------------------------------------
__global__ __launch_bounds__(64) void gemm_qk_mfma_kernel(
    const unsigned short* __restrict__ Xh, const unsigned short* __restrict__ Xl,
    const unsigned short* __restrict__ WQh, const unsigned short* __restrict__ WQl,
    const unsigned short* __restrict__ WKh, const unsigned short* __restrict__ WKl,
    unsigned short* __restrict__ Qhi, unsigned short* __restrict__ Qlo,
    unsigned short* __restrict__ Khi, unsigned short* __restrict__ Klo)
{
  const int l = threadIdx.x;
  const int sel = blockIdx.y >> 7;
  const int m0 = (blockIdx.y & 127) * 64;
  const int n0 = blockIdx.x * 64;
  const int mr = l & 15, quad = l >> 4;
  const unsigned short* Bh = sel ? WKh : WQh;
  const unsigned short* Bl = sel ? WKl : WQl;
  unsigned short* Chi = sel ? Khi : Qhi;
  unsigned short* Clo = sel ? Klo : Qlo;

  f32x4 acc[4][4];
  const f32x4 zero = {0.f, 0.f, 0.f, 0.f};
#pragma unroll
  for (int i = 0; i < 4; ++i)
#pragma unroll
    for (int j = 0; j < 4; ++j) acc[i][j] = zero;

  const unsigned short* Ah = Xh + (size_t)(m0 + mr) * Dz + quad * 8;
  const unsigned short* Al = Xl + (size_t)(m0 + mr) * Dz + quad * 8;
  const unsigned short* Bhp = Bh + (size_t)(n0 + mr) * Dz + quad * 8;
  const unsigned short* Blp = Bl + (size_t)(n0 + mr) * Dz + quad * 8;

  for (int k0 = 0; k0 < Dz; k0 += 32) {
    short8 ah[4], al[4], bh[4], bl[4];
#pragma unroll
    for (int i = 0; i < 4; ++i) {
      ah[i] = *reinterpret_cast<const short8*>(Ah + (size_t)i * 16 * Dz + k0);
      al[i] = *reinterpret_cast<const short8*>(Al + (size_t)i * 16 * Dz + k0);
      bh[i] = *reinterpret_cast<const short8*>(Bhp + (size_t)i * 16 * Dz + k0);
      bl[i] = *reinterpret_cast<const short8*>(Blp + (size_t)i * 16 * Dz + k0);
    }
#pragma unroll
    for (int i = 0; i < 4; ++i)
#pragma unroll
      for (int j = 0; j < 4; ++j) {
        acc[i][j] = __builtin_amdgcn_mfma_f32_16x16x32_bf16(al[i], bh[j], acc[i][j], 0, 0, 0);
        acc[i][j] = __builtin_amdgcn_mfma_f32_16x16x32_bf16(ah[i], bl[j], acc[i][j], 0, 0, 0);
        acc[i][j] = __builtin_amdgcn_mfma_f32_16x16x32_bf16(ah[i], bh[j], acc[i][j], 0, 0, 0);
      }
  }

#pragma unroll
  for (int i = 0; i < 4; ++i)
#pragma unroll
    for (int j = 0; j < 4; ++j) {
      const int col = n0 + j * 16 + mr;
#pragma unroll
      for (int rr = 0; rr < 4; ++rr) {
        const size_t row = (size_t)(m0 + i * 16 + quad * 4 + rr);
        float v = acc[i][j][rr];
        unsigned short hv = f2bf(v);
        Chi[row * Dz + col] = hv;
        Clo[row * Dz + col] = f2bf(v - bf2f(hv));
      }
    }
}

// ---------------------------------------------------------------------------
// Layer-1 z pass, CHEAP: plain-bf16 QK^T. XCD-swizzled decode.
// ---------------------------------------------------------------------------
__global__ __launch_bounds__(256) void attn_z_kernel(
    const unsigned short* __restrict__ Qh, const unsigned short* __restrict__ Kh,
    float* __restrict__ invzG)
{
  const int tid = threadIdx.x;
  const int lane = tid & 63, wave = tid >> 6;
  const int c = lane & 15, quad = lane >> 4;
  int b, h, qt;
  attn_decode(blockIdx.x, b, h, qt);
  const size_t bT = (size_t)b * Tz;
  const int qrow = qt * 64 + wave * 16;
  const int hoff = h * DHz;

  const size_t qbase = (bT + qrow + c) * Dz + hoff + quad * 8;
  short8 q0 = *reinterpret_cast<const short8*>(Qh + qbase);
  short8 q1 = *reinterpret_cast<const short8*>(Qh + qbase + 32);

  const f32x4 zf = {0.f, 0.f, 0.f, 0.f};
  float z[4] = {0.f, 0.f, 0.f, 0.f};

  for (int t = 0; t < 16; ++t) {
    const int k0 = t * 64;
#pragma unroll
    for (int sub = 0; sub < 4; ++sub) {
      const size_t kb = (bT + k0 + sub * 16 + c) * Dz + hoff + quad * 8;
      short8 kh0 = *reinterpret_cast<const short8*>(Kh + kb);
      short8 kh1 = *reinterpret_cast<const short8*>(Kh + kb + 32);
      f32x4 aA = zf, aB = zf;
      aA = __builtin_amdgcn_mfma_f32_16x16x32_bf16(q0, kh0, aA, 0, 0, 0);
      aB = __builtin_amdgcn_mfma_f32_16x16x32_bf16(q1, kh1, aB, 0, 0, 0);
#pragma unroll
      for (int rr = 0; rr < 4; ++rr) z[rr] += __expf((aA[rr] + aB[rr]) * 0.125f);
    }
  }
#pragma unroll
  for (int w = 1; w < 16; w <<= 1) {
#pragma unroll
    for (int rr = 0; rr < 4; ++rr) z[rr] += __shfl_xor(z[rr], w);
  }
  if (c == 0) {
#pragma unroll
    for (int rr = 0; rr < 4; ++rr)
      invzG[(size_t)(b * Hz + h) * Tz + qrow + quad * 4 + rr] = 1.f / z[rr];
  }
}

// ---------------------------------------------------------------------------
// Layer-1 ctx, K-SPLIT x2 for occupancy (32 waves/CU): each block handles
// half the key range (8 k-tiles). Colsum partials per key are computed by
// exactly one block with the identical wave/quad/shfl order as before and
// land in the same PART slot -> CS1 bits unchanged. PV partials are written
// fp32 to O0/O1 and combined (fixed 2-addend order) by ctx_combine.
// ---------------------------------------------------------------------------
__global__ __launch_bounds__(256) void attn_ctx_kernel(
    const unsigned short* __restrict__ Qh, const unsigned short* __restrict__ Ql,
    const unsigned short* __restrict__ Kh, const unsigned short* __restrict__ Kl,
    const unsigned short* __restrict__ Vt, const float* __restrict__ invzG,
    float* __restrict__ O0, float* __restrict__ O1, float* __restrict__ part)
{
  __shared__ unsigned short Pld[64][76];
  __shared__ float CSP[4][512];  // per-wave colsum partials (half key range)
  const int tid = threadIdx.x;
  const int lane = tid & 63, wave = tid >> 6;
  const int c = lane & 15, quad = lane >> 4;
  // decode: 2048 blocks = 8 xcd x (2 khalf x 16 qt x 8 bhi)
  const int xcd = blockIdx.x & 7;
  const int j = blockIdx.x >> 3;
  const int kh = j & 1;
  const int qt = (j >> 1) & 15;
  const int bhi = j >> 5;
  const int b = bhi, h = xcd;
  const size_t bT = (size_t)b * Tz;
  const int qrow = qt * 64 + wave * 16;
  const int hoff = h * DHz;
  const int lidx = b * 128 + h * 16 + qt;  // logical PART slot

  const size_t qbase = (bT + qrow + c) * Dz + hoff + quad * 8;
  short8 q0h = *reinterpret_cast<const short8*>(Qh + qbase);
  short8 q1h = *reinterpret_cast<const short8*>(Qh + qbase + 32);
  short8 q0l = *reinterpret_cast<const short8*>(Ql + qbase);
  short8 q1l = *reinterpret_cast<const short8*>(Ql + qbase + 32);

  float invz[4];
#pragma unroll
  for (int rr = 0; rr < 4; ++rr)
    invz[rr] = invzG[(size_t)(b * Hz + h) * Tz + qrow + quad * 4 + rr];

  const f32x4 zf = {0.f, 0.f, 0.f, 0.f};
  f32x4 ot[4] = {zf, zf, zf, zf};

  const int tbeg = kh * 8;
  for (int t = tbeg; t < tbeg + 8; ++t) {
    const int k0 = t * 64;
#pragma unroll
    for (int sub = 0; sub < 4; ++sub) {
      const size_t kb = (bT + k0 + sub * 16 + c) * Dz + hoff + quad * 8;
      short8 kh0 = *reinterpret_cast<const short8*>(Kh + kb);
      short8 kh1 = *reinterpret_cast<const short8*>(Kh + kb + 32);
      short8 kl0 = *reinterpret_cast<const short8*>(Kl + kb);
      short8 kl1 = *reinterpret_cast<const short8*>(Kl + kb + 32);
      f32x4 aA = zf, aB = zf;  // two independent chains (depth 3 each)
      aA = __builtin_amdgcn_mfma_f32_16x16x32_bf16(q0h, kh0, aA, 0, 0, 0);
      aB = __builtin_amdgcn_mfma_f32_16x16x32_bf16(q1h, kh1, aB, 0, 0, 0);
      aA = __builtin_amdgcn_mfma_f32_16x16x32_bf16(q0h, kl0, aA, 0, 0, 0);
      aB = __builtin_amdgcn_mfma_f32_16x16x32_bf16(q1h, kl1, aB, 0, 0, 0);
      aA = __builtin_amdgcn_mfma_f32_16x16x32_bf16(q0l, kh0, aA, 0, 0, 0);
      aB = __builtin_amdgcn_mfma_f32_16x16x32_bf16(q1l, kh1, aB, 0, 0, 0);
      float p[4];
#pragma unroll
      for (int rr = 0; rr < 4; ++rr)
        p[rr] = __expf((aA[rr] + aB[rr]) * 0.125f) * invz[rr];
      float cs = p[0] + p[1] + p[2] + p[3];
      cs += __shfl_xor(cs, 16);
      cs += __shfl_xor(cs, 32);
      if (quad == 0) CSP[wave][(t & 7) * 64 + sub * 16 + c] = cs;
#pragma unroll
      for (int rr = 0; rr < 4; ++rr)
        Pld[(wave << 4) + quad * 4 + rr][sub * 16 + c] = f2bf(p[rr]);
    }
    union { short8 v; ushort4 hh[2]; } pb0, pb1;
    pb0.hh[0] = *reinterpret_cast<const ushort4*>(&Pld[(wave << 4) + c][quad * 8]);
    pb0.hh[1] = *reinterpret_cast<const ushort4*>(&Pld[(wave << 4) + c][quad * 8 + 4]);
    pb1.hh[0] = *reinterpret_cast<const ushort4*>(&Pld[(wave << 4) + c][32 + quad * 8]);
    pb1.hh[1] = *reinterpret_cast<const ushort4*>(&Pld[(wave << 4) + c][32 + quad * 8 + 4]);
#pragma unroll
    for (int ds = 0; ds < 4; ++ds) {
      const size_t va = ((size_t)((b * Hz + h) * DHz + ds * 16 + c)) * Tz + k0 + quad * 8;
      short8 v0 = *reinterpret_cast<const short8*>(Vt + va);
      short8 v1 = *reinterpret_cast<const short8*>(Vt + va + 32);
      ot[ds] = __builtin_amdgcn_mfma_f32_16x16x32_bf16(v0, pb0.v, ot[ds], 0, 0, 0);
      ot[ds] = __builtin_amdgcn_mfma_f32_16x16x32_bf16(v1, pb1.v, ot[ds], 0, 0, 0);
    }
  }

  float* Op = kh ? O1 : O0;
  const size_t cb = (bT + qrow + c) * Dz + hoff;
#pragma unroll
  for (int ds = 0; ds < 4; ++ds) {
    float4 pk;
    pk.x = ot[ds][0]; pk.y = ot[ds][1]; pk.z = ot[ds][2]; pk.w = ot[ds][3];
    *reinterpret_cast<float4*>(&Op[cb + ds * 16 + quad * 4]) = pk;
  }
  __syncthreads();
  // fixed-order combine + non-atomic block-partial write (deterministic)
  for (int i = tid; i < 512; i += 256) {
    float v = ((CSP[0][i] + CSP[1][i]) + CSP[2][i]) + CSP[3][i];
    part[(size_t)lidx * 1024 + kh * 512 + i] = v * (1.f / Hz);
  }
}

// ---------------------------------------------------------------------------
// ctx = bf16(O0 + O1): fixed 2-addend combine (deterministic).
// ---------------------------------------------------------------------------
__global__ __launch_bounds__(256) void ctx_combine_kernel(
    const float* __restrict__ O0, const float* __restrict__ O1,
    unsigned short* __restrict__ ctx)
{
  const size_t i = ((size_t)blockIdx.x * 256 + threadIdx.x) * 8;
  float4 a0 = *reinterpret_cast<const float4*>(&O0[i]);
  float4 a1 = *reinterpret_cast<const float4*>(&O0[i + 4]);
  float4 b0 = *reinterpret_cast<const float4*>(&O1[i]);
  float4 b1 = *reinterpret_cast<const float4*>(&O1[i + 4]);
  ushort4 o0, o1;
  o0.x = f2bf(a0.x + b0.x); o0.y = f2bf(a0.y + b0.y);
  o0.z = f2bf(a0.z + b0.z); o0.w = f2bf(a0.w + b0.w);
  o1.x = f2bf(a1.x + b1.x); o1.y = f2bf(a1.y + b1.y);
  o1.z = f2bf(a1.z + b1.z); o1.w = f2bf(a1.w + b1.w);
  *reinterpret_cast<ushort4*>(&ctx[i]) = o0;
  *reinterpret_cast<ushort4*>(&ctx[i + 4]) = o1;
}

// ---------------------------------------------------------------------------
// Deterministic colsum reduce: CS1[b,key] = sum over the 128 (h,qt) block
// partials in fixed ascending order. One thread per output.
// ---------------------------------------------------------------------------
__global__ __launch_bounds__(256) void colsum_reduce_kernel(
    const float* __restrict__ part, float* __restrict__ colsum)
{
  const int i = blockIdx.x * 256 + threadIdx.x;  // 0..8191
  const int b = i >> 10, k = i & 1023;
  const float* p = part + (size_t)(b * 128) * 1024 + k;
  float s = 0.f;
  for (int j = 0; j < 128; ++j) s += p[(size_t)j * 1024];
  colsum[i] = s;
}

// ---------------------------------------------------------------------------
// Layer-2 MFMA attention (masked), with k-tile range skipping. CS2 feeds only
// the continuous wl softmax -> atomics are fine here. XCD-swizzled decode.
// ---------------------------------------------------------------------------
__global__ __launch_bounds__(256) void attn_mfma2_kernel(
    const unsigned short* __restrict__ Qh, const unsigned short* __restrict__ Kh,
    const unsigned short* __restrict__ Vt, const int* __restrict__ ids,
    const int* __restrict__ wst,
    unsigned short* __restrict__ ctx, float* __restrict__ colsum)
{
  __shared__ unsigned short Pld[64][76];
  __shared__ float csb[1024];

  const int tid = threadIdx.x;
  const int lane = tid & 63, wave = tid >> 6;
  const int c = lane & 15, quad = lane >> 4;
  int b, h, qt;
  attn_decode(blockIdx.x, b, h, qt);
  const size_t bT = (size_t)b * Tz;
  const int qrow = qt * 64 + wave * 16;
  const int hoff = h * DHz;

  for (int i = tid; i < 1024; i += 256) csb[i] = 0.f;

  const int id_lo = ids[bT + qt * 64];
  const int id_hi = ids[bT + qt * 64 + 63];
  const int klo = wst[b * (Tz + 1) + id_lo];
  const int khi = wst[b * (Tz + 1) + id_hi + 1];
  const int t0 = klo >> 6, t1 = (khi - 1) >> 6;

  const size_t qbase = (bT + qrow + c) * Dz + hoff + quad * 8;
  short8 q0 = *reinterpret_cast<const short8*>(Qh + qbase);
  short8 q1 = *reinterpret_cast<const short8*>(Qh + qbase + 32);

  int qid[4];
#pragma unroll
  for (int rr = 0; rr < 4; ++rr) qid[rr] = ids[bT + qrow + quad * 4 + rr];
  __syncthreads();  // csb zeros visible before pass-2 atomics

  const f32x4 zf = {0.f, 0.f, 0.f, 0.f};

  // pass 1: z
  float z[4] = {0.f, 0.f, 0.f, 0.f};
  for (int t = t0; t <= t1; ++t) {
    const int k0 = t * 64;
#pragma unroll
    for (int sub = 0; sub < 4; ++sub) {
      const size_t kb = (bT + k0 + sub * 16 + c) * Dz + hoff + quad * 8;
      short8 kh0 = *reinterpret_cast<const short8*>(Kh + kb);
      short8 kh1 = *reinterpret_cast<const short8*>(Kh + kb + 32);
      f32x4 acc = zf;
      acc = __builtin_amdgcn_mfma_f32_16x16x32_bf16(q0, kh0, acc, 0, 0, 0);
      acc = __builtin_amdgcn_mfma_f32_16x16x32_bf16(q1, kh1, acc, 0, 0, 0);
      int kidv = ids[bT + k0 + sub * 16 + c];
#pragma unroll
      for (int rr = 0; rr < 4; ++rr) {
        float e = __expf(acc[rr] * 0.125f);
        if (qid[rr] != kidv) e = 0.f;
        z[rr] += e;
      }
    }
  }
#pragma unroll
  for (int w = 1; w < 16; w <<= 1) {
#pragma unroll
    for (int rr = 0; rr < 4; ++rr) z[rr] += __shfl_xor(z[rr], w);
  }
  float invz[4];
#pragma unroll
  for (int rr = 0; rr < 4; ++rr) invz[rr] = 1.f / z[rr];

  // pass 2: P, colsum, PV
  f32x4 ot[4] = {zf, zf, zf, zf};
  for (int t = t0; t <= t1; ++t) {
    const int k0 = t * 64;
#pragma unroll
    for (int sub = 0; sub < 4; ++sub) {
      const size_t kb = (bT + k0 + sub * 16 + c) * Dz + hoff + quad * 8;
      short8 kh0 = *reinterpret_cast<const short8*>(Kh + kb);
      short8 kh1 = *reinterpret_cast<const short8*>(Kh + kb + 32);
      f32x4 acc = zf;
      acc = __builtin_amdgcn_mfma_f32_16x16x32_bf16(q0, kh0, acc, 0, 0, 0);
      acc = __builtin_amdgcn_mfma_f32_16x16x32_bf16(q1, kh1, acc, 0, 0, 0);
      int kidv = ids[bT + k0 + sub * 16 + c];
      float p[4];
#pragma unroll
      for (int rr = 0; rr < 4; ++rr) {
        float e = __expf(acc[rr] * 0.125f);
        if (qid[rr] != kidv) e = 0.f;
        p[rr] = e * invz[rr];
      }
      float cs = p[0] + p[1] + p[2] + p[3];
      cs += __shfl_xor(cs, 16);
      cs += __shfl_xor(cs, 32);
      if (quad == 0) atomicAdd(&csb[k0 + sub * 16 + c], cs);
#pragma unroll
      for (int rr = 0; rr < 4; ++rr)
        Pld[(wave << 4) + quad * 4 + rr][sub * 16 + c] = f2bf(p[rr]);
    }
    union { short8 v; ushort4 hh[2]; } pb0, pb1;
    pb0.hh[0] = *reinterpret_cast<const ushort4*>(&Pld[(wave << 4) + c][quad * 8]);
    pb0.hh[1] = *reinterpret_cast<const ushort4*>(&Pld[(wave << 4) + c][quad * 8 + 4]);
    pb1.hh[0] = *reinterpret_cast<const ushort4*>(&Pld[(wave << 4) + c][32 + quad * 8]);
    pb1.hh[1] = *reinterpret_cast<const ushort4*>(&Pld[(wave << 4) + c][32 + quad * 8 + 4]);
#pragma unroll
    for (int ds = 0; ds < 4; ++ds) {
      const size_t va = ((size_t)((b * Hz + h) * DHz + ds * 16 + c)) * Tz + k0 + quad * 8;
      short8 v0 = *reinterpret_cast<const short8*>(Vt + va);
      short8 v1 = *reinterpret_cast<const short8*>(Vt + va + 32);
      ot[ds] = __builtin_amdgcn_mfma_f32_16x16x32_bf16(v0, pb0.v, ot[ds], 0, 0, 0);
      ot[ds] = __builtin_amdgcn_mfma_f32_16x16x32_bf16(v1, pb1.v, ot[ds], 0, 0, 0);
    }
  }

  const size_t cb = (bT + qrow + c) * Dz + hoff;
#pragma unroll
  for (int ds = 0; ds < 4; ++ds) {
    ushort4 pk;
    pk.x = f2bf(ot[ds][0]); pk.y = f2bf(ot[ds][1]);
    pk.z = f2bf(ot[ds][2]); pk.w = f2bf(ot[ds][3]);
    *reinterpret_cast<ushort4*>(&ctx[cb + ds * 16 + quad * 4]) = pk;
  }
  __syncthreads();
  for (int i = tid; i < 1024; i += 256)
    atomicAdd(&colsum[bT + i], csb[i] * (1.f / Hz));
}

// ---------------------------------------------------------------------------
// out = LayerNorm(resid + delta). resid fp32 (residf) if non-null else bf16.
// ---------------------------------------------------------------------------
__global__ __launch_bounds__(256) void ln_kernel(const float* __restrict__ residf,
    const unsigned short* __restrict__ residbf, const float* __restrict__ delta,
    float* __restrict__ outf, unsigned short* __restrict__ outbf)
{
  const size_t base = (size_t)blockIdx.x * Dz;
  const int tid = threadIdx.x;
  float r0, r1;
  if (residf) {
    r0 = residf[base + tid]; r1 = residf[base + tid + 256];
  } else {
    r0 = bf2f(residbf[base + tid]); r1 = bf2f(residbf[base + tid + 256]);
  }
  float x0 = r0 + delta[base + tid];
  float x1 = r1 + delta[base + tid + 256];
  __shared__ float red[4];
  float s = x0 + x1;
#pragma unroll
  for (int off = 32; off; off >>= 1) s += __shfl_down(s, off);
  if ((tid & 63) == 0) red[tid >> 6] = s;
  __syncthreads();
  const float mean = (red[0] + red[1] + red[2] + red[3]) * (1.f / Dz);
  __syncthreads();
  float d0 = x0 - mean, d1 = x1 - mean;
  float v = d0 * d0 + d1 * d1;
#pragma unroll
  for (int off = 32; off; off >>= 1) v += __shfl_down(v, off);
  if ((tid & 63) == 0) red[tid >> 6] = v;
  __syncthreads();
  const float var = (red[0] + red[1] + red[2] + red[3]) * (1.f / Dz);
  const float rstd = rsqrtf(var + 1e-5f);
  float y0 = d0 * rstd, y1 = d1 * rstd;
  if (outf) {
    outf[base + tid] = y0;
    outf[base + tid + 256] = y1;
  }
  outbf[base + tid] = f2bf(y0);
  outbf[base + tid + 256] = f2bf(y1);
}

// ---------------------------------------------------------------------------
// Per batch: min-max normalize colsum, threshold 0.5, run-length window scan.
// ---------------------------------------------------------------------------
__global__ __launch_bounds__(256) void window_ids_kernel(const float* __restrict__ cs,
    int* __restrict__ ids, int* __restrict__ wst, int* __restrict__ nwin)
{
  const int b = blockIdx.x, tid = threadIdx.x;
  __shared__ float vals[Tz];
  __shared__ unsigned char wb[Tz];
  __shared__ int sids[Tz];
  __shared__ float rmin[4], rmax[4];
  float mn = INFINITY, mx = -INFINITY;
  for (int t = tid; t < Tz; t += 256) {
    float v = cs[b * Tz + t];
    vals[t] = v;
    mn = fminf(mn, v); mx = fmaxf(mx, v);
  }
#pragma unroll
  for (int off = 32; off; off >>= 1) {
    mn = fminf(mn, __shfl_down(mn, off));
    mx = fmaxf(mx, __shfl_down(mx, off));
  }
  if ((tid & 63) == 0) { rmin[tid >> 6] = mn; rmax[tid >> 6] = mx; }
  __syncthreads();
  mn = fminf(fminf(rmin[0], rmin[1]), fminf(rmin[2], rmin[3]));
  mx = fmaxf(fmaxf(rmax[0], rmax[1]), fmaxf(rmax[2], rmax[3]));
  const float inv = 1.f / (mx - mn + 1e-8f);
  for (int t = tid; t < Tz; t += 256) wb[t] = (((vals[t] - mn) * inv) >= 0.5f) ? 1 : 0;
  __syncthreads();
  if (tid == 0) {
    int cur = wb[0], start = 0, wid = 0;
    sids[0] = 0;
    wst[b * (Tz + 1)] = 0;
    for (int t = 1; t < Tz; ++t) {
      int wt = wb[t];
      if (wt != cur) {
        cur = wt;
        if (start + 1 != t) {
          start = t;
          ++wid;
          wst[b * (Tz + 1) + wid] = t;
        }
      }
      sids[t] = wid;
    }
    nwin[b] = wid + 1;
    wst[b * (Tz + 1) + wid + 1] = Tz;
  }
  __syncthreads();
  for (int t = tid; t < Tz; t += 256) ids[b * Tz + t] = sids[t];
}

// ---------------------------------------------------------------------------
// wl[b,:] = softmax over keys of layer-2 colsum.
// ---------------------------------------------------------------------------
__global__ __launch_bounds__(256) void wl_softmax_kernel(const float* __restrict__ cs,
                                                         float* __restrict__ wl)
{
  const int b = blockIdx.x, tid = threadIdx.x;
  __shared__ float vals[Tz];
  __shared__ float red[4];
  float mx = -INFINITY;
  for (int t = tid; t < Tz; t += 256) {
    float v = cs[b * Tz + t];
    vals[t] = v;
    mx = fmaxf(mx, v);
  }
#pragma unroll
  for (int off = 32; off; off >>= 1) mx = fmaxf(mx, __shfl_down(mx, off));
  if ((tid & 63) == 0) red[tid >> 6] = mx;
  __syncthreads();
  mx = fmaxf(fmaxf(red[0], red[1]), fmaxf(red[2], red[3]));
  __syncthreads();
  float se = 0.f;
  for (int t = tid; t < Tz; t += 256) {
    float e = expf(vals[t] - mx);
    vals[t] = e;
    se += e;
  }
#pragma unroll
  for (int off = 32; off; off >>= 1) se += __shfl_down(se, off);
  if ((tid & 63) == 0) red[tid >> 6] = se;
  __syncthreads();
  const float inv = 1.f / (red[0] + red[1] + red[2] + red[3]);
  for (int t = tid; t < Tz; t += 256) wl[b * Tz + t] = vals[t] * inv;
}

// ---------------------------------------------------------------------------
// Fused outputs: word_tokens (blocks 0..8191), winmap (8192..16383),
// copy_x (16384..20479).
// ---------------------------------------------------------------------------
__global__ __launch_bounds__(256) void outputs_kernel(
    const unsigned short* __restrict__ outl, const float* __restrict__ wl,
    const int* __restrict__ wst, const int* __restrict__ nwin,
    const int* __restrict__ ids, const float* __restrict__ x,
    float* __restrict__ out, float* __restrict__ out2)
{
  const int bid = blockIdx.x;
  const int tid = threadIdx.x;
  if (bid < 8192) {  // word_tokens
    const int w = bid & (Tz - 1);
    const int b = bid >> 10;
    float a0 = 0.f, a1 = 0.f;
    if (w < nwin[b]) {
      const int s = wst[b * (Tz + 1) + w], e = wst[b * (Tz + 1) + w + 1];
      for (int t = s; t < e; ++t) {
        const float sc = wl[b * Tz + t];
        const unsigned short* p = &outl[((size_t)(b * Tz + t)) * Dz];
        a0 += bf2f(p[tid]) * sc;
        a1 += bf2f(p[tid + 256]) * sc;
      }
    }
    float* o = &out[((size_t)(b * 2 * Tz + w)) * Dz];
    o[tid] = a0;
    o[tid + 256] = a1;
  } else if (bid < 16384) {  // winmap
    const int lb = bid - 8192;
    const int w = lb & (Tz - 1);
    const int b = lb >> 10;
    const int j = tid * 4;
    int4 id4 = *reinterpret_cast<const int4*>(&ids[b * Tz + j]);
    float4 v;
    v.x = (id4.x == w) ? 1.f : 0.f;
    v.y = (id4.y == w) ? 1.f : 0.f;
    v.z = (id4.z == w) ? 1.f : 0.f;
    v.w = (id4.w == w) ? 1.f : 0.f;
    *reinterpret_cast<float4*>(&out2[((size_t)(b * Tz + w)) * Tz + j]) = v;
  } else {  // copy_x
    size_t i = (size_t)(bid - 16384) * 256 + tid;
    size_t idx = i * 4;
    size_t rowi = idx >> 9;
    size_t d = idx & 511;
    size_t b = rowi >> 10, t = rowi & 1023;
    float4 v = *reinterpret_cast<const float4*>(&x[idx]);
    *reinterpret_cast<float4*>(&out[(((b * 2 * Tz) + Tz + t) << 9) + d]) = v;
  }
}

// ---------------------------------------------------------------------------
// Orchestration: 23 dispatches. gemm_qk -> MFMA bf16x3; attn_ctx K-split x2
// (32 waves/CU) + deterministic fp32 combine.
// ---------------------------------------------------------------------------
extern "C" void kernel_launch(void* const* d_in, const int* in_sizes, int n_in,
                              void* d_out, int out_size, void* d_ws, size_t ws_size,
                              hipStream_t stream)
{
  (void)in_sizes; (void)n_in; (void)out_size; (void)ws_size;
  const float* x     = (const float*)d_in[0];
  const float* vqkv  = (const float*)d_in[1];
  const float* voutw = (const float*)d_in[2];
  const float* vw1   = (const float*)d_in[3];
  const float* vw2   = (const float*)d_in[4];
  const float* lqkv  = (const float*)d_in[5];
  const float* loutw = (const float*)d_in[6];
  const float* lw1   = (const float*)d_in[7];
  const float* lw2   = (const float*)d_in[8];
  float* out = (float*)d_out;
  float* ws  = (float*)d_ws;

  unsigned short* QLbf = (unsigned short*)(ws + 0);        // bf16 Q lo (L1)
  unsigned short* KLbf = (unsigned short*)(ws + 2097152);  // bf16 K lo (L1)
  float* PROJ = ws + 0;         // written after attn_ctx (QL/KL dead)
  float* O0   = ws + 4194304;   // ctx fp32 partial (khalf=0), aliases Y1
  float* Y1   = ws + 4194304;   // written by LN after ctx_combine (O0 dead)
  unsigned short* QHbf = (unsigned short*)(ws + 8388608);   // bf16 Q hi (L1+L2)
  unsigned short* KHbf = (unsigned short*)(ws + 10485760);  // bf16 K hi (L1+L2)
  unsigned short* VT   = (unsigned short*)(ws + 12582912);
  unsigned short* SLOT1 = (unsigned short*)(ws + 14680064); // attn ctx bf16
  unsigned short* SLOT2 = (unsigned short*)(ws + 16777216); // LN bf16 out
  unsigned short* HIDbf = (unsigned short*)(ws + 18874368); // FFN hidden
  unsigned short* XBF   = (unsigned short*)(ws + 18874368); // x hi bf16 (pre-FFN)
  float* PART = ws + 18874368;  // colsum block partials (1024x1024); written
                                // by attn_ctx after XBF/XLO dead, dead by FFN1
  unsigned short* XLO = (unsigned short*)(ws + 20971520);   // x lo bf16
  float* O1   = ws + 20971520 + 2097152;  // ctx fp32 partial (khalf=1); written
                                // after XLO dead, dead before FFN1 (@23068672)
  // bf16 transposed weights (WLQ0..2 contiguous -> merged [1536,512] matrix)
  unsigned short* WVQV = (unsigned short*)(ws + 27262976);
  unsigned short* WVO  = (unsigned short*)(ws + 27394048);
  unsigned short* WV1  = (unsigned short*)(ws + 27525120);
  unsigned short* WV2  = (unsigned short*)(ws + 28049408);
  unsigned short* WLQ0 = (unsigned short*)(ws + 28573696);
  unsigned short* WLQ1 = (unsigned short*)(ws + 28704768);
  unsigned short* WLQ2 = (unsigned short*)(ws + 28835840);
  unsigned short* WLO  = (unsigned short*)(ws + 28966912);
  unsigned short* WL1  = (unsigned short*)(ws + 29097984);
  unsigned short* WL2  = (unsigned short*)(ws + 29622272);
  // small buffers
  float* CS1   = ws + 30146560;
  float* CS2   = ws + 30154752;
  float* WLs   = ws + 30162944;
  int*   IDS   = (int*)(ws + 30171136);
  int*   WST   = (int*)(ws + 30179328);
  int*   NWIN  = (int*)(ws + 30187776);
  float* INVZ  = ws + 30195968;  // (B*H*T) = 65536 floats
  // layer-1 Q/K weights, bf16 transposed hi/lo (512x512 each = 131072 floats)
  unsigned short* WQH = (unsigned short*)(ws + 30261504);
  unsigned short* WQL = (unsigned short*)(ws + 30392576);
  unsigned short* WKH = (unsigned short*)(ws + 30523648);
  unsigned short* WKL = (unsigned short*)(ws + 30654720);

  dim3 blk(256);

  // ---- fused prep: 12 wconv + zero + fconv(hi/lo) ----
  PrepArgs P;
  auto setw = [&](int i, const float* s, unsigned short* d, unsigned short* dl,
                  int K, int N, int b0) {
    P.d[i].src = s; P.d[i].dst = d; P.d[i].dstlo = dl;
    P.d[i].K = K; P.d[i].N = N; P.d[i].blk0 = b0;
  };
  int b0 = 0;
  setw(0, vqkv + 2 * Dz * Dz, WVQV, nullptr, Dz, Dz, b0); b0 += 256;
  setw(1, voutw, WVO, nullptr, Dz, Dz, b0); b0 += 256;
  setw(2, vw1, WV1, nullptr, Dz, FFz, b0); b0 += 1024;
  setw(3, vw2, WV2, nullptr, FFz, Dz, b0); b0 += 1024;
  setw(4, lqkv + 0 * Dz * Dz, WLQ0, nullptr, Dz, Dz, b0); b0 += 256;
  setw(5, lqkv + 1 * Dz * Dz, WLQ1, nullptr, Dz, Dz, b0); b0 += 256;
  setw(6, lqkv + 2 * Dz * Dz, WLQ2, nullptr, Dz, Dz, b0); b0 += 256;
  setw(7, loutw, WLO, nullptr, Dz, Dz, b0); b0 += 256;
  setw(8, lw1, WL1, nullptr, Dz, FFz, b0); b0 += 1024;
  setw(9, lw2, WL2, nullptr, FFz, Dz, b0); b0 += 1024;
  setw(10, vqkv + 0 * Dz * Dz, WQH, WQL, Dz, Dz, b0); b0 += 256;
  setw(11, vqkv + 1 * Dz * Dz, WKH, WKL, Dz, Dz, b0); b0 += 256;
  P.nwc = b0;  // 6144
  prep_kernel<<<dim3(P.nwc + 64 + 4096), blk, 0, stream>>>(P, x, XBF, XLO, CS1);

  auto mgemm = [&](const unsigned short* A, const unsigned short* BT, void* p1,
                   void* p2, void* p3, int K, int N, int mode) {
    mfma_gemm_kernel<<<dim3(N / 64, Mz / 64), dim3(64), 0, stream>>>(
        A, BT, p1, p2, p3, K, N, mode);
  };

  // ---------------- layer 1 (vanilla) ----------------
  gemm_qk_mfma_kernel<<<dim3(8, 256), dim3(64), 0, stream>>>(
      XBF, XLO, WQH, WQL, WKH, WKL, QHbf, QLbf, KHbf, KLbf);
  attn_z_kernel<<<dim3(Bz * Hz * 16), blk, 0, stream>>>(QHbf, KHbf, INVZ);
  mgemm(XBF, WVQV, VT, nullptr, nullptr, Dz, Dz, 4);        // V -> V^T (XBF/XLO dead)
  attn_ctx_kernel<<<dim3(2 * Bz * Hz * 16), blk, 0, stream>>>(
      QHbf, QLbf, KHbf, KLbf, VT, INVZ, O0, O1, PART);
  ctx_combine_kernel<<<dim3(2048), blk, 0, stream>>>(O0, O1, SLOT1);
  colsum_reduce_kernel<<<dim3(32), blk, 0, stream>>>(PART, CS1);
  window_ids_kernel<<<dim3(Bz), blk, 0, stream>>>(CS1, IDS, WST, NWIN);
  mgemm(SLOT1, WVO, PROJ, nullptr, nullptr, Dz, Dz, 0);     // proj (QL/KL dead)
  ln_kernel<<<dim3(Mz), blk, 0, stream>>>(x, nullptr, PROJ, Y1, SLOT2);  // O0 dead
  mgemm(SLOT2, WV1, HIDbf, nullptr, nullptr, Dz, FFz, 2);   // FFN1 (PART/O1 dead)
  mgemm(HIDbf, WV2, PROJ, nullptr, nullptr, FFz, Dz, 0);    // FFN2
  ln_kernel<<<dim3(Mz), blk, 0, stream>>>(Y1, nullptr, PROJ, nullptr, SLOT2);

  // ---------------- layer 2 (block-diagonal window mask) ----------------
  mgemm(SLOT2, WLQ0, QHbf, KHbf, VT, Dz, 3 * Dz, 5);        // merged QKV
  attn_mfma2_kernel<<<dim3(Bz * Hz * 16), blk, 0, stream>>>(
      QHbf, KHbf, VT, IDS, WST, SLOT1, CS2);
  mgemm(SLOT1, WLO, PROJ, nullptr, nullptr, Dz, Dz, 0);
  ln_kernel<<<dim3(Mz), blk, 0, stream>>>(nullptr, SLOT2, PROJ, Y1, SLOT2);
  mgemm(SLOT2, WL1, HIDbf, nullptr, nullptr, Dz, FFz, 2);
  mgemm(HIDbf, WL2, PROJ, nullptr, nullptr, FFz, Dz, 0);
  ln_kernel<<<dim3(Mz), blk, 0, stream>>>(Y1, nullptr, PROJ, nullptr, SLOT2);

  // ---------------- pooling + outputs ----------------
  wl_softmax_kernel<<<dim3(Bz), blk, 0, stream>>>(CS2, WLs);
  outputs_kernel<<<dim3(20480), blk, 0, stream>>>(SLOT2, WLs, WST, NWIN, IDS, x,
                                                  out, out + (size_t)Bz * 2 * Tz * Dz);
}

// Round 6
// 819.664 us; speedup vs baseline: 1.3247x; 1.1568x over previous
//
#include <hip/hip_runtime.h>
#include <math.h>

// Problem constants (fixed by setup_inputs)
#define Bz 8
#define Tz 1024
#define Dz 512
#define FFz 2048
#define Hz 8
#define DHz 64
#define Mz (Bz * Tz)  // 8192 rows

typedef __attribute__((ext_vector_type(8))) short short8;   // 8 bf16 (4 VGPRs)
typedef __attribute__((ext_vector_type(4))) float f32x4;    // MFMA accumulator

__device__ inline unsigned short f2bf(float f) {  // RNE fp32 -> bf16
  unsigned u = __builtin_bit_cast(unsigned, f);
  return (unsigned short)((u + 0x7FFFu + ((u >> 16) & 1u)) >> 16);
}
__device__ inline float bf2f(unsigned short h) {
  unsigned u = (unsigned)h << 16;
  return __builtin_bit_cast(float, u);
}

// XCD-aware decode for the 1024-block attention grids (8 XCDs round-robin by
// blockIdx). g = xcd + 8*(qt + 16*bhi), bh = bhi*8 + xcd.
__device__ inline void attn_decode(int g, int& b, int& h, int& qt) {
  const int xcd = g & 7;
  const int j = g >> 3;
  qt = j & 15;
  const int bh = ((j >> 4) << 3) | xcd;
  b = bh >> 3;
  h = bh & 7;
}

// Swizzled byte offset inside a [64 rows x 128B] LDS tile: 16B slot XOR'd by
// row&7 -> every fragment read/write lands at the 8-words/bank LDS floor.
__device__ inline int swz(int row, int slotByte) {
  return row * 128 + (slotByte ^ ((row & 7) << 4));
}

// ---------------------------------------------------------------------------
// Fused prep: 12 weight convert+transposes (fp32 [K,N] -> bf16 [N,K], with
// optional lo-residual output) + colsum zero-fill + x -> bf16 hi/lo.
// ---------------------------------------------------------------------------
struct WDesc { const float* src; unsigned short* dst; unsigned short* dstlo;
               int K; int N; int blk0; };
struct PrepArgs { WDesc d[12]; int nwc; };

__global__ __launch_bounds__(256) void prep_kernel(PrepArgs P,
    const float* __restrict__ x, unsigned short* __restrict__ xbf,
    unsigned short* __restrict__ xlo, float* __restrict__ csz)
{
  const int bid = blockIdx.x;
  const int tid = threadIdx.x;
  if (bid < P.nwc) {  // wconv slice
    int i = 0;
    while (i < 11 && bid >= P.d[i + 1].blk0) ++i;
    const WDesc w = P.d[i];
    const int lb = bid - w.blk0;
    const int nbn = w.N / 32;
    const int bn = (lb % nbn) * 32, bk = (lb / nbn) * 32;
    __shared__ float t[32][33];
    const int tx = tid & 31, ty = tid >> 5;
#pragma unroll
    for (int r = 0; r < 32; r += 8)
      t[ty + r][tx] = w.src[(size_t)(bk + ty + r) * w.N + bn + tx];
    __syncthreads();
#pragma unroll
    for (int r = 0; r < 32; r += 8) {
      float v = t[tx][ty + r];
      unsigned short hv = f2bf(v);
      w.dst[(size_t)(bn + ty + r) * w.K + bk + tx] = hv;
      if (w.dstlo)
        w.dstlo[(size_t)(bn + ty + r) * w.K + bk + tx] = f2bf(v - bf2f(hv));
    }
  } else if (bid < P.nwc + 64) {  // zero slice (CS1+CS2 = 16384 floats)
    int idx = (bid - P.nwc) * 256 + tid;
    csz[idx] = 0.f;
  } else {  // fconv slice: 4096 blocks, 4 floats/thread -> hi + lo
    int i = (bid - P.nwc - 64) * 256 + tid;
    float4 v = *reinterpret_cast<const float4*>(&x[(size_t)i * 4]);
    ushort4 o, ol;
    o.x = f2bf(v.x); o.y = f2bf(v.y); o.z = f2bf(v.z); o.w = f2bf(v.w);
    ol.x = f2bf(v.x - bf2f(o.x)); ol.y = f2bf(v.y - bf2f(o.y));
    ol.z = f2bf(v.z - bf2f(o.z)); ol.w = f2bf(v.w - bf2f(o.w));
    *reinterpret_cast<ushort4*>(&xbf[(size_t)i * 4]) = o;
    *reinterpret_cast<ushort4*>(&xlo[(size_t)i * 4]) = ol;
  }
}

// ---------------------------------------------------------------------------
// bf16 MFMA GEMM, 64x64 tile per wave, direct-from-global fragments.
// Epilogue modes: 0 fp32 C | 1 bf16 C | 2 bf16 C + ReLU
//   | 4 V^T layout | 5 merged QKV (N=1536).
// ---------------------------------------------------------------------------
__global__ __launch_bounds__(64) void mfma_gemm_kernel(
    const unsigned short* __restrict__ A, const unsigned short* __restrict__ BT,
    void* __restrict__ p1, void* __restrict__ p2, void* __restrict__ p3,
    int K, int N, int mode)
{
  const int l = threadIdx.x;
  const int m0 = blockIdx.y * 64;
  const int n0 = blockIdx.x * 64;
  const int mr = l & 15, quad = l >> 4;

  f32x4 acc[4][4];
  const f32x4 zero = {0.f, 0.f, 0.f, 0.f};
#pragma unroll
  for (int i = 0; i < 4; ++i)
#pragma unroll
    for (int j = 0; j < 4; ++j) acc[i][j] = zero;

  const unsigned short* Ap = A + (size_t)(m0 + mr) * K + quad * 8;
  const unsigned short* Bp = BT + (size_t)(n0 + mr) * K + quad * 8;

  short8 a[4], b[4], an[4], bn[4];
#pragma unroll
  for (int i = 0; i < 4; ++i) {
    a[i] = *reinterpret_cast<const short8*>(Ap + (size_t)i * 16 * K);
    b[i] = *reinterpret_cast<const short8*>(Bp + (size_t)i * 16 * K);
  }
  for (int k0 = 0; k0 < K; k0 += 32) {
    if (k0 + 32 < K) {
#pragma unroll
      for (int i = 0; i < 4; ++i) {
        an[i] = *reinterpret_cast<const short8*>(Ap + (size_t)i * 16 * K + k0 + 32);
        bn[i] = *reinterpret_cast<const short8*>(Bp + (size_t)i * 16 * K + k0 + 32);
      }
    }
#pragma unroll
    for (int i = 0; i < 4; ++i)
#pragma unroll
      for (int j = 0; j < 4; ++j)
        acc[i][j] = __builtin_amdgcn_mfma_f32_16x16x32_bf16(a[i], b[j], acc[i][j], 0, 0, 0);
#pragma unroll
    for (int i = 0; i < 4; ++i) { a[i] = an[i]; b[i] = bn[i]; }
  }

  // C/D layout: col = lane&15, row = quad*4 + reg   [measured: m89/m91]
  int emode = mode;
  unsigned short* Cbf = (unsigned short*)p1;
  unsigned short* Vt  = (unsigned short*)p1;
  int ncol = N, coff = 0;
  if (mode == 5) {  // uniform per block: n0 is a multiple of 64
    if (n0 < 512)       { emode = 1; Cbf = (unsigned short*)p1; ncol = 512; coff = 0; }
    else if (n0 < 1024) { emode = 1; Cbf = (unsigned short*)p2; ncol = 512; coff = 512; }
    else                { emode = 4; Vt = (unsigned short*)p3; coff = 1024; }
  }
  if (emode == 4) {  // V^T: 4 consecutive tokens same feature -> ushort4
#pragma unroll
    for (int i = 0; i < 4; ++i)
#pragma unroll
      for (int j = 0; j < 4; ++j) {
        const int col = n0 - coff + j * 16 + mr;  // feature: h = col>>6, d = col&63
        const int row0 = m0 + i * 16 + quad * 4;  // token base (4 consecutive)
        const int bb = row0 >> 10, t0 = row0 & 1023;
        ushort4 pk;
        pk.x = f2bf(acc[i][j][0]); pk.y = f2bf(acc[i][j][1]);
        pk.z = f2bf(acc[i][j][2]); pk.w = f2bf(acc[i][j][3]);
        *reinterpret_cast<ushort4*>(
            &Vt[((size_t)((bb * Hz + (col >> 6)) * DHz + (col & 63))) * Tz + t0]) = pk;
      }
  } else if (emode == 0) {
    float* Cf = (float*)p1;
#pragma unroll
    for (int i = 0; i < 4; ++i)
#pragma unroll
      for (int j = 0; j < 4; ++j) {
        const int col = n0 + j * 16 + mr;
#pragma unroll
        for (int rr = 0; rr < 4; ++rr)
          Cf[(size_t)(m0 + i * 16 + quad * 4 + rr) * N + col] = acc[i][j][rr];
      }
  } else {
    const bool relu = (emode == 2);
#pragma unroll
    for (int i = 0; i < 4; ++i)
#pragma unroll
      for (int j = 0; j < 4; ++j) {
        const int col = n0 - coff + j * 16 + mr;
#pragma unroll
        for (int rr = 0; rr < 4; ++rr) {
          float v = acc[i][j][rr];
          if (relu) v = fmaxf(v, 0.f);
          Cbf[(size_t)(m0 + i * 16 + quad * 4 + rr) * ncol + col] = f2bf(v);
        }
      }
  }
}

// ---------------------------------------------------------------------------
// Layer-1 Q,K via bf16x3 MFMA: Q = Xh.Wh + Xh.Wl + Xl.Wh (fp32 accum,
// ~1.5e-5 rel err vs fp32 GEMM — mask-grade). Epilogue re-splits into
// bf16 hi/lo pairs.
// ---------------------------------------------------------------------------
__global__ __launch_bounds__(64) void gemm_qk_mfma_kernel(
    const unsigned short* __restrict__ Xh, const unsigned short* __restrict__ Xl,
    const unsigned short* __restrict__ WQh, const unsigned short* __restrict__ WQl,
    const unsigned short* __restrict__ WKh, const unsigned short* __restrict__ WKl,
    unsigned short* __restrict__ Qhi, unsigned short* __restrict__ Qlo,
    unsigned short* __restrict__ Khi, unsigned short* __restrict__ Klo)
{
  const int l = threadIdx.x;
  const int sel = blockIdx.y >> 7;
  const int m0 = (blockIdx.y & 127) * 64;
  const int n0 = blockIdx.x * 64;
  const int mr = l & 15, quad = l >> 4;
  const unsigned short* Bh = sel ? WKh : WQh;
  const unsigned short* Bl = sel ? WKl : WQl;
  unsigned short* Chi = sel ? Khi : Qhi;
  unsigned short* Clo = sel ? Klo : Qlo;

  f32x4 acc[4][4];
  const f32x4 zero = {0.f, 0.f, 0.f, 0.f};
#pragma unroll
  for (int i = 0; i < 4; ++i)
#pragma unroll
    for (int j = 0; j < 4; ++j) acc[i][j] = zero;

  const unsigned short* Ah = Xh + (size_t)(m0 + mr) * Dz + quad * 8;
  const unsigned short* Al = Xl + (size_t)(m0 + mr) * Dz + quad * 8;
  const unsigned short* Bhp = Bh + (size_t)(n0 + mr) * Dz + quad * 8;
  const unsigned short* Blp = Bl + (size_t)(n0 + mr) * Dz + quad * 8;

  for (int k0 = 0; k0 < Dz; k0 += 32) {
    short8 ah[4], al[4], bh[4], bl[4];
#pragma unroll
    for (int i = 0; i < 4; ++i) {
      ah[i] = *reinterpret_cast<const short8*>(Ah + (size_t)i * 16 * Dz + k0);
      al[i] = *reinterpret_cast<const short8*>(Al + (size_t)i * 16 * Dz + k0);
      bh[i] = *reinterpret_cast<const short8*>(Bhp + (size_t)i * 16 * Dz + k0);
      bl[i] = *reinterpret_cast<const short8*>(Blp + (size_t)i * 16 * Dz + k0);
    }
#pragma unroll
    for (int i = 0; i < 4; ++i)
#pragma unroll
      for (int j = 0; j < 4; ++j) {
        acc[i][j] = __builtin_amdgcn_mfma_f32_16x16x32_bf16(al[i], bh[j], acc[i][j], 0, 0, 0);
        acc[i][j] = __builtin_amdgcn_mfma_f32_16x16x32_bf16(ah[i], bl[j], acc[i][j], 0, 0, 0);
        acc[i][j] = __builtin_amdgcn_mfma_f32_16x16x32_bf16(ah[i], bh[j], acc[i][j], 0, 0, 0);
      }
  }

#pragma unroll
  for (int i = 0; i < 4; ++i)
#pragma unroll
    for (int j = 0; j < 4; ++j) {
      const int col = n0 + j * 16 + mr;
#pragma unroll
      for (int rr = 0; rr < 4; ++rr) {
        const size_t row = (size_t)(m0 + i * 16 + quad * 4 + rr);
        float v = acc[i][j][rr];
        unsigned short hv = f2bf(v);
        Chi[row * Dz + col] = hv;
        Clo[row * Dz + col] = f2bf(v - bf2f(hv));
      }
    }
}

// ---------------------------------------------------------------------------
// Layer-1 z pass, CHEAP: plain-bf16 QK^T. XCD-swizzled decode.
// ---------------------------------------------------------------------------
__global__ __launch_bounds__(256) void attn_z_kernel(
    const unsigned short* __restrict__ Qh, const unsigned short* __restrict__ Kh,
    float* __restrict__ invzG)
{
  const int tid = threadIdx.x;
  const int lane = tid & 63, wave = tid >> 6;
  const int c = lane & 15, quad = lane >> 4;
  int b, h, qt;
  attn_decode(blockIdx.x, b, h, qt);
  const size_t bT = (size_t)b * Tz;
  const int qrow = qt * 64 + wave * 16;
  const int hoff = h * DHz;

  const size_t qbase = (bT + qrow + c) * Dz + hoff + quad * 8;
  short8 q0 = *reinterpret_cast<const short8*>(Qh + qbase);
  short8 q1 = *reinterpret_cast<const short8*>(Qh + qbase + 32);

  const f32x4 zf = {0.f, 0.f, 0.f, 0.f};
  float z[4] = {0.f, 0.f, 0.f, 0.f};

  for (int t = 0; t < 16; ++t) {
    const int k0 = t * 64;
#pragma unroll
    for (int sub = 0; sub < 4; ++sub) {
      const size_t kb = (bT + k0 + sub * 16 + c) * Dz + hoff + quad * 8;
      short8 kh0 = *reinterpret_cast<const short8*>(Kh + kb);
      short8 kh1 = *reinterpret_cast<const short8*>(Kh + kb + 32);
      f32x4 aA = zf, aB = zf;
      aA = __builtin_amdgcn_mfma_f32_16x16x32_bf16(q0, kh0, aA, 0, 0, 0);
      aB = __builtin_amdgcn_mfma_f32_16x16x32_bf16(q1, kh1, aB, 0, 0, 0);
#pragma unroll
      for (int rr = 0; rr < 4; ++rr) z[rr] += __expf((aA[rr] + aB[rr]) * 0.125f);
    }
  }
#pragma unroll
  for (int w = 1; w < 16; w <<= 1) {
#pragma unroll
    for (int rr = 0; rr < 4; ++rr) z[rr] += __shfl_xor(z[rr], w);
  }
  if (c == 0) {
#pragma unroll
    for (int rr = 0; rr < 4; ++rr)
      invzG[(size_t)(b * Hz + h) * Tz + qrow + quad * 4 + rr] = 1.f / z[rr];
  }
}

// ---------------------------------------------------------------------------
// Layer-1 ctx with LDS-STAGED K/V: the block stages the 64-key Kh/Kl/V tiles
// once per tile with fully coalesced loads (8 rows x 128B contiguous per
// instr), then all 4 waves read MFMA fragments from LDS (XOR-swizzled 128B
// rows -> 8-words/bank structural floor). Removes the 16-line-per-instr
// global gathers and the 4x per-wave duplication that bound rounds 3-5.
// All arithmetic values/order and PART slots are bit-identical to round 4.
// ---------------------------------------------------------------------------
__global__ __launch_bounds__(256) void attn_ctx_kernel(
    const unsigned short* __restrict__ Qh, const unsigned short* __restrict__ Ql,
    const unsigned short* __restrict__ Kh, const unsigned short* __restrict__ Kl,
    const unsigned short* __restrict__ Vt, const float* __restrict__ invzG,
    unsigned short* __restrict__ ctx, float* __restrict__ part)
{
  __shared__ unsigned short Ksh[64 * 64];  // 8KB: 64 keys x 128B (swizzled)
  __shared__ unsigned short Ksl[64 * 64];  // 8KB
  __shared__ unsigned short Vsh[64 * 64];  // 8KB: 64 features x 128B (swizzled)
  __shared__ unsigned short Pld[64][76];   // 9.5KB
  __shared__ float CSPt[4][64];            // per-wave per-tile colsum partials
  const int tid = threadIdx.x;
  const int lane = tid & 63, wave = tid >> 6;
  const int c = lane & 15, quad = lane >> 4;
  int b, h, qt;
  attn_decode(blockIdx.x, b, h, qt);
  const size_t bT = (size_t)b * Tz;
  const int qrow = qt * 64 + wave * 16;
  const int hoff = h * DHz;
  const int lidx = b * 128 + h * 16 + qt;  // logical PART slot

  const size_t qbase = (bT + qrow + c) * Dz + hoff + quad * 8;
  short8 q0h = *reinterpret_cast<const short8*>(Qh + qbase);
  short8 q1h = *reinterpret_cast<const short8*>(Qh + qbase + 32);
  short8 q0l = *reinterpret_cast<const short8*>(Ql + qbase);
  short8 q1l = *reinterpret_cast<const short8*>(Ql + qbase + 32);

  float invz[4];
#pragma unroll
  for (int rr = 0; rr < 4; ++rr)
    invz[rr] = invzG[(size_t)(b * Hz + h) * Tz + qrow + quad * 4 + rr];

  // staging coords: 256 threads cover 32 rows x 8 slots (16B) per pass
  const int sr = tid >> 3;        // row 0..31
  const int sj = (tid & 7) * 16;  // slot byte 0..112
  const unsigned short* khb = Kh + (bT + sr) * Dz + hoff + (tid & 7) * 8;
  const unsigned short* klb = Kl + (bT + sr) * Dz + hoff + (tid & 7) * 8;
  const unsigned short* vtb = Vt + ((size_t)(b * Hz + h) * DHz + sr) * Tz + (tid & 7) * 8;

  const f32x4 zf = {0.f, 0.f, 0.f, 0.f};
  f32x4 ot[4] = {zf, zf, zf, zf};

  char* KshB = (char*)Ksh;
  char* KslB = (char*)Ksl;
  char* VshB = (char*)Vsh;

  for (int t = 0; t < 16; ++t) {
    const int k0 = t * 64;
    // ---- stage tile t: coalesced global -> regs -> swizzled LDS ----
    short8 g0 = *reinterpret_cast<const short8*>(khb + (size_t)k0 * Dz);
    short8 g1 = *reinterpret_cast<const short8*>(khb + (size_t)(k0 + 32) * Dz);
    short8 g2 = *reinterpret_cast<const short8*>(klb + (size_t)k0 * Dz);
    short8 g3 = *reinterpret_cast<const short8*>(klb + (size_t)(k0 + 32) * Dz);
    short8 g4 = *reinterpret_cast<const short8*>(vtb + k0);
    short8 g5 = *reinterpret_cast<const short8*>(vtb + 32 * Tz + k0);
    // prev tile fully consumed at the tail barrier of the previous iteration
    *reinterpret_cast<short8*>(KshB + swz(sr, sj)) = g0;
    *reinterpret_cast<short8*>(KshB + swz(sr + 32, sj)) = g1;
    *reinterpret_cast<short8*>(KslB + swz(sr, sj)) = g2;
    *reinterpret_cast<short8*>(KslB + swz(sr + 32, sj)) = g3;
    *reinterpret_cast<short8*>(VshB + swz(sr, sj)) = g4;
    *reinterpret_cast<short8*>(VshB + swz(sr + 32, sj)) = g5;
    __syncthreads();  // staged data visible

    // ---- QK^T subtiles (bf16x3, 2-acc split) ----
#pragma unroll
    for (int sub = 0; sub < 4; ++sub) {
      const int row = sub * 16 + c;
      short8 kh0 = *reinterpret_cast<const short8*>(KshB + swz(row, quad * 16));
      short8 kh1 = *reinterpret_cast<const short8*>(KshB + swz(row, 64 + quad * 16));
      short8 kl0 = *reinterpret_cast<const short8*>(KslB + swz(row, quad * 16));
      short8 kl1 = *reinterpret_cast<const short8*>(KslB + swz(row, 64 + quad * 16));
      f32x4 aA = zf, aB = zf;
      aA = __builtin_amdgcn_mfma_f32_16x16x32_bf16(q0h, kh0, aA, 0, 0, 0);
      aB = __builtin_amdgcn_mfma_f32_16x16x32_bf16(q1h, kh1, aB, 0, 0, 0);
      aA = __builtin_amdgcn_mfma_f32_16x16x32_bf16(q0h, kl0, aA, 0, 0, 0);
      aB = __builtin_amdgcn_mfma_f32_16x16x32_bf16(q1h, kl1, aB, 0, 0, 0);
      aA = __builtin_amdgcn_mfma_f32_16x16x32_bf16(q0l, kh0, aA, 0, 0, 0);
      aB = __builtin_amdgcn_mfma_f32_16x16x32_bf16(q1l, kh1, aB, 0, 0, 0);
      float p[4];
#pragma unroll
      for (int rr = 0; rr < 4; ++rr)
        p[rr] = __expf((aA[rr] + aB[rr]) * 0.125f) * invz[rr];
      float cs = p[0] + p[1] + p[2] + p[3];
      cs += __shfl_xor(cs, 16);
      cs += __shfl_xor(cs, 32);
      if (quad == 0) CSPt[wave][sub * 16 + c] = cs;  // key visited once
#pragma unroll
      for (int rr = 0; rr < 4; ++rr)
        Pld[(wave << 4) + quad * 4 + rr][sub * 16 + c] = f2bf(p[rr]);
    }

    // ---- PV from LDS ----
    union { short8 v; ushort4 hh[2]; } pb0, pb1;
    pb0.hh[0] = *reinterpret_cast<const ushort4*>(&Pld[(wave << 4) + c][quad * 8]);
    pb0.hh[1] = *reinterpret_cast<const ushort4*>(&Pld[(wave << 4) + c][quad * 8 + 4]);
    pb1.hh[0] = *reinterpret_cast<const ushort4*>(&Pld[(wave << 4) + c][32 + quad * 8]);
    pb1.hh[1] = *reinterpret_cast<const ushort4*>(&Pld[(wave << 4) + c][32 + quad * 8 + 4]);
#pragma unroll
    for (int ds = 0; ds < 4; ++ds) {
      const int row = ds * 16 + c;
      short8 v0 = *reinterpret_cast<const short8*>(VshB + swz(row, quad * 16));
      short8 v1 = *reinterpret_cast<const short8*>(VshB + swz(row, 64 + quad * 16));
      ot[ds] = __builtin_amdgcn_mfma_f32_16x16x32_bf16(v0, pb0.v, ot[ds], 0, 0, 0);
      ot[ds] = __builtin_amdgcn_mfma_f32_16x16x32_bf16(v1, pb1.v, ot[ds], 0, 0, 0);
    }
    __syncthreads();  // all LDS reads done; CSPt complete across waves

    // ---- deterministic per-tile colsum combine (same 4-addend order) ----
    if (tid < 64) {
      float v = ((CSPt[0][tid] + CSPt[1][tid]) + CSPt[2][tid]) + CSPt[3][tid];
      part[(size_t)lidx * 1024 + k0 + tid] = v * (1.f / Hz);
    }
  }

  const size_t cb = (bT + qrow + c) * Dz + hoff;
#pragma unroll
  for (int ds = 0; ds < 4; ++ds) {
    ushort4 pk;
    pk.x = f2bf(ot[ds][0]); pk.y = f2bf(ot[ds][1]);
    pk.z = f2bf(ot[ds][2]); pk.w = f2bf(ot[ds][3]);
    *reinterpret_cast<ushort4*>(&ctx[cb + ds * 16 + quad * 4]) = pk;
  }
}

// ---------------------------------------------------------------------------
// Deterministic colsum reduce: CS1[b,key] = sum over the 128 (h,qt) block
// partials in fixed ascending order. One thread per output.
// ---------------------------------------------------------------------------
__global__ __launch_bounds__(256) void colsum_reduce_kernel(
    const float* __restrict__ part, float* __restrict__ colsum)
{
  const int i = blockIdx.x * 256 + threadIdx.x;  // 0..8191
  const int b = i >> 10, k = i & 1023;
  const float* p = part + (size_t)(b * 128) * 1024 + k;
  float s = 0.f;
  for (int j = 0; j < 128; ++j) s += p[(size_t)j * 1024];
  colsum[i] = s;
}

// ---------------------------------------------------------------------------
// Layer-2 MFMA attention (masked), with k-tile range skipping. CS2 feeds only
// the continuous wl softmax -> atomics are fine here. XCD-swizzled decode.
// ---------------------------------------------------------------------------
__global__ __launch_bounds__(256) void attn_mfma2_kernel(
    const unsigned short* __restrict__ Qh, const unsigned short* __restrict__ Kh,
    const unsigned short* __restrict__ Vt, const int* __restrict__ ids,
    const int* __restrict__ wst,
    unsigned short* __restrict__ ctx, float* __restrict__ colsum)
{
  __shared__ unsigned short Pld[64][76];
  __shared__ float csb[1024];

  const int tid = threadIdx.x;
  const int lane = tid & 63, wave = tid >> 6;
  const int c = lane & 15, quad = lane >> 4;
  int b, h, qt;
  attn_decode(blockIdx.x, b, h, qt);
  const size_t bT = (size_t)b * Tz;
  const int qrow = qt * 64 + wave * 16;
  const int hoff = h * DHz;

  for (int i = tid; i < 1024; i += 256) csb[i] = 0.f;

  const int id_lo = ids[bT + qt * 64];
  const int id_hi = ids[bT + qt * 64 + 63];
  const int klo = wst[b * (Tz + 1) + id_lo];
  const int khi = wst[b * (Tz + 1) + id_hi + 1];
  const int t0 = klo >> 6, t1 = (khi - 1) >> 6;

  const size_t qbase = (bT + qrow + c) * Dz + hoff + quad * 8;
  short8 q0 = *reinterpret_cast<const short8*>(Qh + qbase);
  short8 q1 = *reinterpret_cast<const short8*>(Qh + qbase + 32);

  int qid[4];
#pragma unroll
  for (int rr = 0; rr < 4; ++rr) qid[rr] = ids[bT + qrow + quad * 4 + rr];
  __syncthreads();  // csb zeros visible before pass-2 atomics

  const f32x4 zf = {0.f, 0.f, 0.f, 0.f};

  // pass 1: z
  float z[4] = {0.f, 0.f, 0.f, 0.f};
  for (int t = t0; t <= t1; ++t) {
    const int k0 = t * 64;
#pragma unroll
    for (int sub = 0; sub < 4; ++sub) {
      const size_t kb = (bT + k0 + sub * 16 + c) * Dz + hoff + quad * 8;
      short8 kh0 = *reinterpret_cast<const short8*>(Kh + kb);
      short8 kh1 = *reinterpret_cast<const short8*>(Kh + kb + 32);
      f32x4 acc = zf;
      acc = __builtin_amdgcn_mfma_f32_16x16x32_bf16(q0, kh0, acc, 0, 0, 0);
      acc = __builtin_amdgcn_mfma_f32_16x16x32_bf16(q1, kh1, acc, 0, 0, 0);
      int kidv = ids[bT + k0 + sub * 16 + c];
#pragma unroll
      for (int rr = 0; rr < 4; ++rr) {
        float e = __expf(acc[rr] * 0.125f);
        if (qid[rr] != kidv) e = 0.f;
        z[rr] += e;
      }
    }
  }
#pragma unroll
  for (int w = 1; w < 16; w <<= 1) {
#pragma unroll
    for (int rr = 0; rr < 4; ++rr) z[rr] += __shfl_xor(z[rr], w);
  }
  float invz[4];
#pragma unroll
  for (int rr = 0; rr < 4; ++rr) invz[rr] = 1.f / z[rr];

  // pass 2: P, colsum, PV
  f32x4 ot[4] = {zf, zf, zf, zf};
  for (int t = t0; t <= t1; ++t) {
    const int k0 = t * 64;
#pragma unroll
    for (int sub = 0; sub < 4; ++sub) {
      const size_t kb = (bT + k0 + sub * 16 + c) * Dz + hoff + quad * 8;
      short8 kh0 = *reinterpret_cast<const short8*>(Kh + kb);
      short8 kh1 = *reinterpret_cast<const short8*>(Kh + kb + 32);
      f32x4 acc = zf;
      acc = __builtin_amdgcn_mfma_f32_16x16x32_bf16(q0, kh0, acc, 0, 0, 0);
      acc = __builtin_amdgcn_mfma_f32_16x16x32_bf16(q1, kh1, acc, 0, 0, 0);
      int kidv = ids[bT + k0 + sub * 16 + c];
      float p[4];
#pragma unroll
      for (int rr = 0; rr < 4; ++rr) {
        float e = __expf(acc[rr] * 0.125f);
        if (qid[rr] != kidv) e = 0.f;
        p[rr] = e * invz[rr];
      }
      float cs = p[0] + p[1] + p[2] + p[3];
      cs += __shfl_xor(cs, 16);
      cs += __shfl_xor(cs, 32);
      if (quad == 0) atomicAdd(&csb[k0 + sub * 16 + c], cs);
#pragma unroll
      for (int rr = 0; rr < 4; ++rr)
        Pld[(wave << 4) + quad * 4 + rr][sub * 16 + c] = f2bf(p[rr]);
    }
    union { short8 v; ushort4 hh[2]; } pb0, pb1;
    pb0.hh[0] = *reinterpret_cast<const ushort4*>(&Pld[(wave << 4) + c][quad * 8]);
    pb0.hh[1] = *reinterpret_cast<const ushort4*>(&Pld[(wave << 4) + c][quad * 8 + 4]);
    pb1.hh[0] = *reinterpret_cast<const ushort4*>(&Pld[(wave << 4) + c][32 + quad * 8]);
    pb1.hh[1] = *reinterpret_cast<const ushort4*>(&Pld[(wave << 4) + c][32 + quad * 8 + 4]);
#pragma unroll
    for (int ds = 0; ds < 4; ++ds) {
      const size_t va = ((size_t)((b * Hz + h) * DHz + ds * 16 + c)) * Tz + k0 + quad * 8;
      short8 v0 = *reinterpret_cast<const short8*>(Vt + va);
      short8 v1 = *reinterpret_cast<const short8*>(Vt + va + 32);
      ot[ds] = __builtin_amdgcn_mfma_f32_16x16x32_bf16(v0, pb0.v, ot[ds], 0, 0, 0);
      ot[ds] = __builtin_amdgcn_mfma_f32_16x16x32_bf16(v1, pb1.v, ot[ds], 0, 0, 0);
    }
  }

  const size_t cb = (bT + qrow + c) * Dz + hoff;
#pragma unroll
  for (int ds = 0; ds < 4; ++ds) {
    ushort4 pk;
    pk.x = f2bf(ot[ds][0]); pk.y = f2bf(ot[ds][1]);
    pk.z = f2bf(ot[ds][2]); pk.w = f2bf(ot[ds][3]);
    *reinterpret_cast<ushort4*>(&ctx[cb + ds * 16 + quad * 4]) = pk;
  }
  __syncthreads();
  for (int i = tid; i < 1024; i += 256)
    atomicAdd(&colsum[bT + i], csb[i] * (1.f / Hz));
}

// ---------------------------------------------------------------------------
// out = LayerNorm(resid + delta). resid fp32 (residf) if non-null else bf16.
// ---------------------------------------------------------------------------
__global__ __launch_bounds__(256) void ln_kernel(const float* __restrict__ residf,
    const unsigned short* __restrict__ residbf, const float* __restrict__ delta,
    float* __restrict__ outf, unsigned short* __restrict__ outbf)
{
  const size_t base = (size_t)blockIdx.x * Dz;
  const int tid = threadIdx.x;
  float r0, r1;
  if (residf) {
    r0 = residf[base + tid]; r1 = residf[base + tid + 256];
  } else {
    r0 = bf2f(residbf[base + tid]); r1 = bf2f(residbf[base + tid + 256]);
  }
  float x0 = r0 + delta[base + tid];
  float x1 = r1 + delta[base + tid + 256];
  __shared__ float red[4];
  float s = x0 + x1;
#pragma unroll
  for (int off = 32; off; off >>= 1) s += __shfl_down(s, off);
  if ((tid & 63) == 0) red[tid >> 6] = s;
  __syncthreads();
  const float mean = (red[0] + red[1] + red[2] + red[3]) * (1.f / Dz);
  __syncthreads();
  float d0 = x0 - mean, d1 = x1 - mean;
  float v = d0 * d0 + d1 * d1;
#pragma unroll
  for (int off = 32; off; off >>= 1) v += __shfl_down(v, off);
  if ((tid & 63) == 0) red[tid >> 6] = v;
  __syncthreads();
  const float var = (red[0] + red[1] + red[2] + red[3]) * (1.f / Dz);
  const float rstd = rsqrtf(var + 1e-5f);
  float y0 = d0 * rstd, y1 = d1 * rstd;
  if (outf) {
    outf[base + tid] = y0;
    outf[base + tid + 256] = y1;
  }
  outbf[base + tid] = f2bf(y0);
  outbf[base + tid + 256] = f2bf(y1);
}

// ---------------------------------------------------------------------------
// Per batch: min-max normalize colsum, threshold 0.5, run-length window scan.
// ---------------------------------------------------------------------------
__global__ __launch_bounds__(256) void window_ids_kernel(const float* __restrict__ cs,
    int* __restrict__ ids, int* __restrict__ wst, int* __restrict__ nwin)
{
  const int b = blockIdx.x, tid = threadIdx.x;
  __shared__ float vals[Tz];
  __shared__ unsigned char wb[Tz];
  __shared__ int sids[Tz];
  __shared__ float rmin[4], rmax[4];
  float mn = INFINITY, mx = -INFINITY;
  for (int t = tid; t < Tz; t += 256) {
    float v = cs[b * Tz + t];
    vals[t] = v;
    mn = fminf(mn, v); mx = fmaxf(mx, v);
  }
#pragma unroll
  for (int off = 32; off; off >>= 1) {
    mn = fminf(mn, __shfl_down(mn, off));
    mx = fmaxf(mx, __shfl_down(mx, off));
  }
  if ((tid & 63) == 0) { rmin[tid >> 6] = mn; rmax[tid >> 6] = mx; }
  __syncthreads();
  mn = fminf(fminf(rmin[0], rmin[1]), fminf(rmin[2], rmin[3]));
  mx = fmaxf(fmaxf(rmax[0], rmax[1]), fmaxf(rmax[2], rmax[3]));
  const float inv = 1.f / (mx - mn + 1e-8f);
  for (int t = tid; t < Tz; t += 256) wb[t] = (((vals[t] - mn) * inv) >= 0.5f) ? 1 : 0;
  __syncthreads();
  if (tid == 0) {
    int cur = wb[0], start = 0, wid = 0;
    sids[0] = 0;
    wst[b * (Tz + 1)] = 0;
    for (int t = 1; t < Tz; ++t) {
      int wt = wb[t];
      if (wt != cur) {
        cur = wt;
        if (start + 1 != t) {
          start = t;
          ++wid;
          wst[b * (Tz + 1) + wid] = t;
        }
      }
      sids[t] = wid;
    }
    nwin[b] = wid + 1;
    wst[b * (Tz + 1) + wid + 1] = Tz;
  }
  __syncthreads();
  for (int t = tid; t < Tz; t += 256) ids[b * Tz + t] = sids[t];
}

// ---------------------------------------------------------------------------
// wl[b,:] = softmax over keys of layer-2 colsum.
// ---------------------------------------------------------------------------
__global__ __launch_bounds__(256) void wl_softmax_kernel(const float* __restrict__ cs,
                                                         float* __restrict__ wl)
{
  const int b = blockIdx.x, tid = threadIdx.x;
  __shared__ float vals[Tz];
  __shared__ float red[4];
  float mx = -INFINITY;
  for (int t = tid; t < Tz; t += 256) {
    float v = cs[b * Tz + t];
    vals[t] = v;
    mx = fmaxf(mx, v);
  }
#pragma unroll
  for (int off = 32; off; off >>= 1) mx = fmaxf(mx, __shfl_down(mx, off));
  if ((tid & 63) == 0) red[tid >> 6] = mx;
  __syncthreads();
  mx = fmaxf(fmaxf(red[0], red[1]), fmaxf(red[2], red[3]));
  __syncthreads();
  float se = 0.f;
  for (int t = tid; t < Tz; t += 256) {
    float e = expf(vals[t] - mx);
    vals[t] = e;
    se += e;
  }
#pragma unroll
  for (int off = 32; off; off >>= 1) se += __shfl_down(se, off);
  if ((tid & 63) == 0) red[tid >> 6] = se;
  __syncthreads();
  const float inv = 1.f / (red[0] + red[1] + red[2] + red[3]);
  for (int t = tid; t < Tz; t += 256) wl[b * Tz + t] = vals[t] * inv;
}

// ---------------------------------------------------------------------------
// Fused outputs: word_tokens (blocks 0..8191), winmap (8192..16383),
// copy_x (16384..20479).
// ---------------------------------------------------------------------------
__global__ __launch_bounds__(256) void outputs_kernel(
    const unsigned short* __restrict__ outl, const float* __restrict__ wl,
    const int* __restrict__ wst, const int* __restrict__ nwin,
    const int* __restrict__ ids, const float* __restrict__ x,
    float* __restrict__ out, float* __restrict__ out2)
{
  const int bid = blockIdx.x;
  const int tid = threadIdx.x;
  if (bid < 8192) {  // word_tokens
    const int w = bid & (Tz - 1);
    const int b = bid >> 10;
    float a0 = 0.f, a1 = 0.f;
    if (w < nwin[b]) {
      const int s = wst[b * (Tz + 1) + w], e = wst[b * (Tz + 1) + w + 1];
      for (int t = s; t < e; ++t) {
        const float sc = wl[b * Tz + t];
        const unsigned short* p = &outl[((size_t)(b * Tz + t)) * Dz];
        a0 += bf2f(p[tid]) * sc;
        a1 += bf2f(p[tid + 256]) * sc;
      }
    }
    float* o = &out[((size_t)(b * 2 * Tz + w)) * Dz];
    o[tid] = a0;
    o[tid + 256] = a1;
  } else if (bid < 16384) {  // winmap
    const int lb = bid - 8192;
    const int w = lb & (Tz - 1);
    const int b = lb >> 10;
    const int j = tid * 4;
    int4 id4 = *reinterpret_cast<const int4*>(&ids[b * Tz + j]);
    float4 v;
    v.x = (id4.x == w) ? 1.f : 0.f;
    v.y = (id4.y == w) ? 1.f : 0.f;
    v.z = (id4.z == w) ? 1.f : 0.f;
    v.w = (id4.w == w) ? 1.f : 0.f;
    *reinterpret_cast<float4*>(&out2[((size_t)(b * Tz + w)) * Tz + j]) = v;
  } else {  // copy_x
    size_t i = (size_t)(bid - 16384) * 256 + tid;
    size_t idx = i * 4;
    size_t rowi = idx >> 9;
    size_t d = idx & 511;
    size_t b = rowi >> 10, t = rowi & 1023;
    float4 v = *reinterpret_cast<const float4*>(&x[idx]);
    *reinterpret_cast<float4*>(&out[(((b * 2 * Tz) + Tz + t) << 9) + d]) = v;
  }
}

// ---------------------------------------------------------------------------
// Orchestration: 22 dispatches. attn_ctx reverted to 1024 blocks, now with
// cooperative LDS staging of K/V (coalesced, swizzled).
// ---------------------------------------------------------------------------
extern "C" void kernel_launch(void* const* d_in, const int* in_sizes, int n_in,
                              void* d_out, int out_size, void* d_ws, size_t ws_size,
                              hipStream_t stream)
{
  (void)in_sizes; (void)n_in; (void)out_size; (void)ws_size;
  const float* x     = (const float*)d_in[0];
  const float* vqkv  = (const float*)d_in[1];
  const float* voutw = (const float*)d_in[2];
  const float* vw1   = (const float*)d_in[3];
  const float* vw2   = (const float*)d_in[4];
  const float* lqkv  = (const float*)d_in[5];
  const float* loutw = (const float*)d_in[6];
  const float* lw1   = (const float*)d_in[7];
  const float* lw2   = (const float*)d_in[8];
  float* out = (float*)d_out;
  float* ws  = (float*)d_ws;

  unsigned short* QLbf = (unsigned short*)(ws + 0);        // bf16 Q lo (L1)
  unsigned short* KLbf = (unsigned short*)(ws + 2097152);  // bf16 K lo (L1)
  float* PROJ = ws + 0;         // written after attn_ctx (QL/KL dead)
  float* Y1   = ws + 4194304;
  unsigned short* QHbf = (unsigned short*)(ws + 8388608);   // bf16 Q hi (L1+L2)
  unsigned short* KHbf = (unsigned short*)(ws + 10485760);  // bf16 K hi (L1+L2)
  unsigned short* VT   = (unsigned short*)(ws + 12582912);
  unsigned short* SLOT1 = (unsigned short*)(ws + 14680064); // attn ctx bf16
  unsigned short* SLOT2 = (unsigned short*)(ws + 16777216); // LN bf16 out
  unsigned short* HIDbf = (unsigned short*)(ws + 18874368); // FFN hidden
  unsigned short* XBF   = (unsigned short*)(ws + 18874368); // x hi bf16 (pre-FFN)
  float* PART = ws + 18874368;  // colsum block partials (1024x1024); written
                                // by attn_ctx after XBF/XLO dead, dead by FFN1
  unsigned short* XLO = (unsigned short*)(ws + 20971520);   // x lo bf16
  // bf16 transposed weights (WLQ0..2 contiguous -> merged [1536,512] matrix)
  unsigned short* WVQV = (unsigned short*)(ws + 27262976);
  unsigned short* WVO  = (unsigned short*)(ws + 27394048);
  unsigned short* WV1  = (unsigned short*)(ws + 27525120);
  unsigned short* WV2  = (unsigned short*)(ws + 28049408);
  unsigned short* WLQ0 = (unsigned short*)(ws + 28573696);
  unsigned short* WLQ1 = (unsigned short*)(ws + 28704768);
  unsigned short* WLQ2 = (unsigned short*)(ws + 28835840);
  unsigned short* WLO  = (unsigned short*)(ws + 28966912);
  unsigned short* WL1  = (unsigned short*)(ws + 29097984);
  unsigned short* WL2  = (unsigned short*)(ws + 29622272);
  // small buffers
  float* CS1   = ws + 30146560;
  float* CS2   = ws + 30154752;
  float* WLs   = ws + 30162944;
  int*   IDS   = (int*)(ws + 30171136);
  int*   WST   = (int*)(ws + 30179328);
  int*   NWIN  = (int*)(ws + 30187776);
  float* INVZ  = ws + 30195968;  // (B*H*T) = 65536 floats
  // layer-1 Q/K weights, bf16 transposed hi/lo (512x512 each = 131072 floats)
  unsigned short* WQH = (unsigned short*)(ws + 30261504);
  unsigned short* WQL = (unsigned short*)(ws + 30392576);
  unsigned short* WKH = (unsigned short*)(ws + 30523648);
  unsigned short* WKL = (unsigned short*)(ws + 30654720);

  dim3 blk(256);

  // ---- fused prep: 12 wconv + zero + fconv(hi/lo) ----
  PrepArgs P;
  auto setw = [&](int i, const float* s, unsigned short* d, unsigned short* dl,
                  int K, int N, int b0) {
    P.d[i].src = s; P.d[i].dst = d; P.d[i].dstlo = dl;
    P.d[i].K = K; P.d[i].N = N; P.d[i].blk0 = b0;
  };
  int b0 = 0;
  setw(0, vqkv + 2 * Dz * Dz, WVQV, nullptr, Dz, Dz, b0); b0 += 256;
  setw(1, voutw, WVO, nullptr, Dz, Dz, b0); b0 += 256;
  setw(2, vw1, WV1, nullptr, Dz, FFz, b0); b0 += 1024;
  setw(3, vw2, WV2, nullptr, FFz, Dz, b0); b0 += 1024;
  setw(4, lqkv + 0 * Dz * Dz, WLQ0, nullptr, Dz, Dz, b0); b0 += 256;
  setw(5, lqkv + 1 * Dz * Dz, WLQ1, nullptr, Dz, Dz, b0); b0 += 256;
  setw(6, lqkv + 2 * Dz * Dz, WLQ2, nullptr, Dz, Dz, b0); b0 += 256;
  setw(7, loutw, WLO, nullptr, Dz, Dz, b0); b0 += 256;
  setw(8, lw1, WL1, nullptr, Dz, FFz, b0); b0 += 1024;
  setw(9, lw2, WL2, nullptr, FFz, Dz, b0); b0 += 1024;
  setw(10, vqkv + 0 * Dz * Dz, WQH, WQL, Dz, Dz, b0); b0 += 256;
  setw(11, vqkv + 1 * Dz * Dz, WKH, WKL, Dz, Dz, b0); b0 += 256;
  P.nwc = b0;  // 6144
  prep_kernel<<<dim3(P.nwc + 64 + 4096), blk, 0, stream>>>(P, x, XBF, XLO, CS1);

  auto mgemm = [&](const unsigned short* A, const unsigned short* BT, void* p1,
                   void* p2, void* p3, int K, int N, int mode) {
    mfma_gemm_kernel<<<dim3(N / 64, Mz / 64), dim3(64), 0, stream>>>(
        A, BT, p1, p2, p3, K, N, mode);
  };

  // ---------------- layer 1 (vanilla) ----------------
  gemm_qk_mfma_kernel<<<dim3(8, 256), dim3(64), 0, stream>>>(
      XBF, XLO, WQH, WQL, WKH, WKL, QHbf, QLbf, KHbf, KLbf);
  attn_z_kernel<<<dim3(Bz * Hz * 16), blk, 0, stream>>>(QHbf, KHbf, INVZ);
  mgemm(XBF, WVQV, VT, nullptr, nullptr, Dz, Dz, 4);        // V -> V^T (XBF/XLO dead)
  attn_ctx_kernel<<<dim3(Bz * Hz * 16), blk, 0, stream>>>(
      QHbf, QLbf, KHbf, KLbf, VT, INVZ, SLOT1, PART);
  colsum_reduce_kernel<<<dim3(32), blk, 0, stream>>>(PART, CS1);
  window_ids_kernel<<<dim3(Bz), blk, 0, stream>>>(CS1, IDS, WST, NWIN);
  mgemm(SLOT1, WVO, PROJ, nullptr, nullptr, Dz, Dz, 0);     // proj (QL/KL dead)
  ln_kernel<<<dim3(Mz), blk, 0, stream>>>(x, nullptr, PROJ, Y1, SLOT2);
  mgemm(SLOT2, WV1, HIDbf, nullptr, nullptr, Dz, FFz, 2);   // FFN1 (PART dead)
  mgemm(HIDbf, WV2, PROJ, nullptr, nullptr, FFz, Dz, 0);    // FFN2
  ln_kernel<<<dim3(Mz), blk, 0, stream>>>(Y1, nullptr, PROJ, nullptr, SLOT2);

  // ---------------- layer 2 (block-diagonal window mask) ----------------
  mgemm(SLOT2, WLQ0, QHbf, KHbf, VT, Dz, 3 * Dz, 5);        // merged QKV
  attn_mfma2_kernel<<<dim3(Bz * Hz * 16), blk, 0, stream>>>(
      QHbf, KHbf, VT, IDS, WST, SLOT1, CS2);
  mgemm(SLOT1, WLO, PROJ, nullptr, nullptr, Dz, Dz, 0);
  ln_kernel<<<dim3(Mz), blk, 0, stream>>>(nullptr, SLOT2, PROJ, Y1, SLOT2);
  mgemm(SLOT2, WL1, HIDbf, nullptr, nullptr, Dz, FFz, 2);
  mgemm(HIDbf, WL2, PROJ, nullptr, nullptr, FFz, Dz, 0);
  ln_kernel<<<dim3(Mz), blk, 0, stream>>>(Y1, nullptr, PROJ, nullptr, SLOT2);

  // ---------------- pooling + outputs ----------------
  wl_softmax_kernel<<<dim3(Bz), blk, 0, stream>>>(CS2, WLs);
  outputs_kernel<<<dim3(20480), blk, 0, stream>>>(SLOT2, WLs, WST, NWIN, IDS, x,
                                                  out, out + (size_t)Bz * 2 * Tz * Dz);
}

// Round 7
// 753.151 us; speedup vs baseline: 1.4417x; 1.0883x over previous
//
#include <hip/hip_runtime.h>
#include <math.h>

// Problem constants (fixed by setup_inputs)
#define Bz 8
#define Tz 1024
#define Dz 512
#define FFz 2048
#define Hz 8
#define DHz 64
#define Mz (Bz * Tz)  // 8192 rows

typedef __attribute__((ext_vector_type(8))) short short8;   // 8 bf16 (4 VGPRs)
typedef __attribute__((ext_vector_type(4))) float f32x4;    // MFMA accumulator

__device__ inline unsigned short f2bf(float f) {  // RNE fp32 -> bf16
  unsigned u = __builtin_bit_cast(unsigned, f);
  return (unsigned short)((u + 0x7FFFu + ((u >> 16) & 1u)) >> 16);
}
__device__ inline float bf2f(unsigned short h) {
  unsigned u = (unsigned)h << 16;
  return __builtin_bit_cast(float, u);
}

// XCD-aware decode for the 1024-block attention grids (8 XCDs round-robin by
// blockIdx). g = xcd + 8*(qt + 16*bhi), bh = bhi*8 + xcd.
__device__ inline void attn_decode(int g, int& b, int& h, int& qt) {
  const int xcd = g & 7;
  const int j = g >> 3;
  qt = j & 15;
  const int bh = ((j >> 4) << 3) | xcd;
  b = bh >> 3;
  h = bh & 7;
}

// Swizzled byte offset inside a [64 rows x 128B] LDS tile: 16B slot XOR'd by
// row&7 -> every fragment read/write lands at the 8-words/bank LDS floor.
__device__ inline int swz(int row, int slotByte) {
  return row * 128 + (slotByte ^ ((row & 7) << 4));
}

// ---------------------------------------------------------------------------
// Fused prep: 12 weight convert+transposes (fp32 [K,N] -> bf16 [N,K], with
// optional lo-residual output) + colsum zero-fill + x -> bf16 hi/lo.
// ---------------------------------------------------------------------------
struct WDesc { const float* src; unsigned short* dst; unsigned short* dstlo;
               int K; int N; int blk0; };
struct PrepArgs { WDesc d[12]; int nwc; };

__global__ __launch_bounds__(256) void prep_kernel(PrepArgs P,
    const float* __restrict__ x, unsigned short* __restrict__ xbf,
    unsigned short* __restrict__ xlo, float* __restrict__ csz)
{
  const int bid = blockIdx.x;
  const int tid = threadIdx.x;
  if (bid < P.nwc) {  // wconv slice
    int i = 0;
    while (i < 11 && bid >= P.d[i + 1].blk0) ++i;
    const WDesc w = P.d[i];
    const int lb = bid - w.blk0;
    const int nbn = w.N / 32;
    const int bn = (lb % nbn) * 32, bk = (lb / nbn) * 32;
    __shared__ float t[32][33];
    const int tx = tid & 31, ty = tid >> 5;
#pragma unroll
    for (int r = 0; r < 32; r += 8)
      t[ty + r][tx] = w.src[(size_t)(bk + ty + r) * w.N + bn + tx];
    __syncthreads();
#pragma unroll
    for (int r = 0; r < 32; r += 8) {
      float v = t[tx][ty + r];
      unsigned short hv = f2bf(v);
      w.dst[(size_t)(bn + ty + r) * w.K + bk + tx] = hv;
      if (w.dstlo)
        w.dstlo[(size_t)(bn + ty + r) * w.K + bk + tx] = f2bf(v - bf2f(hv));
    }
  } else if (bid < P.nwc + 64) {  // zero slice (CS1+CS2 = 16384 floats)
    int idx = (bid - P.nwc) * 256 + tid;
    csz[idx] = 0.f;
  } else {  // fconv slice: 4096 blocks, 4 floats/thread -> hi + lo
    int i = (bid - P.nwc - 64) * 256 + tid;
    float4 v = *reinterpret_cast<const float4*>(&x[(size_t)i * 4]);
    ushort4 o, ol;
    o.x = f2bf(v.x); o.y = f2bf(v.y); o.z = f2bf(v.z); o.w = f2bf(v.w);
    ol.x = f2bf(v.x - bf2f(o.x)); ol.y = f2bf(v.y - bf2f(o.y));
    ol.z = f2bf(v.z - bf2f(o.z)); ol.w = f2bf(v.w - bf2f(o.w));
    *reinterpret_cast<ushort4*>(&xbf[(size_t)i * 4]) = o;
    *reinterpret_cast<ushort4*>(&xlo[(size_t)i * 4]) = ol;
  }
}

// ---------------------------------------------------------------------------
// bf16 MFMA GEMM, 64x64 tile per wave, direct-from-global fragments.
// Epilogue modes: 0 fp32 C | 1 bf16 C | 2 bf16 C + ReLU
//   | 4 V^T layout | 5 merged QKV (N=1536).
// ---------------------------------------------------------------------------
__global__ __launch_bounds__(64) void mfma_gemm_kernel(
    const unsigned short* __restrict__ A, const unsigned short* __restrict__ BT,
    void* __restrict__ p1, void* __restrict__ p2, void* __restrict__ p3,
    int K, int N, int mode)
{
  const int l = threadIdx.x;
  const int m0 = blockIdx.y * 64;
  const int n0 = blockIdx.x * 64;
  const int mr = l & 15, quad = l >> 4;

  f32x4 acc[4][4];
  const f32x4 zero = {0.f, 0.f, 0.f, 0.f};
#pragma unroll
  for (int i = 0; i < 4; ++i)
#pragma unroll
    for (int j = 0; j < 4; ++j) acc[i][j] = zero;

  const unsigned short* Ap = A + (size_t)(m0 + mr) * K + quad * 8;
  const unsigned short* Bp = BT + (size_t)(n0 + mr) * K + quad * 8;

  short8 a[4], b[4], an[4], bn[4];
#pragma unroll
  for (int i = 0; i < 4; ++i) {
    a[i] = *reinterpret_cast<const short8*>(Ap + (size_t)i * 16 * K);
    b[i] = *reinterpret_cast<const short8*>(Bp + (size_t)i * 16 * K);
  }
  for (int k0 = 0; k0 < K; k0 += 32) {
    if (k0 + 32 < K) {
#pragma unroll
      for (int i = 0; i < 4; ++i) {
        an[i] = *reinterpret_cast<const short8*>(Ap + (size_t)i * 16 * K + k0 + 32);
        bn[i] = *reinterpret_cast<const short8*>(Bp + (size_t)i * 16 * K + k0 + 32);
      }
    }
#pragma unroll
    for (int i = 0; i < 4; ++i)
#pragma unroll
      for (int j = 0; j < 4; ++j)
        acc[i][j] = __builtin_amdgcn_mfma_f32_16x16x32_bf16(a[i], b[j], acc[i][j], 0, 0, 0);
#pragma unroll
    for (int i = 0; i < 4; ++i) { a[i] = an[i]; b[i] = bn[i]; }
  }

  // C/D layout: col = lane&15, row = quad*4 + reg   [measured: m89/m91]
  int emode = mode;
  unsigned short* Cbf = (unsigned short*)p1;
  unsigned short* Vt  = (unsigned short*)p1;
  int ncol = N, coff = 0;
  if (mode == 5) {  // uniform per block: n0 is a multiple of 64
    if (n0 < 512)       { emode = 1; Cbf = (unsigned short*)p1; ncol = 512; coff = 0; }
    else if (n0 < 1024) { emode = 1; Cbf = (unsigned short*)p2; ncol = 512; coff = 512; }
    else                { emode = 4; Vt = (unsigned short*)p3; coff = 1024; }
  }
  if (emode == 4) {  // V^T: 4 consecutive tokens same feature -> ushort4
#pragma unroll
    for (int i = 0; i < 4; ++i)
#pragma unroll
      for (int j = 0; j < 4; ++j) {
        const int col = n0 - coff + j * 16 + mr;  // feature: h = col>>6, d = col&63
        const int row0 = m0 + i * 16 + quad * 4;  // token base (4 consecutive)
        const int bb = row0 >> 10, t0 = row0 & 1023;
        ushort4 pk;
        pk.x = f2bf(acc[i][j][0]); pk.y = f2bf(acc[i][j][1]);
        pk.z = f2bf(acc[i][j][2]); pk.w = f2bf(acc[i][j][3]);
        *reinterpret_cast<ushort4*>(
            &Vt[((size_t)((bb * Hz + (col >> 6)) * DHz + (col & 63))) * Tz + t0]) = pk;
      }
  } else if (emode == 0) {
    float* Cf = (float*)p1;
#pragma unroll
    for (int i = 0; i < 4; ++i)
#pragma unroll
      for (int j = 0; j < 4; ++j) {
        const int col = n0 + j * 16 + mr;
#pragma unroll
        for (int rr = 0; rr < 4; ++rr)
          Cf[(size_t)(m0 + i * 16 + quad * 4 + rr) * N + col] = acc[i][j][rr];
      }
  } else {
    const bool relu = (emode == 2);
#pragma unroll
    for (int i = 0; i < 4; ++i)
#pragma unroll
      for (int j = 0; j < 4; ++j) {
        const int col = n0 - coff + j * 16 + mr;
#pragma unroll
        for (int rr = 0; rr < 4; ++rr) {
          float v = acc[i][j][rr];
          if (relu) v = fmaxf(v, 0.f);
          Cbf[(size_t)(m0 + i * 16 + quad * 4 + rr) * ncol + col] = f2bf(v);
        }
      }
  }
}

// ---------------------------------------------------------------------------
// Layer-1 Q,K via bf16x3 MFMA: Q = Xh.Wh + Xh.Wl + Xl.Wh (fp32 accum,
// ~1.5e-5 rel err vs fp32 GEMM — mask-grade). Epilogue re-splits into
// bf16 hi/lo pairs.
// ---------------------------------------------------------------------------
__global__ __launch_bounds__(64) void gemm_qk_mfma_kernel(
    const unsigned short* __restrict__ Xh, const unsigned short* __restrict__ Xl,
    const unsigned short* __restrict__ WQh, const unsigned short* __restrict__ WQl,
    const unsigned short* __restrict__ WKh, const unsigned short* __restrict__ WKl,
    unsigned short* __restrict__ Qhi, unsigned short* __restrict__ Qlo,
    unsigned short* __restrict__ Khi, unsigned short* __restrict__ Klo)
{
  const int l = threadIdx.x;
  const int sel = blockIdx.y >> 7;
  const int m0 = (blockIdx.y & 127) * 64;
  const int n0 = blockIdx.x * 64;
  const int mr = l & 15, quad = l >> 4;
  const unsigned short* Bh = sel ? WKh : WQh;
  const unsigned short* Bl = sel ? WKl : WQl;
  unsigned short* Chi = sel ? Khi : Qhi;
  unsigned short* Clo = sel ? Klo : Qlo;

  f32x4 acc[4][4];
  const f32x4 zero = {0.f, 0.f, 0.f, 0.f};
#pragma unroll
  for (int i = 0; i < 4; ++i)
#pragma unroll
    for (int j = 0; j < 4; ++j) acc[i][j] = zero;

  const unsigned short* Ah = Xh + (size_t)(m0 + mr) * Dz + quad * 8;
  const unsigned short* Al = Xl + (size_t)(m0 + mr) * Dz + quad * 8;
  const unsigned short* Bhp = Bh + (size_t)(n0 + mr) * Dz + quad * 8;
  const unsigned short* Blp = Bl + (size_t)(n0 + mr) * Dz + quad * 8;

  for (int k0 = 0; k0 < Dz; k0 += 32) {
    short8 ah[4], al[4], bh[4], bl[4];
#pragma unroll
    for (int i = 0; i < 4; ++i) {
      ah[i] = *reinterpret_cast<const short8*>(Ah + (size_t)i * 16 * Dz + k0);
      al[i] = *reinterpret_cast<const short8*>(Al + (size_t)i * 16 * Dz + k0);
      bh[i] = *reinterpret_cast<const short8*>(Bhp + (size_t)i * 16 * Dz + k0);
      bl[i] = *reinterpret_cast<const short8*>(Blp + (size_t)i * 16 * Dz + k0);
    }
#pragma unroll
    for (int i = 0; i < 4; ++i)
#pragma unroll
      for (int j = 0; j < 4; ++j) {
        acc[i][j] = __builtin_amdgcn_mfma_f32_16x16x32_bf16(al[i], bh[j], acc[i][j], 0, 0, 0);
        acc[i][j] = __builtin_amdgcn_mfma_f32_16x16x32_bf16(ah[i], bl[j], acc[i][j], 0, 0, 0);
        acc[i][j] = __builtin_amdgcn_mfma_f32_16x16x32_bf16(ah[i], bh[j], acc[i][j], 0, 0, 0);
      }
  }

#pragma unroll
  for (int i = 0; i < 4; ++i)
#pragma unroll
    for (int j = 0; j < 4; ++j) {
      const int col = n0 + j * 16 + mr;
#pragma unroll
      for (int rr = 0; rr < 4; ++rr) {
        const size_t row = (size_t)(m0 + i * 16 + quad * 4 + rr);
        float v = acc[i][j][rr];
        unsigned short hv = f2bf(v);
        Chi[row * Dz + col] = hv;
        Clo[row * Dz + col] = f2bf(v - bf2f(hv));
      }
    }
}

// ---------------------------------------------------------------------------
// Layer-1 z pass, CHEAP plain-bf16 QK^T, now LDS-STAGED like attn_ctx:
// the block stages each 64-key Kh tile once (coalesced), all 4 waves read
// fragments from swizzled LDS. Arithmetic values/order identical -> invz
// bits unchanged.
// ---------------------------------------------------------------------------
__global__ __launch_bounds__(256) void attn_z_kernel(
    const unsigned short* __restrict__ Qh, const unsigned short* __restrict__ Kh,
    float* __restrict__ invzG)
{
  __shared__ unsigned short Ksh[64 * 64];  // 8KB: 64 keys x 128B (swizzled)
  const int tid = threadIdx.x;
  const int lane = tid & 63, wave = tid >> 6;
  const int c = lane & 15, quad = lane >> 4;
  int b, h, qt;
  attn_decode(blockIdx.x, b, h, qt);
  const size_t bT = (size_t)b * Tz;
  const int qrow = qt * 64 + wave * 16;
  const int hoff = h * DHz;

  const size_t qbase = (bT + qrow + c) * Dz + hoff + quad * 8;
  short8 q0 = *reinterpret_cast<const short8*>(Qh + qbase);
  short8 q1 = *reinterpret_cast<const short8*>(Qh + qbase + 32);

  const int sr = tid >> 3;        // row 0..31
  const int sj = (tid & 7) * 16;  // slot byte
  const unsigned short* khb = Kh + (bT + sr) * Dz + hoff + (tid & 7) * 8;
  char* KshB = (char*)Ksh;

  const f32x4 zf = {0.f, 0.f, 0.f, 0.f};
  float z[4] = {0.f, 0.f, 0.f, 0.f};

  for (int t = 0; t < 16; ++t) {
    const int k0 = t * 64;
    short8 g0 = *reinterpret_cast<const short8*>(khb + (size_t)k0 * Dz);
    short8 g1 = *reinterpret_cast<const short8*>(khb + (size_t)(k0 + 32) * Dz);
    *reinterpret_cast<short8*>(KshB + swz(sr, sj)) = g0;
    *reinterpret_cast<short8*>(KshB + swz(sr + 32, sj)) = g1;
    __syncthreads();
#pragma unroll
    for (int sub = 0; sub < 4; ++sub) {
      const int row = sub * 16 + c;
      short8 kh0 = *reinterpret_cast<const short8*>(KshB + swz(row, quad * 16));
      short8 kh1 = *reinterpret_cast<const short8*>(KshB + swz(row, 64 + quad * 16));
      f32x4 aA = zf, aB = zf;
      aA = __builtin_amdgcn_mfma_f32_16x16x32_bf16(q0, kh0, aA, 0, 0, 0);
      aB = __builtin_amdgcn_mfma_f32_16x16x32_bf16(q1, kh1, aB, 0, 0, 0);
#pragma unroll
      for (int rr = 0; rr < 4; ++rr) z[rr] += __expf((aA[rr] + aB[rr]) * 0.125f);
    }
    __syncthreads();  // reads done before next stage overwrites
  }
#pragma unroll
  for (int w = 1; w < 16; w <<= 1) {
#pragma unroll
    for (int rr = 0; rr < 4; ++rr) z[rr] += __shfl_xor(z[rr], w);
  }
  if (c == 0) {
#pragma unroll
    for (int rr = 0; rr < 4; ++rr)
      invzG[(size_t)(b * Hz + h) * Tz + qrow + quad * 4 + rr] = 1.f / z[rr];
  }
}

// ---------------------------------------------------------------------------
// Layer-1 ctx with LDS-STAGED K/V (proven round 6). All arithmetic values,
// order and PART slots bit-identical to round 4.
// ---------------------------------------------------------------------------
__global__ __launch_bounds__(256) void attn_ctx_kernel(
    const unsigned short* __restrict__ Qh, const unsigned short* __restrict__ Ql,
    const unsigned short* __restrict__ Kh, const unsigned short* __restrict__ Kl,
    const unsigned short* __restrict__ Vt, const float* __restrict__ invzG,
    unsigned short* __restrict__ ctx, float* __restrict__ part)
{
  __shared__ unsigned short Ksh[64 * 64];  // 8KB: 64 keys x 128B (swizzled)
  __shared__ unsigned short Ksl[64 * 64];  // 8KB
  __shared__ unsigned short Vsh[64 * 64];  // 8KB: 64 features x 128B (swizzled)
  __shared__ unsigned short Pld[64][76];   // 9.5KB
  __shared__ float CSPt[4][64];            // per-wave per-tile colsum partials
  const int tid = threadIdx.x;
  const int lane = tid & 63, wave = tid >> 6;
  const int c = lane & 15, quad = lane >> 4;
  int b, h, qt;
  attn_decode(blockIdx.x, b, h, qt);
  const size_t bT = (size_t)b * Tz;
  const int qrow = qt * 64 + wave * 16;
  const int hoff = h * DHz;
  const int lidx = b * 128 + h * 16 + qt;  // logical PART slot

  const size_t qbase = (bT + qrow + c) * Dz + hoff + quad * 8;
  short8 q0h = *reinterpret_cast<const short8*>(Qh + qbase);
  short8 q1h = *reinterpret_cast<const short8*>(Qh + qbase + 32);
  short8 q0l = *reinterpret_cast<const short8*>(Ql + qbase);
  short8 q1l = *reinterpret_cast<const short8*>(Ql + qbase + 32);

  float invz[4];
#pragma unroll
  for (int rr = 0; rr < 4; ++rr)
    invz[rr] = invzG[(size_t)(b * Hz + h) * Tz + qrow + quad * 4 + rr];

  // staging coords: 256 threads cover 32 rows x 8 slots (16B) per pass
  const int sr = tid >> 3;        // row 0..31
  const int sj = (tid & 7) * 16;  // slot byte 0..112
  const unsigned short* khb = Kh + (bT + sr) * Dz + hoff + (tid & 7) * 8;
  const unsigned short* klb = Kl + (bT + sr) * Dz + hoff + (tid & 7) * 8;
  const unsigned short* vtb = Vt + ((size_t)(b * Hz + h) * DHz + sr) * Tz + (tid & 7) * 8;

  const f32x4 zf = {0.f, 0.f, 0.f, 0.f};
  f32x4 ot[4] = {zf, zf, zf, zf};

  char* KshB = (char*)Ksh;
  char* KslB = (char*)Ksl;
  char* VshB = (char*)Vsh;

  for (int t = 0; t < 16; ++t) {
    const int k0 = t * 64;
    // ---- stage tile t: coalesced global -> regs -> swizzled LDS ----
    short8 g0 = *reinterpret_cast<const short8*>(khb + (size_t)k0 * Dz);
    short8 g1 = *reinterpret_cast<const short8*>(khb + (size_t)(k0 + 32) * Dz);
    short8 g2 = *reinterpret_cast<const short8*>(klb + (size_t)k0 * Dz);
    short8 g3 = *reinterpret_cast<const short8*>(klb + (size_t)(k0 + 32) * Dz);
    short8 g4 = *reinterpret_cast<const short8*>(vtb + k0);
    short8 g5 = *reinterpret_cast<const short8*>(vtb + 32 * Tz + k0);
    // prev tile fully consumed at the tail barrier of the previous iteration
    *reinterpret_cast<short8*>(KshB + swz(sr, sj)) = g0;
    *reinterpret_cast<short8*>(KshB + swz(sr + 32, sj)) = g1;
    *reinterpret_cast<short8*>(KslB + swz(sr, sj)) = g2;
    *reinterpret_cast<short8*>(KslB + swz(sr + 32, sj)) = g3;
    *reinterpret_cast<short8*>(VshB + swz(sr, sj)) = g4;
    *reinterpret_cast<short8*>(VshB + swz(sr + 32, sj)) = g5;
    __syncthreads();  // staged data visible

    // ---- QK^T subtiles (bf16x3, 2-acc split) ----
#pragma unroll
    for (int sub = 0; sub < 4; ++sub) {
      const int row = sub * 16 + c;
      short8 kh0 = *reinterpret_cast<const short8*>(KshB + swz(row, quad * 16));
      short8 kh1 = *reinterpret_cast<const short8*>(KshB + swz(row, 64 + quad * 16));
      short8 kl0 = *reinterpret_cast<const short8*>(KslB + swz(row, quad * 16));
      short8 kl1 = *reinterpret_cast<const short8*>(KslB + swz(row, 64 + quad * 16));
      f32x4 aA = zf, aB = zf;
      aA = __builtin_amdgcn_mfma_f32_16x16x32_bf16(q0h, kh0, aA, 0, 0, 0);
      aB = __builtin_amdgcn_mfma_f32_16x16x32_bf16(q1h, kh1, aB, 0, 0, 0);
      aA = __builtin_amdgcn_mfma_f32_16x16x32_bf16(q0h, kl0, aA, 0, 0, 0);
      aB = __builtin_amdgcn_mfma_f32_16x16x32_bf16(q1h, kl1, aB, 0, 0, 0);
      aA = __builtin_amdgcn_mfma_f32_16x16x32_bf16(q0l, kh0, aA, 0, 0, 0);
      aB = __builtin_amdgcn_mfma_f32_16x16x32_bf16(q1l, kh1, aB, 0, 0, 0);
      float p[4];
#pragma unroll
      for (int rr = 0; rr < 4; ++rr)
        p[rr] = __expf((aA[rr] + aB[rr]) * 0.125f) * invz[rr];
      float cs = p[0] + p[1] + p[2] + p[3];
      cs += __shfl_xor(cs, 16);
      cs += __shfl_xor(cs, 32);
      if (quad == 0) CSPt[wave][sub * 16 + c] = cs;  // key visited once
#pragma unroll
      for (int rr = 0; rr < 4; ++rr)
        Pld[(wave << 4) + quad * 4 + rr][sub * 16 + c] = f2bf(p[rr]);
    }

    // ---- PV from LDS ----
    union { short8 v; ushort4 hh[2]; } pb0, pb1;
    pb0.hh[0] = *reinterpret_cast<const ushort4*>(&Pld[(wave << 4) + c][quad * 8]);
    pb0.hh[1] = *reinterpret_cast<const ushort4*>(&Pld[(wave << 4) + c][quad * 8 + 4]);
    pb1.hh[0] = *reinterpret_cast<const ushort4*>(&Pld[(wave << 4) + c][32 + quad * 8]);
    pb1.hh[1] = *reinterpret_cast<const ushort4*>(&Pld[(wave << 4) + c][32 + quad * 8 + 4]);
#pragma unroll
    for (int ds = 0; ds < 4; ++ds) {
      const int row = ds * 16 + c;
      short8 v0 = *reinterpret_cast<const short8*>(VshB + swz(row, quad * 16));
      short8 v1 = *reinterpret_cast<const short8*>(VshB + swz(row, 64 + quad * 16));
      ot[ds] = __builtin_amdgcn_mfma_f32_16x16x32_bf16(v0, pb0.v, ot[ds], 0, 0, 0);
      ot[ds] = __builtin_amdgcn_mfma_f32_16x16x32_bf16(v1, pb1.v, ot[ds], 0, 0, 0);
    }
    __syncthreads();  // all LDS reads done; CSPt complete across waves

    // ---- deterministic per-tile colsum combine (same 4-addend order) ----
    if (tid < 64) {
      float v = ((CSPt[0][tid] + CSPt[1][tid]) + CSPt[2][tid]) + CSPt[3][tid];
      part[(size_t)lidx * 1024 + k0 + tid] = v * (1.f / Hz);
    }
  }

  const size_t cb = (bT + qrow + c) * Dz + hoff;
#pragma unroll
  for (int ds = 0; ds < 4; ++ds) {
    ushort4 pk;
    pk.x = f2bf(ot[ds][0]); pk.y = f2bf(ot[ds][1]);
    pk.z = f2bf(ot[ds][2]); pk.w = f2bf(ot[ds][3]);
    *reinterpret_cast<ushort4*>(&ctx[cb + ds * 16 + quad * 4]) = pk;
  }
}

// ---------------------------------------------------------------------------
// Deterministic colsum reduce: CS1[b,key] = sum over the 128 (h,qt) block
// partials in fixed ascending order. One thread per output.
// ---------------------------------------------------------------------------
__global__ __launch_bounds__(256) void colsum_reduce_kernel(
    const float* __restrict__ part, float* __restrict__ colsum)
{
  const int i = blockIdx.x * 256 + threadIdx.x;  // 0..8191
  const int b = i >> 10, k = i & 1023;
  const float* p = part + (size_t)(b * 128) * 1024 + k;
  float s = 0.f;
  for (int j = 0; j < 128; ++j) s += p[(size_t)j * 1024];
  colsum[i] = s;
}

// ---------------------------------------------------------------------------
// Layer-2 MFMA attention (masked), with k-tile range skipping. CS2 feeds only
// the continuous wl softmax -> atomics are fine here. XCD-swizzled decode.
// ---------------------------------------------------------------------------
__global__ __launch_bounds__(256) void attn_mfma2_kernel(
    const unsigned short* __restrict__ Qh, const unsigned short* __restrict__ Kh,
    const unsigned short* __restrict__ Vt, const int* __restrict__ ids,
    const int* __restrict__ wst,
    unsigned short* __restrict__ ctx, float* __restrict__ colsum)
{
  __shared__ unsigned short Pld[64][76];
  __shared__ float csb[1024];

  const int tid = threadIdx.x;
  const int lane = tid & 63, wave = tid >> 6;
  const int c = lane & 15, quad = lane >> 4;
  int b, h, qt;
  attn_decode(blockIdx.x, b, h, qt);
  const size_t bT = (size_t)b * Tz;
  const int qrow = qt * 64 + wave * 16;
  const int hoff = h * DHz;

  for (int i = tid; i < 1024; i += 256) csb[i] = 0.f;

  const int id_lo = ids[bT + qt * 64];
  const int id_hi = ids[bT + qt * 64 + 63];
  const int klo = wst[b * (Tz + 1) + id_lo];
  const int khi = wst[b * (Tz + 1) + id_hi + 1];
  const int t0 = klo >> 6, t1 = (khi - 1) >> 6;

  const size_t qbase = (bT + qrow + c) * Dz + hoff + quad * 8;
  short8 q0 = *reinterpret_cast<const short8*>(Qh + qbase);
  short8 q1 = *reinterpret_cast<const short8*>(Qh + qbase + 32);

  int qid[4];
#pragma unroll
  for (int rr = 0; rr < 4; ++rr) qid[rr] = ids[bT + qrow + quad * 4 + rr];
  __syncthreads();  // csb zeros visible before pass-2 atomics

  const f32x4 zf = {0.f, 0.f, 0.f, 0.f};

  // pass 1: z
  float z[4] = {0.f, 0.f, 0.f, 0.f};
  for (int t = t0; t <= t1; ++t) {
    const int k0 = t * 64;
#pragma unroll
    for (int sub = 0; sub < 4; ++sub) {
      const size_t kb = (bT + k0 + sub * 16 + c) * Dz + hoff + quad * 8;
      short8 kh0 = *reinterpret_cast<const short8*>(Kh + kb);
      short8 kh1 = *reinterpret_cast<const short8*>(Kh + kb + 32);
      f32x4 acc = zf;
      acc = __builtin_amdgcn_mfma_f32_16x16x32_bf16(q0, kh0, acc, 0, 0, 0);
      acc = __builtin_amdgcn_mfma_f32_16x16x32_bf16(q1, kh1, acc, 0, 0, 0);
      int kidv = ids[bT + k0 + sub * 16 + c];
#pragma unroll
      for (int rr = 0; rr < 4; ++rr) {
        float e = __expf(acc[rr] * 0.125f);
        if (qid[rr] != kidv) e = 0.f;
        z[rr] += e;
      }
    }
  }
#pragma unroll
  for (int w = 1; w < 16; w <<= 1) {
#pragma unroll
    for (int rr = 0; rr < 4; ++rr) z[rr] += __shfl_xor(z[rr], w);
  }
  float invz[4];
#pragma unroll
  for (int rr = 0; rr < 4; ++rr) invz[rr] = 1.f / z[rr];

  // pass 2: P, colsum, PV
  f32x4 ot[4] = {zf, zf, zf, zf};
  for (int t = t0; t <= t1; ++t) {
    const int k0 = t * 64;
#pragma unroll
    for (int sub = 0; sub < 4; ++sub) {
      const size_t kb = (bT + k0 + sub * 16 + c) * Dz + hoff + quad * 8;
      short8 kh0 = *reinterpret_cast<const short8*>(Kh + kb);
      short8 kh1 = *reinterpret_cast<const short8*>(Kh + kb + 32);
      f32x4 acc = zf;
      acc = __builtin_amdgcn_mfma_f32_16x16x32_bf16(q0, kh0, acc, 0, 0, 0);
      acc = __builtin_amdgcn_mfma_f32_16x16x32_bf16(q1, kh1, acc, 0, 0, 0);
      int kidv = ids[bT + k0 + sub * 16 + c];
      float p[4];
#pragma unroll
      for (int rr = 0; rr < 4; ++rr) {
        float e = __expf(acc[rr] * 0.125f);
        if (qid[rr] != kidv) e = 0.f;
        p[rr] = e * invz[rr];
      }
      float cs = p[0] + p[1] + p[2] + p[3];
      cs += __shfl_xor(cs, 16);
      cs += __shfl_xor(cs, 32);
      if (quad == 0) atomicAdd(&csb[k0 + sub * 16 + c], cs);
#pragma unroll
      for (int rr = 0; rr < 4; ++rr)
        Pld[(wave << 4) + quad * 4 + rr][sub * 16 + c] = f2bf(p[rr]);
    }
    union { short8 v; ushort4 hh[2]; } pb0, pb1;
    pb0.hh[0] = *reinterpret_cast<const ushort4*>(&Pld[(wave << 4) + c][quad * 8]);
    pb0.hh[1] = *reinterpret_cast<const ushort4*>(&Pld[(wave << 4) + c][quad * 8 + 4]);
    pb1.hh[0] = *reinterpret_cast<const ushort4*>(&Pld[(wave << 4) + c][32 + quad * 8]);
    pb1.hh[1] = *reinterpret_cast<const ushort4*>(&Pld[(wave << 4) + c][32 + quad * 8 + 4]);
#pragma unroll
    for (int ds = 0; ds < 4; ++ds) {
      const size_t va = ((size_t)((b * Hz + h) * DHz + ds * 16 + c)) * Tz + k0 + quad * 8;
      short8 v0 = *reinterpret_cast<const short8*>(Vt + va);
      short8 v1 = *reinterpret_cast<const short8*>(Vt + va + 32);
      ot[ds] = __builtin_amdgcn_mfma_f32_16x16x32_bf16(v0, pb0.v, ot[ds], 0, 0, 0);
      ot[ds] = __builtin_amdgcn_mfma_f32_16x16x32_bf16(v1, pb1.v, ot[ds], 0, 0, 0);
    }
  }

  const size_t cb = (bT + qrow + c) * Dz + hoff;
#pragma unroll
  for (int ds = 0; ds < 4; ++ds) {
    ushort4 pk;
    pk.x = f2bf(ot[ds][0]); pk.y = f2bf(ot[ds][1]);
    pk.z = f2bf(ot[ds][2]); pk.w = f2bf(ot[ds][3]);
    *reinterpret_cast<ushort4*>(&ctx[cb + ds * 16 + quad * 4]) = pk;
  }
  __syncthreads();
  for (int i = tid; i < 1024; i += 256)
    atomicAdd(&colsum[bT + i], csb[i] * (1.f / Hz));
}

// ---------------------------------------------------------------------------
// out = LayerNorm(resid + delta). resid fp32 (residf) if non-null else bf16.
// ---------------------------------------------------------------------------
__global__ __launch_bounds__(256) void ln_kernel(const float* __restrict__ residf,
    const unsigned short* __restrict__ residbf, const float* __restrict__ delta,
    float* __restrict__ outf, unsigned short* __restrict__ outbf)
{
  const size_t base = (size_t)blockIdx.x * Dz;
  const int tid = threadIdx.x;
  float r0, r1;
  if (residf) {
    r0 = residf[base + tid]; r1 = residf[base + tid + 256];
  } else {
    r0 = bf2f(residbf[base + tid]); r1 = bf2f(residbf[base + tid + 256]);
  }
  float x0 = r0 + delta[base + tid];
  float x1 = r1 + delta[base + tid + 256];
  __shared__ float red[4];
  float s = x0 + x1;
#pragma unroll
  for (int off = 32; off; off >>= 1) s += __shfl_down(s, off);
  if ((tid & 63) == 0) red[tid >> 6] = s;
  __syncthreads();
  const float mean = (red[0] + red[1] + red[2] + red[3]) * (1.f / Dz);
  __syncthreads();
  float d0 = x0 - mean, d1 = x1 - mean;
  float v = d0 * d0 + d1 * d1;
#pragma unroll
  for (int off = 32; off; off >>= 1) v += __shfl_down(v, off);
  if ((tid & 63) == 0) red[tid >> 6] = v;
  __syncthreads();
  const float var = (red[0] + red[1] + red[2] + red[3]) * (1.f / Dz);
  const float rstd = rsqrtf(var + 1e-5f);
  float y0 = d0 * rstd, y1 = d1 * rstd;
  if (outf) {
    outf[base + tid] = y0;
    outf[base + tid + 256] = y1;
  }
  outbf[base + tid] = f2bf(y0);
  outbf[base + tid + 256] = f2bf(y1);
}

// ---------------------------------------------------------------------------
// Per batch: min-max normalize colsum, threshold 0.5, run-length window scan.
// PARALLELIZED: cur==wb[t] always after step t, so a transition occurs iff
// wb[t]!=wb[t-1] (the merge rule only gates start/wid). Bits are packed via
// __ballot; thread 0 scans only SET BITS of the transition mask in registers
// (identical start/wid decisions -> bit-identical wst/nwin); ids filled by
// parallel binary search (sids[t] = #closes <= t, identical to reference).
// ---------------------------------------------------------------------------
__global__ __launch_bounds__(256) void window_ids_kernel(const float* __restrict__ cs,
    int* __restrict__ ids, int* __restrict__ wst, int* __restrict__ nwin)
{
  const int b = blockIdx.x, tid = threadIdx.x;
  __shared__ float vals[Tz];
  __shared__ int swst[Tz + 1];
  __shared__ unsigned long long words[16];
  __shared__ float rmin[4], rmax[4];
  __shared__ int snw;
  float mn = INFINITY, mx = -INFINITY;
  for (int t = tid; t < Tz; t += 256) {
    float v = cs[b * Tz + t];
    vals[t] = v;
    mn = fminf(mn, v); mx = fmaxf(mx, v);
  }
#pragma unroll
  for (int off = 32; off; off >>= 1) {
    mn = fminf(mn, __shfl_down(mn, off));
    mx = fmaxf(mx, __shfl_down(mx, off));
  }
  if ((tid & 63) == 0) { rmin[tid >> 6] = mn; rmax[tid >> 6] = mx; }
  __syncthreads();
  mn = fminf(fminf(rmin[0], rmin[1]), fminf(rmin[2], rmin[3]));
  mx = fmaxf(fmaxf(rmax[0], rmax[1]), fmaxf(rmax[2], rmax[3]));
  const float inv = 1.f / (mx - mn + 1e-8f);
  const int lane = tid & 63, wave = tid >> 6;
#pragma unroll
  for (int pass = 0; pass < 4; ++pass) {
    const int t = pass * 256 + wave * 64 + lane;
    const bool bit = ((vals[t] - mn) * inv) >= 0.5f;  // identical threshold op
    unsigned long long m = __ballot(bit);
    if (lane == 0) words[pass * 4 + wave] = m;
  }
  __syncthreads();
  if (tid == 0) {
    int start = 0, wid = 0;
    swst[0] = 0;
    unsigned long long carry = 0;
    for (int i = 0; i < 16; ++i) {
      const unsigned long long wi = words[i];
      unsigned long long tr = wi ^ ((wi << 1) | carry);
      carry = wi >> 63;
      if (i == 0) tr &= ~1ULL;  // t=0 is not a transition
      while (tr) {
        const int t = i * 64 + __builtin_ctzll(tr);
        tr &= tr - 1;
        if (start + 1 != t) { start = t; ++wid; swst[wid] = t; }
      }
    }
    nwin[b] = wid + 1;
    swst[wid + 1] = Tz;
    snw = wid + 1;
  }
  __syncthreads();
  const int nw = snw;
  for (int j = tid; j <= nw; j += 256) wst[b * (Tz + 1) + j] = swst[j];
  for (int t = tid; t < Tz; t += 256) {
    int lo = 0, hi = nw;  // swst[0]=0 <= t, swst[nw]=Tz > t
    while (hi - lo > 1) {
      const int mid = (lo + hi) >> 1;
      if (swst[mid] <= t) lo = mid; else hi = mid;
    }
    ids[b * Tz + t] = lo;
  }
}

// ---------------------------------------------------------------------------
// wl[b,:] = softmax over keys of layer-2 colsum.
// ---------------------------------------------------------------------------
__global__ __launch_bounds__(256) void wl_softmax_kernel(const float* __restrict__ cs,
                                                         float* __restrict__ wl)
{
  const int b = blockIdx.x, tid = threadIdx.x;
  __shared__ float vals[Tz];
  __shared__ float red[4];
  float mx = -INFINITY;
  for (int t = tid; t < Tz; t += 256) {
    float v = cs[b * Tz + t];
    vals[t] = v;
    mx = fmaxf(mx, v);
  }
#pragma unroll
  for (int off = 32; off; off >>= 1) mx = fmaxf(mx, __shfl_down(mx, off));
  if ((tid & 63) == 0) red[tid >> 6] = mx;
  __syncthreads();
  mx = fmaxf(fmaxf(red[0], red[1]), fmaxf(red[2], red[3]));
  __syncthreads();
  float se = 0.f;
  for (int t = tid; t < Tz; t += 256) {
    float e = expf(vals[t] - mx);
    vals[t] = e;
    se += e;
  }
#pragma unroll
  for (int off = 32; off; off >>= 1) se += __shfl_down(se, off);
  if ((tid & 63) == 0) red[tid >> 6] = se;
  __syncthreads();
  const float inv = 1.f / (red[0] + red[1] + red[2] + red[3]);
  for (int t = tid; t < Tz; t += 256) wl[b * Tz + t] = vals[t] * inv;
}

// ---------------------------------------------------------------------------
// Fused outputs: word_tokens (blocks 0..8191), winmap (8192..16383),
// copy_x (16384..20479).
// ---------------------------------------------------------------------------
__global__ __launch_bounds__(256) void outputs_kernel(
    const unsigned short* __restrict__ outl, const float* __restrict__ wl,
    const int* __restrict__ wst, const int* __restrict__ nwin,
    const int* __restrict__ ids, const float* __restrict__ x,
    float* __restrict__ out, float* __restrict__ out2)
{
  const int bid = blockIdx.x;
  const int tid = threadIdx.x;
  if (bid < 8192) {  // word_tokens
    const int w = bid & (Tz - 1);
    const int b = bid >> 10;
    float a0 = 0.f, a1 = 0.f;
    if (w < nwin[b]) {
      const int s = wst[b * (Tz + 1) + w], e = wst[b * (Tz + 1) + w + 1];
      for (int t = s; t < e; ++t) {
        const float sc = wl[b * Tz + t];
        const unsigned short* p = &outl[((size_t)(b * Tz + t)) * Dz];
        a0 += bf2f(p[tid]) * sc;
        a1 += bf2f(p[tid + 256]) * sc;
      }
    }
    float* o = &out[((size_t)(b * 2 * Tz + w)) * Dz];
    o[tid] = a0;
    o[tid + 256] = a1;
  } else if (bid < 16384) {  // winmap
    const int lb = bid - 8192;
    const int w = lb & (Tz - 1);
    const int b = lb >> 10;
    const int j = tid * 4;
    int4 id4 = *reinterpret_cast<const int4*>(&ids[b * Tz + j]);
    float4 v;
    v.x = (id4.x == w) ? 1.f : 0.f;
    v.y = (id4.y == w) ? 1.f : 0.f;
    v.z = (id4.z == w) ? 1.f : 0.f;
    v.w = (id4.w == w) ? 1.f : 0.f;
    *reinterpret_cast<float4*>(&out2[((size_t)(b * Tz + w)) * Tz + j]) = v;
  } else {  // copy_x
    size_t i = (size_t)(bid - 16384) * 256 + tid;
    size_t idx = i * 4;
    size_t rowi = idx >> 9;
    size_t d = idx & 511;
    size_t b = rowi >> 10, t = rowi & 1023;
    float4 v = *reinterpret_cast<const float4*>(&x[idx]);
    *reinterpret_cast<float4*>(&out[(((b * 2 * Tz) + Tz + t) << 9) + d]) = v;
  }
}

// ---------------------------------------------------------------------------
// Orchestration: 22 dispatches. window_ids parallelized (ballot + bit-scan);
// attn_z LDS-staged like attn_ctx.
// ---------------------------------------------------------------------------
extern "C" void kernel_launch(void* const* d_in, const int* in_sizes, int n_in,
                              void* d_out, int out_size, void* d_ws, size_t ws_size,
                              hipStream_t stream)
{
  (void)in_sizes; (void)n_in; (void)out_size; (void)ws_size;
  const float* x     = (const float*)d_in[0];
  const float* vqkv  = (const float*)d_in[1];
  const float* voutw = (const float*)d_in[2];
  const float* vw1   = (const float*)d_in[3];
  const float* vw2   = (const float*)d_in[4];
  const float* lqkv  = (const float*)d_in[5];
  const float* loutw = (const float*)d_in[6];
  const float* lw1   = (const float*)d_in[7];
  const float* lw2   = (const float*)d_in[8];
  float* out = (float*)d_out;
  float* ws  = (float*)d_ws;

  unsigned short* QLbf = (unsigned short*)(ws + 0);        // bf16 Q lo (L1)
  unsigned short* KLbf = (unsigned short*)(ws + 2097152);  // bf16 K lo (L1)
  float* PROJ = ws + 0;         // written after attn_ctx (QL/KL dead)
  float* Y1   = ws + 4194304;
  unsigned short* QHbf = (unsigned short*)(ws + 8388608);   // bf16 Q hi (L1+L2)
  unsigned short* KHbf = (unsigned short*)(ws + 10485760);  // bf16 K hi (L1+L2)
  unsigned short* VT   = (unsigned short*)(ws + 12582912);
  unsigned short* SLOT1 = (unsigned short*)(ws + 14680064); // attn ctx bf16
  unsigned short* SLOT2 = (unsigned short*)(ws + 16777216); // LN bf16 out
  unsigned short* HIDbf = (unsigned short*)(ws + 18874368); // FFN hidden
  unsigned short* XBF   = (unsigned short*)(ws + 18874368); // x hi bf16 (pre-FFN)
  float* PART = ws + 18874368;  // colsum block partials (1024x1024); written
                                // by attn_ctx after XBF/XLO dead, dead by FFN1
  unsigned short* XLO = (unsigned short*)(ws + 20971520);   // x lo bf16
  // bf16 transposed weights (WLQ0..2 contiguous -> merged [1536,512] matrix)
  unsigned short* WVQV = (unsigned short*)(ws + 27262976);
  unsigned short* WVO  = (unsigned short*)(ws + 27394048);
  unsigned short* WV1  = (unsigned short*)(ws + 27525120);
  unsigned short* WV2  = (unsigned short*)(ws + 28049408);
  unsigned short* WLQ0 = (unsigned short*)(ws + 28573696);
  unsigned short* WLQ1 = (unsigned short*)(ws + 28704768);
  unsigned short* WLQ2 = (unsigned short*)(ws + 28835840);
  unsigned short* WLO  = (unsigned short*)(ws + 28966912);
  unsigned short* WL1  = (unsigned short*)(ws + 29097984);
  unsigned short* WL2  = (unsigned short*)(ws + 29622272);
  // small buffers
  float* CS1   = ws + 30146560;
  float* CS2   = ws + 30154752;
  float* WLs   = ws + 30162944;
  int*   IDS   = (int*)(ws + 30171136);
  int*   WST   = (int*)(ws + 30179328);
  int*   NWIN  = (int*)(ws + 30187776);
  float* INVZ  = ws + 30195968;  // (B*H*T) = 65536 floats
  // layer-1 Q/K weights, bf16 transposed hi/lo (512x512 each = 131072 floats)
  unsigned short* WQH = (unsigned short*)(ws + 30261504);
  unsigned short* WQL = (unsigned short*)(ws + 30392576);
  unsigned short* WKH = (unsigned short*)(ws + 30523648);
  unsigned short* WKL = (unsigned short*)(ws + 30654720);

  dim3 blk(256);

  // ---- fused prep: 12 wconv + zero + fconv(hi/lo) ----
  PrepArgs P;
  auto setw = [&](int i, const float* s, unsigned short* d, unsigned short* dl,
                  int K, int N, int b0) {
    P.d[i].src = s; P.d[i].dst = d; P.d[i].dstlo = dl;
    P.d[i].K = K; P.d[i].N = N; P.d[i].blk0 = b0;
  };
  int b0 = 0;
  setw(0, vqkv + 2 * Dz * Dz, WVQV, nullptr, Dz, Dz, b0); b0 += 256;
  setw(1, voutw, WVO, nullptr, Dz, Dz, b0); b0 += 256;
  setw(2, vw1, WV1, nullptr, Dz, FFz, b0); b0 += 1024;
  setw(3, vw2, WV2, nullptr, FFz, Dz, b0); b0 += 1024;
  setw(4, lqkv + 0 * Dz * Dz, WLQ0, nullptr, Dz, Dz, b0); b0 += 256;
  setw(5, lqkv + 1 * Dz * Dz, WLQ1, nullptr, Dz, Dz, b0); b0 += 256;
  setw(6, lqkv + 2 * Dz * Dz, WLQ2, nullptr, Dz, Dz, b0); b0 += 256;
  setw(7, loutw, WLO, nullptr, Dz, Dz, b0); b0 += 256;
  setw(8, lw1, WL1, nullptr, Dz, FFz, b0); b0 += 1024;
  setw(9, lw2, WL2, nullptr, FFz, Dz, b0); b0 += 1024;
  setw(10, vqkv + 0 * Dz * Dz, WQH, WQL, Dz, Dz, b0); b0 += 256;
  setw(11, vqkv + 1 * Dz * Dz, WKH, WKL, Dz, Dz, b0); b0 += 256;
  P.nwc = b0;  // 6144
  prep_kernel<<<dim3(P.nwc + 64 + 4096), blk, 0, stream>>>(P, x, XBF, XLO, CS1);

  auto mgemm = [&](const unsigned short* A, const unsigned short* BT, void* p1,
                   void* p2, void* p3, int K, int N, int mode) {
    mfma_gemm_kernel<<<dim3(N / 64, Mz / 64), dim3(64), 0, stream>>>(
        A, BT, p1, p2, p3, K, N, mode);
  };

  // ---------------- layer 1 (vanilla) ----------------
  gemm_qk_mfma_kernel<<<dim3(8, 256), dim3(64), 0, stream>>>(
      XBF, XLO, WQH, WQL, WKH, WKL, QHbf, QLbf, KHbf, KLbf);
  attn_z_kernel<<<dim3(Bz * Hz * 16), blk, 0, stream>>>(QHbf, KHbf, INVZ);
  mgemm(XBF, WVQV, VT, nullptr, nullptr, Dz, Dz, 4);        // V -> V^T (XBF/XLO dead)
  attn_ctx_kernel<<<dim3(Bz * Hz * 16), blk, 0, stream>>>(
      QHbf, QLbf, KHbf, KLbf, VT, INVZ, SLOT1, PART);
  colsum_reduce_kernel<<<dim3(32), blk, 0, stream>>>(PART, CS1);
  window_ids_kernel<<<dim3(Bz), blk, 0, stream>>>(CS1, IDS, WST, NWIN);
  mgemm(SLOT1, WVO, PROJ, nullptr, nullptr, Dz, Dz, 0);     // proj (QL/KL dead)
  ln_kernel<<<dim3(Mz), blk, 0, stream>>>(x, nullptr, PROJ, Y1, SLOT2);
  mgemm(SLOT2, WV1, HIDbf, nullptr, nullptr, Dz, FFz, 2);   // FFN1 (PART dead)
  mgemm(HIDbf, WV2, PROJ, nullptr, nullptr, FFz, Dz, 0);    // FFN2
  ln_kernel<<<dim3(Mz), blk, 0, stream>>>(Y1, nullptr, PROJ, nullptr, SLOT2);

  // ---------------- layer 2 (block-diagonal window mask) ----------------
  mgemm(SLOT2, WLQ0, QHbf, KHbf, VT, Dz, 3 * Dz, 5);        // merged QKV
  attn_mfma2_kernel<<<dim3(Bz * Hz * 16), blk, 0, stream>>>(
      QHbf, KHbf, VT, IDS, WST, SLOT1, CS2);
  mgemm(SLOT1, WLO, PROJ, nullptr, nullptr, Dz, Dz, 0);
  ln_kernel<<<dim3(Mz), blk, 0, stream>>>(nullptr, SLOT2, PROJ, Y1, SLOT2);
  mgemm(SLOT2, WL1, HIDbf, nullptr, nullptr, Dz, FFz, 2);
  mgemm(HIDbf, WL2, PROJ, nullptr, nullptr, FFz, Dz, 0);
  ln_kernel<<<dim3(Mz), blk, 0, stream>>>(Y1, nullptr, PROJ, nullptr, SLOT2);

  // ---------------- pooling + outputs ----------------
  wl_softmax_kernel<<<dim3(Bz), blk, 0, stream>>>(CS2, WLs);
  outputs_kernel<<<dim3(20480), blk, 0, stream>>>(SLOT2, WLs, WST, NWIN, IDS, x,
                                                  out, out + (size_t)Bz * 2 * Tz * Dz);
}

// Round 8
// 599.519 us; speedup vs baseline: 1.8111x; 1.2563x over previous
//
#include <hip/hip_runtime.h>
#include <math.h>

// Problem constants (fixed by setup_inputs)
#define Bz 8
#define Tz 1024
#define Dz 512
#define FFz 2048
#define Hz 8
#define DHz 64
#define Mz (Bz * Tz)  // 8192 rows

typedef __attribute__((ext_vector_type(8))) short short8;   // 8 bf16 (4 VGPRs)
typedef __attribute__((ext_vector_type(4))) float f32x4;    // MFMA accumulator

__device__ inline unsigned short f2bf(float f) {  // RNE fp32 -> bf16
  unsigned u = __builtin_bit_cast(unsigned, f);
  return (unsigned short)((u + 0x7FFFu + ((u >> 16) & 1u)) >> 16);
}
__device__ inline float bf2f(unsigned short h) {
  unsigned u = (unsigned)h << 16;
  return __builtin_bit_cast(float, u);
}

// XCD-aware decode for the 1024-block attention grids (8 XCDs round-robin by
// blockIdx). g = xcd + 8*(qt + 16*bhi), bh = bhi*8 + xcd.
__device__ inline void attn_decode(int g, int& b, int& h, int& qt) {
  const int xcd = g & 7;
  const int j = g >> 3;
  qt = j & 15;
  const int bh = ((j >> 4) << 3) | xcd;
  b = bh >> 3;
  h = bh & 7;
}

// Swizzled byte offset inside a [64 rows x 128B] LDS tile: 16B slot XOR'd by
// row&7 -> every fragment read/write lands at the 8-words/bank LDS floor.
__device__ inline int swz(int row, int slotByte) {
  return row * 128 + (slotByte ^ ((row & 7) << 4));
}

// ---------------------------------------------------------------------------
// Fused prep: 12 weight convert+transposes (fp32 [K,N] -> bf16 [N,K], with
// optional lo-residual output) + colsum zero-fill + x -> bf16 hi/lo.
// ---------------------------------------------------------------------------
struct WDesc { const float* src; unsigned short* dst; unsigned short* dstlo;
               int K; int N; int blk0; };
struct PrepArgs { WDesc d[12]; int nwc; };

__global__ __launch_bounds__(256) void prep_kernel(PrepArgs P,
    const float* __restrict__ x, unsigned short* __restrict__ xbf,
    unsigned short* __restrict__ xlo, float* __restrict__ csz)
{
  const int bid = blockIdx.x;
  const int tid = threadIdx.x;
  if (bid < P.nwc) {  // wconv slice
    int i = 0;
    while (i < 11 && bid >= P.d[i + 1].blk0) ++i;
    const WDesc w = P.d[i];
    const int lb = bid - w.blk0;
    const int nbn = w.N / 32;
    const int bn = (lb % nbn) * 32, bk = (lb / nbn) * 32;
    __shared__ float t[32][33];
    const int tx = tid & 31, ty = tid >> 5;
#pragma unroll
    for (int r = 0; r < 32; r += 8)
      t[ty + r][tx] = w.src[(size_t)(bk + ty + r) * w.N + bn + tx];
    __syncthreads();
#pragma unroll
    for (int r = 0; r < 32; r += 8) {
      float v = t[tx][ty + r];
      unsigned short hv = f2bf(v);
      w.dst[(size_t)(bn + ty + r) * w.K + bk + tx] = hv;
      if (w.dstlo)
        w.dstlo[(size_t)(bn + ty + r) * w.K + bk + tx] = f2bf(v - bf2f(hv));
    }
  } else if (bid < P.nwc + 64) {  // zero slice (CS1+CS2 = 16384 floats)
    int idx = (bid - P.nwc) * 256 + tid;
    csz[idx] = 0.f;
  } else {  // fconv slice: 4096 blocks, 4 floats/thread -> hi + lo
    int i = (bid - P.nwc - 64) * 256 + tid;
    float4 v = *reinterpret_cast<const float4*>(&x[(size_t)i * 4]);
    ushort4 o, ol;
    o.x = f2bf(v.x); o.y = f2bf(v.y); o.z = f2bf(v.z); o.w = f2bf(v.w);
    ol.x = f2bf(v.x - bf2f(o.x)); ol.y = f2bf(v.y - bf2f(o.y));
    ol.z = f2bf(v.z - bf2f(o.z)); ol.w = f2bf(v.w - bf2f(o.w));
    *reinterpret_cast<ushort4*>(&xbf[(size_t)i * 4]) = o;
    *reinterpret_cast<ushort4*>(&xlo[(size_t)i * 4]) = ol;
  }
}

// ---------------------------------------------------------------------------
// bf16 MFMA GEMM, LDS-STAGED: 256-thread blocks (4 waves), 128x128 tile,
// each wave a 64x64 sub-tile. Per BK=32 step the block stages A[128x32] and
// B^T[128x32] with coalesced 16B loads (each LDS write/read instruction
// covers a contiguous 1KB -> conflict-free floor), then waves read fragments
// via ds_read_b128. K-loop order and per-acc MFMA sequence identical to the
// direct-global version -> outputs bit-identical.
// Epilogue modes: 0 fp32 C | 1 bf16 C | 2 bf16 C + ReLU
//   | 4 V^T layout | 5 merged QKV (N=1536).
// ---------------------------------------------------------------------------
__global__ __launch_bounds__(256) void mfma_gemm_kernel(
    const unsigned short* __restrict__ A, const unsigned short* __restrict__ BT,
    void* __restrict__ p1, void* __restrict__ p2, void* __restrict__ p3,
    int K, int N, int mode)
{
  __shared__ unsigned short As[128 * 32];  // 8KB: 128 rows x 64B
  __shared__ unsigned short Bs[128 * 32];  // 8KB
  const int tid = threadIdx.x;
  const int lane = tid & 63, wave = tid >> 6;
  const int mr = lane & 15, quad = lane >> 4;
  const int wr = wave >> 1, wc = wave & 1;
  const int m0 = blockIdx.y * 128;
  const int n0 = blockIdx.x * 128;

  f32x4 acc[4][4];
  const f32x4 zero = {0.f, 0.f, 0.f, 0.f};
#pragma unroll
  for (int i = 0; i < 4; ++i)
#pragma unroll
    for (int j = 0; j < 4; ++j) acc[i][j] = zero;

  const int srow = tid >> 2;       // 0..63 (+64 second pass)
  const int sslot = tid & 3;       // 16B slot within the 64B row
  const unsigned short* Ag = A + (size_t)(m0 + srow) * K + sslot * 8;
  const unsigned short* Bg = BT + (size_t)(n0 + srow) * K + sslot * 8;
  char* AsB = (char*)As;
  char* BsB = (char*)Bs;

  for (int k0 = 0; k0 < K; k0 += 32) {
    short8 a0 = *reinterpret_cast<const short8*>(Ag + k0);
    short8 a1 = *reinterpret_cast<const short8*>(Ag + (size_t)64 * K + k0);
    short8 b0 = *reinterpret_cast<const short8*>(Bg + k0);
    short8 b1 = *reinterpret_cast<const short8*>(Bg + (size_t)64 * K + k0);
    *reinterpret_cast<short8*>(AsB + srow * 64 + sslot * 16) = a0;
    *reinterpret_cast<short8*>(AsB + (srow + 64) * 64 + sslot * 16) = a1;
    *reinterpret_cast<short8*>(BsB + srow * 64 + sslot * 16) = b0;
    *reinterpret_cast<short8*>(BsB + (srow + 64) * 64 + sslot * 16) = b1;
    __syncthreads();
    short8 af[4], bf[4];
#pragma unroll
    for (int i = 0; i < 4; ++i)
      af[i] = *reinterpret_cast<const short8*>(AsB + (wr * 64 + i * 16 + mr) * 64 + quad * 16);
#pragma unroll
    for (int j = 0; j < 4; ++j)
      bf[j] = *reinterpret_cast<const short8*>(BsB + (wc * 64 + j * 16 + mr) * 64 + quad * 16);
#pragma unroll
    for (int i = 0; i < 4; ++i)
#pragma unroll
      for (int j = 0; j < 4; ++j)
        acc[i][j] = __builtin_amdgcn_mfma_f32_16x16x32_bf16(af[i], bf[j], acc[i][j], 0, 0, 0);
    __syncthreads();
  }

  // per-wave 64x64 epilogue at (m0w, n0w)
  const int m0w = m0 + wr * 64;
  const int n0w = n0 + wc * 64;
  // C/D layout: col = lane&15, row = quad*4 + reg   [measured: m89/m91]
  int emode = mode;
  unsigned short* Cbf = (unsigned short*)p1;
  unsigned short* Vt  = (unsigned short*)p1;
  int ncol = N, coff = 0;
  if (mode == 5) {  // uniform per wave: n0w is a multiple of 64
    if (n0w < 512)       { emode = 1; Cbf = (unsigned short*)p1; ncol = 512; coff = 0; }
    else if (n0w < 1024) { emode = 1; Cbf = (unsigned short*)p2; ncol = 512; coff = 512; }
    else                 { emode = 4; Vt = (unsigned short*)p3; coff = 1024; }
  }
  if (emode == 4) {  // V^T: 4 consecutive tokens same feature -> ushort4
#pragma unroll
    for (int i = 0; i < 4; ++i)
#pragma unroll
      for (int j = 0; j < 4; ++j) {
        const int col = n0w - coff + j * 16 + mr;  // feature: h = col>>6, d = col&63
        const int row0 = m0w + i * 16 + quad * 4;  // token base (4 consecutive)
        const int bb = row0 >> 10, t0 = row0 & 1023;
        ushort4 pk;
        pk.x = f2bf(acc[i][j][0]); pk.y = f2bf(acc[i][j][1]);
        pk.z = f2bf(acc[i][j][2]); pk.w = f2bf(acc[i][j][3]);
        *reinterpret_cast<ushort4*>(
            &Vt[((size_t)((bb * Hz + (col >> 6)) * DHz + (col & 63))) * Tz + t0]) = pk;
      }
  } else if (emode == 0) {
    float* Cf = (float*)p1;
#pragma unroll
    for (int i = 0; i < 4; ++i)
#pragma unroll
      for (int j = 0; j < 4; ++j) {
        const int col = n0w + j * 16 + mr;
#pragma unroll
        for (int rr = 0; rr < 4; ++rr)
          Cf[(size_t)(m0w + i * 16 + quad * 4 + rr) * N + col] = acc[i][j][rr];
      }
  } else {
    const bool relu = (emode == 2);
#pragma unroll
    for (int i = 0; i < 4; ++i)
#pragma unroll
      for (int j = 0; j < 4; ++j) {
        const int col = n0w - coff + j * 16 + mr;
#pragma unroll
        for (int rr = 0; rr < 4; ++rr) {
          float v = acc[i][j][rr];
          if (relu) v = fmaxf(v, 0.f);
          Cbf[(size_t)(m0w + i * 16 + quad * 4 + rr) * ncol + col] = f2bf(v);
        }
      }
  }
}

// ---------------------------------------------------------------------------
// Layer-1 Q,K via bf16x3 MFMA, LDS-STAGED (same recipe): 4-wave blocks,
// 128x128 tile, stages Xh/Xl/Wh/Wl panels (32KB LDS). MFMA order per acc
// (al.bh, ah.bl, ah.bh per K-step, k ascending) identical to round 7 ->
// Q/K hi/lo outputs bit-identical.
// ---------------------------------------------------------------------------
__global__ __launch_bounds__(256) void gemm_qk_mfma_kernel(
    const unsigned short* __restrict__ Xh, const unsigned short* __restrict__ Xl,
    const unsigned short* __restrict__ WQh, const unsigned short* __restrict__ WQl,
    const unsigned short* __restrict__ WKh, const unsigned short* __restrict__ WKl,
    unsigned short* __restrict__ Qhi, unsigned short* __restrict__ Qlo,
    unsigned short* __restrict__ Khi, unsigned short* __restrict__ Klo)
{
  __shared__ unsigned short Ash[128 * 32];  // 8KB each
  __shared__ unsigned short Asl[128 * 32];
  __shared__ unsigned short Bsh[128 * 32];
  __shared__ unsigned short Bsl[128 * 32];
  const int tid = threadIdx.x;
  const int lane = tid & 63, wave = tid >> 6;
  const int mr = lane & 15, quad = lane >> 4;
  const int wr = wave >> 1, wc = wave & 1;
  const int sel = blockIdx.y >> 6;
  const int m0 = (blockIdx.y & 63) * 128;
  const int n0 = blockIdx.x * 128;
  const unsigned short* Bh = sel ? WKh : WQh;
  const unsigned short* Bl = sel ? WKl : WQl;
  unsigned short* Chi = sel ? Khi : Qhi;
  unsigned short* Clo = sel ? Klo : Qlo;

  f32x4 acc[4][4];
  const f32x4 zero = {0.f, 0.f, 0.f, 0.f};
#pragma unroll
  for (int i = 0; i < 4; ++i)
#pragma unroll
    for (int j = 0; j < 4; ++j) acc[i][j] = zero;

  const int srow = tid >> 2;
  const int sslot = tid & 3;
  const unsigned short* Ahg = Xh + (size_t)(m0 + srow) * Dz + sslot * 8;
  const unsigned short* Alg = Xl + (size_t)(m0 + srow) * Dz + sslot * 8;
  const unsigned short* Bhg = Bh + (size_t)(n0 + srow) * Dz + sslot * 8;
  const unsigned short* Blg = Bl + (size_t)(n0 + srow) * Dz + sslot * 8;
  char* AhB = (char*)Ash; char* AlB = (char*)Asl;
  char* BhB = (char*)Bsh; char* BlB = (char*)Bsl;

  for (int k0 = 0; k0 < Dz; k0 += 32) {
    short8 ah0 = *reinterpret_cast<const short8*>(Ahg + k0);
    short8 ah1 = *reinterpret_cast<const short8*>(Ahg + (size_t)64 * Dz + k0);
    short8 al0 = *reinterpret_cast<const short8*>(Alg + k0);
    short8 al1 = *reinterpret_cast<const short8*>(Alg + (size_t)64 * Dz + k0);
    short8 bh0 = *reinterpret_cast<const short8*>(Bhg + k0);
    short8 bh1 = *reinterpret_cast<const short8*>(Bhg + (size_t)64 * Dz + k0);
    short8 bl0 = *reinterpret_cast<const short8*>(Blg + k0);
    short8 bl1 = *reinterpret_cast<const short8*>(Blg + (size_t)64 * Dz + k0);
    *reinterpret_cast<short8*>(AhB + srow * 64 + sslot * 16) = ah0;
    *reinterpret_cast<short8*>(AhB + (srow + 64) * 64 + sslot * 16) = ah1;
    *reinterpret_cast<short8*>(AlB + srow * 64 + sslot * 16) = al0;
    *reinterpret_cast<short8*>(AlB + (srow + 64) * 64 + sslot * 16) = al1;
    *reinterpret_cast<short8*>(BhB + srow * 64 + sslot * 16) = bh0;
    *reinterpret_cast<short8*>(BhB + (srow + 64) * 64 + sslot * 16) = bh1;
    *reinterpret_cast<short8*>(BlB + srow * 64 + sslot * 16) = bl0;
    *reinterpret_cast<short8*>(BlB + (srow + 64) * 64 + sslot * 16) = bl1;
    __syncthreads();
    short8 ah[4], al[4], bh[4], bl[4];
#pragma unroll
    for (int i = 0; i < 4; ++i) {
      const int ab = (wr * 64 + i * 16 + mr) * 64 + quad * 16;
      ah[i] = *reinterpret_cast<const short8*>(AhB + ab);
      al[i] = *reinterpret_cast<const short8*>(AlB + ab);
    }
#pragma unroll
    for (int j = 0; j < 4; ++j) {
      const int bb = (wc * 64 + j * 16 + mr) * 64 + quad * 16;
      bh[j] = *reinterpret_cast<const short8*>(BhB + bb);
      bl[j] = *reinterpret_cast<const short8*>(BlB + bb);
    }
#pragma unroll
    for (int i = 0; i < 4; ++i)
#pragma unroll
      for (int j = 0; j < 4; ++j) {
        acc[i][j] = __builtin_amdgcn_mfma_f32_16x16x32_bf16(al[i], bh[j], acc[i][j], 0, 0, 0);
        acc[i][j] = __builtin_amdgcn_mfma_f32_16x16x32_bf16(ah[i], bl[j], acc[i][j], 0, 0, 0);
        acc[i][j] = __builtin_amdgcn_mfma_f32_16x16x32_bf16(ah[i], bh[j], acc[i][j], 0, 0, 0);
      }
    __syncthreads();
  }

  const int m0w = m0 + wr * 64;
  const int n0w = n0 + wc * 64;
#pragma unroll
  for (int i = 0; i < 4; ++i)
#pragma unroll
    for (int j = 0; j < 4; ++j) {
      const int col = n0w + j * 16 + mr;
#pragma unroll
      for (int rr = 0; rr < 4; ++rr) {
        const size_t row = (size_t)(m0w + i * 16 + quad * 4 + rr);
        float v = acc[i][j][rr];
        unsigned short hv = f2bf(v);
        Chi[row * Dz + col] = hv;
        Clo[row * Dz + col] = f2bf(v - bf2f(hv));
      }
    }
}

// ---------------------------------------------------------------------------
// Layer-1 z pass, CHEAP plain-bf16 QK^T, LDS-STAGED (round 7, proven).
// ---------------------------------------------------------------------------
__global__ __launch_bounds__(256) void attn_z_kernel(
    const unsigned short* __restrict__ Qh, const unsigned short* __restrict__ Kh,
    float* __restrict__ invzG)
{
  __shared__ unsigned short Ksh[64 * 64];  // 8KB: 64 keys x 128B (swizzled)
  const int tid = threadIdx.x;
  const int lane = tid & 63, wave = tid >> 6;
  const int c = lane & 15, quad = lane >> 4;
  int b, h, qt;
  attn_decode(blockIdx.x, b, h, qt);
  const size_t bT = (size_t)b * Tz;
  const int qrow = qt * 64 + wave * 16;
  const int hoff = h * DHz;

  const size_t qbase = (bT + qrow + c) * Dz + hoff + quad * 8;
  short8 q0 = *reinterpret_cast<const short8*>(Qh + qbase);
  short8 q1 = *reinterpret_cast<const short8*>(Qh + qbase + 32);

  const int sr = tid >> 3;        // row 0..31
  const int sj = (tid & 7) * 16;  // slot byte
  const unsigned short* khb = Kh + (bT + sr) * Dz + hoff + (tid & 7) * 8;
  char* KshB = (char*)Ksh;

  const f32x4 zf = {0.f, 0.f, 0.f, 0.f};
  float z[4] = {0.f, 0.f, 0.f, 0.f};

  for (int t = 0; t < 16; ++t) {
    const int k0 = t * 64;
    short8 g0 = *reinterpret_cast<const short8*>(khb + (size_t)k0 * Dz);
    short8 g1 = *reinterpret_cast<const short8*>(khb + (size_t)(k0 + 32) * Dz);
    *reinterpret_cast<short8*>(KshB + swz(sr, sj)) = g0;
    *reinterpret_cast<short8*>(KshB + swz(sr + 32, sj)) = g1;
    __syncthreads();
#pragma unroll
    for (int sub = 0; sub < 4; ++sub) {
      const int row = sub * 16 + c;
      short8 kh0 = *reinterpret_cast<const short8*>(KshB + swz(row, quad * 16));
      short8 kh1 = *reinterpret_cast<const short8*>(KshB + swz(row, 64 + quad * 16));
      f32x4 aA = zf, aB = zf;
      aA = __builtin_amdgcn_mfma_f32_16x16x32_bf16(q0, kh0, aA, 0, 0, 0);
      aB = __builtin_amdgcn_mfma_f32_16x16x32_bf16(q1, kh1, aB, 0, 0, 0);
#pragma unroll
      for (int rr = 0; rr < 4; ++rr) z[rr] += __expf((aA[rr] + aB[rr]) * 0.125f);
    }
    __syncthreads();  // reads done before next stage overwrites
  }
#pragma unroll
  for (int w = 1; w < 16; w <<= 1) {
#pragma unroll
    for (int rr = 0; rr < 4; ++rr) z[rr] += __shfl_xor(z[rr], w);
  }
  if (c == 0) {
#pragma unroll
    for (int rr = 0; rr < 4; ++rr)
      invzG[(size_t)(b * Hz + h) * Tz + qrow + quad * 4 + rr] = 1.f / z[rr];
  }
}

// ---------------------------------------------------------------------------
// Layer-1 ctx with LDS-STAGED K/V (proven round 6). All arithmetic values,
// order and PART slots bit-identical to round 4.
// ---------------------------------------------------------------------------
__global__ __launch_bounds__(256) void attn_ctx_kernel(
    const unsigned short* __restrict__ Qh, const unsigned short* __restrict__ Ql,
    const unsigned short* __restrict__ Kh, const unsigned short* __restrict__ Kl,
    const unsigned short* __restrict__ Vt, const float* __restrict__ invzG,
    unsigned short* __restrict__ ctx, float* __restrict__ part)
{
  __shared__ unsigned short Ksh[64 * 64];  // 8KB: 64 keys x 128B (swizzled)
  __shared__ unsigned short Ksl[64 * 64];  // 8KB
  __shared__ unsigned short Vsh[64 * 64];  // 8KB: 64 features x 128B (swizzled)
  __shared__ unsigned short Pld[64][76];   // 9.5KB
  __shared__ float CSPt[4][64];            // per-wave per-tile colsum partials
  const int tid = threadIdx.x;
  const int lane = tid & 63, wave = tid >> 6;
  const int c = lane & 15, quad = lane >> 4;
  int b, h, qt;
  attn_decode(blockIdx.x, b, h, qt);
  const size_t bT = (size_t)b * Tz;
  const int qrow = qt * 64 + wave * 16;
  const int hoff = h * DHz;
  const int lidx = b * 128 + h * 16 + qt;  // logical PART slot

  const size_t qbase = (bT + qrow + c) * Dz + hoff + quad * 8;
  short8 q0h = *reinterpret_cast<const short8*>(Qh + qbase);
  short8 q1h = *reinterpret_cast<const short8*>(Qh + qbase + 32);
  short8 q0l = *reinterpret_cast<const short8*>(Ql + qbase);
  short8 q1l = *reinterpret_cast<const short8*>(Ql + qbase + 32);

  float invz[4];
#pragma unroll
  for (int rr = 0; rr < 4; ++rr)
    invz[rr] = invzG[(size_t)(b * Hz + h) * Tz + qrow + quad * 4 + rr];

  // staging coords: 256 threads cover 32 rows x 8 slots (16B) per pass
  const int sr = tid >> 3;        // row 0..31
  const int sj = (tid & 7) * 16;  // slot byte 0..112
  const unsigned short* khb = Kh + (bT + sr) * Dz + hoff + (tid & 7) * 8;
  const unsigned short* klb = Kl + (bT + sr) * Dz + hoff + (tid & 7) * 8;
  const unsigned short* vtb = Vt + ((size_t)(b * Hz + h) * DHz + sr) * Tz + (tid & 7) * 8;

  const f32x4 zf = {0.f, 0.f, 0.f, 0.f};
  f32x4 ot[4] = {zf, zf, zf, zf};

  char* KshB = (char*)Ksh;
  char* KslB = (char*)Ksl;
  char* VshB = (char*)Vsh;

  for (int t = 0; t < 16; ++t) {
    const int k0 = t * 64;
    // ---- stage tile t: coalesced global -> regs -> swizzled LDS ----
    short8 g0 = *reinterpret_cast<const short8*>(khb + (size_t)k0 * Dz);
    short8 g1 = *reinterpret_cast<const short8*>(khb + (size_t)(k0 + 32) * Dz);
    short8 g2 = *reinterpret_cast<const short8*>(klb + (size_t)k0 * Dz);
    short8 g3 = *reinterpret_cast<const short8*>(klb + (size_t)(k0 + 32) * Dz);
    short8 g4 = *reinterpret_cast<const short8*>(vtb + k0);
    short8 g5 = *reinterpret_cast<const short8*>(vtb + 32 * Tz + k0);
    // prev tile fully consumed at the tail barrier of the previous iteration
    *reinterpret_cast<short8*>(KshB + swz(sr, sj)) = g0;
    *reinterpret_cast<short8*>(KshB + swz(sr + 32, sj)) = g1;
    *reinterpret_cast<short8*>(KslB + swz(sr, sj)) = g2;
    *reinterpret_cast<short8*>(KslB + swz(sr + 32, sj)) = g3;
    *reinterpret_cast<short8*>(VshB + swz(sr, sj)) = g4;
    *reinterpret_cast<short8*>(VshB + swz(sr + 32, sj)) = g5;
    __syncthreads();  // staged data visible

    // ---- QK^T subtiles (bf16x3, 2-acc split) ----
#pragma unroll
    for (int sub = 0; sub < 4; ++sub) {
      const int row = sub * 16 + c;
      short8 kh0 = *reinterpret_cast<const short8*>(KshB + swz(row, quad * 16));
      short8 kh1 = *reinterpret_cast<const short8*>(KshB + swz(row, 64 + quad * 16));
      short8 kl0 = *reinterpret_cast<const short8*>(KslB + swz(row, quad * 16));
      short8 kl1 = *reinterpret_cast<const short8*>(KslB + swz(row, 64 + quad * 16));
      f32x4 aA = zf, aB = zf;
      aA = __builtin_amdgcn_mfma_f32_16x16x32_bf16(q0h, kh0, aA, 0, 0, 0);
      aB = __builtin_amdgcn_mfma_f32_16x16x32_bf16(q1h, kh1, aB, 0, 0, 0);
      aA = __builtin_amdgcn_mfma_f32_16x16x32_bf16(q0h, kl0, aA, 0, 0, 0);
      aB = __builtin_amdgcn_mfma_f32_16x16x32_bf16(q1h, kl1, aB, 0, 0, 0);
      aA = __builtin_amdgcn_mfma_f32_16x16x32_bf16(q0l, kh0, aA, 0, 0, 0);
      aB = __builtin_amdgcn_mfma_f32_16x16x32_bf16(q1l, kh1, aB, 0, 0, 0);
      float p[4];
#pragma unroll
      for (int rr = 0; rr < 4; ++rr)
        p[rr] = __expf((aA[rr] + aB[rr]) * 0.125f) * invz[rr];
      float cs = p[0] + p[1] + p[2] + p[3];
      cs += __shfl_xor(cs, 16);
      cs += __shfl_xor(cs, 32);
      if (quad == 0) CSPt[wave][sub * 16 + c] = cs;  // key visited once
#pragma unroll
      for (int rr = 0; rr < 4; ++rr)
        Pld[(wave << 4) + quad * 4 + rr][sub * 16 + c] = f2bf(p[rr]);
    }

    // ---- PV from LDS ----
    union { short8 v; ushort4 hh[2]; } pb0, pb1;
    pb0.hh[0] = *reinterpret_cast<const ushort4*>(&Pld[(wave << 4) + c][quad * 8]);
    pb0.hh[1] = *reinterpret_cast<const ushort4*>(&Pld[(wave << 4) + c][quad * 8 + 4]);
    pb1.hh[0] = *reinterpret_cast<const ushort4*>(&Pld[(wave << 4) + c][32 + quad * 8]);
    pb1.hh[1] = *reinterpret_cast<const ushort4*>(&Pld[(wave << 4) + c][32 + quad * 8 + 4]);
#pragma unroll
    for (int ds = 0; ds < 4; ++ds) {
      const int row = ds * 16 + c;
      short8 v0 = *reinterpret_cast<const short8*>(VshB + swz(row, quad * 16));
      short8 v1 = *reinterpret_cast<const short8*>(VshB + swz(row, 64 + quad * 16));
      ot[ds] = __builtin_amdgcn_mfma_f32_16x16x32_bf16(v0, pb0.v, ot[ds], 0, 0, 0);
      ot[ds] = __builtin_amdgcn_mfma_f32_16x16x32_bf16(v1, pb1.v, ot[ds], 0, 0, 0);
    }
    __syncthreads();  // all LDS reads done; CSPt complete across waves

    // ---- deterministic per-tile colsum combine (same 4-addend order) ----
    if (tid < 64) {
      float v = ((CSPt[0][tid] + CSPt[1][tid]) + CSPt[2][tid]) + CSPt[3][tid];
      part[(size_t)lidx * 1024 + k0 + tid] = v * (1.f / Hz);
    }
  }

  const size_t cb = (bT + qrow + c) * Dz + hoff;
#pragma unroll
  for (int ds = 0; ds < 4; ++ds) {
    ushort4 pk;
    pk.x = f2bf(ot[ds][0]); pk.y = f2bf(ot[ds][1]);
    pk.z = f2bf(ot[ds][2]); pk.w = f2bf(ot[ds][3]);
    *reinterpret_cast<ushort4*>(&ctx[cb + ds * 16 + quad * 4]) = pk;
  }
}

// ---------------------------------------------------------------------------
// Deterministic colsum reduce: CS1[b,key] = sum over the 128 (h,qt) block
// partials in fixed ascending order. One thread per output.
// ---------------------------------------------------------------------------
__global__ __launch_bounds__(256) void colsum_reduce_kernel(
    const float* __restrict__ part, float* __restrict__ colsum)
{
  const int i = blockIdx.x * 256 + threadIdx.x;  // 0..8191
  const int b = i >> 10, k = i & 1023;
  const float* p = part + (size_t)(b * 128) * 1024 + k;
  float s = 0.f;
  for (int j = 0; j < 128; ++j) s += p[(size_t)j * 1024];
  colsum[i] = s;
}

// ---------------------------------------------------------------------------
// Layer-2 MFMA attention (masked), with k-tile range skipping. CS2 feeds only
// the continuous wl softmax -> atomics are fine here. XCD-swizzled decode.
// ---------------------------------------------------------------------------
__global__ __launch_bounds__(256) void attn_mfma2_kernel(
    const unsigned short* __restrict__ Qh, const unsigned short* __restrict__ Kh,
    const unsigned short* __restrict__ Vt, const int* __restrict__ ids,
    const int* __restrict__ wst,
    unsigned short* __restrict__ ctx, float* __restrict__ colsum)
{
  __shared__ unsigned short Pld[64][76];
  __shared__ float csb[1024];

  const int tid = threadIdx.x;
  const int lane = tid & 63, wave = tid >> 6;
  const int c = lane & 15, quad = lane >> 4;
  int b, h, qt;
  attn_decode(blockIdx.x, b, h, qt);
  const size_t bT = (size_t)b * Tz;
  const int qrow = qt * 64 + wave * 16;
  const int hoff = h * DHz;

  for (int i = tid; i < 1024; i += 256) csb[i] = 0.f;

  const int id_lo = ids[bT + qt * 64];
  const int id_hi = ids[bT + qt * 64 + 63];
  const int klo = wst[b * (Tz + 1) + id_lo];
  const int khi = wst[b * (Tz + 1) + id_hi + 1];
  const int t0 = klo >> 6, t1 = (khi - 1) >> 6;

  const size_t qbase = (bT + qrow + c) * Dz + hoff + quad * 8;
  short8 q0 = *reinterpret_cast<const short8*>(Qh + qbase);
  short8 q1 = *reinterpret_cast<const short8*>(Qh + qbase + 32);

  int qid[4];
#pragma unroll
  for (int rr = 0; rr < 4; ++rr) qid[rr] = ids[bT + qrow + quad * 4 + rr];
  __syncthreads();  // csb zeros visible before pass-2 atomics

  const f32x4 zf = {0.f, 0.f, 0.f, 0.f};

  // pass 1: z
  float z[4] = {0.f, 0.f, 0.f, 0.f};
  for (int t = t0; t <= t1; ++t) {
    const int k0 = t * 64;
#pragma unroll
    for (int sub = 0; sub < 4; ++sub) {
      const size_t kb = (bT + k0 + sub * 16 + c) * Dz + hoff + quad * 8;
      short8 kh0 = *reinterpret_cast<const short8*>(Kh + kb);
      short8 kh1 = *reinterpret_cast<const short8*>(Kh + kb + 32);
      f32x4 acc = zf;
      acc = __builtin_amdgcn_mfma_f32_16x16x32_bf16(q0, kh0, acc, 0, 0, 0);
      acc = __builtin_amdgcn_mfma_f32_16x16x32_bf16(q1, kh1, acc, 0, 0, 0);
      int kidv = ids[bT + k0 + sub * 16 + c];
#pragma unroll
      for (int rr = 0; rr < 4; ++rr) {
        float e = __expf(acc[rr] * 0.125f);
        if (qid[rr] != kidv) e = 0.f;
        z[rr] += e;
      }
    }
  }
#pragma unroll
  for (int w = 1; w < 16; w <<= 1) {
#pragma unroll
    for (int rr = 0; rr < 4; ++rr) z[rr] += __shfl_xor(z[rr], w);
  }
  float invz[4];
#pragma unroll
  for (int rr = 0; rr < 4; ++rr) invz[rr] = 1.f / z[rr];

  // pass 2: P, colsum, PV
  f32x4 ot[4] = {zf, zf, zf, zf};
  for (int t = t0; t <= t1; ++t) {
    const int k0 = t * 64;
#pragma unroll
    for (int sub = 0; sub < 4; ++sub) {
      const size_t kb = (bT + k0 + sub * 16 + c) * Dz + hoff + quad * 8;
      short8 kh0 = *reinterpret_cast<const short8*>(Kh + kb);
      short8 kh1 = *reinterpret_cast<const short8*>(Kh + kb + 32);
      f32x4 acc = zf;
      acc = __builtin_amdgcn_mfma_f32_16x16x32_bf16(q0, kh0, acc, 0, 0, 0);
      acc = __builtin_amdgcn_mfma_f32_16x16x32_bf16(q1, kh1, acc, 0, 0, 0);
      int kidv = ids[bT + k0 + sub * 16 + c];
      float p[4];
#pragma unroll
      for (int rr = 0; rr < 4; ++rr) {
        float e = __expf(acc[rr] * 0.125f);
        if (qid[rr] != kidv) e = 0.f;
        p[rr] = e * invz[rr];
      }
      float cs = p[0] + p[1] + p[2] + p[3];
      cs += __shfl_xor(cs, 16);
      cs += __shfl_xor(cs, 32);
      if (quad == 0) atomicAdd(&csb[k0 + sub * 16 + c], cs);
#pragma unroll
      for (int rr = 0; rr < 4; ++rr)
        Pld[(wave << 4) + quad * 4 + rr][sub * 16 + c] = f2bf(p[rr]);
    }
    union { short8 v; ushort4 hh[2]; } pb0, pb1;
    pb0.hh[0] = *reinterpret_cast<const ushort4*>(&Pld[(wave << 4) + c][quad * 8]);
    pb0.hh[1] = *reinterpret_cast<const ushort4*>(&Pld[(wave << 4) + c][quad * 8 + 4]);
    pb1.hh[0] = *reinterpret_cast<const ushort4*>(&Pld[(wave << 4) + c][32 + quad * 8]);
    pb1.hh[1] = *reinterpret_cast<const ushort4*>(&Pld[(wave << 4) + c][32 + quad * 8 + 4]);
#pragma unroll
    for (int ds = 0; ds < 4; ++ds) {
      const size_t va = ((size_t)((b * Hz + h) * DHz + ds * 16 + c)) * Tz + k0 + quad * 8;
      short8 v0 = *reinterpret_cast<const short8*>(Vt + va);
      short8 v1 = *reinterpret_cast<const short8*>(Vt + va + 32);
      ot[ds] = __builtin_amdgcn_mfma_f32_16x16x32_bf16(v0, pb0.v, ot[ds], 0, 0, 0);
      ot[ds] = __builtin_amdgcn_mfma_f32_16x16x32_bf16(v1, pb1.v, ot[ds], 0, 0, 0);
    }
  }

  const size_t cb = (bT + qrow + c) * Dz + hoff;
#pragma unroll
  for (int ds = 0; ds < 4; ++ds) {
    ushort4 pk;
    pk.x = f2bf(ot[ds][0]); pk.y = f2bf(ot[ds][1]);
    pk.z = f2bf(ot[ds][2]); pk.w = f2bf(ot[ds][3]);
    *reinterpret_cast<ushort4*>(&ctx[cb + ds * 16 + quad * 4]) = pk;
  }
  __syncthreads();
  for (int i = tid; i < 1024; i += 256)
    atomicAdd(&colsum[bT + i], csb[i] * (1.f / Hz));
}

// ---------------------------------------------------------------------------
// out = LayerNorm(resid + delta). resid fp32 (residf) if non-null else bf16.
// ---------------------------------------------------------------------------
__global__ __launch_bounds__(256) void ln_kernel(const float* __restrict__ residf,
    const unsigned short* __restrict__ residbf, const float* __restrict__ delta,
    float* __restrict__ outf, unsigned short* __restrict__ outbf)
{
  const size_t base = (size_t)blockIdx.x * Dz;
  const int tid = threadIdx.x;
  float r0, r1;
  if (residf) {
    r0 = residf[base + tid]; r1 = residf[base + tid + 256];
  } else {
    r0 = bf2f(residbf[base + tid]); r1 = bf2f(residbf[base + tid + 256]);
  }
  float x0 = r0 + delta[base + tid];
  float x1 = r1 + delta[base + tid + 256];
  __shared__ float red[4];
  float s = x0 + x1;
#pragma unroll
  for (int off = 32; off; off >>= 1) s += __shfl_down(s, off);
  if ((tid & 63) == 0) red[tid >> 6] = s;
  __syncthreads();
  const float mean = (red[0] + red[1] + red[2] + red[3]) * (1.f / Dz);
  __syncthreads();
  float d0 = x0 - mean, d1 = x1 - mean;
  float v = d0 * d0 + d1 * d1;
#pragma unroll
  for (int off = 32; off; off >>= 1) v += __shfl_down(v, off);
  if ((tid & 63) == 0) red[tid >> 6] = v;
  __syncthreads();
  const float var = (red[0] + red[1] + red[2] + red[3]) * (1.f / Dz);
  const float rstd = rsqrtf(var + 1e-5f);
  float y0 = d0 * rstd, y1 = d1 * rstd;
  if (outf) {
    outf[base + tid] = y0;
    outf[base + tid + 256] = y1;
  }
  outbf[base + tid] = f2bf(y0);
  outbf[base + tid + 256] = f2bf(y1);
}

// ---------------------------------------------------------------------------
// Per batch: min-max normalize colsum, threshold 0.5, run-length window scan.
// PARALLELIZED (round 7, proven): ballot-packed bits + register bit-scan of
// transitions + parallel binary-search ids fill. Bit-identical to reference.
// ---------------------------------------------------------------------------
__global__ __launch_bounds__(256) void window_ids_kernel(const float* __restrict__ cs,
    int* __restrict__ ids, int* __restrict__ wst, int* __restrict__ nwin)
{
  const int b = blockIdx.x, tid = threadIdx.x;
  __shared__ float vals[Tz];
  __shared__ int swst[Tz + 1];
  __shared__ unsigned long long words[16];
  __shared__ float rmin[4], rmax[4];
  __shared__ int snw;
  float mn = INFINITY, mx = -INFINITY;
  for (int t = tid; t < Tz; t += 256) {
    float v = cs[b * Tz + t];
    vals[t] = v;
    mn = fminf(mn, v); mx = fmaxf(mx, v);
  }
#pragma unroll
  for (int off = 32; off; off >>= 1) {
    mn = fminf(mn, __shfl_down(mn, off));
    mx = fmaxf(mx, __shfl_down(mx, off));
  }
  if ((tid & 63) == 0) { rmin[tid >> 6] = mn; rmax[tid >> 6] = mx; }
  __syncthreads();
  mn = fminf(fminf(rmin[0], rmin[1]), fminf(rmin[2], rmin[3]));
  mx = fmaxf(fmaxf(rmax[0], rmax[1]), fmaxf(rmax[2], rmax[3]));
  const float inv = 1.f / (mx - mn + 1e-8f);
  const int lane = tid & 63, wave = tid >> 6;
#pragma unroll
  for (int pass = 0; pass < 4; ++pass) {
    const int t = pass * 256 + wave * 64 + lane;
    const bool bit = ((vals[t] - mn) * inv) >= 0.5f;  // identical threshold op
    unsigned long long m = __ballot(bit);
    if (lane == 0) words[pass * 4 + wave] = m;
  }
  __syncthreads();
  if (tid == 0) {
    int start = 0, wid = 0;
    swst[0] = 0;
    unsigned long long carry = 0;
    for (int i = 0; i < 16; ++i) {
      const unsigned long long wi = words[i];
      unsigned long long tr = wi ^ ((wi << 1) | carry);
      carry = wi >> 63;
      if (i == 0) tr &= ~1ULL;  // t=0 is not a transition
      while (tr) {
        const int t = i * 64 + __builtin_ctzll(tr);
        tr &= tr - 1;
        if (start + 1 != t) { start = t; ++wid; swst[wid] = t; }
      }
    }
    nwin[b] = wid + 1;
    swst[wid + 1] = Tz;
    snw = wid + 1;
  }
  __syncthreads();
  const int nw = snw;
  for (int j = tid; j <= nw; j += 256) wst[b * (Tz + 1) + j] = swst[j];
  for (int t = tid; t < Tz; t += 256) {
    int lo = 0, hi = nw;  // swst[0]=0 <= t, swst[nw]=Tz > t
    while (hi - lo > 1) {
      const int mid = (lo + hi) >> 1;
      if (swst[mid] <= t) lo = mid; else hi = mid;
    }
    ids[b * Tz + t] = lo;
  }
}

// ---------------------------------------------------------------------------
// wl[b,:] = softmax over keys of layer-2 colsum.
// ---------------------------------------------------------------------------
__global__ __launch_bounds__(256) void wl_softmax_kernel(const float* __restrict__ cs,
                                                         float* __restrict__ wl)
{
  const int b = blockIdx.x, tid = threadIdx.x;
  __shared__ float vals[Tz];
  __shared__ float red[4];
  float mx = -INFINITY;
  for (int t = tid; t < Tz; t += 256) {
    float v = cs[b * Tz + t];
    vals[t] = v;
    mx = fmaxf(mx, v);
  }
#pragma unroll
  for (int off = 32; off; off >>= 1) mx = fmaxf(mx, __shfl_down(mx, off));
  if ((tid & 63) == 0) red[tid >> 6] = mx;
  __syncthreads();
  mx = fmaxf(fmaxf(red[0], red[1]), fmaxf(red[2], red[3]));
  __syncthreads();
  float se = 0.f;
  for (int t = tid; t < Tz; t += 256) {
    float e = expf(vals[t] - mx);
    vals[t] = e;
    se += e;
  }
#pragma unroll
  for (int off = 32; off; off >>= 1) se += __shfl_down(se, off);
  if ((tid & 63) == 0) red[tid >> 6] = se;
  __syncthreads();
  const float inv = 1.f / (red[0] + red[1] + red[2] + red[3]);
  for (int t = tid; t < Tz; t += 256) wl[b * Tz + t] = vals[t] * inv;
}

// ---------------------------------------------------------------------------
// Fused outputs: word_tokens (blocks 0..8191), winmap (8192..16383),
// copy_x (16384..20479).
// ---------------------------------------------------------------------------
__global__ __launch_bounds__(256) void outputs_kernel(
    const unsigned short* __restrict__ outl, const float* __restrict__ wl,
    const int* __restrict__ wst, const int* __restrict__ nwin,
    const int* __restrict__ ids, const float* __restrict__ x,
    float* __restrict__ out, float* __restrict__ out2)
{
  const int bid = blockIdx.x;
  const int tid = threadIdx.x;
  if (bid < 8192) {  // word_tokens
    const int w = bid & (Tz - 1);
    const int b = bid >> 10;
    float a0 = 0.f, a1 = 0.f;
    if (w < nwin[b]) {
      const int s = wst[b * (Tz + 1) + w], e = wst[b * (Tz + 1) + w + 1];
      for (int t = s; t < e; ++t) {
        const float sc = wl[b * Tz + t];
        const unsigned short* p = &outl[((size_t)(b * Tz + t)) * Dz];
        a0 += bf2f(p[tid]) * sc;
        a1 += bf2f(p[tid + 256]) * sc;
      }
    }
    float* o = &out[((size_t)(b * 2 * Tz + w)) * Dz];
    o[tid] = a0;
    o[tid + 256] = a1;
  } else if (bid < 16384) {  // winmap
    const int lb = bid - 8192;
    const int w = lb & (Tz - 1);
    const int b = lb >> 10;
    const int j = tid * 4;
    int4 id4 = *reinterpret_cast<const int4*>(&ids[b * Tz + j]);
    float4 v;
    v.x = (id4.x == w) ? 1.f : 0.f;
    v.y = (id4.y == w) ? 1.f : 0.f;
    v.z = (id4.z == w) ? 1.f : 0.f;
    v.w = (id4.w == w) ? 1.f : 0.f;
    *reinterpret_cast<float4*>(&out2[((size_t)(b * Tz + w)) * Tz + j]) = v;
  } else {  // copy_x
    size_t i = (size_t)(bid - 16384) * 256 + tid;
    size_t idx = i * 4;
    size_t rowi = idx >> 9;
    size_t d = idx & 511;
    size_t b = rowi >> 10, t = rowi & 1023;
    float4 v = *reinterpret_cast<const float4*>(&x[idx]);
    *reinterpret_cast<float4*>(&out[(((b * 2 * Tz) + Tz + t) << 9) + d]) = v;
  }
}

// ---------------------------------------------------------------------------
// Orchestration: 22 dispatches. Both GEMM kernels now LDS-staged 4-wave
// blocks with 128x128 tiles (bit-identical arithmetic order).
// ---------------------------------------------------------------------------
extern "C" void kernel_launch(void* const* d_in, const int* in_sizes, int n_in,
                              void* d_out, int out_size, void* d_ws, size_t ws_size,
                              hipStream_t stream)
{
  (void)in_sizes; (void)n_in; (void)out_size; (void)ws_size;
  const float* x     = (const float*)d_in[0];
  const float* vqkv  = (const float*)d_in[1];
  const float* voutw = (const float*)d_in[2];
  const float* vw1   = (const float*)d_in[3];
  const float* vw2   = (const float*)d_in[4];
  const float* lqkv  = (const float*)d_in[5];
  const float* loutw = (const float*)d_in[6];
  const float* lw1   = (const float*)d_in[7];
  const float* lw2   = (const float*)d_in[8];
  float* out = (float*)d_out;
  float* ws  = (float*)d_ws;

  unsigned short* QLbf = (unsigned short*)(ws + 0);        // bf16 Q lo (L1)
  unsigned short* KLbf = (unsigned short*)(ws + 2097152);  // bf16 K lo (L1)
  float* PROJ = ws + 0;         // written after attn_ctx (QL/KL dead)
  float* Y1   = ws + 4194304;
  unsigned short* QHbf = (unsigned short*)(ws + 8388608);   // bf16 Q hi (L1+L2)
  unsigned short* KHbf = (unsigned short*)(ws + 10485760);  // bf16 K hi (L1+L2)
  unsigned short* VT   = (unsigned short*)(ws + 12582912);
  unsigned short* SLOT1 = (unsigned short*)(ws + 14680064); // attn ctx bf16
  unsigned short* SLOT2 = (unsigned short*)(ws + 16777216); // LN bf16 out
  unsigned short* HIDbf = (unsigned short*)(ws + 18874368); // FFN hidden
  unsigned short* XBF   = (unsigned short*)(ws + 18874368); // x hi bf16 (pre-FFN)
  float* PART = ws + 18874368;  // colsum block partials (1024x1024); written
                                // by attn_ctx after XBF/XLO dead, dead by FFN1
  unsigned short* XLO = (unsigned short*)(ws + 20971520);   // x lo bf16
  // bf16 transposed weights (WLQ0..2 contiguous -> merged [1536,512] matrix)
  unsigned short* WVQV = (unsigned short*)(ws + 27262976);
  unsigned short* WVO  = (unsigned short*)(ws + 27394048);
  unsigned short* WV1  = (unsigned short*)(ws + 27525120);
  unsigned short* WV2  = (unsigned short*)(ws + 28049408);
  unsigned short* WLQ0 = (unsigned short*)(ws + 28573696);
  unsigned short* WLQ1 = (unsigned short*)(ws + 28704768);
  unsigned short* WLQ2 = (unsigned short*)(ws + 28835840);
  unsigned short* WLO  = (unsigned short*)(ws + 28966912);
  unsigned short* WL1  = (unsigned short*)(ws + 29097984);
  unsigned short* WL2  = (unsigned short*)(ws + 29622272);
  // small buffers
  float* CS1   = ws + 30146560;
  float* CS2   = ws + 30154752;
  float* WLs   = ws + 30162944;
  int*   IDS   = (int*)(ws + 30171136);
  int*   WST   = (int*)(ws + 30179328);
  int*   NWIN  = (int*)(ws + 30187776);
  float* INVZ  = ws + 30195968;  // (B*H*T) = 65536 floats
  // layer-1 Q/K weights, bf16 transposed hi/lo (512x512 each = 131072 floats)
  unsigned short* WQH = (unsigned short*)(ws + 30261504);
  unsigned short* WQL = (unsigned short*)(ws + 30392576);
  unsigned short* WKH = (unsigned short*)(ws + 30523648);
  unsigned short* WKL = (unsigned short*)(ws + 30654720);

  dim3 blk(256);

  // ---- fused prep: 12 wconv + zero + fconv(hi/lo) ----
  PrepArgs P;
  auto setw = [&](int i, const float* s, unsigned short* d, unsigned short* dl,
                  int K, int N, int b0) {
    P.d[i].src = s; P.d[i].dst = d; P.d[i].dstlo = dl;
    P.d[i].K = K; P.d[i].N = N; P.d[i].blk0 = b0;
  };
  int b0 = 0;
  setw(0, vqkv + 2 * Dz * Dz, WVQV, nullptr, Dz, Dz, b0); b0 += 256;
  setw(1, voutw, WVO, nullptr, Dz, Dz, b0); b0 += 256;
  setw(2, vw1, WV1, nullptr, Dz, FFz, b0); b0 += 1024;
  setw(3, vw2, WV2, nullptr, FFz, Dz, b0); b0 += 1024;
  setw(4, lqkv + 0 * Dz * Dz, WLQ0, nullptr, Dz, Dz, b0); b0 += 256;
  setw(5, lqkv + 1 * Dz * Dz, WLQ1, nullptr, Dz, Dz, b0); b0 += 256;
  setw(6, lqkv + 2 * Dz * Dz, WLQ2, nullptr, Dz, Dz, b0); b0 += 256;
  setw(7, loutw, WLO, nullptr, Dz, Dz, b0); b0 += 256;
  setw(8, lw1, WL1, nullptr, Dz, FFz, b0); b0 += 1024;
  setw(9, lw2, WL2, nullptr, FFz, Dz, b0); b0 += 1024;
  setw(10, vqkv + 0 * Dz * Dz, WQH, WQL, Dz, Dz, b0); b0 += 256;
  setw(11, vqkv + 1 * Dz * Dz, WKH, WKL, Dz, Dz, b0); b0 += 256;
  P.nwc = b0;  // 6144
  prep_kernel<<<dim3(P.nwc + 64 + 4096), blk, 0, stream>>>(P, x, XBF, XLO, CS1);

  auto mgemm = [&](const unsigned short* A, const unsigned short* BT, void* p1,
                   void* p2, void* p3, int K, int N, int mode) {
    mfma_gemm_kernel<<<dim3(N / 128, Mz / 128), dim3(256), 0, stream>>>(
        A, BT, p1, p2, p3, K, N, mode);
  };

  // ---------------- layer 1 (vanilla) ----------------
  gemm_qk_mfma_kernel<<<dim3(4, 128), dim3(256), 0, stream>>>(
      XBF, XLO, WQH, WQL, WKH, WKL, QHbf, QLbf, KHbf, KLbf);
  attn_z_kernel<<<dim3(Bz * Hz * 16), blk, 0, stream>>>(QHbf, KHbf, INVZ);
  mgemm(XBF, WVQV, VT, nullptr, nullptr, Dz, Dz, 4);        // V -> V^T (XBF/XLO dead)
  attn_ctx_kernel<<<dim3(Bz * Hz * 16), blk, 0, stream>>>(
      QHbf, QLbf, KHbf, KLbf, VT, INVZ, SLOT1, PART);
  colsum_reduce_kernel<<<dim3(32), blk, 0, stream>>>(PART, CS1);
  window_ids_kernel<<<dim3(Bz), blk, 0, stream>>>(CS1, IDS, WST, NWIN);
  mgemm(SLOT1, WVO, PROJ, nullptr, nullptr, Dz, Dz, 0);     // proj (QL/KL dead)
  ln_kernel<<<dim3(Mz), blk, 0, stream>>>(x, nullptr, PROJ, Y1, SLOT2);
  mgemm(SLOT2, WV1, HIDbf, nullptr, nullptr, Dz, FFz, 2);   // FFN1 (PART dead)
  mgemm(HIDbf, WV2, PROJ, nullptr, nullptr, FFz, Dz, 0);    // FFN2
  ln_kernel<<<dim3(Mz), blk, 0, stream>>>(Y1, nullptr, PROJ, nullptr, SLOT2);

  // ---------------- layer 2 (block-diagonal window mask) ----------------
  mgemm(SLOT2, WLQ0, QHbf, KHbf, VT, Dz, 3 * Dz, 5);        // merged QKV
  attn_mfma2_kernel<<<dim3(Bz * Hz * 16), blk, 0, stream>>>(
      QHbf, KHbf, VT, IDS, WST, SLOT1, CS2);
  mgemm(SLOT1, WLO, PROJ, nullptr, nullptr, Dz, Dz, 0);
  ln_kernel<<<dim3(Mz), blk, 0, stream>>>(nullptr, SLOT2, PROJ, Y1, SLOT2);
  mgemm(SLOT2, WL1, HIDbf, nullptr, nullptr, Dz, FFz, 2);
  mgemm(HIDbf, WL2, PROJ, nullptr, nullptr, FFz, Dz, 0);
  ln_kernel<<<dim3(Mz), blk, 0, stream>>>(Y1, nullptr, PROJ, nullptr, SLOT2);

  // ---------------- pooling + outputs ----------------
  wl_softmax_kernel<<<dim3(Bz), blk, 0, stream>>>(CS2, WLs);
  outputs_kernel<<<dim3(20480), blk, 0, stream>>>(SLOT2, WLs, WST, NWIN, IDS, x,
                                                  out, out + (size_t)Bz * 2 * Tz * Dz);
}

// Round 9
// 582.501 us; speedup vs baseline: 1.8640x; 1.0292x over previous
//
#include <hip/hip_runtime.h>
#include <math.h>

// Problem constants (fixed by setup_inputs)
#define Bz 8
#define Tz 1024
#define Dz 512
#define FFz 2048
#define Hz 8
#define DHz 64
#define Mz (Bz * Tz)  // 8192 rows

typedef __attribute__((ext_vector_type(8))) short short8;   // 8 bf16 (4 VGPRs)
typedef __attribute__((ext_vector_type(4))) float f32x4;    // MFMA accumulator

__device__ inline unsigned short f2bf(float f) {  // RNE fp32 -> bf16
  unsigned u = __builtin_bit_cast(unsigned, f);
  return (unsigned short)((u + 0x7FFFu + ((u >> 16) & 1u)) >> 16);
}
__device__ inline float bf2f(unsigned short h) {
  unsigned u = (unsigned)h << 16;
  return __builtin_bit_cast(float, u);
}

// Async global->LDS 16B: LDS dest = wave-uniform base + lane*16 (HW rule),
// global src is per-lane. __syncthreads() drains vmcnt before s_barrier.
__device__ inline void gll16(const unsigned short* g, unsigned short* l) {
  __builtin_amdgcn_global_load_lds(
      (const __attribute__((address_space(1))) void*)g,
      (__attribute__((address_space(3))) void*)l, 16, 0, 0);
}

// XCD-aware decode for the 1024-block attention grids (8 XCDs round-robin by
// blockIdx). g = xcd + 8*(qt + 16*bhi), bh = bhi*8 + xcd.
__device__ inline void attn_decode(int g, int& b, int& h, int& qt) {
  const int xcd = g & 7;
  const int j = g >> 3;
  qt = j & 15;
  const int bh = ((j >> 4) << 3) | xcd;
  b = bh >> 3;
  h = bh & 7;
}

// Swizzled byte offset inside a [64 rows x 128B] LDS tile: 16B slot XOR'd by
// row&7 -> every fragment read/write lands at the 8-words/bank LDS floor.
__device__ inline int swz(int row, int slotByte) {
  return row * 128 + (slotByte ^ ((row & 7) << 4));
}

// ---------------------------------------------------------------------------
// Fused prep: 12 weight convert+transposes (fp32 [K,N] -> bf16 [N,K], with
// optional lo-residual output) + colsum zero-fill + x -> bf16 hi/lo.
// ---------------------------------------------------------------------------
struct WDesc { const float* src; unsigned short* dst; unsigned short* dstlo;
               int K; int N; int blk0; };
struct PrepArgs { WDesc d[12]; int nwc; };

__global__ __launch_bounds__(256) void prep_kernel(PrepArgs P,
    const float* __restrict__ x, unsigned short* __restrict__ xbf,
    unsigned short* __restrict__ xlo, float* __restrict__ csz)
{
  const int bid = blockIdx.x;
  const int tid = threadIdx.x;
  if (bid < P.nwc) {  // wconv slice
    int i = 0;
    while (i < 11 && bid >= P.d[i + 1].blk0) ++i;
    const WDesc w = P.d[i];
    const int lb = bid - w.blk0;
    const int nbn = w.N / 32;
    const int bn = (lb % nbn) * 32, bk = (lb / nbn) * 32;
    __shared__ float t[32][33];
    const int tx = tid & 31, ty = tid >> 5;
#pragma unroll
    for (int r = 0; r < 32; r += 8)
      t[ty + r][tx] = w.src[(size_t)(bk + ty + r) * w.N + bn + tx];
    __syncthreads();
#pragma unroll
    for (int r = 0; r < 32; r += 8) {
      float v = t[tx][ty + r];
      unsigned short hv = f2bf(v);
      w.dst[(size_t)(bn + ty + r) * w.K + bk + tx] = hv;
      if (w.dstlo)
        w.dstlo[(size_t)(bn + ty + r) * w.K + bk + tx] = f2bf(v - bf2f(hv));
    }
  } else if (bid < P.nwc + 64) {  // zero slice (CS1+CS2 = 16384 floats)
    int idx = (bid - P.nwc) * 256 + tid;
    csz[idx] = 0.f;
  } else {  // fconv slice: 4096 blocks, 4 floats/thread -> hi + lo
    int i = (bid - P.nwc - 64) * 256 + tid;
    float4 v = *reinterpret_cast<const float4*>(&x[(size_t)i * 4]);
    ushort4 o, ol;
    o.x = f2bf(v.x); o.y = f2bf(v.y); o.z = f2bf(v.z); o.w = f2bf(v.w);
    ol.x = f2bf(v.x - bf2f(o.x)); ol.y = f2bf(v.y - bf2f(o.y));
    ol.z = f2bf(v.z - bf2f(o.z)); ol.w = f2bf(v.w - bf2f(o.w));
    *reinterpret_cast<ushort4*>(&xbf[(size_t)i * 4]) = o;
    *reinterpret_cast<ushort4*>(&xlo[(size_t)i * 4]) = ol;
  }
}

// ---------------------------------------------------------------------------
// bf16 MFMA GEMM, LDS-staged via global_load_lds width=16 (async DMA, no
// VGPR round-trip). LDS image identical to the reg-staged version -> bit-
// identical outputs. 256-thread blocks (4 waves), 128x128 tile.
// Epilogue modes: 0 fp32 C | 1 bf16 C | 2 bf16 C + ReLU
//   | 4 V^T layout | 5 merged QKV (N=1536).
// ---------------------------------------------------------------------------
__global__ __launch_bounds__(256) void mfma_gemm_kernel(
    const unsigned short* __restrict__ A, const unsigned short* __restrict__ BT,
    void* __restrict__ p1, void* __restrict__ p2, void* __restrict__ p3,
    int K, int N, int mode)
{
  __shared__ unsigned short As[128 * 32];  // 8KB: 128 rows x 64B, linear
  __shared__ unsigned short Bs[128 * 32];  // 8KB
  const int tid = threadIdx.x;
  const int lane = tid & 63, wave = tid >> 6;
  const int mr = lane & 15, quad = lane >> 4;
  const int wr = wave >> 1, wc = wave & 1;
  const int m0 = blockIdx.y * 128;
  const int n0 = blockIdx.x * 128;

  f32x4 acc[4][4];
  const f32x4 zero = {0.f, 0.f, 0.f, 0.f};
#pragma unroll
  for (int i = 0; i < 4; ++i)
#pragma unroll
    for (int j = 0; j < 4; ++j) acc[i][j] = zero;

  // staging: instr covers 16 rows x 4 slots; lane l -> row base+(l>>2), slot l&3
  const int lrow = lane >> 2, lslot = lane & 3;
  const unsigned short* Ag0 = A + (size_t)(m0 + wave * 16 + lrow) * K + lslot * 8;
  const unsigned short* Ag1 = A + (size_t)(m0 + 64 + wave * 16 + lrow) * K + lslot * 8;
  const unsigned short* Bg0 = BT + (size_t)(n0 + wave * 16 + lrow) * K + lslot * 8;
  const unsigned short* Bg1 = BT + (size_t)(n0 + 64 + wave * 16 + lrow) * K + lslot * 8;
  unsigned short* Al0 = As + wave * 512;          // byte w*1024
  unsigned short* Al1 = As + 2048 + wave * 512;   // rows 64.. -> byte 4096+w*1024
  unsigned short* Bl0 = Bs + wave * 512;
  unsigned short* Bl1 = Bs + 2048 + wave * 512;
  char* AsB = (char*)As;
  char* BsB = (char*)Bs;

  for (int k0 = 0; k0 < K; k0 += 32) {
    gll16(Ag0 + k0, Al0);
    gll16(Ag1 + k0, Al1);
    gll16(Bg0 + k0, Bl0);
    gll16(Bg1 + k0, Bl1);
    __syncthreads();  // vmcnt(0) drain before barrier -> staged data visible
    short8 af[4], bf[4];
#pragma unroll
    for (int i = 0; i < 4; ++i)
      af[i] = *reinterpret_cast<const short8*>(AsB + (wr * 64 + i * 16 + mr) * 64 + quad * 16);
#pragma unroll
    for (int j = 0; j < 4; ++j)
      bf[j] = *reinterpret_cast<const short8*>(BsB + (wc * 64 + j * 16 + mr) * 64 + quad * 16);
#pragma unroll
    for (int i = 0; i < 4; ++i)
#pragma unroll
      for (int j = 0; j < 4; ++j)
        acc[i][j] = __builtin_amdgcn_mfma_f32_16x16x32_bf16(af[i], bf[j], acc[i][j], 0, 0, 0);
    __syncthreads();  // reads done before next tile's DMA lands
  }

  // per-wave 64x64 epilogue at (m0w, n0w)
  const int m0w = m0 + wr * 64;
  const int n0w = n0 + wc * 64;
  // C/D layout: col = lane&15, row = quad*4 + reg   [measured: m89/m91]
  int emode = mode;
  unsigned short* Cbf = (unsigned short*)p1;
  unsigned short* Vt  = (unsigned short*)p1;
  int ncol = N, coff = 0;
  if (mode == 5) {  // uniform per wave: n0w is a multiple of 64
    if (n0w < 512)       { emode = 1; Cbf = (unsigned short*)p1; ncol = 512; coff = 0; }
    else if (n0w < 1024) { emode = 1; Cbf = (unsigned short*)p2; ncol = 512; coff = 512; }
    else                 { emode = 4; Vt = (unsigned short*)p3; coff = 1024; }
  }
  if (emode == 4) {  // V^T: 4 consecutive tokens same feature -> ushort4
#pragma unroll
    for (int i = 0; i < 4; ++i)
#pragma unroll
      for (int j = 0; j < 4; ++j) {
        const int col = n0w - coff + j * 16 + mr;  // feature: h = col>>6, d = col&63
        const int row0 = m0w + i * 16 + quad * 4;  // token base (4 consecutive)
        const int bb = row0 >> 10, t0 = row0 & 1023;
        ushort4 pk;
        pk.x = f2bf(acc[i][j][0]); pk.y = f2bf(acc[i][j][1]);
        pk.z = f2bf(acc[i][j][2]); pk.w = f2bf(acc[i][j][3]);
        *reinterpret_cast<ushort4*>(
            &Vt[((size_t)((bb * Hz + (col >> 6)) * DHz + (col & 63))) * Tz + t0]) = pk;
      }
  } else if (emode == 0) {
    float* Cf = (float*)p1;
#pragma unroll
    for (int i = 0; i < 4; ++i)
#pragma unroll
      for (int j = 0; j < 4; ++j) {
        const int col = n0w + j * 16 + mr;
#pragma unroll
        for (int rr = 0; rr < 4; ++rr)
          Cf[(size_t)(m0w + i * 16 + quad * 4 + rr) * N + col] = acc[i][j][rr];
      }
  } else {
    const bool relu = (emode == 2);
#pragma unroll
    for (int i = 0; i < 4; ++i)
#pragma unroll
      for (int j = 0; j < 4; ++j) {
        const int col = n0w - coff + j * 16 + mr;
#pragma unroll
        for (int rr = 0; rr < 4; ++rr) {
          float v = acc[i][j][rr];
          if (relu) v = fmaxf(v, 0.f);
          Cbf[(size_t)(m0w + i * 16 + quad * 4 + rr) * ncol + col] = f2bf(v);
        }
      }
  }
}

// ---------------------------------------------------------------------------
// Layer-1 Q,K via bf16x3 MFMA, LDS-staged via global_load_lds (4 panels,
// 32KB LDS). MFMA order per acc (al.bh, ah.bl, ah.bh, k ascending) identical
// -> Q/K hi/lo outputs bit-identical.
// ---------------------------------------------------------------------------
__global__ __launch_bounds__(256) void gemm_qk_mfma_kernel(
    const unsigned short* __restrict__ Xh, const unsigned short* __restrict__ Xl,
    const unsigned short* __restrict__ WQh, const unsigned short* __restrict__ WQl,
    const unsigned short* __restrict__ WKh, const unsigned short* __restrict__ WKl,
    unsigned short* __restrict__ Qhi, unsigned short* __restrict__ Qlo,
    unsigned short* __restrict__ Khi, unsigned short* __restrict__ Klo)
{
  __shared__ unsigned short Ash[128 * 32];  // 8KB each, linear
  __shared__ unsigned short Asl[128 * 32];
  __shared__ unsigned short Bsh[128 * 32];
  __shared__ unsigned short Bsl[128 * 32];
  const int tid = threadIdx.x;
  const int lane = tid & 63, wave = tid >> 6;
  const int mr = lane & 15, quad = lane >> 4;
  const int wr = wave >> 1, wc = wave & 1;
  const int sel = blockIdx.y >> 6;
  const int m0 = (blockIdx.y & 63) * 128;
  const int n0 = blockIdx.x * 128;
  const unsigned short* Bh = sel ? WKh : WQh;
  const unsigned short* Bl = sel ? WKl : WQl;
  unsigned short* Chi = sel ? Khi : Qhi;
  unsigned short* Clo = sel ? Klo : Qlo;

  f32x4 acc[4][4];
  const f32x4 zero = {0.f, 0.f, 0.f, 0.f};
#pragma unroll
  for (int i = 0; i < 4; ++i)
#pragma unroll
    for (int j = 0; j < 4; ++j) acc[i][j] = zero;

  const int lrow = lane >> 2, lslot = lane & 3;
  const unsigned short* gAh0 = Xh + (size_t)(m0 + wave * 16 + lrow) * Dz + lslot * 8;
  const unsigned short* gAh1 = Xh + (size_t)(m0 + 64 + wave * 16 + lrow) * Dz + lslot * 8;
  const unsigned short* gAl0 = Xl + (size_t)(m0 + wave * 16 + lrow) * Dz + lslot * 8;
  const unsigned short* gAl1 = Xl + (size_t)(m0 + 64 + wave * 16 + lrow) * Dz + lslot * 8;
  const unsigned short* gBh0 = Bh + (size_t)(n0 + wave * 16 + lrow) * Dz + lslot * 8;
  const unsigned short* gBh1 = Bh + (size_t)(n0 + 64 + wave * 16 + lrow) * Dz + lslot * 8;
  const unsigned short* gBl0 = Bl + (size_t)(n0 + wave * 16 + lrow) * Dz + lslot * 8;
  const unsigned short* gBl1 = Bl + (size_t)(n0 + 64 + wave * 16 + lrow) * Dz + lslot * 8;
  unsigned short* LAh0 = Ash + wave * 512; unsigned short* LAh1 = Ash + 2048 + wave * 512;
  unsigned short* LAl0 = Asl + wave * 512; unsigned short* LAl1 = Asl + 2048 + wave * 512;
  unsigned short* LBh0 = Bsh + wave * 512; unsigned short* LBh1 = Bsh + 2048 + wave * 512;
  unsigned short* LBl0 = Bsl + wave * 512; unsigned short* LBl1 = Bsl + 2048 + wave * 512;
  char* AhB = (char*)Ash; char* AlB = (char*)Asl;
  char* BhB = (char*)Bsh; char* BlB = (char*)Bsl;

  for (int k0 = 0; k0 < Dz; k0 += 32) {
    gll16(gAh0 + k0, LAh0); gll16(gAh1 + k0, LAh1);
    gll16(gAl0 + k0, LAl0); gll16(gAl1 + k0, LAl1);
    gll16(gBh0 + k0, LBh0); gll16(gBh1 + k0, LBh1);
    gll16(gBl0 + k0, LBl0); gll16(gBl1 + k0, LBl1);
    __syncthreads();
    short8 ah[4], al[4], bh[4], bl[4];
#pragma unroll
    for (int i = 0; i < 4; ++i) {
      const int ab = (wr * 64 + i * 16 + mr) * 64 + quad * 16;
      ah[i] = *reinterpret_cast<const short8*>(AhB + ab);
      al[i] = *reinterpret_cast<const short8*>(AlB + ab);
    }
#pragma unroll
    for (int j = 0; j < 4; ++j) {
      const int bb = (wc * 64 + j * 16 + mr) * 64 + quad * 16;
      bh[j] = *reinterpret_cast<const short8*>(BhB + bb);
      bl[j] = *reinterpret_cast<const short8*>(BlB + bb);
    }
#pragma unroll
    for (int i = 0; i < 4; ++i)
#pragma unroll
      for (int j = 0; j < 4; ++j) {
        acc[i][j] = __builtin_amdgcn_mfma_f32_16x16x32_bf16(al[i], bh[j], acc[i][j], 0, 0, 0);
        acc[i][j] = __builtin_amdgcn_mfma_f32_16x16x32_bf16(ah[i], bl[j], acc[i][j], 0, 0, 0);
        acc[i][j] = __builtin_amdgcn_mfma_f32_16x16x32_bf16(ah[i], bh[j], acc[i][j], 0, 0, 0);
      }
    __syncthreads();
  }

  const int m0w = m0 + wr * 64;
  const int n0w = n0 + wc * 64;
#pragma unroll
  for (int i = 0; i < 4; ++i)
#pragma unroll
    for (int j = 0; j < 4; ++j) {
      const int col = n0w + j * 16 + mr;
#pragma unroll
      for (int rr = 0; rr < 4; ++rr) {
        const size_t row = (size_t)(m0w + i * 16 + quad * 4 + rr);
        float v = acc[i][j][rr];
        unsigned short hv = f2bf(v);
        Chi[row * Dz + col] = hv;
        Clo[row * Dz + col] = f2bf(v - bf2f(hv));
      }
    }
}

// ---------------------------------------------------------------------------
// Layer-1 z pass, CHEAP plain-bf16 QK^T, LDS-STAGED (round 7, proven).
// ---------------------------------------------------------------------------
__global__ __launch_bounds__(256) void attn_z_kernel(
    const unsigned short* __restrict__ Qh, const unsigned short* __restrict__ Kh,
    float* __restrict__ invzG)
{
  __shared__ unsigned short Ksh[64 * 64];  // 8KB: 64 keys x 128B (swizzled)
  const int tid = threadIdx.x;
  const int lane = tid & 63, wave = tid >> 6;
  const int c = lane & 15, quad = lane >> 4;
  int b, h, qt;
  attn_decode(blockIdx.x, b, h, qt);
  const size_t bT = (size_t)b * Tz;
  const int qrow = qt * 64 + wave * 16;
  const int hoff = h * DHz;

  const size_t qbase = (bT + qrow + c) * Dz + hoff + quad * 8;
  short8 q0 = *reinterpret_cast<const short8*>(Qh + qbase);
  short8 q1 = *reinterpret_cast<const short8*>(Qh + qbase + 32);

  const int sr = tid >> 3;        // row 0..31
  const int sj = (tid & 7) * 16;  // slot byte
  const unsigned short* khb = Kh + (bT + sr) * Dz + hoff + (tid & 7) * 8;
  char* KshB = (char*)Ksh;

  const f32x4 zf = {0.f, 0.f, 0.f, 0.f};
  float z[4] = {0.f, 0.f, 0.f, 0.f};

  for (int t = 0; t < 16; ++t) {
    const int k0 = t * 64;
    short8 g0 = *reinterpret_cast<const short8*>(khb + (size_t)k0 * Dz);
    short8 g1 = *reinterpret_cast<const short8*>(khb + (size_t)(k0 + 32) * Dz);
    *reinterpret_cast<short8*>(KshB + swz(sr, sj)) = g0;
    *reinterpret_cast<short8*>(KshB + swz(sr + 32, sj)) = g1;
    __syncthreads();
#pragma unroll
    for (int sub = 0; sub < 4; ++sub) {
      const int row = sub * 16 + c;
      short8 kh0 = *reinterpret_cast<const short8*>(KshB + swz(row, quad * 16));
      short8 kh1 = *reinterpret_cast<const short8*>(KshB + swz(row, 64 + quad * 16));
      f32x4 aA = zf, aB = zf;
      aA = __builtin_amdgcn_mfma_f32_16x16x32_bf16(q0, kh0, aA, 0, 0, 0);
      aB = __builtin_amdgcn_mfma_f32_16x16x32_bf16(q1, kh1, aB, 0, 0, 0);
#pragma unroll
      for (int rr = 0; rr < 4; ++rr) z[rr] += __expf((aA[rr] + aB[rr]) * 0.125f);
    }
    __syncthreads();  // reads done before next stage overwrites
  }
#pragma unroll
  for (int w = 1; w < 16; w <<= 1) {
#pragma unroll
    for (int rr = 0; rr < 4; ++rr) z[rr] += __shfl_xor(z[rr], w);
  }
  if (c == 0) {
#pragma unroll
    for (int rr = 0; rr < 4; ++rr)
      invzG[(size_t)(b * Hz + h) * Tz + qrow + quad * 4 + rr] = 1.f / z[rr];
  }
}

// ---------------------------------------------------------------------------
// Layer-1 ctx with LDS-STAGED K/V (proven round 6). All arithmetic values,
// order and PART slots bit-identical to round 4.
// ---------------------------------------------------------------------------
__global__ __launch_bounds__(256) void attn_ctx_kernel(
    const unsigned short* __restrict__ Qh, const unsigned short* __restrict__ Ql,
    const unsigned short* __restrict__ Kh, const unsigned short* __restrict__ Kl,
    const unsigned short* __restrict__ Vt, const float* __restrict__ invzG,
    unsigned short* __restrict__ ctx, float* __restrict__ part)
{
  __shared__ unsigned short Ksh[64 * 64];  // 8KB: 64 keys x 128B (swizzled)
  __shared__ unsigned short Ksl[64 * 64];  // 8KB
  __shared__ unsigned short Vsh[64 * 64];  // 8KB: 64 features x 128B (swizzled)
  __shared__ unsigned short Pld[64][76];   // 9.5KB
  __shared__ float CSPt[4][64];            // per-wave per-tile colsum partials
  const int tid = threadIdx.x;
  const int lane = tid & 63, wave = tid >> 6;
  const int c = lane & 15, quad = lane >> 4;
  int b, h, qt;
  attn_decode(blockIdx.x, b, h, qt);
  const size_t bT = (size_t)b * Tz;
  const int qrow = qt * 64 + wave * 16;
  const int hoff = h * DHz;
  const int lidx = b * 128 + h * 16 + qt;  // logical PART slot

  const size_t qbase = (bT + qrow + c) * Dz + hoff + quad * 8;
  short8 q0h = *reinterpret_cast<const short8*>(Qh + qbase);
  short8 q1h = *reinterpret_cast<const short8*>(Qh + qbase + 32);
  short8 q0l = *reinterpret_cast<const short8*>(Ql + qbase);
  short8 q1l = *reinterpret_cast<const short8*>(Ql + qbase + 32);

  float invz[4];
#pragma unroll
  for (int rr = 0; rr < 4; ++rr)
    invz[rr] = invzG[(size_t)(b * Hz + h) * Tz + qrow + quad * 4 + rr];

  // staging coords: 256 threads cover 32 rows x 8 slots (16B) per pass
  const int sr = tid >> 3;        // row 0..31
  const int sj = (tid & 7) * 16;  // slot byte 0..112
  const unsigned short* khb = Kh + (bT + sr) * Dz + hoff + (tid & 7) * 8;
  const unsigned short* klb = Kl + (bT + sr) * Dz + hoff + (tid & 7) * 8;
  const unsigned short* vtb = Vt + ((size_t)(b * Hz + h) * DHz + sr) * Tz + (tid & 7) * 8;

  const f32x4 zf = {0.f, 0.f, 0.f, 0.f};
  f32x4 ot[4] = {zf, zf, zf, zf};

  char* KshB = (char*)Ksh;
  char* KslB = (char*)Ksl;
  char* VshB = (char*)Vsh;

  for (int t = 0; t < 16; ++t) {
    const int k0 = t * 64;
    // ---- stage tile t: coalesced global -> regs -> swizzled LDS ----
    short8 g0 = *reinterpret_cast<const short8*>(khb + (size_t)k0 * Dz);
    short8 g1 = *reinterpret_cast<const short8*>(khb + (size_t)(k0 + 32) * Dz);
    short8 g2 = *reinterpret_cast<const short8*>(klb + (size_t)k0 * Dz);
    short8 g3 = *reinterpret_cast<const short8*>(klb + (size_t)(k0 + 32) * Dz);
    short8 g4 = *reinterpret_cast<const short8*>(vtb + k0);
    short8 g5 = *reinterpret_cast<const short8*>(vtb + 32 * Tz + k0);
    // prev tile fully consumed at the tail barrier of the previous iteration
    *reinterpret_cast<short8*>(KshB + swz(sr, sj)) = g0;
    *reinterpret_cast<short8*>(KshB + swz(sr + 32, sj)) = g1;
    *reinterpret_cast<short8*>(KslB + swz(sr, sj)) = g2;
    *reinterpret_cast<short8*>(KslB + swz(sr + 32, sj)) = g3;
    *reinterpret_cast<short8*>(VshB + swz(sr, sj)) = g4;
    *reinterpret_cast<short8*>(VshB + swz(sr + 32, sj)) = g5;
    __syncthreads();  // staged data visible

    // ---- QK^T subtiles (bf16x3, 2-acc split) ----
#pragma unroll
    for (int sub = 0; sub < 4; ++sub) {
      const int row = sub * 16 + c;
      short8 kh0 = *reinterpret_cast<const short8*>(KshB + swz(row, quad * 16));
      short8 kh1 = *reinterpret_cast<const short8*>(KshB + swz(row, 64 + quad * 16));
      short8 kl0 = *reinterpret_cast<const short8*>(KslB + swz(row, quad * 16));
      short8 kl1 = *reinterpret_cast<const short8*>(KslB + swz(row, 64 + quad * 16));
      f32x4 aA = zf, aB = zf;
      aA = __builtin_amdgcn_mfma_f32_16x16x32_bf16(q0h, kh0, aA, 0, 0, 0);
      aB = __builtin_amdgcn_mfma_f32_16x16x32_bf16(q1h, kh1, aB, 0, 0, 0);
      aA = __builtin_amdgcn_mfma_f32_16x16x32_bf16(q0h, kl0, aA, 0, 0, 0);
      aB = __builtin_amdgcn_mfma_f32_16x16x32_bf16(q1h, kl1, aB, 0, 0, 0);
      aA = __builtin_amdgcn_mfma_f32_16x16x32_bf16(q0l, kh0, aA, 0, 0, 0);
      aB = __builtin_amdgcn_mfma_f32_16x16x32_bf16(q1l, kh1, aB, 0, 0, 0);
      float p[4];
#pragma unroll
      for (int rr = 0; rr < 4; ++rr)
        p[rr] = __expf((aA[rr] + aB[rr]) * 0.125f) * invz[rr];
      float cs = p[0] + p[1] + p[2] + p[3];
      cs += __shfl_xor(cs, 16);
      cs += __shfl_xor(cs, 32);
      if (quad == 0) CSPt[wave][sub * 16 + c] = cs;  // key visited once
#pragma unroll
      for (int rr = 0; rr < 4; ++rr)
        Pld[(wave << 4) + quad * 4 + rr][sub * 16 + c] = f2bf(p[rr]);
    }

    // ---- PV from LDS ----
    union { short8 v; ushort4 hh[2]; } pb0, pb1;
    pb0.hh[0] = *reinterpret_cast<const ushort4*>(&Pld[(wave << 4) + c][quad * 8]);
    pb0.hh[1] = *reinterpret_cast<const ushort4*>(&Pld[(wave << 4) + c][quad * 8 + 4]);
    pb1.hh[0] = *reinterpret_cast<const ushort4*>(&Pld[(wave << 4) + c][32 + quad * 8]);
    pb1.hh[1] = *reinterpret_cast<const ushort4*>(&Pld[(wave << 4) + c][32 + quad * 8 + 4]);
#pragma unroll
    for (int ds = 0; ds < 4; ++ds) {
      const int row = ds * 16 + c;
      short8 v0 = *reinterpret_cast<const short8*>(VshB + swz(row, quad * 16));
      short8 v1 = *reinterpret_cast<const short8*>(VshB + swz(row, 64 + quad * 16));
      ot[ds] = __builtin_amdgcn_mfma_f32_16x16x32_bf16(v0, pb0.v, ot[ds], 0, 0, 0);
      ot[ds] = __builtin_amdgcn_mfma_f32_16x16x32_bf16(v1, pb1.v, ot[ds], 0, 0, 0);
    }
    __syncthreads();  // all LDS reads done; CSPt complete across waves

    // ---- deterministic per-tile colsum combine (same 4-addend order) ----
    if (tid < 64) {
      float v = ((CSPt[0][tid] + CSPt[1][tid]) + CSPt[2][tid]) + CSPt[3][tid];
      part[(size_t)lidx * 1024 + k0 + tid] = v * (1.f / Hz);
    }
  }

  const size_t cb = (bT + qrow + c) * Dz + hoff;
#pragma unroll
  for (int ds = 0; ds < 4; ++ds) {
    ushort4 pk;
    pk.x = f2bf(ot[ds][0]); pk.y = f2bf(ot[ds][1]);
    pk.z = f2bf(ot[ds][2]); pk.w = f2bf(ot[ds][3]);
    *reinterpret_cast<ushort4*>(&ctx[cb + ds * 16 + quad * 4]) = pk;
  }
}

// ---------------------------------------------------------------------------
// Deterministic colsum reduce: CS1[b,key] = sum over the 128 (h,qt) block
// partials in fixed ascending order. One thread per output.
// ---------------------------------------------------------------------------
__global__ __launch_bounds__(256) void colsum_reduce_kernel(
    const float* __restrict__ part, float* __restrict__ colsum)
{
  const int i = blockIdx.x * 256 + threadIdx.x;  // 0..8191
  const int b = i >> 10, k = i & 1023;
  const float* p = part + (size_t)(b * 128) * 1024 + k;
  float s = 0.f;
  for (int j = 0; j < 128; ++j) s += p[(size_t)j * 1024];
  colsum[i] = s;
}

// ---------------------------------------------------------------------------
// Layer-2 MFMA attention (masked), k-tile range skipping, now LDS-STAGED
// K/V (same proven reg-staged + swizzle pattern as attn_ctx). Arithmetic
// values/order identical -> ctx/CS2 bits unchanged.
// ---------------------------------------------------------------------------
__global__ __launch_bounds__(256) void attn_mfma2_kernel(
    const unsigned short* __restrict__ Qh, const unsigned short* __restrict__ Kh,
    const unsigned short* __restrict__ Vt, const int* __restrict__ ids,
    const int* __restrict__ wst,
    unsigned short* __restrict__ ctx, float* __restrict__ colsum)
{
  __shared__ unsigned short Ksh[64 * 64];  // 8KB (swizzled)
  __shared__ unsigned short Vsh[64 * 64];  // 8KB (swizzled)
  __shared__ unsigned short Pld[64][76];
  __shared__ float csb[1024];

  const int tid = threadIdx.x;
  const int lane = tid & 63, wave = tid >> 6;
  const int c = lane & 15, quad = lane >> 4;
  int b, h, qt;
  attn_decode(blockIdx.x, b, h, qt);
  const size_t bT = (size_t)b * Tz;
  const int qrow = qt * 64 + wave * 16;
  const int hoff = h * DHz;

  for (int i = tid; i < 1024; i += 256) csb[i] = 0.f;

  const int id_lo = ids[bT + qt * 64];
  const int id_hi = ids[bT + qt * 64 + 63];
  const int klo = wst[b * (Tz + 1) + id_lo];
  const int khi = wst[b * (Tz + 1) + id_hi + 1];
  const int t0 = klo >> 6, t1 = (khi - 1) >> 6;

  const size_t qbase = (bT + qrow + c) * Dz + hoff + quad * 8;
  short8 q0 = *reinterpret_cast<const short8*>(Qh + qbase);
  short8 q1 = *reinterpret_cast<const short8*>(Qh + qbase + 32);

  int qid[4];
#pragma unroll
  for (int rr = 0; rr < 4; ++rr) qid[rr] = ids[bT + qrow + quad * 4 + rr];

  const int sr = tid >> 3;        // staging row 0..31
  const int sj = (tid & 7) * 16;  // slot byte
  const unsigned short* khb = Kh + (bT + sr) * Dz + hoff + (tid & 7) * 8;
  const unsigned short* vtb = Vt + ((size_t)(b * Hz + h) * DHz + sr) * Tz + (tid & 7) * 8;
  char* KshB = (char*)Ksh;
  char* VshB = (char*)Vsh;
  __syncthreads();  // csb zeros visible before pass-2 atomics

  const f32x4 zf = {0.f, 0.f, 0.f, 0.f};

  // pass 1: z (stage Kh per tile)
  float z[4] = {0.f, 0.f, 0.f, 0.f};
  for (int t = t0; t <= t1; ++t) {
    const int k0 = t * 64;
    short8 g0 = *reinterpret_cast<const short8*>(khb + (size_t)k0 * Dz);
    short8 g1 = *reinterpret_cast<const short8*>(khb + (size_t)(k0 + 32) * Dz);
    *reinterpret_cast<short8*>(KshB + swz(sr, sj)) = g0;
    *reinterpret_cast<short8*>(KshB + swz(sr + 32, sj)) = g1;
    __syncthreads();
#pragma unroll
    for (int sub = 0; sub < 4; ++sub) {
      const int row = sub * 16 + c;
      short8 kh0 = *reinterpret_cast<const short8*>(KshB + swz(row, quad * 16));
      short8 kh1 = *reinterpret_cast<const short8*>(KshB + swz(row, 64 + quad * 16));
      f32x4 acc = zf;
      acc = __builtin_amdgcn_mfma_f32_16x16x32_bf16(q0, kh0, acc, 0, 0, 0);
      acc = __builtin_amdgcn_mfma_f32_16x16x32_bf16(q1, kh1, acc, 0, 0, 0);
      int kidv = ids[bT + k0 + sub * 16 + c];
#pragma unroll
      for (int rr = 0; rr < 4; ++rr) {
        float e = __expf(acc[rr] * 0.125f);
        if (qid[rr] != kidv) e = 0.f;
        z[rr] += e;
      }
    }
    __syncthreads();
  }
#pragma unroll
  for (int w = 1; w < 16; w <<= 1) {
#pragma unroll
    for (int rr = 0; rr < 4; ++rr) z[rr] += __shfl_xor(z[rr], w);
  }
  float invz[4];
#pragma unroll
  for (int rr = 0; rr < 4; ++rr) invz[rr] = 1.f / z[rr];

  // pass 2: P, colsum, PV (stage Kh + V per tile)
  f32x4 ot[4] = {zf, zf, zf, zf};
  for (int t = t0; t <= t1; ++t) {
    const int k0 = t * 64;
    short8 g0 = *reinterpret_cast<const short8*>(khb + (size_t)k0 * Dz);
    short8 g1 = *reinterpret_cast<const short8*>(khb + (size_t)(k0 + 32) * Dz);
    short8 g4 = *reinterpret_cast<const short8*>(vtb + k0);
    short8 g5 = *reinterpret_cast<const short8*>(vtb + 32 * Tz + k0);
    *reinterpret_cast<short8*>(KshB + swz(sr, sj)) = g0;
    *reinterpret_cast<short8*>(KshB + swz(sr + 32, sj)) = g1;
    *reinterpret_cast<short8*>(VshB + swz(sr, sj)) = g4;
    *reinterpret_cast<short8*>(VshB + swz(sr + 32, sj)) = g5;
    __syncthreads();
#pragma unroll
    for (int sub = 0; sub < 4; ++sub) {
      const int row = sub * 16 + c;
      short8 kh0 = *reinterpret_cast<const short8*>(KshB + swz(row, quad * 16));
      short8 kh1 = *reinterpret_cast<const short8*>(KshB + swz(row, 64 + quad * 16));
      f32x4 acc = zf;
      acc = __builtin_amdgcn_mfma_f32_16x16x32_bf16(q0, kh0, acc, 0, 0, 0);
      acc = __builtin_amdgcn_mfma_f32_16x16x32_bf16(q1, kh1, acc, 0, 0, 0);
      int kidv = ids[bT + k0 + sub * 16 + c];
      float p[4];
#pragma unroll
      for (int rr = 0; rr < 4; ++rr) {
        float e = __expf(acc[rr] * 0.125f);
        if (qid[rr] != kidv) e = 0.f;
        p[rr] = e * invz[rr];
      }
      float cs = p[0] + p[1] + p[2] + p[3];
      cs += __shfl_xor(cs, 16);
      cs += __shfl_xor(cs, 32);
      if (quad == 0) atomicAdd(&csb[k0 + sub * 16 + c], cs);
#pragma unroll
      for (int rr = 0; rr < 4; ++rr)
        Pld[(wave << 4) + quad * 4 + rr][sub * 16 + c] = f2bf(p[rr]);
    }
    union { short8 v; ushort4 hh[2]; } pb0, pb1;
    pb0.hh[0] = *reinterpret_cast<const ushort4*>(&Pld[(wave << 4) + c][quad * 8]);
    pb0.hh[1] = *reinterpret_cast<const ushort4*>(&Pld[(wave << 4) + c][quad * 8 + 4]);
    pb1.hh[0] = *reinterpret_cast<const ushort4*>(&Pld[(wave << 4) + c][32 + quad * 8]);
    pb1.hh[1] = *reinterpret_cast<const ushort4*>(&Pld[(wave << 4) + c][32 + quad * 8 + 4]);
#pragma unroll
    for (int ds = 0; ds < 4; ++ds) {
      const int row = ds * 16 + c;
      short8 v0 = *reinterpret_cast<const short8*>(VshB + swz(row, quad * 16));
      short8 v1 = *reinterpret_cast<const short8*>(VshB + swz(row, 64 + quad * 16));
      ot[ds] = __builtin_amdgcn_mfma_f32_16x16x32_bf16(v0, pb0.v, ot[ds], 0, 0, 0);
      ot[ds] = __builtin_amdgcn_mfma_f32_16x16x32_bf16(v1, pb1.v, ot[ds], 0, 0, 0);
    }
    __syncthreads();  // LDS reads done before next tile's staging
  }

  const size_t cb = (bT + qrow + c) * Dz + hoff;
#pragma unroll
  for (int ds = 0; ds < 4; ++ds) {
    ushort4 pk;
    pk.x = f2bf(ot[ds][0]); pk.y = f2bf(ot[ds][1]);
    pk.z = f2bf(ot[ds][2]); pk.w = f2bf(ot[ds][3]);
    *reinterpret_cast<ushort4*>(&ctx[cb + ds * 16 + quad * 4]) = pk;
  }
  __syncthreads();
  for (int i = tid; i < 1024; i += 256)
    atomicAdd(&colsum[bT + i], csb[i] * (1.f / Hz));
}

// ---------------------------------------------------------------------------
// out = LayerNorm(resid + delta). resid fp32 (residf) if non-null else bf16.
// ---------------------------------------------------------------------------
__global__ __launch_bounds__(256) void ln_kernel(const float* __restrict__ residf,
    const unsigned short* __restrict__ residbf, const float* __restrict__ delta,
    float* __restrict__ outf, unsigned short* __restrict__ outbf)
{
  const size_t base = (size_t)blockIdx.x * Dz;
  const int tid = threadIdx.x;
  float r0, r1;
  if (residf) {
    r0 = residf[base + tid]; r1 = residf[base + tid + 256];
  } else {
    r0 = bf2f(residbf[base + tid]); r1 = bf2f(residbf[base + tid + 256]);
  }
  float x0 = r0 + delta[base + tid];
  float x1 = r1 + delta[base + tid + 256];
  __shared__ float red[4];
  float s = x0 + x1;
#pragma unroll
  for (int off = 32; off; off >>= 1) s += __shfl_down(s, off);
  if ((tid & 63) == 0) red[tid >> 6] = s;
  __syncthreads();
  const float mean = (red[0] + red[1] + red[2] + red[3]) * (1.f / Dz);
  __syncthreads();
  float d0 = x0 - mean, d1 = x1 - mean;
  float v = d0 * d0 + d1 * d1;
#pragma unroll
  for (int off = 32; off; off >>= 1) v += __shfl_down(v, off);
  if ((tid & 63) == 0) red[tid >> 6] = v;
  __syncthreads();
  const float var = (red[0] + red[1] + red[2] + red[3]) * (1.f / Dz);
  const float rstd = rsqrtf(var + 1e-5f);
  float y0 = d0 * rstd, y1 = d1 * rstd;
  if (outf) {
    outf[base + tid] = y0;
    outf[base + tid + 256] = y1;
  }
  outbf[base + tid] = f2bf(y0);
  outbf[base + tid + 256] = f2bf(y1);
}

// ---------------------------------------------------------------------------
// Per batch: min-max normalize colsum, threshold 0.5, run-length window scan.
// PARALLELIZED (round 7, proven): ballot-packed bits + register bit-scan of
// transitions + parallel binary-search ids fill. Bit-identical to reference.
// ---------------------------------------------------------------------------
__global__ __launch_bounds__(256) void window_ids_kernel(const float* __restrict__ cs,
    int* __restrict__ ids, int* __restrict__ wst, int* __restrict__ nwin)
{
  const int b = blockIdx.x, tid = threadIdx.x;
  __shared__ float vals[Tz];
  __shared__ int swst[Tz + 1];
  __shared__ unsigned long long words[16];
  __shared__ float rmin[4], rmax[4];
  __shared__ int snw;
  float mn = INFINITY, mx = -INFINITY;
  for (int t = tid; t < Tz; t += 256) {
    float v = cs[b * Tz + t];
    vals[t] = v;
    mn = fminf(mn, v); mx = fmaxf(mx, v);
  }
#pragma unroll
  for (int off = 32; off; off >>= 1) {
    mn = fminf(mn, __shfl_down(mn, off));
    mx = fmaxf(mx, __shfl_down(mx, off));
  }
  if ((tid & 63) == 0) { rmin[tid >> 6] = mn; rmax[tid >> 6] = mx; }
  __syncthreads();
  mn = fminf(fminf(rmin[0], rmin[1]), fminf(rmin[2], rmin[3]));
  mx = fmaxf(fmaxf(rmax[0], rmax[1]), fmaxf(rmax[2], rmax[3]));
  const float inv = 1.f / (mx - mn + 1e-8f);
  const int lane = tid & 63, wave = tid >> 6;
#pragma unroll
  for (int pass = 0; pass < 4; ++pass) {
    const int t = pass * 256 + wave * 64 + lane;
    const bool bit = ((vals[t] - mn) * inv) >= 0.5f;  // identical threshold op
    unsigned long long m = __ballot(bit);
    if (lane == 0) words[pass * 4 + wave] = m;
  }
  __syncthreads();
  if (tid == 0) {
    int start = 0, wid = 0;
    swst[0] = 0;
    unsigned long long carry = 0;
    for (int i = 0; i < 16; ++i) {
      const unsigned long long wi = words[i];
      unsigned long long tr = wi ^ ((wi << 1) | carry);
      carry = wi >> 63;
      if (i == 0) tr &= ~1ULL;  // t=0 is not a transition
      while (tr) {
        const int t = i * 64 + __builtin_ctzll(tr);
        tr &= tr - 1;
        if (start + 1 != t) { start = t; ++wid; swst[wid] = t; }
      }
    }
    nwin[b] = wid + 1;
    swst[wid + 1] = Tz;
    snw = wid + 1;
  }
  __syncthreads();
  const int nw = snw;
  for (int j = tid; j <= nw; j += 256) wst[b * (Tz + 1) + j] = swst[j];
  for (int t = tid; t < Tz; t += 256) {
    int lo = 0, hi = nw;  // swst[0]=0 <= t, swst[nw]=Tz > t
    while (hi - lo > 1) {
      const int mid = (lo + hi) >> 1;
      if (swst[mid] <= t) lo = mid; else hi = mid;
    }
    ids[b * Tz + t] = lo;
  }
}

// ---------------------------------------------------------------------------
// wl[b,:] = softmax over keys of layer-2 colsum.
// ---------------------------------------------------------------------------
__global__ __launch_bounds__(256) void wl_softmax_kernel(const float* __restrict__ cs,
                                                         float* __restrict__ wl)
{
  const int b = blockIdx.x, tid = threadIdx.x;
  __shared__ float vals[Tz];
  __shared__ float red[4];
  float mx = -INFINITY;
  for (int t = tid; t < Tz; t += 256) {
    float v = cs[b * Tz + t];
    vals[t] = v;
    mx = fmaxf(mx, v);
  }
#pragma unroll
  for (int off = 32; off; off >>= 1) mx = fmaxf(mx, __shfl_down(mx, off));
  if ((tid & 63) == 0) red[tid >> 6] = mx;
  __syncthreads();
  mx = fmaxf(fmaxf(red[0], red[1]), fmaxf(red[2], red[3]));
  __syncthreads();
  float se = 0.f;
  for (int t = tid; t < Tz; t += 256) {
    float e = expf(vals[t] - mx);
    vals[t] = e;
    se += e;
  }
#pragma unroll
  for (int off = 32; off; off >>= 1) se += __shfl_down(se, off);
  if ((tid & 63) == 0) red[tid >> 6] = se;
  __syncthreads();
  const float inv = 1.f / (red[0] + red[1] + red[2] + red[3]);
  for (int t = tid; t < Tz; t += 256) wl[b * Tz + t] = vals[t] * inv;
}

// ---------------------------------------------------------------------------
// Fused outputs: word_tokens (blocks 0..8191), winmap (8192..16383),
// copy_x (16384..20479).
// ---------------------------------------------------------------------------
__global__ __launch_bounds__(256) void outputs_kernel(
    const unsigned short* __restrict__ outl, const float* __restrict__ wl,
    const int* __restrict__ wst, const int* __restrict__ nwin,
    const int* __restrict__ ids, const float* __restrict__ x,
    float* __restrict__ out, float* __restrict__ out2)
{
  const int bid = blockIdx.x;
  const int tid = threadIdx.x;
  if (bid < 8192) {  // word_tokens
    const int w = bid & (Tz - 1);
    const int b = bid >> 10;
    float a0 = 0.f, a1 = 0.f;
    if (w < nwin[b]) {
      const int s = wst[b * (Tz + 1) + w], e = wst[b * (Tz + 1) + w + 1];
      for (int t = s; t < e; ++t) {
        const float sc = wl[b * Tz + t];
        const unsigned short* p = &outl[((size_t)(b * Tz + t)) * Dz];
        a0 += bf2f(p[tid]) * sc;
        a1 += bf2f(p[tid + 256]) * sc;
      }
    }
    float* o = &out[((size_t)(b * 2 * Tz + w)) * Dz];
    o[tid] = a0;
    o[tid + 256] = a1;
  } else if (bid < 16384) {  // winmap
    const int lb = bid - 8192;
    const int w = lb & (Tz - 1);
    const int b = lb >> 10;
    const int j = tid * 4;
    int4 id4 = *reinterpret_cast<const int4*>(&ids[b * Tz + j]);
    float4 v;
    v.x = (id4.x == w) ? 1.f : 0.f;
    v.y = (id4.y == w) ? 1.f : 0.f;
    v.z = (id4.z == w) ? 1.f : 0.f;
    v.w = (id4.w == w) ? 1.f : 0.f;
    *reinterpret_cast<float4*>(&out2[((size_t)(b * Tz + w)) * Tz + j]) = v;
  } else {  // copy_x
    size_t i = (size_t)(bid - 16384) * 256 + tid;
    size_t idx = i * 4;
    size_t rowi = idx >> 9;
    size_t d = idx & 511;
    size_t b = rowi >> 10, t = rowi & 1023;
    float4 v = *reinterpret_cast<const float4*>(&x[idx]);
    *reinterpret_cast<float4*>(&out[(((b * 2 * Tz) + Tz + t) << 9) + d]) = v;
  }
}

// ---------------------------------------------------------------------------
// Orchestration: 22 dispatches. GEMMs use global_load_lds staging; attn2
// LDS-staged.
// ---------------------------------------------------------------------------
extern "C" void kernel_launch(void* const* d_in, const int* in_sizes, int n_in,
                              void* d_out, int out_size, void* d_ws, size_t ws_size,
                              hipStream_t stream)
{
  (void)in_sizes; (void)n_in; (void)out_size; (void)ws_size;
  const float* x     = (const float*)d_in[0];
  const float* vqkv  = (const float*)d_in[1];
  const float* voutw = (const float*)d_in[2];
  const float* vw1   = (const float*)d_in[3];
  const float* vw2   = (const float*)d_in[4];
  const float* lqkv  = (const float*)d_in[5];
  const float* loutw = (const float*)d_in[6];
  const float* lw1   = (const float*)d_in[7];
  const float* lw2   = (const float*)d_in[8];
  float* out = (float*)d_out;
  float* ws  = (float*)d_ws;

  unsigned short* QLbf = (unsigned short*)(ws + 0);        // bf16 Q lo (L1)
  unsigned short* KLbf = (unsigned short*)(ws + 2097152);  // bf16 K lo (L1)
  float* PROJ = ws + 0;         // written after attn_ctx (QL/KL dead)
  float* Y1   = ws + 4194304;
  unsigned short* QHbf = (unsigned short*)(ws + 8388608);   // bf16 Q hi (L1+L2)
  unsigned short* KHbf = (unsigned short*)(ws + 10485760);  // bf16 K hi (L1+L2)
  unsigned short* VT   = (unsigned short*)(ws + 12582912);
  unsigned short* SLOT1 = (unsigned short*)(ws + 14680064); // attn ctx bf16
  unsigned short* SLOT2 = (unsigned short*)(ws + 16777216); // LN bf16 out
  unsigned short* HIDbf = (unsigned short*)(ws + 18874368); // FFN hidden
  unsigned short* XBF   = (unsigned short*)(ws + 18874368); // x hi bf16 (pre-FFN)
  float* PART = ws + 18874368;  // colsum block partials (1024x1024); written
                                // by attn_ctx after XBF/XLO dead, dead by FFN1
  unsigned short* XLO = (unsigned short*)(ws + 20971520);   // x lo bf16
  // bf16 transposed weights (WLQ0..2 contiguous -> merged [1536,512] matrix)
  unsigned short* WVQV = (unsigned short*)(ws + 27262976);
  unsigned short* WVO  = (unsigned short*)(ws + 27394048);
  unsigned short* WV1  = (unsigned short*)(ws + 27525120);
  unsigned short* WV2  = (unsigned short*)(ws + 28049408);
  unsigned short* WLQ0 = (unsigned short*)(ws + 28573696);
  unsigned short* WLQ1 = (unsigned short*)(ws + 28704768);
  unsigned short* WLQ2 = (unsigned short*)(ws + 28835840);
  unsigned short* WLO  = (unsigned short*)(ws + 28966912);
  unsigned short* WL1  = (unsigned short*)(ws + 29097984);
  unsigned short* WL2  = (unsigned short*)(ws + 29622272);
  // small buffers
  float* CS1   = ws + 30146560;
  float* CS2   = ws + 30154752;
  float* WLs   = ws + 30162944;
  int*   IDS   = (int*)(ws + 30171136);
  int*   WST   = (int*)(ws + 30179328);
  int*   NWIN  = (int*)(ws + 30187776);
  float* INVZ  = ws + 30195968;  // (B*H*T) = 65536 floats
  // layer-1 Q/K weights, bf16 transposed hi/lo (512x512 each = 131072 floats)
  unsigned short* WQH = (unsigned short*)(ws + 30261504);
  unsigned short* WQL = (unsigned short*)(ws + 30392576);
  unsigned short* WKH = (unsigned short*)(ws + 30523648);
  unsigned short* WKL = (unsigned short*)(ws + 30654720);

  dim3 blk(256);

  // ---- fused prep: 12 wconv + zero + fconv(hi/lo) ----
  PrepArgs P;
  auto setw = [&](int i, const float* s, unsigned short* d, unsigned short* dl,
                  int K, int N, int b0) {
    P.d[i].src = s; P.d[i].dst = d; P.d[i].dstlo = dl;
    P.d[i].K = K; P.d[i].N = N; P.d[i].blk0 = b0;
  };
  int b0 = 0;
  setw(0, vqkv + 2 * Dz * Dz, WVQV, nullptr, Dz, Dz, b0); b0 += 256;
  setw(1, voutw, WVO, nullptr, Dz, Dz, b0); b0 += 256;
  setw(2, vw1, WV1, nullptr, Dz, FFz, b0); b0 += 1024;
  setw(3, vw2, WV2, nullptr, FFz, Dz, b0); b0 += 1024;
  setw(4, lqkv + 0 * Dz * Dz, WLQ0, nullptr, Dz, Dz, b0); b0 += 256;
  setw(5, lqkv + 1 * Dz * Dz, WLQ1, nullptr, Dz, Dz, b0); b0 += 256;
  setw(6, lqkv + 2 * Dz * Dz, WLQ2, nullptr, Dz, Dz, b0); b0 += 256;
  setw(7, loutw, WLO, nullptr, Dz, Dz, b0); b0 += 256;
  setw(8, lw1, WL1, nullptr, Dz, FFz, b0); b0 += 1024;
  setw(9, lw2, WL2, nullptr, FFz, Dz, b0); b0 += 1024;
  setw(10, vqkv + 0 * Dz * Dz, WQH, WQL, Dz, Dz, b0); b0 += 256;
  setw(11, vqkv + 1 * Dz * Dz, WKH, WKL, Dz, Dz, b0); b0 += 256;
  P.nwc = b0;  // 6144
  prep_kernel<<<dim3(P.nwc + 64 + 4096), blk, 0, stream>>>(P, x, XBF, XLO, CS1);

  auto mgemm = [&](const unsigned short* A, const unsigned short* BT, void* p1,
                   void* p2, void* p3, int K, int N, int mode) {
    mfma_gemm_kernel<<<dim3(N / 128, Mz / 128), dim3(256), 0, stream>>>(
        A, BT, p1, p2, p3, K, N, mode);
  };

  // ---------------- layer 1 (vanilla) ----------------
  gemm_qk_mfma_kernel<<<dim3(4, 128), dim3(256), 0, stream>>>(
      XBF, XLO, WQH, WQL, WKH, WKL, QHbf, QLbf, KHbf, KLbf);
  attn_z_kernel<<<dim3(Bz * Hz * 16), blk, 0, stream>>>(QHbf, KHbf, INVZ);
  mgemm(XBF, WVQV, VT, nullptr, nullptr, Dz, Dz, 4);        // V -> V^T (XBF/XLO dead)
  attn_ctx_kernel<<<dim3(Bz * Hz * 16), blk, 0, stream>>>(
      QHbf, QLbf, KHbf, KLbf, VT, INVZ, SLOT1, PART);
  colsum_reduce_kernel<<<dim3(32), blk, 0, stream>>>(PART, CS1);
  window_ids_kernel<<<dim3(Bz), blk, 0, stream>>>(CS1, IDS, WST, NWIN);
  mgemm(SLOT1, WVO, PROJ, nullptr, nullptr, Dz, Dz, 0);     // proj (QL/KL dead)
  ln_kernel<<<dim3(Mz), blk, 0, stream>>>(x, nullptr, PROJ, Y1, SLOT2);
  mgemm(SLOT2, WV1, HIDbf, nullptr, nullptr, Dz, FFz, 2);   // FFN1 (PART dead)
  mgemm(HIDbf, WV2, PROJ, nullptr, nullptr, FFz, Dz, 0);    // FFN2
  ln_kernel<<<dim3(Mz), blk, 0, stream>>>(Y1, nullptr, PROJ, nullptr, SLOT2);

  // ---------------- layer 2 (block-diagonal window mask) ----------------
  mgemm(SLOT2, WLQ0, QHbf, KHbf, VT, Dz, 3 * Dz, 5);        // merged QKV
  attn_mfma2_kernel<<<dim3(Bz * Hz * 16), blk, 0, stream>>>(
      QHbf, KHbf, VT, IDS, WST, SLOT1, CS2);
  mgemm(SLOT1, WLO, PROJ, nullptr, nullptr, Dz, Dz, 0);
  ln_kernel<<<dim3(Mz), blk, 0, stream>>>(nullptr, SLOT2, PROJ, Y1, SLOT2);
  mgemm(SLOT2, WL1, HIDbf, nullptr, nullptr, Dz, FFz, 2);
  mgemm(HIDbf, WL2, PROJ, nullptr, nullptr, FFz, Dz, 0);
  ln_kernel<<<dim3(Mz), blk, 0, stream>>>(Y1, nullptr, PROJ, nullptr, SLOT2);

  // ---------------- pooling + outputs ----------------
  wl_softmax_kernel<<<dim3(Bz), blk, 0, stream>>>(CS2, WLs);
  outputs_kernel<<<dim3(20480), blk, 0, stream>>>(SLOT2, WLs, WST, NWIN, IDS, x,
                                                  out, out + (size_t)Bz * 2 * Tz * Dz);
}

// Round 10
// 540.062 us; speedup vs baseline: 2.0105x; 1.0786x over previous
//
#include <hip/hip_runtime.h>
#include <math.h>

// Problem constants (fixed by setup_inputs)
#define Bz 8
#define Tz 1024
#define Dz 512
#define FFz 2048
#define Hz 8
#define DHz 64
#define Mz (Bz * Tz)  // 8192 rows

typedef __attribute__((ext_vector_type(8))) short short8;   // 8 bf16 (4 VGPRs)
typedef __attribute__((ext_vector_type(4))) float f32x4;    // MFMA accumulator

__device__ inline unsigned short f2bf(float f) {  // RNE fp32 -> bf16
  unsigned u = __builtin_bit_cast(unsigned, f);
  return (unsigned short)((u + 0x7FFFu + ((u >> 16) & 1u)) >> 16);
}
__device__ inline float bf2f(unsigned short h) {
  unsigned u = (unsigned)h << 16;
  return __builtin_bit_cast(float, u);
}

// Async global->LDS 16B: LDS dest = wave-uniform base + lane*16 (HW rule),
// global src is per-lane. __syncthreads() drains vmcnt before s_barrier.
__device__ inline void gll16(const unsigned short* g, unsigned short* l) {
  __builtin_amdgcn_global_load_lds(
      (const __attribute__((address_space(1))) void*)g,
      (__attribute__((address_space(3))) void*)l, 16, 0, 0);
}

// XCD-aware decode for the 1024-block attention grids (8 XCDs round-robin by
// blockIdx). g = xcd + 8*(qt + 16*bhi), bh = bhi*8 + xcd.
__device__ inline void attn_decode(int g, int& b, int& h, int& qt) {
  const int xcd = g & 7;
  const int j = g >> 3;
  qt = j & 15;
  const int bh = ((j >> 4) << 3) | xcd;
  b = bh >> 3;
  h = bh & 7;
}

// Swizzled byte offset inside a [rows x 128B] LDS tile: 16B slot XOR'd by
// row&7 -> fragment reads land at the LDS structural floor (measured zero
// conflicts in rounds 6-9). Staged via gll with PRE-SWIZZLED source slot:
// for 8-row gll groups the source slot is (lane&7)^(lane>>3) (lane-pure).
__device__ inline int swz(int row, int slotByte) {
  return row * 128 + (slotByte ^ ((row & 7) << 4));
}

// ---------------------------------------------------------------------------
// Fused prep: 12 weight convert+transposes (fp32 [K,N] -> bf16 [N,K], with
// optional lo-residual output) + colsum zero-fill + x -> bf16 hi/lo.
// ---------------------------------------------------------------------------
struct WDesc { const float* src; unsigned short* dst; unsigned short* dstlo;
               int K; int N; int blk0; };
struct PrepArgs { WDesc d[12]; int nwc; };

__global__ __launch_bounds__(256) void prep_kernel(PrepArgs P,
    const float* __restrict__ x, unsigned short* __restrict__ xbf,
    unsigned short* __restrict__ xlo, float* __restrict__ csz)
{
  const int bid = blockIdx.x;
  const int tid = threadIdx.x;
  if (bid < P.nwc) {  // wconv slice
    int i = 0;
    while (i < 11 && bid >= P.d[i + 1].blk0) ++i;
    const WDesc w = P.d[i];
    const int lb = bid - w.blk0;
    const int nbn = w.N / 32;
    const int bn = (lb % nbn) * 32, bk = (lb / nbn) * 32;
    __shared__ float t[32][33];
    const int tx = tid & 31, ty = tid >> 5;
#pragma unroll
    for (int r = 0; r < 32; r += 8)
      t[ty + r][tx] = w.src[(size_t)(bk + ty + r) * w.N + bn + tx];
    __syncthreads();
#pragma unroll
    for (int r = 0; r < 32; r += 8) {
      float v = t[tx][ty + r];
      unsigned short hv = f2bf(v);
      w.dst[(size_t)(bn + ty + r) * w.K + bk + tx] = hv;
      if (w.dstlo)
        w.dstlo[(size_t)(bn + ty + r) * w.K + bk + tx] = f2bf(v - bf2f(hv));
    }
  } else if (bid < P.nwc + 64) {  // zero slice (CS1+CS2 = 16384 floats)
    int idx = (bid - P.nwc) * 256 + tid;
    csz[idx] = 0.f;
  } else {  // fconv slice: 4096 blocks, 4 floats/thread -> hi + lo
    int i = (bid - P.nwc - 64) * 256 + tid;
    float4 v = *reinterpret_cast<const float4*>(&x[(size_t)i * 4]);
    ushort4 o, ol;
    o.x = f2bf(v.x); o.y = f2bf(v.y); o.z = f2bf(v.z); o.w = f2bf(v.w);
    ol.x = f2bf(v.x - bf2f(o.x)); ol.y = f2bf(v.y - bf2f(o.y));
    ol.z = f2bf(v.z - bf2f(o.z)); ol.w = f2bf(v.w - bf2f(o.w));
    *reinterpret_cast<ushort4*>(&xbf[(size_t)i * 4]) = o;
    *reinterpret_cast<ushort4*>(&xlo[(size_t)i * 4]) = ol;
  }
}

// ---------------------------------------------------------------------------
// bf16 MFMA GEMM: BK=64, 128B LDS rows with XOR swizzle (conflict-free reads)
// staged via pre-swizzled-source global_load_lds. 32 MFMA per barrier pair.
// Fragment values and per-acc MFMA order (k ascending) identical to the
// BK=32 version -> bit-identical outputs.
// Epilogue modes: 0 fp32 C | 1 bf16 C | 2 bf16 C + ReLU
//   | 4 V^T layout | 5 merged QKV (N=1536).
// ---------------------------------------------------------------------------
__global__ __launch_bounds__(256) void mfma_gemm_kernel(
    const unsigned short* __restrict__ A, const unsigned short* __restrict__ BT,
    void* __restrict__ p1, void* __restrict__ p2, void* __restrict__ p3,
    int K, int N, int mode)
{
  __shared__ unsigned short As[128 * 64];  // 16KB: 128 rows x 128B
  __shared__ unsigned short Bs[128 * 64];  // 16KB
  const int tid = threadIdx.x;
  const int lane = tid & 63, wave = tid >> 6;
  const int mr = lane & 15, quad = lane >> 4;
  const int wr = wave >> 1, wc = wave & 1;
  const int m0 = blockIdx.y * 128;
  const int n0 = blockIdx.x * 128;

  f32x4 acc[4][4];
  const f32x4 zero = {0.f, 0.f, 0.f, 0.f};
#pragma unroll
  for (int i = 0; i < 4; ++i)
#pragma unroll
    for (int j = 0; j < 4; ++j) acc[i][j] = zero;

  // gll staging: instr = 8 rows x 8 slots; lane -> row lane>>3, dest slot
  // lane&7, SOURCE slot (lane&7)^(lane>>3) (row&7 == lane>>3).
  const int r8 = lane >> 3;
  const int s8 = (lane & 7) ^ r8;
  const unsigned short* Agb = A + (size_t)(m0 + wave * 8 + r8) * K + s8 * 8;
  const unsigned short* Bgb = BT + (size_t)(n0 + wave * 8 + r8) * K + s8 * 8;
  unsigned short* Adb = As + wave * 512;   // row stride 64 shorts (128B)
  unsigned short* Bdb = Bs + wave * 512;
  char* AsB = (char*)As;
  char* BsB = (char*)Bs;
  const int xr = (mr & 7) << 4;  // read-side XOR (byte)

  for (int k0 = 0; k0 < K; k0 += 64) {
#pragma unroll
    for (int p = 0; p < 4; ++p) {
      gll16(Agb + (size_t)(p * 32) * K + k0, Adb + p * 2048);
      gll16(Bgb + (size_t)(p * 32) * K + k0, Bdb + p * 2048);
    }
    __syncthreads();  // vmcnt drain -> staged data visible
    short8 af[2][4], bf[2][4];
#pragma unroll
    for (int hh = 0; hh < 2; ++hh) {
#pragma unroll
      for (int i = 0; i < 4; ++i)
        af[hh][i] = *reinterpret_cast<const short8*>(
            AsB + (wr * 64 + i * 16 + mr) * 128 + ((((hh << 2) + quad) << 4) ^ xr));
#pragma unroll
      for (int j = 0; j < 4; ++j)
        bf[hh][j] = *reinterpret_cast<const short8*>(
            BsB + (wc * 64 + j * 16 + mr) * 128 + ((((hh << 2) + quad) << 4) ^ xr));
    }
#pragma unroll
    for (int hh = 0; hh < 2; ++hh)
#pragma unroll
      for (int i = 0; i < 4; ++i)
#pragma unroll
        for (int j = 0; j < 4; ++j)
          acc[i][j] = __builtin_amdgcn_mfma_f32_16x16x32_bf16(af[hh][i], bf[hh][j], acc[i][j], 0, 0, 0);
    __syncthreads();  // reads done before next tile's DMA lands
  }

  // per-wave 64x64 epilogue at (m0w, n0w)
  const int m0w = m0 + wr * 64;
  const int n0w = n0 + wc * 64;
  // C/D layout: col = lane&15, row = quad*4 + reg   [measured: m89/m91]
  int emode = mode;
  unsigned short* Cbf = (unsigned short*)p1;
  unsigned short* Vt  = (unsigned short*)p1;
  int ncol = N, coff = 0;
  if (mode == 5) {  // uniform per wave: n0w is a multiple of 64
    if (n0w < 512)       { emode = 1; Cbf = (unsigned short*)p1; ncol = 512; coff = 0; }
    else if (n0w < 1024) { emode = 1; Cbf = (unsigned short*)p2; ncol = 512; coff = 512; }
    else                 { emode = 4; Vt = (unsigned short*)p3; coff = 1024; }
  }
  if (emode == 4) {  // V^T: 4 consecutive tokens same feature -> ushort4
#pragma unroll
    for (int i = 0; i < 4; ++i)
#pragma unroll
      for (int j = 0; j < 4; ++j) {
        const int col = n0w - coff + j * 16 + mr;  // feature: h = col>>6, d = col&63
        const int row0 = m0w + i * 16 + quad * 4;  // token base (4 consecutive)
        const int bb = row0 >> 10, t0 = row0 & 1023;
        ushort4 pk;
        pk.x = f2bf(acc[i][j][0]); pk.y = f2bf(acc[i][j][1]);
        pk.z = f2bf(acc[i][j][2]); pk.w = f2bf(acc[i][j][3]);
        *reinterpret_cast<ushort4*>(
            &Vt[((size_t)((bb * Hz + (col >> 6)) * DHz + (col & 63))) * Tz + t0]) = pk;
      }
  } else if (emode == 0) {
    float* Cf = (float*)p1;
#pragma unroll
    for (int i = 0; i < 4; ++i)
#pragma unroll
      for (int j = 0; j < 4; ++j) {
        const int col = n0w + j * 16 + mr;
#pragma unroll
        for (int rr = 0; rr < 4; ++rr)
          Cf[(size_t)(m0w + i * 16 + quad * 4 + rr) * N + col] = acc[i][j][rr];
      }
  } else {
    const bool relu = (emode == 2);
#pragma unroll
    for (int i = 0; i < 4; ++i)
#pragma unroll
      for (int j = 0; j < 4; ++j) {
        const int col = n0w - coff + j * 16 + mr;
#pragma unroll
        for (int rr = 0; rr < 4; ++rr) {
          float v = acc[i][j][rr];
          if (relu) v = fmaxf(v, 0.f);
          Cbf[(size_t)(m0w + i * 16 + quad * 4 + rr) * ncol + col] = f2bf(v);
        }
      }
  }
}

// ---------------------------------------------------------------------------
// Layer-1 Q,K via bf16x3 MFMA: BK=64 swizzled gll staging (4 panels, 64KB
// LDS). Per-acc MFMA order (al.bh, ah.bl, ah.bh, k ascending) identical ->
// Q/K hi/lo outputs bit-identical.
// ---------------------------------------------------------------------------
__global__ __launch_bounds__(256) void gemm_qk_mfma_kernel(
    const unsigned short* __restrict__ Xh, const unsigned short* __restrict__ Xl,
    const unsigned short* __restrict__ WQh, const unsigned short* __restrict__ WQl,
    const unsigned short* __restrict__ WKh, const unsigned short* __restrict__ WKl,
    unsigned short* __restrict__ Qhi, unsigned short* __restrict__ Qlo,
    unsigned short* __restrict__ Khi, unsigned short* __restrict__ Klo)
{
  __shared__ unsigned short Ash[128 * 64];  // 16KB each
  __shared__ unsigned short Asl[128 * 64];
  __shared__ unsigned short Bsh[128 * 64];
  __shared__ unsigned short Bsl[128 * 64];
  const int tid = threadIdx.x;
  const int lane = tid & 63, wave = tid >> 6;
  const int mr = lane & 15, quad = lane >> 4;
  const int wr = wave >> 1, wc = wave & 1;
  const int sel = blockIdx.y >> 6;
  const int m0 = (blockIdx.y & 63) * 128;
  const int n0 = blockIdx.x * 128;
  const unsigned short* Bh = sel ? WKh : WQh;
  const unsigned short* Bl = sel ? WKl : WQl;
  unsigned short* Chi = sel ? Khi : Qhi;
  unsigned short* Clo = sel ? Klo : Qlo;

  f32x4 acc[4][4];
  const f32x4 zero = {0.f, 0.f, 0.f, 0.f};
#pragma unroll
  for (int i = 0; i < 4; ++i)
#pragma unroll
    for (int j = 0; j < 4; ++j) acc[i][j] = zero;

  const int r8 = lane >> 3;
  const int s8 = (lane & 7) ^ r8;
  const unsigned short* gAh = Xh + (size_t)(m0 + wave * 8 + r8) * Dz + s8 * 8;
  const unsigned short* gAl = Xl + (size_t)(m0 + wave * 8 + r8) * Dz + s8 * 8;
  const unsigned short* gBh = Bh + (size_t)(n0 + wave * 8 + r8) * Dz + s8 * 8;
  const unsigned short* gBl = Bl + (size_t)(n0 + wave * 8 + r8) * Dz + s8 * 8;
  unsigned short* dAh = Ash + wave * 512;
  unsigned short* dAl = Asl + wave * 512;
  unsigned short* dBh = Bsh + wave * 512;
  unsigned short* dBl = Bsl + wave * 512;
  char* AhB = (char*)Ash; char* AlB = (char*)Asl;
  char* BhB = (char*)Bsh; char* BlB = (char*)Bsl;
  const int xr = (mr & 7) << 4;

  for (int k0 = 0; k0 < Dz; k0 += 64) {
#pragma unroll
    for (int p = 0; p < 4; ++p) {
      gll16(gAh + (size_t)(p * 32) * Dz + k0, dAh + p * 2048);
      gll16(gAl + (size_t)(p * 32) * Dz + k0, dAl + p * 2048);
      gll16(gBh + (size_t)(p * 32) * Dz + k0, dBh + p * 2048);
      gll16(gBl + (size_t)(p * 32) * Dz + k0, dBl + p * 2048);
    }
    __syncthreads();
    short8 ah[2][4], al[2][4], bh[2][4], bl[2][4];
#pragma unroll
    for (int hh = 0; hh < 2; ++hh) {
#pragma unroll
      for (int i = 0; i < 4; ++i) {
        const int ab = (wr * 64 + i * 16 + mr) * 128 + ((((hh << 2) + quad) << 4) ^ xr);
        ah[hh][i] = *reinterpret_cast<const short8*>(AhB + ab);
        al[hh][i] = *reinterpret_cast<const short8*>(AlB + ab);
      }
#pragma unroll
      for (int j = 0; j < 4; ++j) {
        const int bb = (wc * 64 + j * 16 + mr) * 128 + ((((hh << 2) + quad) << 4) ^ xr);
        bh[hh][j] = *reinterpret_cast<const short8*>(BhB + bb);
        bl[hh][j] = *reinterpret_cast<const short8*>(BlB + bb);
      }
    }
#pragma unroll
    for (int hh = 0; hh < 2; ++hh)
#pragma unroll
      for (int i = 0; i < 4; ++i)
#pragma unroll
        for (int j = 0; j < 4; ++j) {
          acc[i][j] = __builtin_amdgcn_mfma_f32_16x16x32_bf16(al[hh][i], bh[hh][j], acc[i][j], 0, 0, 0);
          acc[i][j] = __builtin_amdgcn_mfma_f32_16x16x32_bf16(ah[hh][i], bl[hh][j], acc[i][j], 0, 0, 0);
          acc[i][j] = __builtin_amdgcn_mfma_f32_16x16x32_bf16(ah[hh][i], bh[hh][j], acc[i][j], 0, 0, 0);
        }
    __syncthreads();
  }

  const int m0w = m0 + wr * 64;
  const int n0w = n0 + wc * 64;
#pragma unroll
  for (int i = 0; i < 4; ++i)
#pragma unroll
    for (int j = 0; j < 4; ++j) {
      const int col = n0w + j * 16 + mr;
#pragma unroll
      for (int rr = 0; rr < 4; ++rr) {
        const size_t row = (size_t)(m0w + i * 16 + quad * 4 + rr);
        float v = acc[i][j][rr];
        unsigned short hv = f2bf(v);
        Chi[row * Dz + col] = hv;
        Clo[row * Dz + col] = f2bf(v - bf2f(hv));
      }
    }
}

// ---------------------------------------------------------------------------
// Layer-1 FUSED attention: pass 0 computes z (cheap plain-bf16 QK^T over
// gll-staged K-hi tiles; local invz=1/z is bit-identical to the old global
// round-trip since the xor-butterfly yields identical bits in all lanes);
// pass 1 is the proven ctx loop (bf16x3 QK^T + deterministic colsum + PV)
// with gll-staged Kh/Kl/V. All arithmetic values/order and PART slots are
// bit-identical to rounds 4-9.
// ---------------------------------------------------------------------------
__global__ __launch_bounds__(256) void attn_fused_kernel(
    const unsigned short* __restrict__ Qh, const unsigned short* __restrict__ Ql,
    const unsigned short* __restrict__ Kh, const unsigned short* __restrict__ Kl,
    const unsigned short* __restrict__ Vt,
    unsigned short* __restrict__ ctx, float* __restrict__ part)
{
  __shared__ unsigned short Ksh[64 * 64];  // 8KB: 64 keys x 128B (swizzled)
  __shared__ unsigned short Ksl[64 * 64];  // 8KB
  __shared__ unsigned short Vsh[64 * 64];  // 8KB
  __shared__ unsigned short Pld[64][76];   // 9.5KB
  __shared__ float CSPt[4][64];
  const int tid = threadIdx.x;
  const int lane = tid & 63, wave = tid >> 6;
  const int c = lane & 15, quad = lane >> 4;
  int b, h, qt;
  attn_decode(blockIdx.x, b, h, qt);
  const size_t bT = (size_t)b * Tz;
  const int qrow = qt * 64 + wave * 16;
  const int hoff = h * DHz;
  const int lidx = b * 128 + h * 16 + qt;  // logical PART slot

  const size_t qbase = (bT + qrow + c) * Dz + hoff + quad * 8;
  short8 q0h = *reinterpret_cast<const short8*>(Qh + qbase);
  short8 q1h = *reinterpret_cast<const short8*>(Qh + qbase + 32);
  short8 q0l = *reinterpret_cast<const short8*>(Ql + qbase);
  short8 q1l = *reinterpret_cast<const short8*>(Ql + qbase + 32);

  // gll staging coords: instr = 8 rows x 8 slots; src slot pre-swizzled.
  const int r8 = lane >> 3;
  const int s8 = (lane & 7) ^ r8;
  const unsigned short* khg = Kh + (bT + wave * 8 + r8) * Dz + hoff + s8 * 8;
  const unsigned short* klg = Kl + (bT + wave * 8 + r8) * Dz + hoff + s8 * 8;
  const unsigned short* vtg = Vt + ((size_t)((b * Hz + h) * DHz) + wave * 8 + r8) * Tz + s8 * 8;
  unsigned short* KshW = Ksh + wave * 512;
  unsigned short* KslW = Ksl + wave * 512;
  unsigned short* VshW = Vsh + wave * 512;
  char* KshB = (char*)Ksh;
  char* KslB = (char*)Ksl;
  char* VshB = (char*)Vsh;

  const f32x4 zf = {0.f, 0.f, 0.f, 0.f};

  // ---------------- pass 0: z (plain bf16, K-hi only) ----------------
  float z[4] = {0.f, 0.f, 0.f, 0.f};
  for (int t = 0; t < 16; ++t) {
    const int k0 = t * 64;
    gll16(khg + (size_t)k0 * Dz, KshW);
    gll16(khg + (size_t)(k0 + 32) * Dz, KshW + 2048);
    __syncthreads();
#pragma unroll
    for (int sub = 0; sub < 4; ++sub) {
      const int row = sub * 16 + c;
      short8 kh0 = *reinterpret_cast<const short8*>(KshB + swz(row, quad * 16));
      short8 kh1 = *reinterpret_cast<const short8*>(KshB + swz(row, 64 + quad * 16));
      f32x4 aA = zf, aB = zf;
      aA = __builtin_amdgcn_mfma_f32_16x16x32_bf16(q0h, kh0, aA, 0, 0, 0);
      aB = __builtin_amdgcn_mfma_f32_16x16x32_bf16(q1h, kh1, aB, 0, 0, 0);
#pragma unroll
      for (int rr = 0; rr < 4; ++rr) z[rr] += __expf((aA[rr] + aB[rr]) * 0.125f);
    }
    __syncthreads();
  }
#pragma unroll
  for (int w = 1; w < 16; w <<= 1) {
#pragma unroll
    for (int rr = 0; rr < 4; ++rr) z[rr] += __shfl_xor(z[rr], w);
  }
  float invz[4];
#pragma unroll
  for (int rr = 0; rr < 4; ++rr) invz[rr] = 1.f / z[rr];

  // ---------------- pass 1: P, colsum, PV ----------------
  f32x4 ot[4] = {zf, zf, zf, zf};
  for (int t = 0; t < 16; ++t) {
    const int k0 = t * 64;
    gll16(khg + (size_t)k0 * Dz, KshW);
    gll16(khg + (size_t)(k0 + 32) * Dz, KshW + 2048);
    gll16(klg + (size_t)k0 * Dz, KslW);
    gll16(klg + (size_t)(k0 + 32) * Dz, KslW + 2048);
    gll16(vtg + k0, VshW);
    gll16(vtg + (size_t)32 * Tz + k0, VshW + 2048);
    __syncthreads();  // staged data visible

    // ---- QK^T subtiles (bf16x3, 2-acc split) ----
#pragma unroll
    for (int sub = 0; sub < 4; ++sub) {
      const int row = sub * 16 + c;
      short8 kh0 = *reinterpret_cast<const short8*>(KshB + swz(row, quad * 16));
      short8 kh1 = *reinterpret_cast<const short8*>(KshB + swz(row, 64 + quad * 16));
      short8 kl0 = *reinterpret_cast<const short8*>(KslB + swz(row, quad * 16));
      short8 kl1 = *reinterpret_cast<const short8*>(KslB + swz(row, 64 + quad * 16));
      f32x4 aA = zf, aB = zf;
      aA = __builtin_amdgcn_mfma_f32_16x16x32_bf16(q0h, kh0, aA, 0, 0, 0);
      aB = __builtin_amdgcn_mfma_f32_16x16x32_bf16(q1h, kh1, aB, 0, 0, 0);
      aA = __builtin_amdgcn_mfma_f32_16x16x32_bf16(q0h, kl0, aA, 0, 0, 0);
      aB = __builtin_amdgcn_mfma_f32_16x16x32_bf16(q1h, kl1, aB, 0, 0, 0);
      aA = __builtin_amdgcn_mfma_f32_16x16x32_bf16(q0l, kh0, aA, 0, 0, 0);
      aB = __builtin_amdgcn_mfma_f32_16x16x32_bf16(q1l, kh1, aB, 0, 0, 0);
      float p[4];
#pragma unroll
      for (int rr = 0; rr < 4; ++rr)
        p[rr] = __expf((aA[rr] + aB[rr]) * 0.125f) * invz[rr];
      float cs = p[0] + p[1] + p[2] + p[3];
      cs += __shfl_xor(cs, 16);
      cs += __shfl_xor(cs, 32);
      if (quad == 0) CSPt[wave][sub * 16 + c] = cs;  // key visited once
#pragma unroll
      for (int rr = 0; rr < 4; ++rr)
        Pld[(wave << 4) + quad * 4 + rr][sub * 16 + c] = f2bf(p[rr]);
    }

    // ---- PV from LDS ----
    union { short8 v; ushort4 hh[2]; } pb0, pb1;
    pb0.hh[0] = *reinterpret_cast<const ushort4*>(&Pld[(wave << 4) + c][quad * 8]);
    pb0.hh[1] = *reinterpret_cast<const ushort4*>(&Pld[(wave << 4) + c][quad * 8 + 4]);
    pb1.hh[0] = *reinterpret_cast<const ushort4*>(&Pld[(wave << 4) + c][32 + quad * 8]);
    pb1.hh[1] = *reinterpret_cast<const ushort4*>(&Pld[(wave << 4) + c][32 + quad * 8 + 4]);
#pragma unroll
    for (int ds = 0; ds < 4; ++ds) {
      const int row = ds * 16 + c;
      short8 v0 = *reinterpret_cast<const short8*>(VshB + swz(row, quad * 16));
      short8 v1 = *reinterpret_cast<const short8*>(VshB + swz(row, 64 + quad * 16));
      ot[ds] = __builtin_amdgcn_mfma_f32_16x16x32_bf16(v0, pb0.v, ot[ds], 0, 0, 0);
      ot[ds] = __builtin_amdgcn_mfma_f32_16x16x32_bf16(v1, pb1.v, ot[ds], 0, 0, 0);
    }
    __syncthreads();  // all LDS reads done; CSPt complete across waves

    // ---- deterministic per-tile colsum combine (same 4-addend order) ----
    if (tid < 64) {
      float v = ((CSPt[0][tid] + CSPt[1][tid]) + CSPt[2][tid]) + CSPt[3][tid];
      part[(size_t)lidx * 1024 + k0 + tid] = v * (1.f / Hz);
    }
  }

  const size_t cb = (bT + qrow + c) * Dz + hoff;
#pragma unroll
  for (int ds = 0; ds < 4; ++ds) {
    ushort4 pk;
    pk.x = f2bf(ot[ds][0]); pk.y = f2bf(ot[ds][1]);
    pk.z = f2bf(ot[ds][2]); pk.w = f2bf(ot[ds][3]);
    *reinterpret_cast<ushort4*>(&ctx[cb + ds * 16 + quad * 4]) = pk;
  }
}

// ---------------------------------------------------------------------------
// Deterministic colsum reduce: CS1[b,key] = sum over the 128 (h,qt) block
// partials in fixed ascending order. One thread per output.
// ---------------------------------------------------------------------------
__global__ __launch_bounds__(256) void colsum_reduce_kernel(
    const float* __restrict__ part, float* __restrict__ colsum)
{
  const int i = blockIdx.x * 256 + threadIdx.x;  // 0..8191
  const int b = i >> 10, k = i & 1023;
  const float* p = part + (size_t)(b * 128) * 1024 + k;
  float s = 0.f;
  for (int j = 0; j < 128; ++j) s += p[(size_t)j * 1024];
  colsum[i] = s;
}

// ---------------------------------------------------------------------------
// Layer-2 MFMA attention (masked), k-tile range skipping, gll-staged K/V.
// Arithmetic values/order identical -> ctx/CS2 bits unchanged.
// ---------------------------------------------------------------------------
__global__ __launch_bounds__(256) void attn_mfma2_kernel(
    const unsigned short* __restrict__ Qh, const unsigned short* __restrict__ Kh,
    const unsigned short* __restrict__ Vt, const int* __restrict__ ids,
    const int* __restrict__ wst,
    unsigned short* __restrict__ ctx, float* __restrict__ colsum)
{
  __shared__ unsigned short Ksh[64 * 64];  // 8KB (swizzled)
  __shared__ unsigned short Vsh[64 * 64];  // 8KB (swizzled)
  __shared__ unsigned short Pld[64][76];
  __shared__ float csb[1024];

  const int tid = threadIdx.x;
  const int lane = tid & 63, wave = tid >> 6;
  const int c = lane & 15, quad = lane >> 4;
  int b, h, qt;
  attn_decode(blockIdx.x, b, h, qt);
  const size_t bT = (size_t)b * Tz;
  const int qrow = qt * 64 + wave * 16;
  const int hoff = h * DHz;

  for (int i = tid; i < 1024; i += 256) csb[i] = 0.f;

  const int id_lo = ids[bT + qt * 64];
  const int id_hi = ids[bT + qt * 64 + 63];
  const int klo = wst[b * (Tz + 1) + id_lo];
  const int khi = wst[b * (Tz + 1) + id_hi + 1];
  const int t0 = klo >> 6, t1 = (khi - 1) >> 6;

  const size_t qbase = (bT + qrow + c) * Dz + hoff + quad * 8;
  short8 q0 = *reinterpret_cast<const short8*>(Qh + qbase);
  short8 q1 = *reinterpret_cast<const short8*>(Qh + qbase + 32);

  int qid[4];
#pragma unroll
  for (int rr = 0; rr < 4; ++rr) qid[rr] = ids[bT + qrow + quad * 4 + rr];

  const int r8 = lane >> 3;
  const int s8 = (lane & 7) ^ r8;
  const unsigned short* khg = Kh + (bT + wave * 8 + r8) * Dz + hoff + s8 * 8;
  const unsigned short* vtg = Vt + ((size_t)((b * Hz + h) * DHz) + wave * 8 + r8) * Tz + s8 * 8;
  unsigned short* KshW = Ksh + wave * 512;
  unsigned short* VshW = Vsh + wave * 512;
  char* KshB = (char*)Ksh;
  char* VshB = (char*)Vsh;
  __syncthreads();  // csb zeros visible before pass-2 atomics

  const f32x4 zf = {0.f, 0.f, 0.f, 0.f};

  // pass 1: z (stage Kh per tile)
  float z[4] = {0.f, 0.f, 0.f, 0.f};
  for (int t = t0; t <= t1; ++t) {
    const int k0 = t * 64;
    gll16(khg + (size_t)k0 * Dz, KshW);
    gll16(khg + (size_t)(k0 + 32) * Dz, KshW + 2048);
    __syncthreads();
#pragma unroll
    for (int sub = 0; sub < 4; ++sub) {
      const int row = sub * 16 + c;
      short8 kh0 = *reinterpret_cast<const short8*>(KshB + swz(row, quad * 16));
      short8 kh1 = *reinterpret_cast<const short8*>(KshB + swz(row, 64 + quad * 16));
      f32x4 acc = zf;
      acc = __builtin_amdgcn_mfma_f32_16x16x32_bf16(q0, kh0, acc, 0, 0, 0);
      acc = __builtin_amdgcn_mfma_f32_16x16x32_bf16(q1, kh1, acc, 0, 0, 0);
      int kidv = ids[bT + k0 + sub * 16 + c];
#pragma unroll
      for (int rr = 0; rr < 4; ++rr) {
        float e = __expf(acc[rr] * 0.125f);
        if (qid[rr] != kidv) e = 0.f;
        z[rr] += e;
      }
    }
    __syncthreads();
  }
#pragma unroll
  for (int w = 1; w < 16; w <<= 1) {
#pragma unroll
    for (int rr = 0; rr < 4; ++rr) z[rr] += __shfl_xor(z[rr], w);
  }
  float invz[4];
#pragma unroll
  for (int rr = 0; rr < 4; ++rr) invz[rr] = 1.f / z[rr];

  // pass 2: P, colsum, PV (stage Kh + V per tile)
  f32x4 ot[4] = {zf, zf, zf, zf};
  for (int t = t0; t <= t1; ++t) {
    const int k0 = t * 64;
    gll16(khg + (size_t)k0 * Dz, KshW);
    gll16(khg + (size_t)(k0 + 32) * Dz, KshW + 2048);
    gll16(vtg + k0, VshW);
    gll16(vtg + (size_t)32 * Tz + k0, VshW + 2048);
    __syncthreads();
#pragma unroll
    for (int sub = 0; sub < 4; ++sub) {
      const int row = sub * 16 + c;
      short8 kh0 = *reinterpret_cast<const short8*>(KshB + swz(row, quad * 16));
      short8 kh1 = *reinterpret_cast<const short8*>(KshB + swz(row, 64 + quad * 16));
      f32x4 acc = zf;
      acc = __builtin_amdgcn_mfma_f32_16x16x32_bf16(q0, kh0, acc, 0, 0, 0);
      acc = __builtin_amdgcn_mfma_f32_16x16x32_bf16(q1, kh1, acc, 0, 0, 0);
      int kidv = ids[bT + k0 + sub * 16 + c];
      float p[4];
#pragma unroll
      for (int rr = 0; rr < 4; ++rr) {
        float e = __expf(acc[rr] * 0.125f);
        if (qid[rr] != kidv) e = 0.f;
        p[rr] = e * invz[rr];
      }
      float cs = p[0] + p[1] + p[2] + p[3];
      cs += __shfl_xor(cs, 16);
      cs += __shfl_xor(cs, 32);
      if (quad == 0) atomicAdd(&csb[k0 + sub * 16 + c], cs);
#pragma unroll
      for (int rr = 0; rr < 4; ++rr)
        Pld[(wave << 4) + quad * 4 + rr][sub * 16 + c] = f2bf(p[rr]);
    }
    union { short8 v; ushort4 hh[2]; } pb0, pb1;
    pb0.hh[0] = *reinterpret_cast<const ushort4*>(&Pld[(wave << 4) + c][quad * 8]);
    pb0.hh[1] = *reinterpret_cast<const ushort4*>(&Pld[(wave << 4) + c][quad * 8 + 4]);
    pb1.hh[0] = *reinterpret_cast<const ushort4*>(&Pld[(wave << 4) + c][32 + quad * 8]);
    pb1.hh[1] = *reinterpret_cast<const ushort4*>(&Pld[(wave << 4) + c][32 + quad * 8 + 4]);
#pragma unroll
    for (int ds = 0; ds < 4; ++ds) {
      const int row = ds * 16 + c;
      short8 v0 = *reinterpret_cast<const short8*>(VshB + swz(row, quad * 16));
      short8 v1 = *reinterpret_cast<const short8*>(VshB + swz(row, 64 + quad * 16));
      ot[ds] = __builtin_amdgcn_mfma_f32_16x16x32_bf16(v0, pb0.v, ot[ds], 0, 0, 0);
      ot[ds] = __builtin_amdgcn_mfma_f32_16x16x32_bf16(v1, pb1.v, ot[ds], 0, 0, 0);
    }
    __syncthreads();  // LDS reads done before next tile's staging
  }

  const size_t cb = (bT + qrow + c) * Dz + hoff;
#pragma unroll
  for (int ds = 0; ds < 4; ++ds) {
    ushort4 pk;
    pk.x = f2bf(ot[ds][0]); pk.y = f2bf(ot[ds][1]);
    pk.z = f2bf(ot[ds][2]); pk.w = f2bf(ot[ds][3]);
    *reinterpret_cast<ushort4*>(&ctx[cb + ds * 16 + quad * 4]) = pk;
  }
  __syncthreads();
  for (int i = tid; i < 1024; i += 256)
    atomicAdd(&colsum[bT + i], csb[i] * (1.f / Hz));
}

// ---------------------------------------------------------------------------
// out = LayerNorm(resid + delta). resid fp32 (residf) if non-null else bf16.
// ---------------------------------------------------------------------------
__global__ __launch_bounds__(256) void ln_kernel(const float* __restrict__ residf,
    const unsigned short* __restrict__ residbf, const float* __restrict__ delta,
    float* __restrict__ outf, unsigned short* __restrict__ outbf)
{
  const size_t base = (size_t)blockIdx.x * Dz;
  const int tid = threadIdx.x;
  float r0, r1;
  if (residf) {
    r0 = residf[base + tid]; r1 = residf[base + tid + 256];
  } else {
    r0 = bf2f(residbf[base + tid]); r1 = bf2f(residbf[base + tid + 256]);
  }
  float x0 = r0 + delta[base + tid];
  float x1 = r1 + delta[base + tid + 256];
  __shared__ float red[4];
  float s = x0 + x1;
#pragma unroll
  for (int off = 32; off; off >>= 1) s += __shfl_down(s, off);
  if ((tid & 63) == 0) red[tid >> 6] = s;
  __syncthreads();
  const float mean = (red[0] + red[1] + red[2] + red[3]) * (1.f / Dz);
  __syncthreads();
  float d0 = x0 - mean, d1 = x1 - mean;
  float v = d0 * d0 + d1 * d1;
#pragma unroll
  for (int off = 32; off; off >>= 1) v += __shfl_down(v, off);
  if ((tid & 63) == 0) red[tid >> 6] = v;
  __syncthreads();
  const float var = (red[0] + red[1] + red[2] + red[3]) * (1.f / Dz);
  const float rstd = rsqrtf(var + 1e-5f);
  float y0 = d0 * rstd, y1 = d1 * rstd;
  if (outf) {
    outf[base + tid] = y0;
    outf[base + tid + 256] = y1;
  }
  outbf[base + tid] = f2bf(y0);
  outbf[base + tid + 256] = f2bf(y1);
}

// ---------------------------------------------------------------------------
// Per batch: min-max normalize colsum, threshold 0.5, run-length window scan.
// PARALLELIZED (round 7, proven): ballot-packed bits + register bit-scan of
// transitions + parallel binary-search ids fill. Bit-identical to reference.
// ---------------------------------------------------------------------------
__global__ __launch_bounds__(256) void window_ids_kernel(const float* __restrict__ cs,
    int* __restrict__ ids, int* __restrict__ wst, int* __restrict__ nwin)
{
  const int b = blockIdx.x, tid = threadIdx.x;
  __shared__ float vals[Tz];
  __shared__ int swst[Tz + 1];
  __shared__ unsigned long long words[16];
  __shared__ float rmin[4], rmax[4];
  __shared__ int snw;
  float mn = INFINITY, mx = -INFINITY;
  for (int t = tid; t < Tz; t += 256) {
    float v = cs[b * Tz + t];
    vals[t] = v;
    mn = fminf(mn, v); mx = fmaxf(mx, v);
  }
#pragma unroll
  for (int off = 32; off; off >>= 1) {
    mn = fminf(mn, __shfl_down(mn, off));
    mx = fmaxf(mx, __shfl_down(mx, off));
  }
  if ((tid & 63) == 0) { rmin[tid >> 6] = mn; rmax[tid >> 6] = mx; }
  __syncthreads();
  mn = fminf(fminf(rmin[0], rmin[1]), fminf(rmin[2], rmin[3]));
  mx = fmaxf(fmaxf(rmax[0], rmax[1]), fmaxf(rmax[2], rmax[3]));
  const float inv = 1.f / (mx - mn + 1e-8f);
  const int lane = tid & 63, wave = tid >> 6;
#pragma unroll
  for (int pass = 0; pass < 4; ++pass) {
    const int t = pass * 256 + wave * 64 + lane;
    const bool bit = ((vals[t] - mn) * inv) >= 0.5f;  // identical threshold op
    unsigned long long m = __ballot(bit);
    if (lane == 0) words[pass * 4 + wave] = m;
  }
  __syncthreads();
  if (tid == 0) {
    int start = 0, wid = 0;
    swst[0] = 0;
    unsigned long long carry = 0;
    for (int i = 0; i < 16; ++i) {
      const unsigned long long wi = words[i];
      unsigned long long tr = wi ^ ((wi << 1) | carry);
      carry = wi >> 63;
      if (i == 0) tr &= ~1ULL;  // t=0 is not a transition
      while (tr) {
        const int t = i * 64 + __builtin_ctzll(tr);
        tr &= tr - 1;
        if (start + 1 != t) { start = t; ++wid; swst[wid] = t; }
      }
    }
    nwin[b] = wid + 1;
    swst[wid + 1] = Tz;
    snw = wid + 1;
  }
  __syncthreads();
  const int nw = snw;
  for (int j = tid; j <= nw; j += 256) wst[b * (Tz + 1) + j] = swst[j];
  for (int t = tid; t < Tz; t += 256) {
    int lo = 0, hi = nw;  // swst[0]=0 <= t, swst[nw]=Tz > t
    while (hi - lo > 1) {
      const int mid = (lo + hi) >> 1;
      if (swst[mid] <= t) lo = mid; else hi = mid;
    }
    ids[b * Tz + t] = lo;
  }
}

// ---------------------------------------------------------------------------
// wl[b,:] = softmax over keys of layer-2 colsum.
// ---------------------------------------------------------------------------
__global__ __launch_bounds__(256) void wl_softmax_kernel(const float* __restrict__ cs,
                                                         float* __restrict__ wl)
{
  const int b = blockIdx.x, tid = threadIdx.x;
  __shared__ float vals[Tz];
  __shared__ float red[4];
  float mx = -INFINITY;
  for (int t = tid; t < Tz; t += 256) {
    float v = cs[b * Tz + t];
    vals[t] = v;
    mx = fmaxf(mx, v);
  }
#pragma unroll
  for (int off = 32; off; off >>= 1) mx = fmaxf(mx, __shfl_down(mx, off));
  if ((tid & 63) == 0) red[tid >> 6] = mx;
  __syncthreads();
  mx = fmaxf(fmaxf(red[0], red[1]), fmaxf(red[2], red[3]));
  __syncthreads();
  float se = 0.f;
  for (int t = tid; t < Tz; t += 256) {
    float e = expf(vals[t] - mx);
    vals[t] = e;
    se += e;
  }
#pragma unroll
  for (int off = 32; off; off >>= 1) se += __shfl_down(se, off);
  if ((tid & 63) == 0) red[tid >> 6] = se;
  __syncthreads();
  const float inv = 1.f / (red[0] + red[1] + red[2] + red[3]);
  for (int t = tid; t < Tz; t += 256) wl[b * Tz + t] = vals[t] * inv;
}

// ---------------------------------------------------------------------------
// Fused outputs: word_tokens (blocks 0..8191), winmap (8192..16383),
// copy_x (16384..20479).
// ---------------------------------------------------------------------------
__global__ __launch_bounds__(256) void outputs_kernel(
    const unsigned short* __restrict__ outl, const float* __restrict__ wl,
    const int* __restrict__ wst, const int* __restrict__ nwin,
    const int* __restrict__ ids, const float* __restrict__ x,
    float* __restrict__ out, float* __restrict__ out2)
{
  const int bid = blockIdx.x;
  const int tid = threadIdx.x;
  if (bid < 8192) {  // word_tokens
    const int w = bid & (Tz - 1);
    const int b = bid >> 10;
    float a0 = 0.f, a1 = 0.f;
    if (w < nwin[b]) {
      const int s = wst[b * (Tz + 1) + w], e = wst[b * (Tz + 1) + w + 1];
      for (int t = s; t < e; ++t) {
        const float sc = wl[b * Tz + t];
        const unsigned short* p = &outl[((size_t)(b * Tz + t)) * Dz];
        a0 += bf2f(p[tid]) * sc;
        a1 += bf2f(p[tid + 256]) * sc;
      }
    }
    float* o = &out[((size_t)(b * 2 * Tz + w)) * Dz];
    o[tid] = a0;
    o[tid + 256] = a1;
  } else if (bid < 16384) {  // winmap
    const int lb = bid - 8192;
    const int w = lb & (Tz - 1);
    const int b = lb >> 10;
    const int j = tid * 4;
    int4 id4 = *reinterpret_cast<const int4*>(&ids[b * Tz + j]);
    float4 v;
    v.x = (id4.x == w) ? 1.f : 0.f;
    v.y = (id4.y == w) ? 1.f : 0.f;
    v.z = (id4.z == w) ? 1.f : 0.f;
    v.w = (id4.w == w) ? 1.f : 0.f;
    *reinterpret_cast<float4*>(&out2[((size_t)(b * Tz + w)) * Tz + j]) = v;
  } else {  // copy_x
    size_t i = (size_t)(bid - 16384) * 256 + tid;
    size_t idx = i * 4;
    size_t rowi = idx >> 9;
    size_t d = idx & 511;
    size_t b = rowi >> 10, t = rowi & 1023;
    float4 v = *reinterpret_cast<const float4*>(&x[idx]);
    *reinterpret_cast<float4*>(&out[(((b * 2 * Tz) + Tz + t) << 9) + d]) = v;
  }
}

// ---------------------------------------------------------------------------
// Orchestration: 21 dispatches. GEMMs: BK=64 swizzled gll; attn_z fused into
// attn_fused; attn2 gll-staged.
// ---------------------------------------------------------------------------
extern "C" void kernel_launch(void* const* d_in, const int* in_sizes, int n_in,
                              void* d_out, int out_size, void* d_ws, size_t ws_size,
                              hipStream_t stream)
{
  (void)in_sizes; (void)n_in; (void)out_size; (void)ws_size;
  const float* x     = (const float*)d_in[0];
  const float* vqkv  = (const float*)d_in[1];
  const float* voutw = (const float*)d_in[2];
  const float* vw1   = (const float*)d_in[3];
  const float* vw2   = (const float*)d_in[4];
  const float* lqkv  = (const float*)d_in[5];
  const float* loutw = (const float*)d_in[6];
  const float* lw1   = (const float*)d_in[7];
  const float* lw2   = (const float*)d_in[8];
  float* out = (float*)d_out;
  float* ws  = (float*)d_ws;

  unsigned short* QLbf = (unsigned short*)(ws + 0);        // bf16 Q lo (L1)
  unsigned short* KLbf = (unsigned short*)(ws + 2097152);  // bf16 K lo (L1)
  float* PROJ = ws + 0;         // written after attn_fused (QL/KL dead)
  float* Y1   = ws + 4194304;
  unsigned short* QHbf = (unsigned short*)(ws + 8388608);   // bf16 Q hi (L1+L2)
  unsigned short* KHbf = (unsigned short*)(ws + 10485760);  // bf16 K hi (L1+L2)
  unsigned short* VT   = (unsigned short*)(ws + 12582912);
  unsigned short* SLOT1 = (unsigned short*)(ws + 14680064); // attn ctx bf16
  unsigned short* SLOT2 = (unsigned short*)(ws + 16777216); // LN bf16 out
  unsigned short* HIDbf = (unsigned short*)(ws + 18874368); // FFN hidden
  unsigned short* XBF   = (unsigned short*)(ws + 18874368); // x hi bf16 (pre-FFN)
  float* PART = ws + 18874368;  // colsum block partials (1024x1024); written
                                // by attn_fused after XBF/XLO dead, dead by FFN1
  unsigned short* XLO = (unsigned short*)(ws + 20971520);   // x lo bf16
  // bf16 transposed weights (WLQ0..2 contiguous -> merged [1536,512] matrix)
  unsigned short* WVQV = (unsigned short*)(ws + 27262976);
  unsigned short* WVO  = (unsigned short*)(ws + 27394048);
  unsigned short* WV1  = (unsigned short*)(ws + 27525120);
  unsigned short* WV2  = (unsigned short*)(ws + 28049408);
  unsigned short* WLQ0 = (unsigned short*)(ws + 28573696);
  unsigned short* WLQ1 = (unsigned short*)(ws + 28704768);
  unsigned short* WLQ2 = (unsigned short*)(ws + 28835840);
  unsigned short* WLO  = (unsigned short*)(ws + 28966912);
  unsigned short* WL1  = (unsigned short*)(ws + 29097984);
  unsigned short* WL2  = (unsigned short*)(ws + 29622272);
  // small buffers
  float* CS1   = ws + 30146560;
  float* CS2   = ws + 30154752;
  float* WLs   = ws + 30162944;
  int*   IDS   = (int*)(ws + 30171136);
  int*   WST   = (int*)(ws + 30179328);
  int*   NWIN  = (int*)(ws + 30187776);
  // layer-1 Q/K weights, bf16 transposed hi/lo (512x512 each = 131072 floats)
  unsigned short* WQH = (unsigned short*)(ws + 30261504);
  unsigned short* WQL = (unsigned short*)(ws + 30392576);
  unsigned short* WKH = (unsigned short*)(ws + 30523648);
  unsigned short* WKL = (unsigned short*)(ws + 30654720);

  dim3 blk(256);

  // ---- fused prep: 12 wconv + zero + fconv(hi/lo) ----
  PrepArgs P;
  auto setw = [&](int i, const float* s, unsigned short* d, unsigned short* dl,
                  int K, int N, int b0) {
    P.d[i].src = s; P.d[i].dst = d; P.d[i].dstlo = dl;
    P.d[i].K = K; P.d[i].N = N; P.d[i].blk0 = b0;
  };
  int b0 = 0;
  setw(0, vqkv + 2 * Dz * Dz, WVQV, nullptr, Dz, Dz, b0); b0 += 256;
  setw(1, voutw, WVO, nullptr, Dz, Dz, b0); b0 += 256;
  setw(2, vw1, WV1, nullptr, Dz, FFz, b0); b0 += 1024;
  setw(3, vw2, WV2, nullptr, FFz, Dz, b0); b0 += 1024;
  setw(4, lqkv + 0 * Dz * Dz, WLQ0, nullptr, Dz, Dz, b0); b0 += 256;
  setw(5, lqkv + 1 * Dz * Dz, WLQ1, nullptr, Dz, Dz, b0); b0 += 256;
  setw(6, lqkv + 2 * Dz * Dz, WLQ2, nullptr, Dz, Dz, b0); b0 += 256;
  setw(7, loutw, WLO, nullptr, Dz, Dz, b0); b0 += 256;
  setw(8, lw1, WL1, nullptr, Dz, FFz, b0); b0 += 1024;
  setw(9, lw2, WL2, nullptr, FFz, Dz, b0); b0 += 1024;
  setw(10, vqkv + 0 * Dz * Dz, WQH, WQL, Dz, Dz, b0); b0 += 256;
  setw(11, vqkv + 1 * Dz * Dz, WKH, WKL, Dz, Dz, b0); b0 += 256;
  P.nwc = b0;  // 6144
  prep_kernel<<<dim3(P.nwc + 64 + 4096), blk, 0, stream>>>(P, x, XBF, XLO, CS1);

  auto mgemm = [&](const unsigned short* A, const unsigned short* BT, void* p1,
                   void* p2, void* p3, int K, int N, int mode) {
    mfma_gemm_kernel<<<dim3(N / 128, Mz / 128), dim3(256), 0, stream>>>(
        A, BT, p1, p2, p3, K, N, mode);
  };

  // ---------------- layer 1 (vanilla) ----------------
  gemm_qk_mfma_kernel<<<dim3(4, 128), dim3(256), 0, stream>>>(
      XBF, XLO, WQH, WQL, WKH, WKL, QHbf, QLbf, KHbf, KLbf);
  mgemm(XBF, WVQV, VT, nullptr, nullptr, Dz, Dz, 4);        // V -> V^T (XBF/XLO dead)
  attn_fused_kernel<<<dim3(Bz * Hz * 16), blk, 0, stream>>>(
      QHbf, QLbf, KHbf, KLbf, VT, SLOT1, PART);
  colsum_reduce_kernel<<<dim3(32), blk, 0, stream>>>(PART, CS1);
  window_ids_kernel<<<dim3(Bz), blk, 0, stream>>>(CS1, IDS, WST, NWIN);
  mgemm(SLOT1, WVO, PROJ, nullptr, nullptr, Dz, Dz, 0);     // proj (QL/KL dead)
  ln_kernel<<<dim3(Mz), blk, 0, stream>>>(x, nullptr, PROJ, Y1, SLOT2);
  mgemm(SLOT2, WV1, HIDbf, nullptr, nullptr, Dz, FFz, 2);   // FFN1 (PART dead)
  mgemm(HIDbf, WV2, PROJ, nullptr, nullptr, FFz, Dz, 0);    // FFN2
  ln_kernel<<<dim3(Mz), blk, 0, stream>>>(Y1, nullptr, PROJ, nullptr, SLOT2);

  // ---------------- layer 2 (block-diagonal window mask) ----------------
  mgemm(SLOT2, WLQ0, QHbf, KHbf, VT, Dz, 3 * Dz, 5);        // merged QKV
  attn_mfma2_kernel<<<dim3(Bz * Hz * 16), blk, 0, stream>>>(
      QHbf, KHbf, VT, IDS, WST, SLOT1, CS2);
  mgemm(SLOT1, WLO, PROJ, nullptr, nullptr, Dz, Dz, 0);
  ln_kernel<<<dim3(Mz), blk, 0, stream>>>(nullptr, SLOT2, PROJ, Y1, SLOT2);
  mgemm(SLOT2, WL1, HIDbf, nullptr, nullptr, Dz, FFz, 2);
  mgemm(HIDbf, WL2, PROJ, nullptr, nullptr, FFz, Dz, 0);
  ln_kernel<<<dim3(Mz), blk, 0, stream>>>(Y1, nullptr, PROJ, nullptr, SLOT2);

  // ---------------- pooling + outputs ----------------
  wl_softmax_kernel<<<dim3(Bz), blk, 0, stream>>>(CS2, WLs);
  outputs_kernel<<<dim3(20480), blk, 0, stream>>>(SLOT2, WLs, WST, NWIN, IDS, x,
                                                  out, out + (size_t)Bz * 2 * Tz * Dz);
}